// Round 2
// baseline (2582.697 us; speedup 1.0000x reference)
//
#include <hip/hip_runtime.h>
#include <math.h>

#define DEV __device__ __forceinline__

DEV float leakyf(float x, float s) { return x > 0.f ? x : s * x; }

DEV float wave_sum(float v) {
#pragma unroll
  for (int o = 1; o < 64; o <<= 1) v += __shfl_xor(v, o);
  return v;
}
DEV float wave_max(float v) {
#pragma unroll
  for (int o = 1; o < 64; o <<= 1) v = fmaxf(v, __shfl_xor(v, o));
  return v;
}

// ---------------- BatchNorm (eval) ----------------
__global__ __launch_bounds__(256) void bn_kernel(
    const float* __restrict__ xin, const float* __restrict__ g,
    const float* __restrict__ b, const float* __restrict__ m,
    const float* __restrict__ v, float* __restrict__ xout, int total) {
  int i = blockIdx.x * 256 + threadIdx.x;
  if (i < total) {
    int c = i & 63;
    xout[i] = (xin[i] - m[c]) * rsqrtf(v[c] + 1e-5f) * g[c] + b[c];
  }
}

// ---------------- Edge encoder: leaky(leaky(attr@W1+b1)@W2+b2), L2-normalized ----------------
__global__ __launch_bounds__(256) void edge_enc_kernel(
    const float* __restrict__ edge_attr, const float* __restrict__ W1,
    const float* __restrict__ b1, const float* __restrict__ W2,
    const float* __restrict__ b2, float* __restrict__ ea2, int E) {
  __shared__ float sW1[16 * 128];
  __shared__ float sb1[128];
  __shared__ float sW2[128 * 64];
  __shared__ float sb2[64];
  __shared__ float sAttr[4][16];
  __shared__ float sEa1[4][128];
  for (int i = threadIdx.x; i < 16 * 128; i += 256) sW1[i] = W1[i];
  for (int i = threadIdx.x; i < 128; i += 256) sb1[i] = b1[i];
  for (int i = threadIdx.x; i < 128 * 64; i += 256) sW2[i] = W2[i];
  for (int i = threadIdx.x; i < 64; i += 256) sb2[i] = b2[i];
  __syncthreads();
  int lane = threadIdx.x & 63, wv = threadIdx.x >> 6;
  int stride = gridDim.x * 4;
  for (int base = blockIdx.x * 4; base < E; base += stride) {
    int e = base + wv;
    bool act = e < E;
    if (act && lane < 16) sAttr[wv][lane] = edge_attr[(size_t)e * 16 + lane];
    __syncthreads();
    if (act) {
      int c0 = 2 * lane;
      float a0 = 0.f, a1v = 0.f;
#pragma unroll
      for (int k = 0; k < 16; k++) {
        float a = sAttr[wv][k];
        a0 += a * sW1[k * 128 + c0];
        a1v += a * sW1[k * 128 + c0 + 1];
      }
      a0 = leakyf(a0 + sb1[c0], 0.01f);
      a1v = leakyf(a1v + sb1[c0 + 1], 0.01f);
      sEa1[wv][c0] = a0;
      sEa1[wv][c0 + 1] = a1v;
    }
    __syncthreads();
    if (act) {
      float v = 0.f;
#pragma unroll 16
      for (int k = 0; k < 128; k++) v += sEa1[wv][k] * sW2[k * 64 + lane];
      v = leakyf(v + sb2[lane], 0.01f);
      float ss = wave_sum(v * v);
      float scale = 1.f / fmaxf(sqrtf(ss), 1e-12f);
      ea2[(size_t)e * 64 + lane] = v * scale;
    }
    __syncthreads();
  }
}

// ---------------- CSR build ----------------
__global__ __launch_bounds__(256) void count_kernel(const int* __restrict__ dst0,
                                                    int* __restrict__ counts, int E, int E2) {
  int i = blockIdx.x * 256 + threadIdx.x;
  if (i < E2) {
    int d = (i < E) ? dst0[i] : (i - E);
    atomicAdd(&counts[d], 1);
  }
}

__global__ __launch_bounds__(256) void scan_kernel(const int* __restrict__ counts,
                                                   int* __restrict__ rowptr,
                                                   int* __restrict__ fill, int N) {
  __shared__ int part[256];
  int tid = threadIdx.x;
  int chunk = (N + 255) / 256;
  int lo = tid * chunk, hi = lo + chunk;
  if (hi > N) hi = N;
  if (lo > N) lo = N;
  int s = 0;
  for (int i = lo; i < hi; i++) s += counts[i];
  part[tid] = s;
  __syncthreads();
  if (tid == 0) {
    int run = 0;
    for (int i = 0; i < 256; i++) {
      int t = part[i];
      part[i] = run;
      run += t;
    }
    rowptr[N] = run;
  }
  __syncthreads();
  int off = part[tid];
  for (int i = lo; i < hi; i++) {
    rowptr[i] = off;
    fill[i] = off;
    off += counts[i];
  }
}

__global__ __launch_bounds__(256) void fill_kernel(const int* __restrict__ dst0,
                                                   int* __restrict__ fill,
                                                   int* __restrict__ csr, int E, int E2) {
  int i = blockIdx.x * 256 + threadIdx.x;
  if (i < E2) {
    int d = (i < E) ? dst0[i] : (i - E);
    int pos = atomicAdd(&fill[d], 1);
    csr[pos] = i;
  }
}

// ---------------- self-loop attr = mean of incoming encoded attrs ----------------
__global__ __launch_bounds__(256) void loopattr_kernel(float* __restrict__ ea2,
                                                       const int* __restrict__ rowptr,
                                                       const int* __restrict__ csr, int N, int E) {
  int lane = threadIdx.x & 63, wv = threadIdx.x >> 6;
  int stride = gridDim.x * 4;
  for (int n = blockIdx.x * 4 + wv; n < N; n += stride) {
    int r0 = rowptr[n], r1 = rowptr[n + 1];
    float acc = 0.f;
    int cnt = 0;
    for (int i = r0; i < r1; i++) {
      int e = csr[i];
      if (e < E) {
        acc += ea2[(size_t)e * 64 + lane];
        cnt++;
      }
    }
    ea2[((size_t)E + n) * 64 + lane] = acc / fmaxf((float)cnt, 1.f);
  }
}

// ---------------- generic f32 GEMM: C = act(A[M,K]@B[K,Nc] + bias) ----------------
// MODE: 0 none, 2 elu, 3 mix: out = s*(v) + (1-s)*aux[row,col]
template <int MODE>
__global__ __launch_bounds__(256) void gemm_kernel(
    const float* __restrict__ A, const float* __restrict__ B,
    const float* __restrict__ bias, float* __restrict__ C, int M, int K, int Nc,
    const float* __restrict__ aux, const float* __restrict__ alpha_p) {
  __shared__ __align__(16) float As[16][68];
  __shared__ __align__(16) float Bs[16][68];
  int bm = blockIdx.y * 64, bn = blockIdx.x * 64;
  int tid = threadIdx.x;
  int tx = tid & 15, ty = tid >> 4;
  float acc[4][4] = {};
  for (int k0 = 0; k0 < K; k0 += 16) {
#pragma unroll
    for (int i = tid; i < 1024; i += 256) {
      int m = i >> 4, k = i & 15;
      int gm = bm + m;
      As[k][m] = (gm < M) ? A[(size_t)gm * K + k0 + k] : 0.f;
    }
#pragma unroll
    for (int i = tid; i < 1024; i += 256) {
      int k = i >> 6, n = i & 63;
      int gn = bn + n;
      Bs[k][n] = (gn < Nc) ? B[(size_t)(k0 + k) * Nc + gn] : 0.f;
    }
    __syncthreads();
#pragma unroll
    for (int k = 0; k < 16; k++) {
      float4 a4 = *(const float4*)&As[k][ty * 4];
      float4 b4 = *(const float4*)&Bs[k][tx * 4];
      float a[4] = {a4.x, a4.y, a4.z, a4.w};
      float b[4] = {b4.x, b4.y, b4.z, b4.w};
#pragma unroll
      for (int i = 0; i < 4; i++)
#pragma unroll
        for (int j = 0; j < 4; j++) acc[i][j] += a[i] * b[j];
    }
    __syncthreads();
  }
  float s = 0.f;
  if (MODE == 3) s = 1.f / (1.f + __expf(-alpha_p[0]));
#pragma unroll
  for (int i = 0; i < 4; i++) {
    int m = bm + ty * 4 + i;
    if (m >= M) continue;
#pragma unroll
    for (int j = 0; j < 4; j++) {
      int n = bn + tx * 4 + j;
      if (n >= Nc) continue;
      float v = acc[i][j] + bias[n];
      if (MODE == 2) v = v > 0.f ? v : (__expf(v) - 1.f);
      if (MODE == 3) v = s * v + (1.f - s) * aux[(size_t)m * Nc + n];
      C[(size_t)m * Nc + n] = v;
    }
  }
}

// ---------------- GATv2 edge scores (fused ee = ea2@We), 128 columns per launch ----------------
template <int C>  // head dim: 32 (layers 1,2) or 64 (layer 3 -> two launches)
__global__ __launch_bounds__(256) void score_kernel(
    const float* __restrict__ ea2, const float* __restrict__ xl,
    const float* __restrict__ xr, const float* __restrict__ We,
    const float* __restrict__ att, const int* __restrict__ src0,
    const int* __restrict__ dst0, float* __restrict__ e_s, int E, int E2,
    int HCfull, int col_off) {
  extern __shared__ float smem[];
  float* sWe = smem;             // [64][128]
  float* sAtt = smem + 64 * 128; // [128]
  float* sEa = sAtt + 128;       // [4][64]
  for (int i = threadIdx.x; i < 64 * 128; i += 256) {
    int k = i >> 7, cc = i & 127;
    sWe[i] = We[(size_t)k * HCfull + col_off + cc];
  }
  for (int i = threadIdx.x; i < 128; i += 256) sAtt[i] = att[col_off + i];
  __syncthreads();
  int lane = threadIdx.x & 63, wv = threadIdx.x >> 6;
  int stride = gridDim.x * 4;
  constexpr int L = C / 2;  // lanes per head
  for (int base = blockIdx.x * 4; base < E2; base += stride) {
    int e = base + wv;
    bool act = e < E2;
    int sn = 0, dn = 0;
    if (act) {
      if (e < E) {
        sn = src0[e];
        dn = dst0[e];
      } else {
        sn = dn = e - E;
      }
      sEa[wv * 64 + lane] = ea2[(size_t)e * 64 + lane];
    }
    __syncthreads();
    if (act) {
      int c0 = 2 * lane;
      float a0 = 0.f, a1v = 0.f;
#pragma unroll 16
      for (int k = 0; k < 64; k++) {
        float a = sEa[wv * 64 + k];
        a0 += a * sWe[k * 128 + c0];
        a1v += a * sWe[k * 128 + c0 + 1];
      }
      float2 xlv = *(const float2*)(xl + (size_t)sn * HCfull + col_off + c0);
      float2 xrv = *(const float2*)(xr + (size_t)dn * HCfull + col_off + c0);
      float mA = xlv.x + xrv.x + a0;
      mA = mA > 0.f ? mA : 0.2f * mA;
      float mB = xlv.y + xrv.y + a1v;
      mB = mB > 0.f ? mB : 0.2f * mB;
      float sres = mA * sAtt[c0] + mB * sAtt[c0 + 1];
#pragma unroll
      for (int o = 1; o < L; o <<= 1) sres += __shfl_xor(sres, o);
      if ((lane & (L - 1)) == 0)
        e_s[(size_t)e * 4 + col_off / C + lane / L] = sres;
    }
    __syncthreads();
  }
}

// ---------------- per-node softmax + aggregation + bias + LN + leaky (+skip mix for L1) ----------------
template <int HC, bool L1MODE>
__global__ __launch_bounds__(256) void aggr_kernel(
    const float* __restrict__ e_s, const float* __restrict__ xl,
    const int* __restrict__ rowptr, const int* __restrict__ csr,
    const int* __restrict__ src0, const float* __restrict__ bias,
    const float* __restrict__ lng, const float* __restrict__ lnb,
    float* __restrict__ alpha_out, float* __restrict__ xout,
    float* __restrict__ x1out, const float* __restrict__ skipproj, int N, int E) {
  constexpr int CPL = HC / 64;
  int lane = threadIdx.x & 63, wv = threadIdx.x >> 6;
  int stride = gridDim.x * 4;
  for (int n = blockIdx.x * 4 + wv; n < N; n += stride) {
    int r0 = rowptr[n], r1 = rowptr[n + 1];
    float m0 = -1e30f, m1 = -1e30f, m2 = -1e30f, m3 = -1e30f;
    for (int i = r0 + lane; i < r1; i += 64) {
      int e = csr[i];
      float4 v = *reinterpret_cast<const float4*>(e_s + (size_t)e * 4);
      m0 = fmaxf(m0, v.x);
      m1 = fmaxf(m1, v.y);
      m2 = fmaxf(m2, v.z);
      m3 = fmaxf(m3, v.w);
    }
    m0 = wave_max(m0);
    m1 = wave_max(m1);
    m2 = wave_max(m2);
    m3 = wave_max(m3);
    float d0 = 0.f, d1 = 0.f, d2 = 0.f, d3 = 0.f;
    for (int i = r0 + lane; i < r1; i += 64) {
      int e = csr[i];
      float4 v = *reinterpret_cast<const float4*>(e_s + (size_t)e * 4);
      d0 += __expf(v.x - m0);
      d1 += __expf(v.y - m1);
      d2 += __expf(v.z - m2);
      d3 += __expf(v.w - m3);
    }
    d0 = wave_sum(d0);
    d1 = wave_sum(d1);
    d2 = wave_sum(d2);
    d3 = wave_sum(d3);
    float i0 = 1.f / (d0 + 1e-16f), i1 = 1.f / (d1 + 1e-16f);
    float i2 = 1.f / (d2 + 1e-16f), i3 = 1.f / (d3 + 1e-16f);
    int h = lane >> 4;
    float mh = (h & 2) ? ((h & 1) ? m3 : m2) : ((h & 1) ? m1 : m0);
    float ih = (h & 2) ? ((h & 1) ? i3 : i2) : ((h & 1) ? i1 : i0);
    float acc[CPL];
#pragma unroll
    for (int j = 0; j < CPL; j++) acc[j] = 0.f;
    int c0 = lane * CPL;
    for (int i = r0; i < r1; i++) {
      int e = csr[i];
      int sn = (e < E) ? src0[e] : (e - E);
      float a = __expf(e_s[(size_t)e * 4 + h] - mh) * ih;
      if ((lane & 15) == 0) alpha_out[(size_t)e * 4 + h] = a;
      const float* xp = xl + (size_t)sn * HC + c0;
      if constexpr (CPL == 2) {
        float2 t = *(const float2*)xp;
        acc[0] += a * t.x;
        acc[1] += a * t.y;
      } else {
        float4 t = *(const float4*)xp;
        acc[0] += a * t.x;
        acc[1] += a * t.y;
        acc[2] += a * t.z;
        acc[3] += a * t.w;
      }
    }
    float vals[CPL];
    float vs = 0.f, vq = 0.f;
#pragma unroll
    for (int j = 0; j < CPL; j++) {
      float t = acc[j] + bias[c0 + j];
      vals[j] = t;
      vs += t;
      vq += t * t;
    }
    vs = wave_sum(vs);
    vq = wave_sum(vq);
    float mean = vs * (1.f / HC);
    float var = vq * (1.f / HC) - mean * mean;
    float rstd = rsqrtf(fmaxf(var, 0.f) + 1e-5f);
#pragma unroll
    for (int j = 0; j < CPL; j++) {
      int c = c0 + j;
      float y = (vals[j] - mean) * rstd * lng[c] + lnb[c];
      y = leakyf(y, 0.01f);
      if constexpr (L1MODE) {
        x1out[(size_t)n * HC + c] = y;
        xout[(size_t)n * HC + c] = 0.01f * skipproj[(size_t)n * HC + c] + y;
      } else {
        xout[(size_t)n * HC + c] = y;
      }
    }
  }
}

extern "C" void kernel_launch(void* const* d_in, const int* in_sizes, int n_in,
                              void* d_out, int out_size, void* d_ws, size_t ws_size,
                              hipStream_t stream) {
  (void)n_in;
  (void)out_size;
  (void)ws_size;
  const float* x_in = (const float*)d_in[0];
  const int* edge_index = (const int*)d_in[1];
  const float* edge_attr = (const float*)d_in[2];
  const float* bn0_g = (const float*)d_in[3];
  const float* bn0_b = (const float*)d_in[4];
  const float* bn0_m = (const float*)d_in[5];
  const float* bn0_v = (const float*)d_in[6];
  const float* eeW1 = (const float*)d_in[7];
  const float* eeb1 = (const float*)d_in[8];
  const float* eeW2 = (const float*)d_in[9];
  const float* eeb2 = (const float*)d_in[10];
  const float* g1_Wl = (const float*)d_in[11];
  const float* g1_bl = (const float*)d_in[12];
  const float* g1_Wr = (const float*)d_in[13];
  const float* g1_br = (const float*)d_in[14];
  const float* g1_We = (const float*)d_in[15];
  const float* g1_att = (const float*)d_in[16];
  const float* g1_bias = (const float*)d_in[17];
  const float* g2_Wl = (const float*)d_in[18];
  const float* g2_bl = (const float*)d_in[19];
  const float* g2_Wr = (const float*)d_in[20];
  const float* g2_br = (const float*)d_in[21];
  const float* g2_We = (const float*)d_in[22];
  const float* g2_att = (const float*)d_in[23];
  const float* g2_bias = (const float*)d_in[24];
  const float* g3_Wl = (const float*)d_in[25];
  const float* g3_bl = (const float*)d_in[26];
  const float* g3_Wr = (const float*)d_in[27];
  const float* g3_br = (const float*)d_in[28];
  const float* g3_We = (const float*)d_in[29];
  const float* g3_att = (const float*)d_in[30];
  const float* g3_bias = (const float*)d_in[31];
  const float* ln1_g = (const float*)d_in[32];
  const float* ln1_b = (const float*)d_in[33];
  const float* ln2_g = (const float*)d_in[34];
  const float* ln2_b = (const float*)d_in[35];
  const float* ln3_g = (const float*)d_in[36];
  const float* ln3_b = (const float*)d_in[37];
  const float* skip_W = (const float*)d_in[38];
  const float* skip_b = (const float*)d_in[39];
  const float* alpha_p = (const float*)d_in[40];
  const float* fp_W = (const float*)d_in[41];
  const float* fp_b = (const float*)d_in[42];
  const float* np_W1 = (const float*)d_in[43];
  const float* np_b1 = (const float*)d_in[44];
  const float* np_W2 = (const float*)d_in[45];
  const float* np_b2 = (const float*)d_in[46];
  const float* np_W3 = (const float*)d_in[47];
  const float* np_b3 = (const float*)d_in[48];

  const int N = in_sizes[0] / 64;
  const int E = in_sizes[2] / 16;
  const int E2 = E + N;
  const int* src0 = edge_index;
  const int* dst0 = edge_index + E;

  float* ws = (float*)d_ws;
  size_t off = 0;
  float* x = ws + off;         off += (size_t)N * 64;
  float* ea2 = ws + off;       off += (size_t)E2 * 64;
  float* xl = ws + off;        off += (size_t)N * 256;
  float* xr = ws + off;        off += (size_t)N * 256;
  float* skipproj = ws + off;  off += (size_t)N * 128;  // reused as h1 at the end
  float* x1 = ws + off;        off += (size_t)N * 128;
  float* skip1 = ws + off;     off += (size_t)N * 128;
  float* x2 = ws + off;        off += (size_t)N * 128;
  float* x3 = ws + off;        off += (size_t)N * 256;
  float* e_s = ws + off;       off += (size_t)E2 * 4;
  float* h2 = ws + off;        off += (size_t)N * 64;
  int* counts = (int*)(ws + off);
  int* rowptr = counts + N;
  int* fill = rowptr + N + 1;
  int* csr = fill + N;

  float* out = (float*)d_out;
  float* xf = out;
  float* npout = out + (size_t)N * 256;
  float* a1 = npout + N;
  float* a2 = a1 + (size_t)E2 * 4;
  float* a3 = a2 + (size_t)E2 * 4;

  hipMemsetAsync(counts, 0, (size_t)N * sizeof(int), stream);
  bn_kernel<<<(N * 64 + 255) / 256, 256, 0, stream>>>(x_in, bn0_g, bn0_b, bn0_m, bn0_v, x, N * 64);
  edge_enc_kernel<<<2048, 256, 0, stream>>>(edge_attr, eeW1, eeb1, eeW2, eeb2, ea2, E);
  count_kernel<<<(E2 + 255) / 256, 256, 0, stream>>>(dst0, counts, E, E2);
  scan_kernel<<<1, 256, 0, stream>>>(counts, rowptr, fill, N);
  fill_kernel<<<(E2 + 255) / 256, 256, 0, stream>>>(dst0, fill, csr, E, E2);
  loopattr_kernel<<<(N + 3) / 4, 256, 0, stream>>>(ea2, rowptr, csr, N, E);

  auto gemm = [&](int mode, const float* A, const float* B, const float* bias,
                  float* Cp, int M, int K, int Nc, const float* aux) {
    dim3 g((Nc + 63) / 64, (M + 63) / 64);
    switch (mode) {
      case 0: gemm_kernel<0><<<g, 256, 0, stream>>>(A, B, bias, Cp, M, K, Nc, nullptr, nullptr); break;
      case 2: gemm_kernel<2><<<g, 256, 0, stream>>>(A, B, bias, Cp, M, K, Nc, nullptr, nullptr); break;
      case 3: gemm_kernel<3><<<g, 256, 0, stream>>>(A, B, bias, Cp, M, K, Nc, aux, alpha_p); break;
    }
  };

  const size_t score_lds = (size_t)(64 * 128 + 128 + 256) * sizeof(float);
  const int nblk_node = (N + 3) / 4;

  // ---- Layer 1 (din=64, HC=128, C=32) ----
  gemm(0, x, g1_Wl, g1_bl, xl, N, 64, 128, nullptr);
  gemm(0, x, g1_Wr, g1_br, xr, N, 64, 128, nullptr);
  gemm(0, x, skip_W, skip_b, skipproj, N, 64, 128, nullptr);
  score_kernel<32><<<2048, 256, score_lds, stream>>>(ea2, xl, xr, g1_We, g1_att, src0, dst0, e_s, E, E2, 128, 0);
  aggr_kernel<128, true><<<nblk_node, 256, 0, stream>>>(e_s, xl, rowptr, csr, src0, g1_bias, ln1_g, ln1_b,
                                                        a1, skip1, x1, skipproj, N, E);
  // ---- Layer 2 (din=128, HC=128, C=32) ----
  gemm(0, skip1, g2_Wl, g2_bl, xl, N, 128, 128, nullptr);
  gemm(0, skip1, g2_Wr, g2_br, xr, N, 128, 128, nullptr);
  score_kernel<32><<<2048, 256, score_lds, stream>>>(ea2, xl, xr, g2_We, g2_att, src0, dst0, e_s, E, E2, 128, 0);
  aggr_kernel<128, false><<<nblk_node, 256, 0, stream>>>(e_s, xl, rowptr, csr, src0, g2_bias, ln2_g, ln2_b,
                                                         a2, x2, nullptr, nullptr, N, E);
  // ---- Layer 3 (din=128, HC=256, C=64) ----
  gemm(0, x2, g3_Wl, g3_bl, xl, N, 128, 256, nullptr);
  gemm(0, x2, g3_Wr, g3_br, xr, N, 128, 256, nullptr);
  score_kernel<64><<<2048, 256, score_lds, stream>>>(ea2, xl, xr, g3_We, g3_att, src0, dst0, e_s, E, E2, 256, 0);
  score_kernel<64><<<2048, 256, score_lds, stream>>>(ea2, xl, xr, g3_We, g3_att, src0, dst0, e_s, E, E2, 256, 128);
  aggr_kernel<256, false><<<nblk_node, 256, 0, stream>>>(e_s, xl, rowptr, csr, src0, g3_bias, ln3_g, ln3_b,
                                                         a3, x3, nullptr, nullptr, N, E);
  // ---- Final: xf = s*(x1@fp_W+fp_b) + (1-s)*x3 ; node MLP ----
  gemm(3, x1, fp_W, fp_b, xf, N, 128, 256, x3);
  gemm(2, xf, np_W1, np_b1, skipproj, N, 256, 128, nullptr);   // h1
  gemm(2, skipproj, np_W2, np_b2, h2, N, 128, 64, nullptr);    // h2
  gemm(0, h2, np_W3, np_b3, npout, N, 64, 1, nullptr);
}

// Round 4
// 2124.685 us; speedup vs baseline: 1.2156x; 1.2156x over previous
//
#include <hip/hip_runtime.h>
#include <math.h>

#define DEV __device__ __forceinline__

DEV float leakyf(float x, float s) { return x > 0.f ? x : s * x; }

DEV float wave_sum(float v) {
#pragma unroll
  for (int o = 1; o < 64; o <<= 1) v += __shfl_xor(v, o);
  return v;
}
DEV float wave_max(float v) {
#pragma unroll
  for (int o = 1; o < 64; o <<= 1) v = fmaxf(v, __shfl_xor(v, o));
  return v;
}

// ---------------- BatchNorm (eval) ----------------
__global__ __launch_bounds__(256) void bn_kernel(
    const float* __restrict__ xin, const float* __restrict__ g,
    const float* __restrict__ b, const float* __restrict__ m,
    const float* __restrict__ v, float* __restrict__ xout, int total) {
  int i = blockIdx.x * 256 + threadIdx.x;
  if (i < total) {
    int c = i & 63;
    xout[i] = (xin[i] - m[c]) * rsqrtf(v[c] + 1e-5f) * g[c] + b[c];
  }
}

// ---------------- Edge encoder: leaky(leaky(attr@W1+b1)@W2+b2), L2-normalized ----------------
__global__ __launch_bounds__(256) void edge_enc_kernel(
    const float* __restrict__ edge_attr, const float* __restrict__ W1,
    const float* __restrict__ b1, const float* __restrict__ W2,
    const float* __restrict__ b2, float* __restrict__ ea2, int E) {
  __shared__ float sW1[16 * 128];
  __shared__ float sb1[128];
  __shared__ float sW2[128 * 64];
  __shared__ float sb2[64];
  __shared__ float sAttr[4][16];
  __shared__ float sEa1[4][128];
  for (int i = threadIdx.x; i < 16 * 128; i += 256) sW1[i] = W1[i];
  for (int i = threadIdx.x; i < 128; i += 256) sb1[i] = b1[i];
  for (int i = threadIdx.x; i < 128 * 64; i += 256) sW2[i] = W2[i];
  for (int i = threadIdx.x; i < 64; i += 256) sb2[i] = b2[i];
  __syncthreads();
  int lane = threadIdx.x & 63, wv = threadIdx.x >> 6;
  int stride = gridDim.x * 4;
  for (int base = blockIdx.x * 4; base < E; base += stride) {
    int e = base + wv;
    bool act = e < E;
    if (act && lane < 16) sAttr[wv][lane] = edge_attr[(size_t)e * 16 + lane];
    __syncthreads();
    if (act) {
      int c0 = 2 * lane;
      float a0 = 0.f, a1v = 0.f;
#pragma unroll
      for (int k = 0; k < 16; k++) {
        float a = sAttr[wv][k];
        a0 += a * sW1[k * 128 + c0];
        a1v += a * sW1[k * 128 + c0 + 1];
      }
      a0 = leakyf(a0 + sb1[c0], 0.01f);
      a1v = leakyf(a1v + sb1[c0 + 1], 0.01f);
      sEa1[wv][c0] = a0;
      sEa1[wv][c0 + 1] = a1v;
    }
    __syncthreads();
    if (act) {
      float v = 0.f;
#pragma unroll 16
      for (int k = 0; k < 128; k++) v += sEa1[wv][k] * sW2[k * 64 + lane];
      v = leakyf(v + sb2[lane], 0.01f);
      float ss = wave_sum(v * v);
      float scale = 1.f / fmaxf(sqrtf(ss), 1e-12f);
      ea2[(size_t)e * 64 + lane] = v * scale;
    }
    __syncthreads();
  }
}

// ---------------- CSR build ----------------
__global__ __launch_bounds__(256) void count_kernel(const int* __restrict__ dst0,
                                                    int* __restrict__ counts, int E, int E2) {
  int i = blockIdx.x * 256 + threadIdx.x;
  if (i < E2) {
    int d = (i < E) ? dst0[i] : (i - E);
    atomicAdd(&counts[d], 1);
  }
}

__global__ __launch_bounds__(256) void scan_kernel(const int* __restrict__ counts,
                                                   int* __restrict__ rowptr,
                                                   int* __restrict__ fill, int N) {
  __shared__ int part[256];
  int tid = threadIdx.x;
  int chunk = (N + 255) / 256;
  int lo = tid * chunk, hi = lo + chunk;
  if (hi > N) hi = N;
  if (lo > N) lo = N;
  int s = 0;
  for (int i = lo; i < hi; i++) s += counts[i];
  part[tid] = s;
  __syncthreads();
  if (tid == 0) {
    int run = 0;
    for (int i = 0; i < 256; i++) {
      int t = part[i];
      part[i] = run;
      run += t;
    }
    rowptr[N] = run;
  }
  __syncthreads();
  int off = part[tid];
  for (int i = lo; i < hi; i++) {
    rowptr[i] = off;
    fill[i] = off;
    off += counts[i];
  }
}

__global__ __launch_bounds__(256) void fill_kernel(const int* __restrict__ dst0,
                                                   int* __restrict__ fill,
                                                   int* __restrict__ csr, int E, int E2) {
  int i = blockIdx.x * 256 + threadIdx.x;
  if (i < E2) {
    int d = (i < E) ? dst0[i] : (i - E);
    int pos = atomicAdd(&fill[d], 1);
    csr[pos] = i;
  }
}

// ---------------- self-loop attr = mean of incoming encoded attrs ----------------
__global__ __launch_bounds__(256) void loopattr_kernel(float* __restrict__ ea2,
                                                       const int* __restrict__ rowptr,
                                                       const int* __restrict__ csr, int N, int E) {
  int lane = threadIdx.x & 63, wv = threadIdx.x >> 6;
  int stride = gridDim.x * 4;
  for (int n = blockIdx.x * 4 + wv; n < N; n += stride) {
    int r0 = rowptr[n], r1 = rowptr[n + 1];
    float acc = 0.f;
    int cnt = 0;
    for (int i = r0; i < r1; i++) {
      int e = csr[i];
      if (e < E) {
        acc += ea2[(size_t)e * 64 + lane];
        cnt++;
      }
    }
    ea2[((size_t)E + n) * 64 + lane] = acc / fmaxf((float)cnt, 1.f);
  }
}

// ---------------- generic f32 GEMM: C = act(A[M,K]@B[K,Nc] + bias) ----------------
// MODE: 0 none, 2 elu, 3 mix: out = s*(v) + (1-s)*aux[row,col]
template <int MODE>
__global__ __launch_bounds__(256) void gemm_kernel(
    const float* __restrict__ A, const float* __restrict__ B,
    const float* __restrict__ bias, float* __restrict__ C, int M, int K, int Nc,
    const float* __restrict__ aux, const float* __restrict__ alpha_p) {
  __shared__ __align__(16) float As[16][68];
  __shared__ __align__(16) float Bs[16][68];
  int bm = blockIdx.y * 64, bn = blockIdx.x * 64;
  int tid = threadIdx.x;
  int tx = tid & 15, ty = tid >> 4;
  float acc[4][4] = {};
  for (int k0 = 0; k0 < K; k0 += 16) {
#pragma unroll
    for (int i = tid; i < 1024; i += 256) {
      int m = i >> 4, k = i & 15;
      int gm = bm + m;
      As[k][m] = (gm < M) ? A[(size_t)gm * K + k0 + k] : 0.f;
    }
#pragma unroll
    for (int i = tid; i < 1024; i += 256) {
      int k = i >> 6, n = i & 63;
      int gn = bn + n;
      Bs[k][n] = (gn < Nc) ? B[(size_t)(k0 + k) * Nc + gn] : 0.f;
    }
    __syncthreads();
#pragma unroll
    for (int k = 0; k < 16; k++) {
      float4 a4 = *(const float4*)&As[k][ty * 4];
      float4 b4 = *(const float4*)&Bs[k][tx * 4];
      float a[4] = {a4.x, a4.y, a4.z, a4.w};
      float b[4] = {b4.x, b4.y, b4.z, b4.w};
#pragma unroll
      for (int i = 0; i < 4; i++)
#pragma unroll
        for (int j = 0; j < 4; j++) acc[i][j] += a[i] * b[j];
    }
    __syncthreads();
  }
  float s = 0.f;
  if (MODE == 3) s = 1.f / (1.f + __expf(-alpha_p[0]));
#pragma unroll
  for (int i = 0; i < 4; i++) {
    int m = bm + ty * 4 + i;
    if (m >= M) continue;
#pragma unroll
    for (int j = 0; j < 4; j++) {
      int n = bn + tx * 4 + j;
      if (n >= Nc) continue;
      float v = acc[i][j] + bias[n];
      if (MODE == 2) v = v > 0.f ? v : (__expf(v) - 1.f);
      if (MODE == 3) v = s * v + (1.f - s) * aux[(size_t)m * Nc + n];
      C[(size_t)m * Nc + n] = v;
    }
  }
}

// ---------------- GATv2 edge scores (fused ee = ea2@We), 128 columns per launch ----------------
// One wave per edge; ea row broadcast via __shfl from registers (no LDS staging, no barriers);
// sWe padded to stride 130 -> worst-case 2-way bank aliasing (free on gfx950).
template <int C>  // head dim: 32 (layers 1,2) or 64 (layer 3 -> two launches)
__global__ __launch_bounds__(256) void score_kernel(
    const float* __restrict__ ea2, const float* __restrict__ xl,
    const float* __restrict__ xr, const float* __restrict__ We,
    const float* __restrict__ att, const int* __restrict__ src0,
    const int* __restrict__ dst0, float* __restrict__ e_s, int E, int E2,
    int HCfull, int col_off) {
  __shared__ float sWe[64][130];
  __shared__ float sAtt[128];
  for (int i = threadIdx.x; i < 64 * 128; i += 256) {
    int k = i >> 7, cc = i & 127;
    sWe[k][cc] = We[(size_t)k * HCfull + col_off + cc];
  }
  for (int i = threadIdx.x; i < 128; i += 256) sAtt[i] = att[col_off + i];
  __syncthreads();
  int lane = threadIdx.x & 63, wv = threadIdx.x >> 6;
  int stride = gridDim.x * 4;
  constexpr int L = C / 2;  // lanes per head
  int c0 = 2 * lane;
  for (int e = blockIdx.x * 4 + wv; e < E2; e += stride) {
    int sn, dn;
    if (e < E) {
      sn = src0[e];
      dn = dst0[e];
    } else {
      sn = dn = e - E;
    }
    float eav = ea2[(size_t)e * 64 + lane];  // lane k holds ea[k], coalesced
    float a0 = 0.f, a1v = 0.f;
#pragma unroll
    for (int k = 0; k < 64; k++) {
      float a = __shfl(eav, k);
      a0 += a * sWe[k][c0];
      a1v += a * sWe[k][c0 + 1];
    }
    float2 xlv = *(const float2*)(xl + (size_t)sn * HCfull + col_off + c0);
    float2 xrv = *(const float2*)(xr + (size_t)dn * HCfull + col_off + c0);
    float mA = xlv.x + xrv.x + a0;
    mA = mA > 0.f ? mA : 0.2f * mA;
    float mB = xlv.y + xrv.y + a1v;
    mB = mB > 0.f ? mB : 0.2f * mB;
    float sres = mA * sAtt[c0] + mB * sAtt[c0 + 1];
#pragma unroll
    for (int o = 1; o < L; o <<= 1) sres += __shfl_xor(sres, o);
    if ((lane & (L - 1)) == 0)
      e_s[(size_t)e * 4 + col_off / C + lane / L] = sres;
  }
}

// ---------------- per-node softmax + aggregation + bias + LN + leaky (+skip mix for L1) ----------------
template <int HC, bool L1MODE>
__global__ __launch_bounds__(256) void aggr_kernel(
    const float* __restrict__ e_s, const float* __restrict__ xl,
    const int* __restrict__ rowptr, const int* __restrict__ csr,
    const int* __restrict__ src0, const float* __restrict__ bias,
    const float* __restrict__ lng, const float* __restrict__ lnb,
    float* __restrict__ alpha_out, float* __restrict__ xout,
    float* __restrict__ x1out, const float* __restrict__ skipproj, int N, int E) {
  constexpr int CPL = HC / 64;
  int lane = threadIdx.x & 63, wv = threadIdx.x >> 6;
  int stride = gridDim.x * 4;
  for (int n = blockIdx.x * 4 + wv; n < N; n += stride) {
    int r0 = rowptr[n], r1 = rowptr[n + 1];
    float m0 = -1e30f, m1 = -1e30f, m2 = -1e30f, m3 = -1e30f;
    for (int i = r0 + lane; i < r1; i += 64) {
      int e = csr[i];
      float4 v = *reinterpret_cast<const float4*>(e_s + (size_t)e * 4);
      m0 = fmaxf(m0, v.x);
      m1 = fmaxf(m1, v.y);
      m2 = fmaxf(m2, v.z);
      m3 = fmaxf(m3, v.w);
    }
    m0 = wave_max(m0);
    m1 = wave_max(m1);
    m2 = wave_max(m2);
    m3 = wave_max(m3);
    float d0 = 0.f, d1 = 0.f, d2 = 0.f, d3 = 0.f;
    for (int i = r0 + lane; i < r1; i += 64) {
      int e = csr[i];
      float4 v = *reinterpret_cast<const float4*>(e_s + (size_t)e * 4);
      d0 += __expf(v.x - m0);
      d1 += __expf(v.y - m1);
      d2 += __expf(v.z - m2);
      d3 += __expf(v.w - m3);
    }
    d0 = wave_sum(d0);
    d1 = wave_sum(d1);
    d2 = wave_sum(d2);
    d3 = wave_sum(d3);
    float i0 = 1.f / (d0 + 1e-16f), i1 = 1.f / (d1 + 1e-16f);
    float i2 = 1.f / (d2 + 1e-16f), i3 = 1.f / (d3 + 1e-16f);
    int h = lane >> 4;
    float mh = (h & 2) ? ((h & 1) ? m3 : m2) : ((h & 1) ? m1 : m0);
    float ih = (h & 2) ? ((h & 1) ? i3 : i2) : ((h & 1) ? i1 : i0);
    float acc[CPL];
#pragma unroll
    for (int j = 0; j < CPL; j++) acc[j] = 0.f;
    int c0 = lane * CPL;
    for (int i = r0; i < r1; i++) {
      int e = csr[i];
      int sn = (e < E) ? src0[e] : (e - E);
      float a = __expf(e_s[(size_t)e * 4 + h] - mh) * ih;
      if ((lane & 15) == 0) alpha_out[(size_t)e * 4 + h] = a;
      const float* xp = xl + (size_t)sn * HC + c0;
      if constexpr (CPL == 2) {
        float2 t = *(const float2*)xp;
        acc[0] += a * t.x;
        acc[1] += a * t.y;
      } else {
        float4 t = *(const float4*)xp;
        acc[0] += a * t.x;
        acc[1] += a * t.y;
        acc[2] += a * t.z;
        acc[3] += a * t.w;
      }
    }
    float vals[CPL];
    float vs = 0.f, vq = 0.f;
#pragma unroll
    for (int j = 0; j < CPL; j++) {
      float t = acc[j] + bias[c0 + j];
      vals[j] = t;
      vs += t;
      vq += t * t;
    }
    vs = wave_sum(vs);
    vq = wave_sum(vq);
    float mean = vs * (1.f / HC);
    float var = vq * (1.f / HC) - mean * mean;
    float rstd = rsqrtf(fmaxf(var, 0.f) + 1e-5f);
#pragma unroll
    for (int j = 0; j < CPL; j++) {
      int c = c0 + j;
      float y = (vals[j] - mean) * rstd * lng[c] + lnb[c];
      y = leakyf(y, 0.01f);
      if constexpr (L1MODE) {
        x1out[(size_t)n * HC + c] = y;
        xout[(size_t)n * HC + c] = 0.01f * skipproj[(size_t)n * HC + c] + y;
      } else {
        xout[(size_t)n * HC + c] = y;
      }
    }
  }
}

extern "C" void kernel_launch(void* const* d_in, const int* in_sizes, int n_in,
                              void* d_out, int out_size, void* d_ws, size_t ws_size,
                              hipStream_t stream) {
  (void)n_in;
  (void)out_size;
  (void)ws_size;
  const float* x_in = (const float*)d_in[0];
  const int* edge_index = (const int*)d_in[1];
  const float* edge_attr = (const float*)d_in[2];
  const float* bn0_g = (const float*)d_in[3];
  const float* bn0_b = (const float*)d_in[4];
  const float* bn0_m = (const float*)d_in[5];
  const float* bn0_v = (const float*)d_in[6];
  const float* eeW1 = (const float*)d_in[7];
  const float* eeb1 = (const float*)d_in[8];
  const float* eeW2 = (const float*)d_in[9];
  const float* eeb2 = (const float*)d_in[10];
  const float* g1_Wl = (const float*)d_in[11];
  const float* g1_bl = (const float*)d_in[12];
  const float* g1_Wr = (const float*)d_in[13];
  const float* g1_br = (const float*)d_in[14];
  const float* g1_We = (const float*)d_in[15];
  const float* g1_att = (const float*)d_in[16];
  const float* g1_bias = (const float*)d_in[17];
  const float* g2_Wl = (const float*)d_in[18];
  const float* g2_bl = (const float*)d_in[19];
  const float* g2_Wr = (const float*)d_in[20];
  const float* g2_br = (const float*)d_in[21];
  const float* g2_We = (const float*)d_in[22];
  const float* g2_att = (const float*)d_in[23];
  const float* g2_bias = (const float*)d_in[24];
  const float* g3_Wl = (const float*)d_in[25];
  const float* g3_bl = (const float*)d_in[26];
  const float* g3_Wr = (const float*)d_in[27];
  const float* g3_br = (const float*)d_in[28];
  const float* g3_We = (const float*)d_in[29];
  const float* g3_att = (const float*)d_in[30];
  const float* g3_bias = (const float*)d_in[31];
  const float* ln1_g = (const float*)d_in[32];
  const float* ln1_b = (const float*)d_in[33];
  const float* ln2_g = (const float*)d_in[34];
  const float* ln2_b = (const float*)d_in[35];
  const float* ln3_g = (const float*)d_in[36];
  const float* ln3_b = (const float*)d_in[37];
  const float* skip_W = (const float*)d_in[38];
  const float* skip_b = (const float*)d_in[39];
  const float* alpha_p = (const float*)d_in[40];
  const float* fp_W = (const float*)d_in[41];
  const float* fp_b = (const float*)d_in[42];
  const float* np_W1 = (const float*)d_in[43];
  const float* np_b1 = (const float*)d_in[44];
  const float* np_W2 = (const float*)d_in[45];
  const float* np_b2 = (const float*)d_in[46];
  const float* np_W3 = (const float*)d_in[47];
  const float* np_b3 = (const float*)d_in[48];

  const int N = in_sizes[0] / 64;
  const int E = in_sizes[2] / 16;
  const int E2 = E + N;
  const int* src0 = edge_index;
  const int* dst0 = edge_index + E;

  float* ws = (float*)d_ws;
  size_t off = 0;
  float* x = ws + off;         off += (size_t)N * 64;
  float* ea2 = ws + off;       off += (size_t)E2 * 64;
  float* xl = ws + off;        off += (size_t)N * 256;
  float* xr = ws + off;        off += (size_t)N * 256;
  float* skipproj = ws + off;  off += (size_t)N * 128;  // reused as h1 at the end
  float* x1 = ws + off;        off += (size_t)N * 128;
  float* skip1 = ws + off;     off += (size_t)N * 128;
  float* x2 = ws + off;        off += (size_t)N * 128;
  float* x3 = ws + off;        off += (size_t)N * 256;
  float* e_s = ws + off;       off += (size_t)E2 * 4;
  float* h2 = ws + off;        off += (size_t)N * 64;
  int* counts = (int*)(ws + off);
  int* rowptr = counts + N;
  int* fill = rowptr + N + 1;
  int* csr = fill + N;

  float* out = (float*)d_out;
  float* xf = out;
  float* npout = out + (size_t)N * 256;
  float* a1 = npout + N;
  float* a2 = a1 + (size_t)E2 * 4;
  float* a3 = a2 + (size_t)E2 * 4;

  hipMemsetAsync(counts, 0, (size_t)N * sizeof(int), stream);
  bn_kernel<<<(N * 64 + 255) / 256, 256, 0, stream>>>(x_in, bn0_g, bn0_b, bn0_m, bn0_v, x, N * 64);
  edge_enc_kernel<<<2048, 256, 0, stream>>>(edge_attr, eeW1, eeb1, eeW2, eeb2, ea2, E);
  count_kernel<<<(E2 + 255) / 256, 256, 0, stream>>>(dst0, counts, E, E2);
  scan_kernel<<<1, 256, 0, stream>>>(counts, rowptr, fill, N);
  fill_kernel<<<(E2 + 255) / 256, 256, 0, stream>>>(dst0, fill, csr, E, E2);
  loopattr_kernel<<<(N + 3) / 4, 256, 0, stream>>>(ea2, rowptr, csr, N, E);

  auto gemm = [&](int mode, const float* A, const float* B, const float* bias,
                  float* Cp, int M, int K, int Nc, const float* aux) {
    dim3 g((Nc + 63) / 64, (M + 63) / 64);
    switch (mode) {
      case 0: gemm_kernel<0><<<g, 256, 0, stream>>>(A, B, bias, Cp, M, K, Nc, nullptr, nullptr); break;
      case 2: gemm_kernel<2><<<g, 256, 0, stream>>>(A, B, bias, Cp, M, K, Nc, nullptr, nullptr); break;
      case 3: gemm_kernel<3><<<g, 256, 0, stream>>>(A, B, bias, Cp, M, K, Nc, aux, alpha_p); break;
    }
  };

  const int nblk_node = (N + 3) / 4;

  // ---- Layer 1 (din=64, HC=128, C=32) ----
  gemm(0, x, g1_Wl, g1_bl, xl, N, 64, 128, nullptr);
  gemm(0, x, g1_Wr, g1_br, xr, N, 64, 128, nullptr);
  gemm(0, x, skip_W, skip_b, skipproj, N, 64, 128, nullptr);
  score_kernel<32><<<2048, 256, 0, stream>>>(ea2, xl, xr, g1_We, g1_att, src0, dst0, e_s, E, E2, 128, 0);
  aggr_kernel<128, true><<<nblk_node, 256, 0, stream>>>(e_s, xl, rowptr, csr, src0, g1_bias, ln1_g, ln1_b,
                                                        a1, skip1, x1, skipproj, N, E);
  // ---- Layer 2 (din=128, HC=128, C=32) ----
  gemm(0, skip1, g2_Wl, g2_bl, xl, N, 128, 128, nullptr);
  gemm(0, skip1, g2_Wr, g2_br, xr, N, 128, 128, nullptr);
  score_kernel<32><<<2048, 256, 0, stream>>>(ea2, xl, xr, g2_We, g2_att, src0, dst0, e_s, E, E2, 128, 0);
  aggr_kernel<128, false><<<nblk_node, 256, 0, stream>>>(e_s, xl, rowptr, csr, src0, g2_bias, ln2_g, ln2_b,
                                                         a2, x2, nullptr, nullptr, N, E);
  // ---- Layer 3 (din=128, HC=256, C=64) ----
  gemm(0, x2, g3_Wl, g3_bl, xl, N, 128, 256, nullptr);
  gemm(0, x2, g3_Wr, g3_br, xr, N, 128, 256, nullptr);
  score_kernel<64><<<2048, 256, 0, stream>>>(ea2, xl, xr, g3_We, g3_att, src0, dst0, e_s, E, E2, 256, 0);
  score_kernel<64><<<2048, 256, 0, stream>>>(ea2, xl, xr, g3_We, g3_att, src0, dst0, e_s, E, E2, 256, 128);
  aggr_kernel<256, false><<<nblk_node, 256, 0, stream>>>(e_s, xl, rowptr, csr, src0, g3_bias, ln3_g, ln3_b,
                                                         a3, x3, nullptr, nullptr, N, E);
  // ---- Final: xf = s*(x1@fp_W+fp_b) + (1-s)*x3 ; node MLP ----
  gemm(3, x1, fp_W, fp_b, xf, N, 128, 256, x3);
  gemm(2, xf, np_W1, np_b1, skipproj, N, 256, 128, nullptr);   // h1
  gemm(2, skipproj, np_W2, np_b2, h2, N, 128, 64, nullptr);    // h2
  gemm(0, h2, np_W3, np_b3, npout, N, 64, 1, nullptr);
}

// Round 5
// 1925.876 us; speedup vs baseline: 1.3411x; 1.1032x over previous
//
#include <hip/hip_runtime.h>
#include <math.h>

#define DEV __device__ __forceinline__

DEV float leakyf(float x, float s) { return x > 0.f ? x : s * x; }

DEV float wave_sum(float v) {
#pragma unroll
  for (int o = 1; o < 64; o <<= 1) v += __shfl_xor(v, o);
  return v;
}
DEV float wave_max(float v) {
#pragma unroll
  for (int o = 1; o < 64; o <<= 1) v = fmaxf(v, __shfl_xor(v, o));
  return v;
}

// ---------------- BatchNorm (eval) ----------------
__global__ __launch_bounds__(256) void bn_kernel(
    const float* __restrict__ xin, const float* __restrict__ g,
    const float* __restrict__ b, const float* __restrict__ m,
    const float* __restrict__ v, float* __restrict__ xout, int total) {
  int i = blockIdx.x * 256 + threadIdx.x;
  if (i < total) {
    int c = i & 63;
    xout[i] = (xin[i] - m[c]) * rsqrtf(v[c] + 1e-5f) * g[c] + b[c];
  }
}

// ---------------- Edge encoder: tiled fused 2-layer MLP + L2 norm ----------------
// Block = 64 edges. Layer1: [64,16]@[16,128] (4x8 micro-tile). ea1 stays in LDS;
// writer group == reader group == the 16-thread ty-group (always within one wave),
// so no __syncthreads is needed after the initial weight-staging barrier.
// Layer2: [64,128]@[128,64] (4x4 micro-tile), fused bias+leaky+row-L2-normalize.
__global__ __launch_bounds__(256) void edge_enc_kernel(
    const float* __restrict__ edge_attr, const float* __restrict__ W1,
    const float* __restrict__ b1, const float* __restrict__ W2,
    const float* __restrict__ b2, float* __restrict__ ea2, int E) {
  __shared__ float sW1[16][128];   // 8 KB
  __shared__ float sW2[128][64];   // 32 KB
  __shared__ float sb1[128];
  __shared__ float sb2[64];
  __shared__ float sAttr[64][18];  // pad 18 -> conflict-free ty-strided scalar reads
  __shared__ float sEa1[64][132];  // pad 132 -> aligned float4, 2-way (free) reads
  int tid = threadIdx.x;
  for (int i = tid; i < 16 * 128; i += 256) sW1[i >> 7][i & 127] = W1[i];
  for (int i = tid; i < 128 * 64; i += 256) sW2[i >> 6][i & 63] = W2[i];
  if (tid < 128) sb1[tid] = b1[tid];
  if (tid < 64) sb2[tid] = b2[tid];
  int e0 = blockIdx.x * 64;
  {
    int r = tid >> 2, c = (tid & 3) * 4;
    int e = e0 + r;
    float4 v = (e < E) ? *(const float4*)(edge_attr + (size_t)e * 16 + c)
                       : make_float4(0.f, 0.f, 0.f, 0.f);
    sAttr[r][c] = v.x;
    sAttr[r][c + 1] = v.y;
    sAttr[r][c + 2] = v.z;
    sAttr[r][c + 3] = v.w;
  }
  __syncthreads();  // the only block barrier (weights + attr staged)
  int tx = tid & 15, ty = tid >> 4;
  // ---- layer 1: rows ty*4+i, cols tx*8+j ----
  float acc1[4][8] = {};
#pragma unroll
  for (int k = 0; k < 16; k++) {
    float a[4];
#pragma unroll
    for (int i = 0; i < 4; i++) a[i] = sAttr[ty * 4 + i][k];
    float4 w0 = *(const float4*)&sW1[k][tx * 8];
    float4 w1 = *(const float4*)&sW1[k][tx * 8 + 4];
    float w[8] = {w0.x, w0.y, w0.z, w0.w, w1.x, w1.y, w1.z, w1.w};
#pragma unroll
    for (int i = 0; i < 4; i++)
#pragma unroll
      for (int j = 0; j < 8; j++) acc1[i][j] += a[i] * w[j];
  }
#pragma unroll
  for (int i = 0; i < 4; i++) {
    int r = ty * 4 + i;
    int c = tx * 8;
    float4 v0, v1;
    v0.x = leakyf(acc1[i][0] + sb1[c + 0], 0.01f);
    v0.y = leakyf(acc1[i][1] + sb1[c + 1], 0.01f);
    v0.z = leakyf(acc1[i][2] + sb1[c + 2], 0.01f);
    v0.w = leakyf(acc1[i][3] + sb1[c + 3], 0.01f);
    v1.x = leakyf(acc1[i][4] + sb1[c + 4], 0.01f);
    v1.y = leakyf(acc1[i][5] + sb1[c + 5], 0.01f);
    v1.z = leakyf(acc1[i][6] + sb1[c + 6], 0.01f);
    v1.w = leakyf(acc1[i][7] + sb1[c + 7], 0.01f);
    *(float4*)&sEa1[r][c] = v0;
    *(float4*)&sEa1[r][c + 4] = v1;
  }
  // ea1 rows ty*4..ty*4+3 were written entirely by this thread's ty-group
  // (16 threads, same wave). Intra-wave LDS ordering handles the dependence.
  // ---- layer 2: rows ty*4+i, cols tx*4+j, K=128 ----
  float acc2[4][4] = {};
  for (int k4 = 0; k4 < 128; k4 += 4) {
    float4 eav[4];
#pragma unroll
    for (int i = 0; i < 4; i++) eav[i] = *(const float4*)&sEa1[ty * 4 + i][k4];
#pragma unroll
    for (int kk = 0; kk < 4; kk++) {
      float4 wv = *(const float4*)&sW2[k4 + kk][tx * 4];
      float w[4] = {wv.x, wv.y, wv.z, wv.w};
      float a0 = (&eav[0].x)[kk];
      float a1 = (&eav[1].x)[kk];
      float a2 = (&eav[2].x)[kk];
      float a3 = (&eav[3].x)[kk];
#pragma unroll
      for (int j = 0; j < 4; j++) {
        acc2[0][j] += a0 * w[j];
        acc2[1][j] += a1 * w[j];
        acc2[2][j] += a2 * w[j];
        acc2[3][j] += a3 * w[j];
      }
    }
  }
  // ---- bias + leaky + row L2-normalize + store ----
#pragma unroll
  for (int i = 0; i < 4; i++) {
    float vout[4];
    float p = 0.f;
#pragma unroll
    for (int j = 0; j < 4; j++) {
      float t = leakyf(acc2[i][j] + sb2[tx * 4 + j], 0.01f);
      vout[j] = t;
      p += t * t;
    }
#pragma unroll
    for (int o = 1; o < 16; o <<= 1) p += __shfl_xor(p, o);
    float sc = 1.f / fmaxf(sqrtf(p), 1e-12f);
    int e = e0 + ty * 4 + i;
    if (e < E) {
      float4 w4 = make_float4(vout[0] * sc, vout[1] * sc, vout[2] * sc, vout[3] * sc);
      *(float4*)(ea2 + (size_t)e * 64 + tx * 4) = w4;
    }
  }
}

// ---------------- CSR build ----------------
__global__ __launch_bounds__(256) void count_kernel(const int* __restrict__ dst0,
                                                    int* __restrict__ counts, int E, int E2) {
  int i = blockIdx.x * 256 + threadIdx.x;
  if (i < E2) {
    int d = (i < E) ? dst0[i] : (i - E);
    atomicAdd(&counts[d], 1);
  }
}

__global__ __launch_bounds__(256) void scan_kernel(const int* __restrict__ counts,
                                                   int* __restrict__ rowptr,
                                                   int* __restrict__ fill, int N) {
  __shared__ int part[256];
  int tid = threadIdx.x;
  int chunk = (N + 255) / 256;
  int lo = tid * chunk, hi = lo + chunk;
  if (hi > N) hi = N;
  if (lo > N) lo = N;
  int s = 0;
  for (int i = lo; i < hi; i++) s += counts[i];
  part[tid] = s;
  __syncthreads();
  if (tid == 0) {
    int run = 0;
    for (int i = 0; i < 256; i++) {
      int t = part[i];
      part[i] = run;
      run += t;
    }
    rowptr[N] = run;
  }
  __syncthreads();
  int off = part[tid];
  for (int i = lo; i < hi; i++) {
    rowptr[i] = off;
    fill[i] = off;
    off += counts[i];
  }
}

__global__ __launch_bounds__(256) void fill_kernel(const int* __restrict__ dst0,
                                                   int* __restrict__ fill,
                                                   int* __restrict__ csr, int E, int E2) {
  int i = blockIdx.x * 256 + threadIdx.x;
  if (i < E2) {
    int d = (i < E) ? dst0[i] : (i - E);
    int pos = atomicAdd(&fill[d], 1);
    csr[pos] = i;
  }
}

// ---------------- self-loop attr = mean of incoming encoded attrs ----------------
__global__ __launch_bounds__(256) void loopattr_kernel(float* __restrict__ ea2,
                                                       const int* __restrict__ rowptr,
                                                       const int* __restrict__ csr, int N, int E) {
  int lane = threadIdx.x & 63, wv = threadIdx.x >> 6;
  int stride = gridDim.x * 4;
  for (int n = blockIdx.x * 4 + wv; n < N; n += stride) {
    int r0 = rowptr[n], r1 = rowptr[n + 1];
    float acc = 0.f;
    int cnt = 0;
    for (int i = r0; i < r1; i++) {
      int e = csr[i];
      if (e < E) {
        acc += ea2[(size_t)e * 64 + lane];
        cnt++;
      }
    }
    ea2[((size_t)E + n) * 64 + lane] = acc / fmaxf((float)cnt, 1.f);
  }
}

// ---------------- generic f32 GEMM: C = act(A[M,K]@B[K,Nc] + bias) ----------------
// MODE: 0 none, 2 elu, 3 mix: out = s*(v) + (1-s)*aux[row,col]
template <int MODE>
__global__ __launch_bounds__(256) void gemm_kernel(
    const float* __restrict__ A, const float* __restrict__ B,
    const float* __restrict__ bias, float* __restrict__ C, int M, int K, int Nc,
    const float* __restrict__ aux, const float* __restrict__ alpha_p) {
  __shared__ __align__(16) float As[16][68];
  __shared__ __align__(16) float Bs[16][68];
  int bm = blockIdx.y * 64, bn = blockIdx.x * 64;
  int tid = threadIdx.x;
  int tx = tid & 15, ty = tid >> 4;
  float acc[4][4] = {};
  for (int k0 = 0; k0 < K; k0 += 16) {
#pragma unroll
    for (int i = tid; i < 1024; i += 256) {
      int m = i >> 4, k = i & 15;
      int gm = bm + m;
      As[k][m] = (gm < M) ? A[(size_t)gm * K + k0 + k] : 0.f;
    }
#pragma unroll
    for (int i = tid; i < 1024; i += 256) {
      int k = i >> 6, n = i & 63;
      int gn = bn + n;
      Bs[k][n] = (gn < Nc) ? B[(size_t)(k0 + k) * Nc + gn] : 0.f;
    }
    __syncthreads();
#pragma unroll
    for (int k = 0; k < 16; k++) {
      float4 a4 = *(const float4*)&As[k][ty * 4];
      float4 b4 = *(const float4*)&Bs[k][tx * 4];
      float a[4] = {a4.x, a4.y, a4.z, a4.w};
      float b[4] = {b4.x, b4.y, b4.z, b4.w};
#pragma unroll
      for (int i = 0; i < 4; i++)
#pragma unroll
        for (int j = 0; j < 4; j++) acc[i][j] += a[i] * b[j];
    }
    __syncthreads();
  }
  float s = 0.f;
  if (MODE == 3) s = 1.f / (1.f + __expf(-alpha_p[0]));
#pragma unroll
  for (int i = 0; i < 4; i++) {
    int m = bm + ty * 4 + i;
    if (m >= M) continue;
#pragma unroll
    for (int j = 0; j < 4; j++) {
      int n = bn + tx * 4 + j;
      if (n >= Nc) continue;
      float v = acc[i][j] + bias[n];
      if (MODE == 2) v = v > 0.f ? v : (__expf(v) - 1.f);
      if (MODE == 3) v = s * v + (1.f - s) * aux[(size_t)m * Nc + n];
      C[(size_t)m * Nc + n] = v;
    }
  }
}

// ---------------- GATv2 edge scores (fused ee = ea2@We), 128 columns per launch ----------------
// One wave per edge; ea row broadcast via __shfl from registers (no LDS staging, no barriers);
// sWe padded to stride 130 -> worst-case 2-way bank aliasing (free on gfx950).
template <int C>  // head dim: 32 (layers 1,2) or 64 (layer 3 -> two launches)
__global__ __launch_bounds__(256) void score_kernel(
    const float* __restrict__ ea2, const float* __restrict__ xl,
    const float* __restrict__ xr, const float* __restrict__ We,
    const float* __restrict__ att, const int* __restrict__ src0,
    const int* __restrict__ dst0, float* __restrict__ e_s, int E, int E2,
    int HCfull, int col_off) {
  __shared__ float sWe[64][130];
  __shared__ float sAtt[128];
  for (int i = threadIdx.x; i < 64 * 128; i += 256) {
    int k = i >> 7, cc = i & 127;
    sWe[k][cc] = We[(size_t)k * HCfull + col_off + cc];
  }
  for (int i = threadIdx.x; i < 128; i += 256) sAtt[i] = att[col_off + i];
  __syncthreads();
  int lane = threadIdx.x & 63, wv = threadIdx.x >> 6;
  int stride = gridDim.x * 4;
  constexpr int L = C / 2;  // lanes per head
  int c0 = 2 * lane;
  for (int e = blockIdx.x * 4 + wv; e < E2; e += stride) {
    int sn, dn;
    if (e < E) {
      sn = src0[e];
      dn = dst0[e];
    } else {
      sn = dn = e - E;
    }
    float eav = ea2[(size_t)e * 64 + lane];  // lane k holds ea[k], coalesced
    float a0 = 0.f, a1v = 0.f;
#pragma unroll
    for (int k = 0; k < 64; k++) {
      float a = __shfl(eav, k);
      a0 += a * sWe[k][c0];
      a1v += a * sWe[k][c0 + 1];
    }
    float2 xlv = *(const float2*)(xl + (size_t)sn * HCfull + col_off + c0);
    float2 xrv = *(const float2*)(xr + (size_t)dn * HCfull + col_off + c0);
    float mA = xlv.x + xrv.x + a0;
    mA = mA > 0.f ? mA : 0.2f * mA;
    float mB = xlv.y + xrv.y + a1v;
    mB = mB > 0.f ? mB : 0.2f * mB;
    float sres = mA * sAtt[c0] + mB * sAtt[c0 + 1];
#pragma unroll
    for (int o = 1; o < L; o <<= 1) sres += __shfl_xor(sres, o);
    if ((lane & (L - 1)) == 0)
      e_s[(size_t)e * 4 + col_off / C + lane / L] = sres;
  }
}

// ---------------- per-node softmax + aggregation + bias + LN + leaky (+skip mix for L1) ----------------
template <int HC, bool L1MODE>
__global__ __launch_bounds__(256) void aggr_kernel(
    const float* __restrict__ e_s, const float* __restrict__ xl,
    const int* __restrict__ rowptr, const int* __restrict__ csr,
    const int* __restrict__ src0, const float* __restrict__ bias,
    const float* __restrict__ lng, const float* __restrict__ lnb,
    float* __restrict__ alpha_out, float* __restrict__ xout,
    float* __restrict__ x1out, const float* __restrict__ skipproj, int N, int E) {
  constexpr int CPL = HC / 64;
  int lane = threadIdx.x & 63, wv = threadIdx.x >> 6;
  int stride = gridDim.x * 4;
  for (int n = blockIdx.x * 4 + wv; n < N; n += stride) {
    int r0 = rowptr[n], r1 = rowptr[n + 1];
    float m0 = -1e30f, m1 = -1e30f, m2 = -1e30f, m3 = -1e30f;
    for (int i = r0 + lane; i < r1; i += 64) {
      int e = csr[i];
      float4 v = *reinterpret_cast<const float4*>(e_s + (size_t)e * 4);
      m0 = fmaxf(m0, v.x);
      m1 = fmaxf(m1, v.y);
      m2 = fmaxf(m2, v.z);
      m3 = fmaxf(m3, v.w);
    }
    m0 = wave_max(m0);
    m1 = wave_max(m1);
    m2 = wave_max(m2);
    m3 = wave_max(m3);
    float d0 = 0.f, d1 = 0.f, d2 = 0.f, d3 = 0.f;
    for (int i = r0 + lane; i < r1; i += 64) {
      int e = csr[i];
      float4 v = *reinterpret_cast<const float4*>(e_s + (size_t)e * 4);
      d0 += __expf(v.x - m0);
      d1 += __expf(v.y - m1);
      d2 += __expf(v.z - m2);
      d3 += __expf(v.w - m3);
    }
    d0 = wave_sum(d0);
    d1 = wave_sum(d1);
    d2 = wave_sum(d2);
    d3 = wave_sum(d3);
    float i0 = 1.f / (d0 + 1e-16f), i1 = 1.f / (d1 + 1e-16f);
    float i2 = 1.f / (d2 + 1e-16f), i3 = 1.f / (d3 + 1e-16f);
    int h = lane >> 4;
    float mh = (h & 2) ? ((h & 1) ? m3 : m2) : ((h & 1) ? m1 : m0);
    float ih = (h & 2) ? ((h & 1) ? i3 : i2) : ((h & 1) ? i1 : i0);
    float acc[CPL];
#pragma unroll
    for (int j = 0; j < CPL; j++) acc[j] = 0.f;
    int c0 = lane * CPL;
    for (int i = r0; i < r1; i++) {
      int e = csr[i];
      int sn = (e < E) ? src0[e] : (e - E);
      float a = __expf(e_s[(size_t)e * 4 + h] - mh) * ih;
      if ((lane & 15) == 0) alpha_out[(size_t)e * 4 + h] = a;
      const float* xp = xl + (size_t)sn * HC + c0;
      if constexpr (CPL == 2) {
        float2 t = *(const float2*)xp;
        acc[0] += a * t.x;
        acc[1] += a * t.y;
      } else {
        float4 t = *(const float4*)xp;
        acc[0] += a * t.x;
        acc[1] += a * t.y;
        acc[2] += a * t.z;
        acc[3] += a * t.w;
      }
    }
    float vals[CPL];
    float vs = 0.f, vq = 0.f;
#pragma unroll
    for (int j = 0; j < CPL; j++) {
      float t = acc[j] + bias[c0 + j];
      vals[j] = t;
      vs += t;
      vq += t * t;
    }
    vs = wave_sum(vs);
    vq = wave_sum(vq);
    float mean = vs * (1.f / HC);
    float var = vq * (1.f / HC) - mean * mean;
    float rstd = rsqrtf(fmaxf(var, 0.f) + 1e-5f);
#pragma unroll
    for (int j = 0; j < CPL; j++) {
      int c = c0 + j;
      float y = (vals[j] - mean) * rstd * lng[c] + lnb[c];
      y = leakyf(y, 0.01f);
      if constexpr (L1MODE) {
        x1out[(size_t)n * HC + c] = y;
        xout[(size_t)n * HC + c] = 0.01f * skipproj[(size_t)n * HC + c] + y;
      } else {
        xout[(size_t)n * HC + c] = y;
      }
    }
  }
}

extern "C" void kernel_launch(void* const* d_in, const int* in_sizes, int n_in,
                              void* d_out, int out_size, void* d_ws, size_t ws_size,
                              hipStream_t stream) {
  (void)n_in;
  (void)out_size;
  (void)ws_size;
  const float* x_in = (const float*)d_in[0];
  const int* edge_index = (const int*)d_in[1];
  const float* edge_attr = (const float*)d_in[2];
  const float* bn0_g = (const float*)d_in[3];
  const float* bn0_b = (const float*)d_in[4];
  const float* bn0_m = (const float*)d_in[5];
  const float* bn0_v = (const float*)d_in[6];
  const float* eeW1 = (const float*)d_in[7];
  const float* eeb1 = (const float*)d_in[8];
  const float* eeW2 = (const float*)d_in[9];
  const float* eeb2 = (const float*)d_in[10];
  const float* g1_Wl = (const float*)d_in[11];
  const float* g1_bl = (const float*)d_in[12];
  const float* g1_Wr = (const float*)d_in[13];
  const float* g1_br = (const float*)d_in[14];
  const float* g1_We = (const float*)d_in[15];
  const float* g1_att = (const float*)d_in[16];
  const float* g1_bias = (const float*)d_in[17];
  const float* g2_Wl = (const float*)d_in[18];
  const float* g2_bl = (const float*)d_in[19];
  const float* g2_Wr = (const float*)d_in[20];
  const float* g2_br = (const float*)d_in[21];
  const float* g2_We = (const float*)d_in[22];
  const float* g2_att = (const float*)d_in[23];
  const float* g2_bias = (const float*)d_in[24];
  const float* g3_Wl = (const float*)d_in[25];
  const float* g3_bl = (const float*)d_in[26];
  const float* g3_Wr = (const float*)d_in[27];
  const float* g3_br = (const float*)d_in[28];
  const float* g3_We = (const float*)d_in[29];
  const float* g3_att = (const float*)d_in[30];
  const float* g3_bias = (const float*)d_in[31];
  const float* ln1_g = (const float*)d_in[32];
  const float* ln1_b = (const float*)d_in[33];
  const float* ln2_g = (const float*)d_in[34];
  const float* ln2_b = (const float*)d_in[35];
  const float* ln3_g = (const float*)d_in[36];
  const float* ln3_b = (const float*)d_in[37];
  const float* skip_W = (const float*)d_in[38];
  const float* skip_b = (const float*)d_in[39];
  const float* alpha_p = (const float*)d_in[40];
  const float* fp_W = (const float*)d_in[41];
  const float* fp_b = (const float*)d_in[42];
  const float* np_W1 = (const float*)d_in[43];
  const float* np_b1 = (const float*)d_in[44];
  const float* np_W2 = (const float*)d_in[45];
  const float* np_b2 = (const float*)d_in[46];
  const float* np_W3 = (const float*)d_in[47];
  const float* np_b3 = (const float*)d_in[48];

  const int N = in_sizes[0] / 64;
  const int E = in_sizes[2] / 16;
  const int E2 = E + N;
  const int* src0 = edge_index;
  const int* dst0 = edge_index + E;

  float* ws = (float*)d_ws;
  size_t off = 0;
  float* x = ws + off;         off += (size_t)N * 64;
  float* ea2 = ws + off;       off += (size_t)E2 * 64;
  float* xl = ws + off;        off += (size_t)N * 256;
  float* xr = ws + off;        off += (size_t)N * 256;
  float* skipproj = ws + off;  off += (size_t)N * 128;  // reused as h1 at the end
  float* x1 = ws + off;        off += (size_t)N * 128;
  float* skip1 = ws + off;     off += (size_t)N * 128;
  float* x2 = ws + off;        off += (size_t)N * 128;
  float* x3 = ws + off;        off += (size_t)N * 256;
  float* e_s = ws + off;       off += (size_t)E2 * 4;
  float* h2 = ws + off;        off += (size_t)N * 64;
  int* counts = (int*)(ws + off);
  int* rowptr = counts + N;
  int* fill = rowptr + N + 1;
  int* csr = fill + N;

  float* out = (float*)d_out;
  float* xf = out;
  float* npout = out + (size_t)N * 256;
  float* a1 = npout + N;
  float* a2 = a1 + (size_t)E2 * 4;
  float* a3 = a2 + (size_t)E2 * 4;

  hipMemsetAsync(counts, 0, (size_t)N * sizeof(int), stream);
  bn_kernel<<<(N * 64 + 255) / 256, 256, 0, stream>>>(x_in, bn0_g, bn0_b, bn0_m, bn0_v, x, N * 64);
  edge_enc_kernel<<<(E + 63) / 64, 256, 0, stream>>>(edge_attr, eeW1, eeb1, eeW2, eeb2, ea2, E);
  count_kernel<<<(E2 + 255) / 256, 256, 0, stream>>>(dst0, counts, E, E2);
  scan_kernel<<<1, 256, 0, stream>>>(counts, rowptr, fill, N);
  fill_kernel<<<(E2 + 255) / 256, 256, 0, stream>>>(dst0, fill, csr, E, E2);
  loopattr_kernel<<<(N + 3) / 4, 256, 0, stream>>>(ea2, rowptr, csr, N, E);

  auto gemm = [&](int mode, const float* A, const float* B, const float* bias,
                  float* Cp, int M, int K, int Nc, const float* aux) {
    dim3 g((Nc + 63) / 64, (M + 63) / 64);
    switch (mode) {
      case 0: gemm_kernel<0><<<g, 256, 0, stream>>>(A, B, bias, Cp, M, K, Nc, nullptr, nullptr); break;
      case 2: gemm_kernel<2><<<g, 256, 0, stream>>>(A, B, bias, Cp, M, K, Nc, nullptr, nullptr); break;
      case 3: gemm_kernel<3><<<g, 256, 0, stream>>>(A, B, bias, Cp, M, K, Nc, aux, alpha_p); break;
    }
  };

  const int nblk_node = (N + 3) / 4;

  // ---- Layer 1 (din=64, HC=128, C=32) ----
  gemm(0, x, g1_Wl, g1_bl, xl, N, 64, 128, nullptr);
  gemm(0, x, g1_Wr, g1_br, xr, N, 64, 128, nullptr);
  gemm(0, x, skip_W, skip_b, skipproj, N, 64, 128, nullptr);
  score_kernel<32><<<2048, 256, 0, stream>>>(ea2, xl, xr, g1_We, g1_att, src0, dst0, e_s, E, E2, 128, 0);
  aggr_kernel<128, true><<<nblk_node, 256, 0, stream>>>(e_s, xl, rowptr, csr, src0, g1_bias, ln1_g, ln1_b,
                                                        a1, skip1, x1, skipproj, N, E);
  // ---- Layer 2 (din=128, HC=128, C=32) ----
  gemm(0, skip1, g2_Wl, g2_bl, xl, N, 128, 128, nullptr);
  gemm(0, skip1, g2_Wr, g2_br, xr, N, 128, 128, nullptr);
  score_kernel<32><<<2048, 256, 0, stream>>>(ea2, xl, xr, g2_We, g2_att, src0, dst0, e_s, E, E2, 128, 0);
  aggr_kernel<128, false><<<nblk_node, 256, 0, stream>>>(e_s, xl, rowptr, csr, src0, g2_bias, ln2_g, ln2_b,
                                                         a2, x2, nullptr, nullptr, N, E);
  // ---- Layer 3 (din=128, HC=256, C=64) ----
  gemm(0, x2, g3_Wl, g3_bl, xl, N, 128, 256, nullptr);
  gemm(0, x2, g3_Wr, g3_br, xr, N, 128, 256, nullptr);
  score_kernel<64><<<2048, 256, 0, stream>>>(ea2, xl, xr, g3_We, g3_att, src0, dst0, e_s, E, E2, 256, 0);
  score_kernel<64><<<2048, 256, 0, stream>>>(ea2, xl, xr, g3_We, g3_att, src0, dst0, e_s, E, E2, 256, 128);
  aggr_kernel<256, false><<<nblk_node, 256, 0, stream>>>(e_s, xl, rowptr, csr, src0, g3_bias, ln3_g, ln3_b,
                                                         a3, x3, nullptr, nullptr, N, E);
  // ---- Final: xf = s*(x1@fp_W+fp_b) + (1-s)*x3 ; node MLP ----
  gemm(3, x1, fp_W, fp_b, xf, N, 128, 256, x3);
  gemm(2, xf, np_W1, np_b1, skipproj, N, 256, 128, nullptr);   // h1
  gemm(2, skipproj, np_W2, np_b2, h2, N, 128, 64, nullptr);    // h2
  gemm(0, h2, np_W3, np_b3, npout, N, 64, 1, nullptr);
}

// Round 6
// 1450.160 us; speedup vs baseline: 1.7810x; 1.3280x over previous
//
#include <hip/hip_runtime.h>
#include <math.h>

#define DEV __device__ __forceinline__

DEV float leakyf(float x, float s) { return x > 0.f ? x : s * x; }

DEV float readlane_f(float v, int k) {
  return __int_as_float(__builtin_amdgcn_readlane(__float_as_int(v), k));
}

DEV float wave_sum(float v) {
#pragma unroll
  for (int o = 1; o < 64; o <<= 1) v += __shfl_xor(v, o);
  return v;
}
DEV float wave_max(float v) {
#pragma unroll
  for (int o = 1; o < 64; o <<= 1) v = fmaxf(v, __shfl_xor(v, o));
  return v;
}

// ---------------- BatchNorm (eval) ----------------
__global__ __launch_bounds__(256) void bn_kernel(
    const float* __restrict__ xin, const float* __restrict__ g,
    const float* __restrict__ b, const float* __restrict__ m,
    const float* __restrict__ v, float* __restrict__ xout, int total) {
  int i = blockIdx.x * 256 + threadIdx.x;
  if (i < total) {
    int c = i & 63;
    xout[i] = (xin[i] - m[c]) * rsqrtf(v[c] + 1e-5f) * g[c] + b[c];
  }
}

// ---------------- Edge encoder: tiled fused 2-layer MLP + L2 norm ----------------
__global__ __launch_bounds__(256) void edge_enc_kernel(
    const float* __restrict__ edge_attr, const float* __restrict__ W1,
    const float* __restrict__ b1, const float* __restrict__ W2,
    const float* __restrict__ b2, float* __restrict__ ea2, int E) {
  __shared__ float sW1[16][128];   // 8 KB
  __shared__ float sW2[128][64];   // 32 KB
  __shared__ float sb1[128];
  __shared__ float sb2[64];
  __shared__ float sAttr[64][18];
  __shared__ float sEa1[64][132];
  int tid = threadIdx.x;
  for (int i = tid; i < 16 * 128; i += 256) sW1[i >> 7][i & 127] = W1[i];
  for (int i = tid; i < 128 * 64; i += 256) sW2[i >> 6][i & 63] = W2[i];
  if (tid < 128) sb1[tid] = b1[tid];
  if (tid < 64) sb2[tid] = b2[tid];
  int e0 = blockIdx.x * 64;
  {
    int r = tid >> 2, c = (tid & 3) * 4;
    int e = e0 + r;
    float4 v = (e < E) ? *(const float4*)(edge_attr + (size_t)e * 16 + c)
                       : make_float4(0.f, 0.f, 0.f, 0.f);
    sAttr[r][c] = v.x;
    sAttr[r][c + 1] = v.y;
    sAttr[r][c + 2] = v.z;
    sAttr[r][c + 3] = v.w;
  }
  __syncthreads();
  int tx = tid & 15, ty = tid >> 4;
  float acc1[4][8] = {};
#pragma unroll
  for (int k = 0; k < 16; k++) {
    float a[4];
#pragma unroll
    for (int i = 0; i < 4; i++) a[i] = sAttr[ty * 4 + i][k];
    float4 w0 = *(const float4*)&sW1[k][tx * 8];
    float4 w1 = *(const float4*)&sW1[k][tx * 8 + 4];
    float w[8] = {w0.x, w0.y, w0.z, w0.w, w1.x, w1.y, w1.z, w1.w};
#pragma unroll
    for (int i = 0; i < 4; i++)
#pragma unroll
      for (int j = 0; j < 8; j++) acc1[i][j] += a[i] * w[j];
  }
#pragma unroll
  for (int i = 0; i < 4; i++) {
    int r = ty * 4 + i;
    int c = tx * 8;
    float4 v0, v1;
    v0.x = leakyf(acc1[i][0] + sb1[c + 0], 0.01f);
    v0.y = leakyf(acc1[i][1] + sb1[c + 1], 0.01f);
    v0.z = leakyf(acc1[i][2] + sb1[c + 2], 0.01f);
    v0.w = leakyf(acc1[i][3] + sb1[c + 3], 0.01f);
    v1.x = leakyf(acc1[i][4] + sb1[c + 4], 0.01f);
    v1.y = leakyf(acc1[i][5] + sb1[c + 5], 0.01f);
    v1.z = leakyf(acc1[i][6] + sb1[c + 6], 0.01f);
    v1.w = leakyf(acc1[i][7] + sb1[c + 7], 0.01f);
    *(float4*)&sEa1[r][c] = v0;
    *(float4*)&sEa1[r][c + 4] = v1;
  }
  float acc2[4][4] = {};
  for (int k4 = 0; k4 < 128; k4 += 4) {
    float4 eav[4];
#pragma unroll
    for (int i = 0; i < 4; i++) eav[i] = *(const float4*)&sEa1[ty * 4 + i][k4];
#pragma unroll
    for (int kk = 0; kk < 4; kk++) {
      float4 wv = *(const float4*)&sW2[k4 + kk][tx * 4];
      float w[4] = {wv.x, wv.y, wv.z, wv.w};
      float a0 = (&eav[0].x)[kk];
      float a1 = (&eav[1].x)[kk];
      float a2 = (&eav[2].x)[kk];
      float a3 = (&eav[3].x)[kk];
#pragma unroll
      for (int j = 0; j < 4; j++) {
        acc2[0][j] += a0 * w[j];
        acc2[1][j] += a1 * w[j];
        acc2[2][j] += a2 * w[j];
        acc2[3][j] += a3 * w[j];
      }
    }
  }
#pragma unroll
  for (int i = 0; i < 4; i++) {
    float vout[4];
    float p = 0.f;
#pragma unroll
    for (int j = 0; j < 4; j++) {
      float t = leakyf(acc2[i][j] + sb2[tx * 4 + j], 0.01f);
      vout[j] = t;
      p += t * t;
    }
#pragma unroll
    for (int o = 1; o < 16; o <<= 1) p += __shfl_xor(p, o);
    float sc = 1.f / fmaxf(sqrtf(p), 1e-12f);
    int e = e0 + ty * 4 + i;
    if (e < E) {
      float4 w4 = make_float4(vout[0] * sc, vout[1] * sc, vout[2] * sc, vout[3] * sc);
      *(float4*)(ea2 + (size_t)e * 64 + tx * 4) = w4;
    }
  }
}

// ---------------- CSR build ----------------
__global__ __launch_bounds__(256) void count_kernel(const int* __restrict__ dst0,
                                                    int* __restrict__ counts, int E, int E2) {
  int i = blockIdx.x * 256 + threadIdx.x;
  if (i < E2) {
    int d = (i < E) ? dst0[i] : (i - E);
    atomicAdd(&counts[d], 1);
  }
}

__global__ __launch_bounds__(256) void scan_kernel(const int* __restrict__ counts,
                                                   int* __restrict__ rowptr,
                                                   int* __restrict__ fill, int N) {
  __shared__ int part[256];
  int tid = threadIdx.x;
  int chunk = (N + 255) / 256;
  int lo = tid * chunk, hi = lo + chunk;
  if (hi > N) hi = N;
  if (lo > N) lo = N;
  int s = 0;
  for (int i = lo; i < hi; i++) s += counts[i];
  part[tid] = s;
  __syncthreads();
  if (tid == 0) {
    int run = 0;
    for (int i = 0; i < 256; i++) {
      int t = part[i];
      part[i] = run;
      run += t;
    }
    rowptr[N] = run;
  }
  __syncthreads();
  int off = part[tid];
  for (int i = lo; i < hi; i++) {
    rowptr[i] = off;
    fill[i] = off;
    off += counts[i];
  }
}

__global__ __launch_bounds__(256) void fill_kernel(const int* __restrict__ dst0,
                                                   int* __restrict__ fill,
                                                   int* __restrict__ csr, int E, int E2) {
  int i = blockIdx.x * 256 + threadIdx.x;
  if (i < E2) {
    int d = (i < E) ? dst0[i] : (i - E);
    int pos = atomicAdd(&fill[d], 1);
    csr[pos] = i;
  }
}

// ---------------- self-loop attr = mean of incoming encoded attrs ----------------
__global__ __launch_bounds__(256) void loopattr_kernel(float* __restrict__ ea2,
                                                       const int* __restrict__ rowptr,
                                                       const int* __restrict__ csr, int N, int E) {
  int lane = threadIdx.x & 63, wv = threadIdx.x >> 6;
  int stride = gridDim.x * 4;
  for (int n = blockIdx.x * 4 + wv; n < N; n += stride) {
    int r0 = rowptr[n], r1 = rowptr[n + 1];
    float acc = 0.f;
    int cnt = 0;
    for (int i = r0; i < r1; i++) {
      int e = csr[i];
      if (e < E) {
        acc += ea2[(size_t)e * 64 + lane];
        cnt++;
      }
    }
    ea2[((size_t)E + n) * 64 + lane] = acc / fmaxf((float)cnt, 1.f);
  }
}

// ---------------- generic f32 GEMM: C = act(A[M,K]@B[K,Nc] + bias) ----------------
// MODE: 0 none, 2 elu, 3 mix: out = s*(v) + (1-s)*aux[row,col]
template <int MODE>
__global__ __launch_bounds__(256) void gemm_kernel(
    const float* __restrict__ A, const float* __restrict__ B,
    const float* __restrict__ bias, float* __restrict__ C, int M, int K, int Nc,
    const float* __restrict__ aux, const float* __restrict__ alpha_p) {
  __shared__ __align__(16) float As[16][68];
  __shared__ __align__(16) float Bs[16][68];
  int bm = blockIdx.y * 64, bn = blockIdx.x * 64;
  int tid = threadIdx.x;
  int tx = tid & 15, ty = tid >> 4;
  float acc[4][4] = {};
  for (int k0 = 0; k0 < K; k0 += 16) {
#pragma unroll
    for (int i = tid; i < 1024; i += 256) {
      int m = i >> 4, k = i & 15;
      int gm = bm + m;
      As[k][m] = (gm < M) ? A[(size_t)gm * K + k0 + k] : 0.f;
    }
#pragma unroll
    for (int i = tid; i < 1024; i += 256) {
      int k = i >> 6, n = i & 63;
      int gn = bn + n;
      Bs[k][n] = (gn < Nc) ? B[(size_t)(k0 + k) * Nc + gn] : 0.f;
    }
    __syncthreads();
#pragma unroll
    for (int k = 0; k < 16; k++) {
      float4 a4 = *(const float4*)&As[k][ty * 4];
      float4 b4 = *(const float4*)&Bs[k][tx * 4];
      float a[4] = {a4.x, a4.y, a4.z, a4.w};
      float b[4] = {b4.x, b4.y, b4.z, b4.w};
#pragma unroll
      for (int i = 0; i < 4; i++)
#pragma unroll
        for (int j = 0; j < 4; j++) acc[i][j] += a[i] * b[j];
    }
    __syncthreads();
  }
  float s = 0.f;
  if (MODE == 3) s = 1.f / (1.f + __expf(-alpha_p[0]));
#pragma unroll
  for (int i = 0; i < 4; i++) {
    int m = bm + ty * 4 + i;
    if (m >= M) continue;
#pragma unroll
    for (int j = 0; j < 4; j++) {
      int n = bn + tx * 4 + j;
      if (n >= Nc) continue;
      float v = acc[i][j] + bias[n];
      if (MODE == 2) v = v > 0.f ? v : (__expf(v) - 1.f);
      if (MODE == 3) v = s * v + (1.f - s) * aux[(size_t)m * Nc + n];
      C[(size_t)m * Nc + n] = v;
    }
  }
}

// ---------------- GATv2 edge scores (fused ee = ea2@We), 128 columns per launch ----------------
// 8 edges per wave-iteration: the ds_read_b64 of the We pair is shared by all 8
// edges; ea broadcast via v_readlane (VALU pipe, NOT ds_bpermute). LDS reads/edge
// drop 8x vs the 1-edge version -> FMA-dominated inner loop.
template <int C>  // head dim: 32 (layers 1,2) or 64 (layer 3 -> two launches)
__global__ __launch_bounds__(256) void score_kernel(
    const float* __restrict__ ea2, const float* __restrict__ xl,
    const float* __restrict__ xr, const float* __restrict__ We,
    const float* __restrict__ att, const int* __restrict__ src0,
    const int* __restrict__ dst0, float* __restrict__ e_s, int E, int E2,
    int HCfull, int col_off) {
  __shared__ float sWe[64][130];
  __shared__ float sAtt[128];
  for (int i = threadIdx.x; i < 64 * 128; i += 256) {
    int k = i >> 7, cc = i & 127;
    sWe[k][cc] = We[(size_t)k * HCfull + col_off + cc];
  }
  for (int i = threadIdx.x; i < 128; i += 256) sAtt[i] = att[col_off + i];
  __syncthreads();
  int lane = threadIdx.x & 63, wv = threadIdx.x >> 6;
  constexpr int L = C / 2;  // lanes per head
  int c0 = 2 * lane;
  float attA = sAtt[c0], attB = sAtt[c0 + 1];
  int gstride = gridDim.x * 4 * 8;
  for (int base = (blockIdx.x * 4 + wv) * 8; base < E2; base += gstride) {
    float eav[8];
#pragma unroll
    for (int j = 0; j < 8; j++) {
      int e = base + j;
      if (e > E2 - 1) e = E2 - 1;
      eav[j] = ea2[(size_t)e * 64 + lane];  // lane k holds ea[k] of edge j
    }
    float acc0[8] = {}, acc1[8] = {};
#pragma unroll 16
    for (int k = 0; k < 64; k++) {
      float2 w = *(const float2*)&sWe[k][c0];  // one b64 read, shared by 8 edges
#pragma unroll
      for (int j = 0; j < 8; j++) {
        float a = readlane_f(eav[j], k);
        acc0[j] += a * w.x;
        acc1[j] += a * w.y;
      }
    }
#pragma unroll
    for (int j = 0; j < 8; j++) {
      int e = base + j;
      if (e >= E2) break;
      int sn, dn;
      if (e < E) {
        sn = src0[e];
        dn = dst0[e];
      } else {
        sn = dn = e - E;
      }
      float2 xlv = *(const float2*)(xl + (size_t)sn * HCfull + col_off + c0);
      float2 xrv = *(const float2*)(xr + (size_t)dn * HCfull + col_off + c0);
      float mA = xlv.x + xrv.x + acc0[j];
      mA = mA > 0.f ? mA : 0.2f * mA;
      float mB = xlv.y + xrv.y + acc1[j];
      mB = mB > 0.f ? mB : 0.2f * mB;
      float sres = mA * attA + mB * attB;
#pragma unroll
      for (int o = 1; o < L; o <<= 1) sres += __shfl_xor(sres, o);
      if ((lane & (L - 1)) == 0)
        e_s[(size_t)e * 4 + col_off / C + lane / L] = sres;
    }
  }
}

// ---------------- per-node softmax + aggregation + bias + LN + leaky (+skip mix for L1) ----------------
template <int HC, bool L1MODE>
__global__ __launch_bounds__(256) void aggr_kernel(
    const float* __restrict__ e_s, const float* __restrict__ xl,
    const int* __restrict__ rowptr, const int* __restrict__ csr,
    const int* __restrict__ src0, const float* __restrict__ bias,
    const float* __restrict__ lng, const float* __restrict__ lnb,
    float* __restrict__ alpha_out, float* __restrict__ xout,
    float* __restrict__ x1out, const float* __restrict__ skipproj, int N, int E) {
  constexpr int CPL = HC / 64;
  int lane = threadIdx.x & 63, wv = threadIdx.x >> 6;
  int stride = gridDim.x * 4;
  for (int n = blockIdx.x * 4 + wv; n < N; n += stride) {
    int r0 = rowptr[n], r1 = rowptr[n + 1];
    float m0 = -1e30f, m1 = -1e30f, m2 = -1e30f, m3 = -1e30f;
    for (int i = r0 + lane; i < r1; i += 64) {
      int e = csr[i];
      float4 v = *reinterpret_cast<const float4*>(e_s + (size_t)e * 4);
      m0 = fmaxf(m0, v.x);
      m1 = fmaxf(m1, v.y);
      m2 = fmaxf(m2, v.z);
      m3 = fmaxf(m3, v.w);
    }
    m0 = wave_max(m0);
    m1 = wave_max(m1);
    m2 = wave_max(m2);
    m3 = wave_max(m3);
    float d0 = 0.f, d1 = 0.f, d2 = 0.f, d3 = 0.f;
    for (int i = r0 + lane; i < r1; i += 64) {
      int e = csr[i];
      float4 v = *reinterpret_cast<const float4*>(e_s + (size_t)e * 4);
      d0 += __expf(v.x - m0);
      d1 += __expf(v.y - m1);
      d2 += __expf(v.z - m2);
      d3 += __expf(v.w - m3);
    }
    d0 = wave_sum(d0);
    d1 = wave_sum(d1);
    d2 = wave_sum(d2);
    d3 = wave_sum(d3);
    float i0 = 1.f / (d0 + 1e-16f), i1 = 1.f / (d1 + 1e-16f);
    float i2 = 1.f / (d2 + 1e-16f), i3 = 1.f / (d3 + 1e-16f);
    int h = lane >> 4;
    float mh = (h & 2) ? ((h & 1) ? m3 : m2) : ((h & 1) ? m1 : m0);
    float ih = (h & 2) ? ((h & 1) ? i3 : i2) : ((h & 1) ? i1 : i0);
    float acc[CPL];
#pragma unroll
    for (int j = 0; j < CPL; j++) acc[j] = 0.f;
    int c0 = lane * CPL;
    for (int i = r0; i < r1; i++) {
      int e = csr[i];
      int sn = (e < E) ? src0[e] : (e - E);
      float a = __expf(e_s[(size_t)e * 4 + h] - mh) * ih;
      if ((lane & 15) == 0) alpha_out[(size_t)e * 4 + h] = a;
      const float* xp = xl + (size_t)sn * HC + c0;
      if constexpr (CPL == 2) {
        float2 t = *(const float2*)xp;
        acc[0] += a * t.x;
        acc[1] += a * t.y;
      } else {
        float4 t = *(const float4*)xp;
        acc[0] += a * t.x;
        acc[1] += a * t.y;
        acc[2] += a * t.z;
        acc[3] += a * t.w;
      }
    }
    float vals[CPL];
    float vs = 0.f, vq = 0.f;
#pragma unroll
    for (int j = 0; j < CPL; j++) {
      float t = acc[j] + bias[c0 + j];
      vals[j] = t;
      vs += t;
      vq += t * t;
    }
    vs = wave_sum(vs);
    vq = wave_sum(vq);
    float mean = vs * (1.f / HC);
    float var = vq * (1.f / HC) - mean * mean;
    float rstd = rsqrtf(fmaxf(var, 0.f) + 1e-5f);
#pragma unroll
    for (int j = 0; j < CPL; j++) {
      int c = c0 + j;
      float y = (vals[j] - mean) * rstd * lng[c] + lnb[c];
      y = leakyf(y, 0.01f);
      if constexpr (L1MODE) {
        x1out[(size_t)n * HC + c] = y;
        xout[(size_t)n * HC + c] = 0.01f * skipproj[(size_t)n * HC + c] + y;
      } else {
        xout[(size_t)n * HC + c] = y;
      }
    }
  }
}

extern "C" void kernel_launch(void* const* d_in, const int* in_sizes, int n_in,
                              void* d_out, int out_size, void* d_ws, size_t ws_size,
                              hipStream_t stream) {
  (void)n_in;
  (void)out_size;
  (void)ws_size;
  const float* x_in = (const float*)d_in[0];
  const int* edge_index = (const int*)d_in[1];
  const float* edge_attr = (const float*)d_in[2];
  const float* bn0_g = (const float*)d_in[3];
  const float* bn0_b = (const float*)d_in[4];
  const float* bn0_m = (const float*)d_in[5];
  const float* bn0_v = (const float*)d_in[6];
  const float* eeW1 = (const float*)d_in[7];
  const float* eeb1 = (const float*)d_in[8];
  const float* eeW2 = (const float*)d_in[9];
  const float* eeb2 = (const float*)d_in[10];
  const float* g1_Wl = (const float*)d_in[11];
  const float* g1_bl = (const float*)d_in[12];
  const float* g1_Wr = (const float*)d_in[13];
  const float* g1_br = (const float*)d_in[14];
  const float* g1_We = (const float*)d_in[15];
  const float* g1_att = (const float*)d_in[16];
  const float* g1_bias = (const float*)d_in[17];
  const float* g2_Wl = (const float*)d_in[18];
  const float* g2_bl = (const float*)d_in[19];
  const float* g2_Wr = (const float*)d_in[20];
  const float* g2_br = (const float*)d_in[21];
  const float* g2_We = (const float*)d_in[22];
  const float* g2_att = (const float*)d_in[23];
  const float* g2_bias = (const float*)d_in[24];
  const float* g3_Wl = (const float*)d_in[25];
  const float* g3_bl = (const float*)d_in[26];
  const float* g3_Wr = (const float*)d_in[27];
  const float* g3_br = (const float*)d_in[28];
  const float* g3_We = (const float*)d_in[29];
  const float* g3_att = (const float*)d_in[30];
  const float* g3_bias = (const float*)d_in[31];
  const float* ln1_g = (const float*)d_in[32];
  const float* ln1_b = (const float*)d_in[33];
  const float* ln2_g = (const float*)d_in[34];
  const float* ln2_b = (const float*)d_in[35];
  const float* ln3_g = (const float*)d_in[36];
  const float* ln3_b = (const float*)d_in[37];
  const float* skip_W = (const float*)d_in[38];
  const float* skip_b = (const float*)d_in[39];
  const float* alpha_p = (const float*)d_in[40];
  const float* fp_W = (const float*)d_in[41];
  const float* fp_b = (const float*)d_in[42];
  const float* np_W1 = (const float*)d_in[43];
  const float* np_b1 = (const float*)d_in[44];
  const float* np_W2 = (const float*)d_in[45];
  const float* np_b2 = (const float*)d_in[46];
  const float* np_W3 = (const float*)d_in[47];
  const float* np_b3 = (const float*)d_in[48];

  const int N = in_sizes[0] / 64;
  const int E = in_sizes[2] / 16;
  const int E2 = E + N;
  const int* src0 = edge_index;
  const int* dst0 = edge_index + E;

  float* ws = (float*)d_ws;
  size_t off = 0;
  float* x = ws + off;         off += (size_t)N * 64;
  float* ea2 = ws + off;       off += (size_t)E2 * 64;
  float* xl = ws + off;        off += (size_t)N * 256;
  float* xr = ws + off;        off += (size_t)N * 256;
  float* skipproj = ws + off;  off += (size_t)N * 128;  // reused as h1 at the end
  float* x1 = ws + off;        off += (size_t)N * 128;
  float* skip1 = ws + off;     off += (size_t)N * 128;
  float* x2 = ws + off;        off += (size_t)N * 128;
  float* x3 = ws + off;        off += (size_t)N * 256;
  float* e_s = ws + off;       off += (size_t)E2 * 4;
  float* h2 = ws + off;        off += (size_t)N * 64;
  int* counts = (int*)(ws + off);
  int* rowptr = counts + N;
  int* fill = rowptr + N + 1;
  int* csr = fill + N;

  float* out = (float*)d_out;
  float* xf = out;
  float* npout = out + (size_t)N * 256;
  float* a1 = npout + N;
  float* a2 = a1 + (size_t)E2 * 4;
  float* a3 = a2 + (size_t)E2 * 4;

  hipMemsetAsync(counts, 0, (size_t)N * sizeof(int), stream);
  bn_kernel<<<(N * 64 + 255) / 256, 256, 0, stream>>>(x_in, bn0_g, bn0_b, bn0_m, bn0_v, x, N * 64);
  edge_enc_kernel<<<(E + 63) / 64, 256, 0, stream>>>(edge_attr, eeW1, eeb1, eeW2, eeb2, ea2, E);
  count_kernel<<<(E2 + 255) / 256, 256, 0, stream>>>(dst0, counts, E, E2);
  scan_kernel<<<1, 256, 0, stream>>>(counts, rowptr, fill, N);
  fill_kernel<<<(E2 + 255) / 256, 256, 0, stream>>>(dst0, fill, csr, E, E2);
  loopattr_kernel<<<(N + 3) / 4, 256, 0, stream>>>(ea2, rowptr, csr, N, E);

  auto gemm = [&](int mode, const float* A, const float* B, const float* bias,
                  float* Cp, int M, int K, int Nc, const float* aux) {
    dim3 g((Nc + 63) / 64, (M + 63) / 64);
    switch (mode) {
      case 0: gemm_kernel<0><<<g, 256, 0, stream>>>(A, B, bias, Cp, M, K, Nc, nullptr, nullptr); break;
      case 2: gemm_kernel<2><<<g, 256, 0, stream>>>(A, B, bias, Cp, M, K, Nc, nullptr, nullptr); break;
      case 3: gemm_kernel<3><<<g, 256, 0, stream>>>(A, B, bias, Cp, M, K, Nc, aux, alpha_p); break;
    }
  };

  const int nblk_node = (N + 3) / 4;

  // ---- Layer 1 (din=64, HC=128, C=32) ----
  gemm(0, x, g1_Wl, g1_bl, xl, N, 64, 128, nullptr);
  gemm(0, x, g1_Wr, g1_br, xr, N, 64, 128, nullptr);
  gemm(0, x, skip_W, skip_b, skipproj, N, 64, 128, nullptr);
  score_kernel<32><<<2048, 256, 0, stream>>>(ea2, xl, xr, g1_We, g1_att, src0, dst0, e_s, E, E2, 128, 0);
  aggr_kernel<128, true><<<nblk_node, 256, 0, stream>>>(e_s, xl, rowptr, csr, src0, g1_bias, ln1_g, ln1_b,
                                                        a1, skip1, x1, skipproj, N, E);
  // ---- Layer 2 (din=128, HC=128, C=32) ----
  gemm(0, skip1, g2_Wl, g2_bl, xl, N, 128, 128, nullptr);
  gemm(0, skip1, g2_Wr, g2_br, xr, N, 128, 128, nullptr);
  score_kernel<32><<<2048, 256, 0, stream>>>(ea2, xl, xr, g2_We, g2_att, src0, dst0, e_s, E, E2, 128, 0);
  aggr_kernel<128, false><<<nblk_node, 256, 0, stream>>>(e_s, xl, rowptr, csr, src0, g2_bias, ln2_g, ln2_b,
                                                         a2, x2, nullptr, nullptr, N, E);
  // ---- Layer 3 (din=128, HC=256, C=64) ----
  gemm(0, x2, g3_Wl, g3_bl, xl, N, 128, 256, nullptr);
  gemm(0, x2, g3_Wr, g3_br, xr, N, 128, 256, nullptr);
  score_kernel<64><<<2048, 256, 0, stream>>>(ea2, xl, xr, g3_We, g3_att, src0, dst0, e_s, E, E2, 256, 0);
  score_kernel<64><<<2048, 256, 0, stream>>>(ea2, xl, xr, g3_We, g3_att, src0, dst0, e_s, E, E2, 256, 128);
  aggr_kernel<256, false><<<nblk_node, 256, 0, stream>>>(e_s, xl, rowptr, csr, src0, g3_bias, ln3_g, ln3_b,
                                                         a3, x3, nullptr, nullptr, N, E);
  // ---- Final: xf = s*(x1@fp_W+fp_b) + (1-s)*x3 ; node MLP ----
  gemm(3, x1, fp_W, fp_b, xf, N, 128, 256, x3);
  gemm(2, xf, np_W1, np_b1, skipproj, N, 256, 128, nullptr);   // h1
  gemm(2, skipproj, np_W2, np_b2, h2, N, 128, 64, nullptr);    // h2
  gemm(0, h2, np_W3, np_b3, npout, N, 64, 1, nullptr);
}

// Round 7
// 961.046 us; speedup vs baseline: 2.6874x; 1.5089x over previous
//
#include <hip/hip_runtime.h>
#include <math.h>

#define DEV __device__ __forceinline__

typedef __attribute__((ext_vector_type(8))) short bf16x8;
typedef __attribute__((ext_vector_type(4))) float f32x4;

DEV float leakyf(float x, float s) { return x > 0.f ? x : s * x; }

DEV unsigned short f2bf(float f) {
  unsigned u = __float_as_uint(f);
  unsigned r = (u + 0x7fff + ((u >> 16) & 1)) >> 16;
  return (unsigned short)r;
}
DEV float bf2f(unsigned short h) { return __uint_as_float((unsigned)h << 16); }

DEV float wave_sum(float v) {
#pragma unroll
  for (int o = 1; o < 64; o <<= 1) v += __shfl_xor(v, o);
  return v;
}
DEV float wave_max(float v) {
#pragma unroll
  for (int o = 1; o < 64; o <<= 1) v = fmaxf(v, __shfl_xor(v, o));
  return v;
}

// ---------------- BatchNorm (eval) ----------------
__global__ __launch_bounds__(256) void bn_kernel(
    const float* __restrict__ xin, const float* __restrict__ g,
    const float* __restrict__ b, const float* __restrict__ m,
    const float* __restrict__ v, float* __restrict__ xout, int total) {
  int i = blockIdx.x * 256 + threadIdx.x;
  if (i < total) {
    int c = i & 63;
    xout[i] = (xin[i] - m[c]) * rsqrtf(v[c] + 1e-5f) * g[c] + b[c];
  }
}

// ---------------- Edge encoder: tiled fused 2-layer MLP + L2 norm -> bf16 out ----------------
__global__ __launch_bounds__(256) void edge_enc_kernel(
    const float* __restrict__ edge_attr, const float* __restrict__ W1,
    const float* __restrict__ b1, const float* __restrict__ W2,
    const float* __restrict__ b2, unsigned short* __restrict__ ea_bf, int E) {
  __shared__ float sW1[16][128];
  __shared__ float sW2[128][64];
  __shared__ float sb1[128];
  __shared__ float sb2[64];
  __shared__ float sAttr[64][18];
  __shared__ float sEa1[64][132];
  int tid = threadIdx.x;
  for (int i = tid; i < 16 * 128; i += 256) sW1[i >> 7][i & 127] = W1[i];
  for (int i = tid; i < 128 * 64; i += 256) sW2[i >> 6][i & 63] = W2[i];
  if (tid < 128) sb1[tid] = b1[tid];
  if (tid < 64) sb2[tid] = b2[tid];
  int e0 = blockIdx.x * 64;
  {
    int r = tid >> 2, c = (tid & 3) * 4;
    int e = e0 + r;
    float4 v = (e < E) ? *(const float4*)(edge_attr + (size_t)e * 16 + c)
                       : make_float4(0.f, 0.f, 0.f, 0.f);
    sAttr[r][c] = v.x;
    sAttr[r][c + 1] = v.y;
    sAttr[r][c + 2] = v.z;
    sAttr[r][c + 3] = v.w;
  }
  __syncthreads();
  int tx = tid & 15, ty = tid >> 4;
  float acc1[4][8] = {};
#pragma unroll
  for (int k = 0; k < 16; k++) {
    float a[4];
#pragma unroll
    for (int i = 0; i < 4; i++) a[i] = sAttr[ty * 4 + i][k];
    float4 w0 = *(const float4*)&sW1[k][tx * 8];
    float4 w1 = *(const float4*)&sW1[k][tx * 8 + 4];
    float w[8] = {w0.x, w0.y, w0.z, w0.w, w1.x, w1.y, w1.z, w1.w};
#pragma unroll
    for (int i = 0; i < 4; i++)
#pragma unroll
      for (int j = 0; j < 8; j++) acc1[i][j] += a[i] * w[j];
  }
#pragma unroll
  for (int i = 0; i < 4; i++) {
    int r = ty * 4 + i;
    int c = tx * 8;
    float4 v0, v1;
    v0.x = leakyf(acc1[i][0] + sb1[c + 0], 0.01f);
    v0.y = leakyf(acc1[i][1] + sb1[c + 1], 0.01f);
    v0.z = leakyf(acc1[i][2] + sb1[c + 2], 0.01f);
    v0.w = leakyf(acc1[i][3] + sb1[c + 3], 0.01f);
    v1.x = leakyf(acc1[i][4] + sb1[c + 4], 0.01f);
    v1.y = leakyf(acc1[i][5] + sb1[c + 5], 0.01f);
    v1.z = leakyf(acc1[i][6] + sb1[c + 6], 0.01f);
    v1.w = leakyf(acc1[i][7] + sb1[c + 7], 0.01f);
    *(float4*)&sEa1[r][c] = v0;
    *(float4*)&sEa1[r][c + 4] = v1;
  }
  float acc2[4][4] = {};
  for (int k4 = 0; k4 < 128; k4 += 4) {
    float4 eav[4];
#pragma unroll
    for (int i = 0; i < 4; i++) eav[i] = *(const float4*)&sEa1[ty * 4 + i][k4];
#pragma unroll
    for (int kk = 0; kk < 4; kk++) {
      float4 wv = *(const float4*)&sW2[k4 + kk][tx * 4];
      float w[4] = {wv.x, wv.y, wv.z, wv.w};
      float a0 = (&eav[0].x)[kk];
      float a1 = (&eav[1].x)[kk];
      float a2 = (&eav[2].x)[kk];
      float a3 = (&eav[3].x)[kk];
#pragma unroll
      for (int j = 0; j < 4; j++) {
        acc2[0][j] += a0 * w[j];
        acc2[1][j] += a1 * w[j];
        acc2[2][j] += a2 * w[j];
        acc2[3][j] += a3 * w[j];
      }
    }
  }
#pragma unroll
  for (int i = 0; i < 4; i++) {
    float vout[4];
    float p = 0.f;
#pragma unroll
    for (int j = 0; j < 4; j++) {
      float t = leakyf(acc2[i][j] + sb2[tx * 4 + j], 0.01f);
      vout[j] = t;
      p += t * t;
    }
#pragma unroll
    for (int o = 1; o < 16; o <<= 1) p += __shfl_xor(p, o);
    float sc = 1.f / fmaxf(sqrtf(p), 1e-12f);
    int e = e0 + ty * 4 + i;
    if (e < E) {
      ushort4 w4;
      w4.x = f2bf(vout[0] * sc);
      w4.y = f2bf(vout[1] * sc);
      w4.z = f2bf(vout[2] * sc);
      w4.w = f2bf(vout[3] * sc);
      *(ushort4*)(ea_bf + (size_t)e * 64 + tx * 4) = w4;
    }
  }
}

// ---------------- CSR build ----------------
__global__ __launch_bounds__(256) void count_kernel(const int* __restrict__ dst0,
                                                    int* __restrict__ counts, int E, int E2) {
  int i = blockIdx.x * 256 + threadIdx.x;
  if (i < E2) {
    int d = (i < E) ? dst0[i] : (i - E);
    atomicAdd(&counts[d], 1);
  }
}

__global__ __launch_bounds__(256) void scan_kernel(const int* __restrict__ counts,
                                                   int* __restrict__ rowptr,
                                                   int* __restrict__ fill, int N) {
  __shared__ int part[256];
  int tid = threadIdx.x;
  int chunk = (N + 255) / 256;
  int lo = tid * chunk, hi = lo + chunk;
  if (hi > N) hi = N;
  if (lo > N) lo = N;
  int s = 0;
  for (int i = lo; i < hi; i++) s += counts[i];
  part[tid] = s;
  __syncthreads();
  if (tid == 0) {
    int run = 0;
    for (int i = 0; i < 256; i++) {
      int t = part[i];
      part[i] = run;
      run += t;
    }
    rowptr[N] = run;
  }
  __syncthreads();
  int off = part[tid];
  for (int i = lo; i < hi; i++) {
    rowptr[i] = off;
    fill[i] = off;
    off += counts[i];
  }
}

__global__ __launch_bounds__(256) void fill_kernel(const int* __restrict__ dst0,
                                                   int* __restrict__ fill,
                                                   int* __restrict__ csr, int E, int E2) {
  int i = blockIdx.x * 256 + threadIdx.x;
  if (i < E2) {
    int d = (i < E) ? dst0[i] : (i - E);
    int pos = atomicAdd(&fill[d], 1);
    csr[pos] = i;
  }
}

// ---------------- self-loop attr = mean of incoming encoded attrs (bf16 in/out) ----------------
__global__ __launch_bounds__(256) void loopattr_kernel(unsigned short* __restrict__ ea_bf,
                                                       const int* __restrict__ rowptr,
                                                       const int* __restrict__ csr, int N, int E) {
  int lane = threadIdx.x & 63, wv = threadIdx.x >> 6;
  int stride = gridDim.x * 4;
  for (int n = blockIdx.x * 4 + wv; n < N; n += stride) {
    int r0 = rowptr[n], r1 = rowptr[n + 1];
    float acc = 0.f;
    int cnt = 0;
    for (int i = r0; i < r1; i++) {
      int e = csr[i];
      if (e < E) {
        acc += bf2f(ea_bf[(size_t)e * 64 + lane]);
        cnt++;
      }
    }
    ea_bf[((size_t)E + n) * 64 + lane] = f2bf(acc / fmaxf((float)cnt, 1.f));
  }
}

// ---------------- generic f32 GEMM: C = act(A[M,K]@B[K,Nc] + bias) ----------------
// MODE: 0 none, 2 elu, 3 mix: out = s*(v) + (1-s)*aux[row,col]
template <int MODE>
__global__ __launch_bounds__(256) void gemm_kernel(
    const float* __restrict__ A, const float* __restrict__ B,
    const float* __restrict__ bias, float* __restrict__ C, int M, int K, int Nc,
    const float* __restrict__ aux, const float* __restrict__ alpha_p) {
  __shared__ __align__(16) float As[16][68];
  __shared__ __align__(16) float Bs[16][68];
  int bm = blockIdx.y * 64, bn = blockIdx.x * 64;
  int tid = threadIdx.x;
  int tx = tid & 15, ty = tid >> 4;
  float acc[4][4] = {};
  for (int k0 = 0; k0 < K; k0 += 16) {
#pragma unroll
    for (int i = tid; i < 1024; i += 256) {
      int m = i >> 4, k = i & 15;
      int gm = bm + m;
      As[k][m] = (gm < M) ? A[(size_t)gm * K + k0 + k] : 0.f;
    }
#pragma unroll
    for (int i = tid; i < 1024; i += 256) {
      int k = i >> 6, n = i & 63;
      int gn = bn + n;
      Bs[k][n] = (gn < Nc) ? B[(size_t)(k0 + k) * Nc + gn] : 0.f;
    }
    __syncthreads();
#pragma unroll
    for (int k = 0; k < 16; k++) {
      float4 a4 = *(const float4*)&As[k][ty * 4];
      float4 b4 = *(const float4*)&Bs[k][tx * 4];
      float a[4] = {a4.x, a4.y, a4.z, a4.w};
      float b[4] = {b4.x, b4.y, b4.z, b4.w};
#pragma unroll
      for (int i = 0; i < 4; i++)
#pragma unroll
        for (int j = 0; j < 4; j++) acc[i][j] += a[i] * b[j];
    }
    __syncthreads();
  }
  float s = 0.f;
  if (MODE == 3) s = 1.f / (1.f + __expf(-alpha_p[0]));
#pragma unroll
  for (int i = 0; i < 4; i++) {
    int m = bm + ty * 4 + i;
    if (m >= M) continue;
#pragma unroll
    for (int j = 0; j < 4; j++) {
      int n = bn + tx * 4 + j;
      if (n >= Nc) continue;
      float v = acc[i][j] + bias[n];
      if (MODE == 2) v = v > 0.f ? v : (__expf(v) - 1.f);
      if (MODE == 3) v = s * v + (1.f - s) * aux[(size_t)m * Nc + n];
      C[(size_t)m * Nc + n] = v;
    }
  }
}

// ---------------- GATv2 edge scores via MFMA ----------------
// One wave per 16-edge tile; We held as bf16 B-fragments in VGPRs (built once);
// ee tile = ea_bf[16x64] @ We[64x128] via 16x mfma_f32_16x16x32_bf16 (8 col-tiles, 2 K-chunks).
// Fragment layouts (m89-verified family): A: row=lane&15, k=8*(lane>>4)+j;
// B: col=lane&15, k=8*(lane>>4)+j; D: col=lane&15, row=(lane>>4)*4+reg.
// Epilogue: e = att . leaky(xl[src]+xr[dst]+ee, 0.2), 16-lane shfl reduce per head.
template <int C>  // head dim: 32 (layers 1,2) or 64 (layer 3 -> two launches)
__global__ __launch_bounds__(256) void score_mfma_kernel(
    const unsigned short* __restrict__ ea_bf, const float* __restrict__ xl,
    const float* __restrict__ xr, const float* __restrict__ We,
    const float* __restrict__ att, const int* __restrict__ src0,
    const int* __restrict__ dst0, float* __restrict__ e_s, int E, int E2,
    int HCfull, int col_off) {
  int lane = threadIdx.x & 63;
  int wv = threadIdx.x >> 6;
  int g = lane >> 4, q = lane & 15;
  // B fragments: 8 col-tiles x 2 K-chunks, each lane holds 8 bf16
  bf16x8 bfrag[8][2];
#pragma unroll
  for (int t = 0; t < 8; t++)
#pragma unroll
    for (int kc = 0; kc < 2; kc++) {
      bf16x8 bv;
#pragma unroll
      for (int j = 0; j < 8; j++) {
        int k = kc * 32 + g * 8 + j;
        bv[j] = (short)f2bf(We[(size_t)k * HCfull + col_off + 16 * t + q]);
      }
      bfrag[t][kc] = bv;
    }
  float attv[8];
#pragma unroll
  for (int t = 0; t < 8; t++) attv[t] = att[col_off + 16 * t + q];

  constexpr int TPH = C / 16;   // col-tiles per head
  constexpr int NH = 8 / TPH;   // heads in this launch
  const int headbase = col_off / C;

  int tiles = (E2 + 15) / 16;
  int nw = gridDim.x * 4;
  for (int tile = blockIdx.x * 4 + wv; tile < tiles; tile += nw) {
    int e0 = tile * 16;
    int erow = e0 + q;
    if (erow >= E2) erow = E2 - 1;
    const unsigned short* ap = ea_bf + (size_t)erow * 64 + g * 8;
    bf16x8 a0 = *(const bf16x8*)(ap);
    bf16x8 a1 = *(const bf16x8*)(ap + 32);
    f32x4 acc[8];
#pragma unroll
    for (int t = 0; t < 8; t++) acc[t] = (f32x4){0.f, 0.f, 0.f, 0.f};
#pragma unroll
    for (int t = 0; t < 8; t++) {
      acc[t] = __builtin_amdgcn_mfma_f32_16x16x32_bf16(a0, bfrag[t][0], acc[t], 0, 0, 0);
      acc[t] = __builtin_amdgcn_mfma_f32_16x16x32_bf16(a1, bfrag[t][1], acc[t], 0, 0, 0);
    }
    // epilogue: this lane's accum rows are edges e0 + g*4 + r, col = col_off+16t+q
    int sn[4], dn[4];
#pragma unroll
    for (int r = 0; r < 4; r++) {
      int e = e0 + g * 4 + r;
      if (e >= E2) e = E2 - 1;
      if (e < E) {
        sn[r] = src0[e];
        dn[r] = dst0[e];
      } else {
        sn[r] = dn[r] = e - E;
      }
    }
    float p[NH][4];
#pragma unroll
    for (int hh = 0; hh < NH; hh++)
#pragma unroll
      for (int r = 0; r < 4; r++) p[hh][r] = 0.f;
#pragma unroll
    for (int t = 0; t < 8; t++) {
      int col = col_off + 16 * t + q;
#pragma unroll
      for (int r = 0; r < 4; r++) {
        float xv = xl[(size_t)sn[r] * HCfull + col] + xr[(size_t)dn[r] * HCfull + col] + acc[t][r];
        xv = xv > 0.f ? xv : 0.2f * xv;
        p[t / TPH][r] += xv * attv[t];
      }
    }
#pragma unroll
    for (int hh = 0; hh < NH; hh++)
#pragma unroll
      for (int r = 0; r < 4; r++) {
#pragma unroll
        for (int o = 1; o < 16; o <<= 1) p[hh][r] += __shfl_xor(p[hh][r], o);
      }
    if (q == 0) {
#pragma unroll
      for (int r = 0; r < 4; r++) {
        int e = e0 + g * 4 + r;
        if (e < E2) {
#pragma unroll
          for (int hh = 0; hh < NH; hh++)
            e_s[(size_t)e * 4 + headbase + hh] = p[hh][r];
        }
      }
    }
  }
}

// ---------------- per-node softmax + aggregation + bias + LN + leaky (+skip mix for L1) ----------------
template <int HC, bool L1MODE>
__global__ __launch_bounds__(256) void aggr_kernel(
    const float* __restrict__ e_s, const float* __restrict__ xl,
    const int* __restrict__ rowptr, const int* __restrict__ csr,
    const int* __restrict__ src0, const float* __restrict__ bias,
    const float* __restrict__ lng, const float* __restrict__ lnb,
    float* __restrict__ alpha_out, float* __restrict__ xout,
    float* __restrict__ x1out, const float* __restrict__ skipproj, int N, int E) {
  constexpr int CPL = HC / 64;
  int lane = threadIdx.x & 63, wv = threadIdx.x >> 6;
  int stride = gridDim.x * 4;
  for (int n = blockIdx.x * 4 + wv; n < N; n += stride) {
    int r0 = rowptr[n], r1 = rowptr[n + 1];
    float m0 = -1e30f, m1 = -1e30f, m2 = -1e30f, m3 = -1e30f;
    for (int i = r0 + lane; i < r1; i += 64) {
      int e = csr[i];
      float4 v = *reinterpret_cast<const float4*>(e_s + (size_t)e * 4);
      m0 = fmaxf(m0, v.x);
      m1 = fmaxf(m1, v.y);
      m2 = fmaxf(m2, v.z);
      m3 = fmaxf(m3, v.w);
    }
    m0 = wave_max(m0);
    m1 = wave_max(m1);
    m2 = wave_max(m2);
    m3 = wave_max(m3);
    float d0 = 0.f, d1 = 0.f, d2 = 0.f, d3 = 0.f;
    for (int i = r0 + lane; i < r1; i += 64) {
      int e = csr[i];
      float4 v = *reinterpret_cast<const float4*>(e_s + (size_t)e * 4);
      d0 += __expf(v.x - m0);
      d1 += __expf(v.y - m1);
      d2 += __expf(v.z - m2);
      d3 += __expf(v.w - m3);
    }
    d0 = wave_sum(d0);
    d1 = wave_sum(d1);
    d2 = wave_sum(d2);
    d3 = wave_sum(d3);
    float i0 = 1.f / (d0 + 1e-16f), i1 = 1.f / (d1 + 1e-16f);
    float i2 = 1.f / (d2 + 1e-16f), i3 = 1.f / (d3 + 1e-16f);
    int h = lane >> 4;
    float mh = (h & 2) ? ((h & 1) ? m3 : m2) : ((h & 1) ? m1 : m0);
    float ih = (h & 2) ? ((h & 1) ? i3 : i2) : ((h & 1) ? i1 : i0);
    float acc[CPL];
#pragma unroll
    for (int j = 0; j < CPL; j++) acc[j] = 0.f;
    int c0 = lane * CPL;
    for (int i = r0; i < r1; i++) {
      int e = csr[i];
      int sn = (e < E) ? src0[e] : (e - E);
      float a = __expf(e_s[(size_t)e * 4 + h] - mh) * ih;
      if ((lane & 15) == 0) alpha_out[(size_t)e * 4 + h] = a;
      const float* xp = xl + (size_t)sn * HC + c0;
      if constexpr (CPL == 2) {
        float2 t = *(const float2*)xp;
        acc[0] += a * t.x;
        acc[1] += a * t.y;
      } else {
        float4 t = *(const float4*)xp;
        acc[0] += a * t.x;
        acc[1] += a * t.y;
        acc[2] += a * t.z;
        acc[3] += a * t.w;
      }
    }
    float vals[CPL];
    float vs = 0.f, vq = 0.f;
#pragma unroll
    for (int j = 0; j < CPL; j++) {
      float t = acc[j] + bias[c0 + j];
      vals[j] = t;
      vs += t;
      vq += t * t;
    }
    vs = wave_sum(vs);
    vq = wave_sum(vq);
    float mean = vs * (1.f / HC);
    float var = vq * (1.f / HC) - mean * mean;
    float rstd = rsqrtf(fmaxf(var, 0.f) + 1e-5f);
#pragma unroll
    for (int j = 0; j < CPL; j++) {
      int c = c0 + j;
      float y = (vals[j] - mean) * rstd * lng[c] + lnb[c];
      y = leakyf(y, 0.01f);
      if constexpr (L1MODE) {
        x1out[(size_t)n * HC + c] = y;
        xout[(size_t)n * HC + c] = 0.01f * skipproj[(size_t)n * HC + c] + y;
      } else {
        xout[(size_t)n * HC + c] = y;
      }
    }
  }
}

extern "C" void kernel_launch(void* const* d_in, const int* in_sizes, int n_in,
                              void* d_out, int out_size, void* d_ws, size_t ws_size,
                              hipStream_t stream) {
  (void)n_in;
  (void)out_size;
  (void)ws_size;
  const float* x_in = (const float*)d_in[0];
  const int* edge_index = (const int*)d_in[1];
  const float* edge_attr = (const float*)d_in[2];
  const float* bn0_g = (const float*)d_in[3];
  const float* bn0_b = (const float*)d_in[4];
  const float* bn0_m = (const float*)d_in[5];
  const float* bn0_v = (const float*)d_in[6];
  const float* eeW1 = (const float*)d_in[7];
  const float* eeb1 = (const float*)d_in[8];
  const float* eeW2 = (const float*)d_in[9];
  const float* eeb2 = (const float*)d_in[10];
  const float* g1_Wl = (const float*)d_in[11];
  const float* g1_bl = (const float*)d_in[12];
  const float* g1_Wr = (const float*)d_in[13];
  const float* g1_br = (const float*)d_in[14];
  const float* g1_We = (const float*)d_in[15];
  const float* g1_att = (const float*)d_in[16];
  const float* g1_bias = (const float*)d_in[17];
  const float* g2_Wl = (const float*)d_in[18];
  const float* g2_bl = (const float*)d_in[19];
  const float* g2_Wr = (const float*)d_in[20];
  const float* g2_br = (const float*)d_in[21];
  const float* g2_We = (const float*)d_in[22];
  const float* g2_att = (const float*)d_in[23];
  const float* g2_bias = (const float*)d_in[24];
  const float* g3_Wl = (const float*)d_in[25];
  const float* g3_bl = (const float*)d_in[26];
  const float* g3_Wr = (const float*)d_in[27];
  const float* g3_br = (const float*)d_in[28];
  const float* g3_We = (const float*)d_in[29];
  const float* g3_att = (const float*)d_in[30];
  const float* g3_bias = (const float*)d_in[31];
  const float* ln1_g = (const float*)d_in[32];
  const float* ln1_b = (const float*)d_in[33];
  const float* ln2_g = (const float*)d_in[34];
  const float* ln2_b = (const float*)d_in[35];
  const float* ln3_g = (const float*)d_in[36];
  const float* ln3_b = (const float*)d_in[37];
  const float* skip_W = (const float*)d_in[38];
  const float* skip_b = (const float*)d_in[39];
  const float* alpha_p = (const float*)d_in[40];
  const float* fp_W = (const float*)d_in[41];
  const float* fp_b = (const float*)d_in[42];
  const float* np_W1 = (const float*)d_in[43];
  const float* np_b1 = (const float*)d_in[44];
  const float* np_W2 = (const float*)d_in[45];
  const float* np_b2 = (const float*)d_in[46];
  const float* np_W3 = (const float*)d_in[47];
  const float* np_b3 = (const float*)d_in[48];

  const int N = in_sizes[0] / 64;
  const int E = in_sizes[2] / 16;
  const int E2 = E + N;
  const int* src0 = edge_index;
  const int* dst0 = edge_index + E;

  float* ws = (float*)d_ws;
  size_t off = 0;
  float* x = ws + off;         off += (size_t)N * 64;
  unsigned short* ea_bf = (unsigned short*)(ws + off); off += (size_t)E2 * 32;  // bf16 [E2][64]
  float* xl = ws + off;        off += (size_t)N * 256;
  float* xr = ws + off;        off += (size_t)N * 256;
  float* skipproj = ws + off;  off += (size_t)N * 128;  // reused as h1 at the end
  float* x1 = ws + off;        off += (size_t)N * 128;
  float* skip1 = ws + off;     off += (size_t)N * 128;
  float* x2 = ws + off;        off += (size_t)N * 128;
  float* x3 = ws + off;        off += (size_t)N * 256;
  float* e_s = ws + off;       off += (size_t)E2 * 4;
  float* h2 = ws + off;        off += (size_t)N * 64;
  int* counts = (int*)(ws + off);
  int* rowptr = counts + N;
  int* fill = rowptr + N + 1;
  int* csr = fill + N;

  float* out = (float*)d_out;
  float* xf = out;
  float* npout = out + (size_t)N * 256;
  float* a1 = npout + N;
  float* a2 = a1 + (size_t)E2 * 4;
  float* a3 = a2 + (size_t)E2 * 4;

  hipMemsetAsync(counts, 0, (size_t)N * sizeof(int), stream);
  bn_kernel<<<(N * 64 + 255) / 256, 256, 0, stream>>>(x_in, bn0_g, bn0_b, bn0_m, bn0_v, x, N * 64);
  edge_enc_kernel<<<(E + 63) / 64, 256, 0, stream>>>(edge_attr, eeW1, eeb1, eeW2, eeb2, ea_bf, E);
  count_kernel<<<(E2 + 255) / 256, 256, 0, stream>>>(dst0, counts, E, E2);
  scan_kernel<<<1, 256, 0, stream>>>(counts, rowptr, fill, N);
  fill_kernel<<<(E2 + 255) / 256, 256, 0, stream>>>(dst0, fill, csr, E, E2);
  loopattr_kernel<<<(N + 3) / 4, 256, 0, stream>>>(ea_bf, rowptr, csr, N, E);

  auto gemm = [&](int mode, const float* A, const float* B, const float* bias,
                  float* Cp, int M, int K, int Nc, const float* aux) {
    dim3 g((Nc + 63) / 64, (M + 63) / 64);
    switch (mode) {
      case 0: gemm_kernel<0><<<g, 256, 0, stream>>>(A, B, bias, Cp, M, K, Nc, nullptr, nullptr); break;
      case 2: gemm_kernel<2><<<g, 256, 0, stream>>>(A, B, bias, Cp, M, K, Nc, nullptr, nullptr); break;
      case 3: gemm_kernel<3><<<g, 256, 0, stream>>>(A, B, bias, Cp, M, K, Nc, aux, alpha_p); break;
    }
  };

  const int nblk_node = (N + 3) / 4;
  const int score_blocks = 1024;

  // ---- Layer 1 (din=64, HC=128, C=32) ----
  gemm(0, x, g1_Wl, g1_bl, xl, N, 64, 128, nullptr);
  gemm(0, x, g1_Wr, g1_br, xr, N, 64, 128, nullptr);
  gemm(0, x, skip_W, skip_b, skipproj, N, 64, 128, nullptr);
  score_mfma_kernel<32><<<score_blocks, 256, 0, stream>>>(ea_bf, xl, xr, g1_We, g1_att, src0, dst0, e_s, E, E2, 128, 0);
  aggr_kernel<128, true><<<nblk_node, 256, 0, stream>>>(e_s, xl, rowptr, csr, src0, g1_bias, ln1_g, ln1_b,
                                                        a1, skip1, x1, skipproj, N, E);
  // ---- Layer 2 (din=128, HC=128, C=32) ----
  gemm(0, skip1, g2_Wl, g2_bl, xl, N, 128, 128, nullptr);
  gemm(0, skip1, g2_Wr, g2_br, xr, N, 128, 128, nullptr);
  score_mfma_kernel<32><<<score_blocks, 256, 0, stream>>>(ea_bf, xl, xr, g2_We, g2_att, src0, dst0, e_s, E, E2, 128, 0);
  aggr_kernel<128, false><<<nblk_node, 256, 0, stream>>>(e_s, xl, rowptr, csr, src0, g2_bias, ln2_g, ln2_b,
                                                         a2, x2, nullptr, nullptr, N, E);
  // ---- Layer 3 (din=128, HC=256, C=64) ----
  gemm(0, x2, g3_Wl, g3_bl, xl, N, 128, 256, nullptr);
  gemm(0, x2, g3_Wr, g3_br, xr, N, 128, 256, nullptr);
  score_mfma_kernel<64><<<score_blocks, 256, 0, stream>>>(ea_bf, xl, xr, g3_We, g3_att, src0, dst0, e_s, E, E2, 256, 0);
  score_mfma_kernel<64><<<score_blocks, 256, 0, stream>>>(ea_bf, xl, xr, g3_We, g3_att, src0, dst0, e_s, E, E2, 256, 128);
  aggr_kernel<256, false><<<nblk_node, 256, 0, stream>>>(e_s, xl, rowptr, csr, src0, g3_bias, ln3_g, ln3_b,
                                                         a3, x3, nullptr, nullptr, N, E);
  // ---- Final: xf = s*(x1@fp_W+fp_b) + (1-s)*x3 ; node MLP ----
  gemm(3, x1, fp_W, fp_b, xf, N, 128, 256, x3);
  gemm(2, xf, np_W1, np_b1, skipproj, N, 256, 128, nullptr);   // h1
  gemm(2, skipproj, np_W2, np_b2, h2, N, 128, 64, nullptr);    // h2
  gemm(0, h2, np_W3, np_b3, npout, N, 64, 1, nullptr);
}

// Round 8
// 745.936 us; speedup vs baseline: 3.4624x; 1.2884x over previous
//
#include <hip/hip_runtime.h>
#include <math.h>

#define DEV __device__ __forceinline__

typedef __attribute__((ext_vector_type(8))) short bf16x8;
typedef __attribute__((ext_vector_type(4))) float f32x4;

DEV float leakyf(float x, float s) { return x > 0.f ? x : s * x; }

DEV unsigned short f2bf(float f) {
  unsigned u = __float_as_uint(f);
  unsigned r = (u + 0x7fff + ((u >> 16) & 1)) >> 16;
  return (unsigned short)r;
}
DEV float bf2f(unsigned short h) { return __uint_as_float((unsigned)h << 16); }

DEV float wave_sum(float v) {
#pragma unroll
  for (int o = 1; o < 64; o <<= 1) v += __shfl_xor(v, o);
  return v;
}
DEV float wave_max(float v) {
#pragma unroll
  for (int o = 1; o < 64; o <<= 1) v = fmaxf(v, __shfl_xor(v, o));
  return v;
}

// ---------------- weight pre-convert: W[K,Nc] f32 -> WT[Nc,K] bf16 ----------------
struct WJob { const float* in; unsigned short* out; int K; int Nc; };
struct WJobs { WJob j[13]; };

__global__ __launch_bounds__(256) void wt_kernel(WJobs jobs) {
  WJob jb = jobs.j[blockIdx.y];
  int total = jb.K * jb.Nc;
  for (int i = blockIdx.x * 256 + threadIdx.x; i < total; i += gridDim.x * 256) {
    int c = i / jb.K, k = i - c * jb.K;
    jb.out[i] = f2bf(jb.in[(size_t)k * jb.Nc + c]);
  }
}

// ---------------- BatchNorm (eval) ----------------
__global__ __launch_bounds__(256) void bn_kernel(
    const float* __restrict__ xin, const float* __restrict__ g,
    const float* __restrict__ b, const float* __restrict__ m,
    const float* __restrict__ v, float* __restrict__ xout, int total) {
  int i = blockIdx.x * 256 + threadIdx.x;
  if (i < total) {
    int c = i & 63;
    xout[i] = (xin[i] - m[c]) * rsqrtf(v[c] + 1e-5f) * g[c] + b[c];
  }
}

// ---------------- Edge encoder: fully-MFMA fused 2-layer MLP + L2 norm ----------------
// Block = 64 edges (4 waves x 16). Layer1: attr[16x16 pad->K32] @ W1 -> 8 MFMA/wave.
// ea1 bf16 in LDS (wave-private rows -> no barrier). Layer2: 16 MFMA/wave.
// Epilogue: bias+leaky+row-L2-norm via 16-lane shfl reduce.
__global__ __launch_bounds__(256) void edge_enc_kernel(
    const float* __restrict__ edge_attr, const unsigned short* __restrict__ WT1,
    const float* __restrict__ b1, const unsigned short* __restrict__ WT2,
    const float* __restrict__ b2, unsigned short* __restrict__ ea_bf, int E) {
  __shared__ unsigned short sEa1[64][136];  // bf16, pad 8
  int tid = threadIdx.x, lane = tid & 63, w = tid >> 6;
  int g = lane >> 4, q = lane & 15;
  // layer-1 B-frags (cols 16t+q, k=8g+j; valid k<16 i.e. g<2)
  bf16x8 w1f[8];
#pragma unroll
  for (int t = 0; t < 8; t++) {
    bf16x8 v = {};
    if (g < 2) v = *(const bf16x8*)(WT1 + (size_t)(16 * t + q) * 16 + 8 * g);
    w1f[t] = v;
  }
  float b1v[8];
#pragma unroll
  for (int t = 0; t < 8; t++) b1v[t] = b1[16 * t + q];
  // layer-2 B-frags (cols 16t+q, k=32kc+8g+j)
  bf16x8 w2f[4][4];
#pragma unroll
  for (int t = 0; t < 4; t++)
#pragma unroll
    for (int kc = 0; kc < 4; kc++)
      w2f[t][kc] = *(const bf16x8*)(WT2 + (size_t)(16 * t + q) * 128 + 32 * kc + 8 * g);
  float b2v[4];
#pragma unroll
  for (int t = 0; t < 4; t++) b2v[t] = b2[16 * t + q];

  int e0 = blockIdx.x * 64 + w * 16;
  // A-frag: row = edge e0+q, k=8g+j (real k<16)
  bf16x8 af = {};
  if (g < 2) {
    int e = e0 + q;
    if (e >= E) e = E - 1;
    const float* ap = edge_attr + (size_t)e * 16 + 8 * g;
    float4 x0 = *(const float4*)ap;
    float4 x1 = *(const float4*)(ap + 4);
    af[0] = (short)f2bf(x0.x); af[1] = (short)f2bf(x0.y);
    af[2] = (short)f2bf(x0.z); af[3] = (short)f2bf(x0.w);
    af[4] = (short)f2bf(x1.x); af[5] = (short)f2bf(x1.y);
    af[6] = (short)f2bf(x1.z); af[7] = (short)f2bf(x1.w);
  }
  f32x4 acc1[8];
#pragma unroll
  for (int t = 0; t < 8; t++) acc1[t] = (f32x4){0.f, 0.f, 0.f, 0.f};
#pragma unroll
  for (int t = 0; t < 8; t++)
    acc1[t] = __builtin_amdgcn_mfma_f32_16x16x32_bf16(af, w1f[t], acc1[t], 0, 0, 0);
  // D: col 16t+q, row g*4+r -> ea1[w*16+g*4+r][16t+q]
#pragma unroll
  for (int t = 0; t < 8; t++)
#pragma unroll
    for (int r = 0; r < 4; r++) {
      float v = leakyf(acc1[t][r] + b1v[t], 0.01f);
      sEa1[w * 16 + g * 4 + r][16 * t + q] = f2bf(v);
    }
  // layer 2 (same wave reads its own rows; intra-wave LDS ordering suffices)
  f32x4 acc2[4];
#pragma unroll
  for (int t = 0; t < 4; t++) acc2[t] = (f32x4){0.f, 0.f, 0.f, 0.f};
#pragma unroll
  for (int kc = 0; kc < 4; kc++) {
    bf16x8 a2 = *(const bf16x8*)&sEa1[w * 16 + q][32 * kc + 8 * g];
#pragma unroll
    for (int t = 0; t < 4; t++)
      acc2[t] = __builtin_amdgcn_mfma_f32_16x16x32_bf16(a2, w2f[t][kc], acc2[t], 0, 0, 0);
  }
  // epilogue: rows g*4+r; L2-norm over 64 cols (4 t x 16 q-lanes)
#pragma unroll
  for (int r = 0; r < 4; r++) {
    float vv[4];
    float p = 0.f;
#pragma unroll
    for (int t = 0; t < 4; t++) {
      float v = leakyf(acc2[t][r] + b2v[t], 0.01f);
      vv[t] = v;
      p += v * v;
    }
#pragma unroll
    for (int o = 1; o < 16; o <<= 1) p += __shfl_xor(p, o);
    float sc = 1.f / fmaxf(sqrtf(p), 1e-12f);
    int e = e0 + g * 4 + r;
    if (e < E) {
#pragma unroll
      for (int t = 0; t < 4; t++)
        ea_bf[(size_t)e * 64 + 16 * t + q] = f2bf(vv[t] * sc);
    }
  }
}

// ---------------- CSR build ----------------
__global__ __launch_bounds__(256) void count_kernel(const int* __restrict__ dst0,
                                                    int* __restrict__ counts, int E, int E2) {
  int i = blockIdx.x * 256 + threadIdx.x;
  if (i < E2) {
    int d = (i < E) ? dst0[i] : (i - E);
    atomicAdd(&counts[d], 1);
  }
}

__global__ __launch_bounds__(256) void scan_kernel(const int* __restrict__ counts,
                                                   int* __restrict__ rowptr,
                                                   int* __restrict__ fill, int N) {
  __shared__ int part[256];
  int tid = threadIdx.x;
  int chunk = (N + 255) / 256;
  int lo = tid * chunk, hi = lo + chunk;
  if (hi > N) hi = N;
  if (lo > N) lo = N;
  int s = 0;
  for (int i = lo; i < hi; i++) s += counts[i];
  part[tid] = s;
  __syncthreads();
  if (tid == 0) {
    int run = 0;
    for (int i = 0; i < 256; i++) {
      int t = part[i];
      part[i] = run;
      run += t;
    }
    rowptr[N] = run;
  }
  __syncthreads();
  int off = part[tid];
  for (int i = lo; i < hi; i++) {
    rowptr[i] = off;
    fill[i] = off;
    off += counts[i];
  }
}

__global__ __launch_bounds__(256) void fill_kernel(const int* __restrict__ dst0,
                                                   int* __restrict__ fill,
                                                   int* __restrict__ csr, int E, int E2) {
  int i = blockIdx.x * 256 + threadIdx.x;
  if (i < E2) {
    int d = (i < E) ? dst0[i] : (i - E);
    int pos = atomicAdd(&fill[d], 1);
    csr[pos] = i;
  }
}

// ---------------- self-loop attr = mean of incoming encoded attrs (bf16 in/out) ----------------
__global__ __launch_bounds__(256) void loopattr_kernel(unsigned short* __restrict__ ea_bf,
                                                       const int* __restrict__ rowptr,
                                                       const int* __restrict__ csr, int N, int E) {
  int lane = threadIdx.x & 63, wv = threadIdx.x >> 6;
  int stride = gridDim.x * 4;
  for (int n = blockIdx.x * 4 + wv; n < N; n += stride) {
    int r0 = rowptr[n], r1 = rowptr[n + 1];
    float acc = 0.f;
    int cnt = 0;
    for (int i = r0; i < r1; i++) {
      int e = csr[i];
      if (e < E) {
        acc += bf2f(ea_bf[(size_t)e * 64 + lane]);
        cnt++;
      }
    }
    ea_bf[((size_t)E + n) * 64 + lane] = f2bf(acc / fmaxf((float)cnt, 1.f));
  }
}

// ---------------- bf16 MFMA GEMM: C = act(A[M,K] @ B[K,Nc] + bias) ----------------
// A f32 (converted during staging), B pre-converted bf16 transposed [Nc][K].
// 64x64 tile, BK=32, 4 waves: wave w rows 16w..16w+15, all 64 cols (4 col-tiles).
// MODE: 0 none, 2 elu, 3 mix: out = s*v + (1-s)*aux
template <int MODE>
__global__ __launch_bounds__(256) void gemm_mfma_kernel(
    const float* __restrict__ A, const unsigned short* __restrict__ BT,
    const float* __restrict__ bias, float* __restrict__ C, int M, int K, int Nc,
    const float* __restrict__ aux, const float* __restrict__ alpha_p) {
  __shared__ unsigned short sA[64][40];  // [row][k] pad 40 -> 2-way banks
  __shared__ unsigned short sB[64][40];  // [col][k]
  int tid = threadIdx.x, lane = tid & 63, w = tid >> 6;
  int g = lane >> 4, q = lane & 15;
  int bm = blockIdx.y * 64, bn = blockIdx.x * 64;
  f32x4 acc[4];
#pragma unroll
  for (int t = 0; t < 4; t++) acc[t] = (f32x4){0.f, 0.f, 0.f, 0.f};
  int r = tid >> 2, ko = (tid & 3) * 8;
  for (int k0 = 0; k0 < K; k0 += 32) {
    {
      int gm = bm + r;
      bf16x8 v = {};
      if (gm < M) {
        const float* ap = A + (size_t)gm * K + k0 + ko;
        float4 x0 = *(const float4*)ap;
        float4 x1 = *(const float4*)(ap + 4);
        v[0] = (short)f2bf(x0.x); v[1] = (short)f2bf(x0.y);
        v[2] = (short)f2bf(x0.z); v[3] = (short)f2bf(x0.w);
        v[4] = (short)f2bf(x1.x); v[5] = (short)f2bf(x1.y);
        v[6] = (short)f2bf(x1.z); v[7] = (short)f2bf(x1.w);
      }
      *(bf16x8*)&sA[r][ko] = v;
      int gc = bn + r;
      bf16x8 bv = {};
      if (gc < Nc) bv = *(const bf16x8*)(BT + (size_t)gc * K + k0 + ko);
      *(bf16x8*)&sB[r][ko] = bv;
    }
    __syncthreads();
    bf16x8 a = *(const bf16x8*)&sA[w * 16 + q][8 * g];
#pragma unroll
    for (int t = 0; t < 4; t++) {
      bf16x8 b = *(const bf16x8*)&sB[16 * t + q][8 * g];
      acc[t] = __builtin_amdgcn_mfma_f32_16x16x32_bf16(a, b, acc[t], 0, 0, 0);
    }
    __syncthreads();
  }
  float s = 0.f;
  if (MODE == 3) s = 1.f / (1.f + __expf(-alpha_p[0]));
#pragma unroll
  for (int t = 0; t < 4; t++) {
    int col = bn + 16 * t + q;
#pragma unroll
    for (int rr = 0; rr < 4; rr++) {
      int row = bm + w * 16 + g * 4 + rr;
      if (row < M && col < Nc) {
        float v = acc[t][rr] + bias[col];
        if (MODE == 2) v = v > 0.f ? v : (__expf(v) - 1.f);
        if (MODE == 3) v = s * v + (1.f - s) * aux[(size_t)row * Nc + col];
        C[(size_t)row * Nc + col] = v;
      }
    }
  }
}

// ---------------- GATv2 edge scores via MFMA ----------------
template <int C>  // head dim: 32 (layers 1,2) or 64 (layer 3 -> two launches)
__global__ __launch_bounds__(256) void score_mfma_kernel(
    const unsigned short* __restrict__ ea_bf, const float* __restrict__ xl,
    const float* __restrict__ xr, const float* __restrict__ We,
    const float* __restrict__ att, const int* __restrict__ src0,
    const int* __restrict__ dst0, float* __restrict__ e_s, int E, int E2,
    int HCfull, int col_off) {
  int lane = threadIdx.x & 63;
  int wv = threadIdx.x >> 6;
  int g = lane >> 4, q = lane & 15;
  bf16x8 bfrag[8][2];
#pragma unroll
  for (int t = 0; t < 8; t++)
#pragma unroll
    for (int kc = 0; kc < 2; kc++) {
      bf16x8 bv;
#pragma unroll
      for (int j = 0; j < 8; j++) {
        int k = kc * 32 + g * 8 + j;
        bv[j] = (short)f2bf(We[(size_t)k * HCfull + col_off + 16 * t + q]);
      }
      bfrag[t][kc] = bv;
    }
  float attv[8];
#pragma unroll
  for (int t = 0; t < 8; t++) attv[t] = att[col_off + 16 * t + q];

  constexpr int TPH = C / 16;
  constexpr int NH = 8 / TPH;
  const int headbase = col_off / C;

  int tiles = (E2 + 15) / 16;
  int nw = gridDim.x * 4;
  for (int tile = blockIdx.x * 4 + wv; tile < tiles; tile += nw) {
    int e0 = tile * 16;
    int erow = e0 + q;
    if (erow >= E2) erow = E2 - 1;
    const unsigned short* ap = ea_bf + (size_t)erow * 64 + g * 8;
    bf16x8 a0 = *(const bf16x8*)(ap);
    bf16x8 a1 = *(const bf16x8*)(ap + 32);
    f32x4 acc[8];
#pragma unroll
    for (int t = 0; t < 8; t++) acc[t] = (f32x4){0.f, 0.f, 0.f, 0.f};
#pragma unroll
    for (int t = 0; t < 8; t++) {
      acc[t] = __builtin_amdgcn_mfma_f32_16x16x32_bf16(a0, bfrag[t][0], acc[t], 0, 0, 0);
      acc[t] = __builtin_amdgcn_mfma_f32_16x16x32_bf16(a1, bfrag[t][1], acc[t], 0, 0, 0);
    }
    int sn[4], dn[4];
#pragma unroll
    for (int r = 0; r < 4; r++) {
      int e = e0 + g * 4 + r;
      if (e >= E2) e = E2 - 1;
      if (e < E) {
        sn[r] = src0[e];
        dn[r] = dst0[e];
      } else {
        sn[r] = dn[r] = e - E;
      }
    }
    float p[NH][4];
#pragma unroll
    for (int hh = 0; hh < NH; hh++)
#pragma unroll
      for (int r = 0; r < 4; r++) p[hh][r] = 0.f;
#pragma unroll
    for (int t = 0; t < 8; t++) {
      int col = col_off + 16 * t + q;
#pragma unroll
      for (int r = 0; r < 4; r++) {
        float xv = xl[(size_t)sn[r] * HCfull + col] + xr[(size_t)dn[r] * HCfull + col] + acc[t][r];
        xv = xv > 0.f ? xv : 0.2f * xv;
        p[t / TPH][r] += xv * attv[t];
      }
    }
#pragma unroll
    for (int hh = 0; hh < NH; hh++)
#pragma unroll
      for (int r = 0; r < 4; r++) {
#pragma unroll
        for (int o = 1; o < 16; o <<= 1) p[hh][r] += __shfl_xor(p[hh][r], o);
      }
    if (q == 0) {
#pragma unroll
      for (int r = 0; r < 4; r++) {
        int e = e0 + g * 4 + r;
        if (e < E2) {
#pragma unroll
          for (int hh = 0; hh < NH; hh++)
            e_s[(size_t)e * 4 + headbase + hh] = p[hh][r];
        }
      }
    }
  }
}

// ---------------- per-node softmax + aggregation + bias + LN + leaky (+skip mix for L1) ----------------
template <int HC, bool L1MODE>
__global__ __launch_bounds__(256) void aggr_kernel(
    const float* __restrict__ e_s, const float* __restrict__ xl,
    const int* __restrict__ rowptr, const int* __restrict__ csr,
    const int* __restrict__ src0, const float* __restrict__ bias,
    const float* __restrict__ lng, const float* __restrict__ lnb,
    float* __restrict__ alpha_out, float* __restrict__ xout,
    float* __restrict__ x1out, const float* __restrict__ skipproj, int N, int E) {
  constexpr int CPL = HC / 64;
  int lane = threadIdx.x & 63, wv = threadIdx.x >> 6;
  int stride = gridDim.x * 4;
  for (int n = blockIdx.x * 4 + wv; n < N; n += stride) {
    int r0 = rowptr[n], r1 = rowptr[n + 1];
    float m0 = -1e30f, m1 = -1e30f, m2 = -1e30f, m3 = -1e30f;
    for (int i = r0 + lane; i < r1; i += 64) {
      int e = csr[i];
      float4 v = *reinterpret_cast<const float4*>(e_s + (size_t)e * 4);
      m0 = fmaxf(m0, v.x);
      m1 = fmaxf(m1, v.y);
      m2 = fmaxf(m2, v.z);
      m3 = fmaxf(m3, v.w);
    }
    m0 = wave_max(m0);
    m1 = wave_max(m1);
    m2 = wave_max(m2);
    m3 = wave_max(m3);
    float d0 = 0.f, d1 = 0.f, d2 = 0.f, d3 = 0.f;
    for (int i = r0 + lane; i < r1; i += 64) {
      int e = csr[i];
      float4 v = *reinterpret_cast<const float4*>(e_s + (size_t)e * 4);
      d0 += __expf(v.x - m0);
      d1 += __expf(v.y - m1);
      d2 += __expf(v.z - m2);
      d3 += __expf(v.w - m3);
    }
    d0 = wave_sum(d0);
    d1 = wave_sum(d1);
    d2 = wave_sum(d2);
    d3 = wave_sum(d3);
    float i0 = 1.f / (d0 + 1e-16f), i1 = 1.f / (d1 + 1e-16f);
    float i2 = 1.f / (d2 + 1e-16f), i3 = 1.f / (d3 + 1e-16f);
    int h = lane >> 4;
    float mh = (h & 2) ? ((h & 1) ? m3 : m2) : ((h & 1) ? m1 : m0);
    float ih = (h & 2) ? ((h & 1) ? i3 : i2) : ((h & 1) ? i1 : i0);
    float acc[CPL];
#pragma unroll
    for (int j = 0; j < CPL; j++) acc[j] = 0.f;
    int c0 = lane * CPL;
    for (int i = r0; i < r1; i++) {
      int e = csr[i];
      int sn = (e < E) ? src0[e] : (e - E);
      float a = __expf(e_s[(size_t)e * 4 + h] - mh) * ih;
      if ((lane & 15) == 0) alpha_out[(size_t)e * 4 + h] = a;
      const float* xp = xl + (size_t)sn * HC + c0;
      if constexpr (CPL == 2) {
        float2 t = *(const float2*)xp;
        acc[0] += a * t.x;
        acc[1] += a * t.y;
      } else {
        float4 t = *(const float4*)xp;
        acc[0] += a * t.x;
        acc[1] += a * t.y;
        acc[2] += a * t.z;
        acc[3] += a * t.w;
      }
    }
    float vals[CPL];
    float vs = 0.f, vq = 0.f;
#pragma unroll
    for (int j = 0; j < CPL; j++) {
      float t = acc[j] + bias[c0 + j];
      vals[j] = t;
      vs += t;
      vq += t * t;
    }
    vs = wave_sum(vs);
    vq = wave_sum(vq);
    float mean = vs * (1.f / HC);
    float var = vq * (1.f / HC) - mean * mean;
    float rstd = rsqrtf(fmaxf(var, 0.f) + 1e-5f);
#pragma unroll
    for (int j = 0; j < CPL; j++) {
      int c = c0 + j;
      float y = (vals[j] - mean) * rstd * lng[c] + lnb[c];
      y = leakyf(y, 0.01f);
      if constexpr (L1MODE) {
        x1out[(size_t)n * HC + c] = y;
        xout[(size_t)n * HC + c] = 0.01f * skipproj[(size_t)n * HC + c] + y;
      } else {
        xout[(size_t)n * HC + c] = y;
      }
    }
  }
}

extern "C" void kernel_launch(void* const* d_in, const int* in_sizes, int n_in,
                              void* d_out, int out_size, void* d_ws, size_t ws_size,
                              hipStream_t stream) {
  (void)n_in;
  (void)out_size;
  (void)ws_size;
  const float* x_in = (const float*)d_in[0];
  const int* edge_index = (const int*)d_in[1];
  const float* edge_attr = (const float*)d_in[2];
  const float* bn0_g = (const float*)d_in[3];
  const float* bn0_b = (const float*)d_in[4];
  const float* bn0_m = (const float*)d_in[5];
  const float* bn0_v = (const float*)d_in[6];
  const float* eeW1 = (const float*)d_in[7];
  const float* eeb1 = (const float*)d_in[8];
  const float* eeW2 = (const float*)d_in[9];
  const float* eeb2 = (const float*)d_in[10];
  const float* g1_Wl = (const float*)d_in[11];
  const float* g1_bl = (const float*)d_in[12];
  const float* g1_Wr = (const float*)d_in[13];
  const float* g1_br = (const float*)d_in[14];
  const float* g1_We = (const float*)d_in[15];
  const float* g1_att = (const float*)d_in[16];
  const float* g1_bias = (const float*)d_in[17];
  const float* g2_Wl = (const float*)d_in[18];
  const float* g2_bl = (const float*)d_in[19];
  const float* g2_Wr = (const float*)d_in[20];
  const float* g2_br = (const float*)d_in[21];
  const float* g2_We = (const float*)d_in[22];
  const float* g2_att = (const float*)d_in[23];
  const float* g2_bias = (const float*)d_in[24];
  const float* g3_Wl = (const float*)d_in[25];
  const float* g3_bl = (const float*)d_in[26];
  const float* g3_Wr = (const float*)d_in[27];
  const float* g3_br = (const float*)d_in[28];
  const float* g3_We = (const float*)d_in[29];
  const float* g3_att = (const float*)d_in[30];
  const float* g3_bias = (const float*)d_in[31];
  const float* ln1_g = (const float*)d_in[32];
  const float* ln1_b = (const float*)d_in[33];
  const float* ln2_g = (const float*)d_in[34];
  const float* ln2_b = (const float*)d_in[35];
  const float* ln3_g = (const float*)d_in[36];
  const float* ln3_b = (const float*)d_in[37];
  const float* skip_W = (const float*)d_in[38];
  const float* skip_b = (const float*)d_in[39];
  const float* alpha_p = (const float*)d_in[40];
  const float* fp_W = (const float*)d_in[41];
  const float* fp_b = (const float*)d_in[42];
  const float* np_W1 = (const float*)d_in[43];
  const float* np_b1 = (const float*)d_in[44];
  const float* np_W2 = (const float*)d_in[45];
  const float* np_b2 = (const float*)d_in[46];
  const float* np_W3 = (const float*)d_in[47];
  const float* np_b3 = (const float*)d_in[48];

  const int N = in_sizes[0] / 64;
  const int E = in_sizes[2] / 16;
  const int E2 = E + N;
  const int* src0 = edge_index;
  const int* dst0 = edge_index + E;

  float* ws = (float*)d_ws;
  size_t off = 0;
  float* x = ws + off;         off += (size_t)N * 64;
  unsigned short* ea_bf = (unsigned short*)(ws + off); off += (size_t)E2 * 32;  // bf16 [E2][64]
  float* xl = ws + off;        off += (size_t)N * 256;
  float* xr = ws + off;        off += (size_t)N * 256;
  float* skipproj = ws + off;  off += (size_t)N * 128;  // reused as h1 at the end
  float* x1 = ws + off;        off += (size_t)N * 128;
  float* skip1 = ws + off;     off += (size_t)N * 128;
  float* x2 = ws + off;        off += (size_t)N * 128;
  float* x3 = ws + off;        off += (size_t)N * 256;
  float* e_s = ws + off;       off += (size_t)E2 * 4;
  float* h2 = ws + off;        off += (size_t)N * 64;
  int* counts = (int*)(ws + off);
  int* rowptr = counts + N;
  int* fill = rowptr + N + 1;
  int* csr = fill + N;
  off += (size_t)(3 * N + 1 + E2);
  off = (off + 3) & ~(size_t)3;  // 16B align for bf16 pool
  unsigned short* wtp = (unsigned short*)(ws + off);
  auto alloc_wt = [&](int elems) {
    unsigned short* p = wtp;
    wtp += (elems + 7) & ~7;
    return p;
  };
  unsigned short* wt_g1l = alloc_wt(64 * 128);
  unsigned short* wt_g1r = alloc_wt(64 * 128);
  unsigned short* wt_skip = alloc_wt(64 * 128);
  unsigned short* wt_g2l = alloc_wt(128 * 128);
  unsigned short* wt_g2r = alloc_wt(128 * 128);
  unsigned short* wt_g3l = alloc_wt(128 * 256);
  unsigned short* wt_g3r = alloc_wt(128 * 256);
  unsigned short* wt_fp = alloc_wt(128 * 256);
  unsigned short* wt_np1 = alloc_wt(256 * 128);
  unsigned short* wt_np2 = alloc_wt(128 * 64);
  unsigned short* wt_np3 = alloc_wt(64 * 1);
  unsigned short* wt_ee1 = alloc_wt(16 * 128);
  unsigned short* wt_ee2 = alloc_wt(128 * 64);

  float* out = (float*)d_out;
  float* xf = out;
  float* npout = out + (size_t)N * 256;
  float* a1 = npout + N;
  float* a2 = a1 + (size_t)E2 * 4;
  float* a3 = a2 + (size_t)E2 * 4;

  WJobs jobs;
  jobs.j[0] = {g1_Wl, wt_g1l, 64, 128};
  jobs.j[1] = {g1_Wr, wt_g1r, 64, 128};
  jobs.j[2] = {skip_W, wt_skip, 64, 128};
  jobs.j[3] = {g2_Wl, wt_g2l, 128, 128};
  jobs.j[4] = {g2_Wr, wt_g2r, 128, 128};
  jobs.j[5] = {g3_Wl, wt_g3l, 128, 256};
  jobs.j[6] = {g3_Wr, wt_g3r, 128, 256};
  jobs.j[7] = {fp_W, wt_fp, 128, 256};
  jobs.j[8] = {np_W1, wt_np1, 256, 128};
  jobs.j[9] = {np_W2, wt_np2, 128, 64};
  jobs.j[10] = {np_W3, wt_np3, 64, 1};
  jobs.j[11] = {eeW1, wt_ee1, 16, 128};
  jobs.j[12] = {eeW2, wt_ee2, 128, 64};

  hipMemsetAsync(counts, 0, (size_t)N * sizeof(int), stream);
  wt_kernel<<<dim3(64, 13), 256, 0, stream>>>(jobs);
  bn_kernel<<<(N * 64 + 255) / 256, 256, 0, stream>>>(x_in, bn0_g, bn0_b, bn0_m, bn0_v, x, N * 64);
  edge_enc_kernel<<<(E + 63) / 64, 256, 0, stream>>>(edge_attr, wt_ee1, eeb1, wt_ee2, eeb2, ea_bf, E);
  count_kernel<<<(E2 + 255) / 256, 256, 0, stream>>>(dst0, counts, E, E2);
  scan_kernel<<<1, 256, 0, stream>>>(counts, rowptr, fill, N);
  fill_kernel<<<(E2 + 255) / 256, 256, 0, stream>>>(dst0, fill, csr, E, E2);
  loopattr_kernel<<<(N + 3) / 4, 256, 0, stream>>>(ea_bf, rowptr, csr, N, E);

  auto gemm = [&](int mode, const float* A, const unsigned short* BT, const float* bias,
                  float* Cp, int M, int K, int Nc, const float* aux) {
    dim3 gdim((Nc + 63) / 64, (M + 63) / 64);
    switch (mode) {
      case 0: gemm_mfma_kernel<0><<<gdim, 256, 0, stream>>>(A, BT, bias, Cp, M, K, Nc, nullptr, nullptr); break;
      case 2: gemm_mfma_kernel<2><<<gdim, 256, 0, stream>>>(A, BT, bias, Cp, M, K, Nc, nullptr, nullptr); break;
      case 3: gemm_mfma_kernel<3><<<gdim, 256, 0, stream>>>(A, BT, bias, Cp, M, K, Nc, aux, alpha_p); break;
    }
  };

  const int nblk_node = (N + 3) / 4;
  const int score_blocks = 1024;

  // ---- Layer 1 (din=64, HC=128, C=32) ----
  gemm(0, x, wt_g1l, g1_bl, xl, N, 64, 128, nullptr);
  gemm(0, x, wt_g1r, g1_br, xr, N, 64, 128, nullptr);
  gemm(0, x, wt_skip, skip_b, skipproj, N, 64, 128, nullptr);
  score_mfma_kernel<32><<<score_blocks, 256, 0, stream>>>(ea_bf, xl, xr, g1_We, g1_att, src0, dst0, e_s, E, E2, 128, 0);
  aggr_kernel<128, true><<<nblk_node, 256, 0, stream>>>(e_s, xl, rowptr, csr, src0, g1_bias, ln1_g, ln1_b,
                                                        a1, skip1, x1, skipproj, N, E);
  // ---- Layer 2 (din=128, HC=128, C=32) ----
  gemm(0, skip1, wt_g2l, g2_bl, xl, N, 128, 128, nullptr);
  gemm(0, skip1, wt_g2r, g2_br, xr, N, 128, 128, nullptr);
  score_mfma_kernel<32><<<score_blocks, 256, 0, stream>>>(ea_bf, xl, xr, g2_We, g2_att, src0, dst0, e_s, E, E2, 128, 0);
  aggr_kernel<128, false><<<nblk_node, 256, 0, stream>>>(e_s, xl, rowptr, csr, src0, g2_bias, ln2_g, ln2_b,
                                                         a2, x2, nullptr, nullptr, N, E);
  // ---- Layer 3 (din=128, HC=256, C=64) ----
  gemm(0, x2, wt_g3l, g3_bl, xl, N, 128, 256, nullptr);
  gemm(0, x2, wt_g3r, g3_br, xr, N, 128, 256, nullptr);
  score_mfma_kernel<64><<<score_blocks, 256, 0, stream>>>(ea_bf, xl, xr, g3_We, g3_att, src0, dst0, e_s, E, E2, 256, 0);
  score_mfma_kernel<64><<<score_blocks, 256, 0, stream>>>(ea_bf, xl, xr, g3_We, g3_att, src0, dst0, e_s, E, E2, 256, 128);
  aggr_kernel<256, false><<<nblk_node, 256, 0, stream>>>(e_s, xl, rowptr, csr, src0, g3_bias, ln3_g, ln3_b,
                                                         a3, x3, nullptr, nullptr, N, E);
  // ---- Final: xf = s*(x1@fp_W+fp_b) + (1-s)*x3 ; node MLP ----
  gemm(3, x1, wt_fp, fp_b, xf, N, 128, 256, x3);
  gemm(2, xf, wt_np1, np_b1, skipproj, N, 256, 128, nullptr);   // h1
  gemm(2, skipproj, wt_np2, np_b2, h2, N, 128, 64, nullptr);    // h2
  gemm(0, h2, wt_np3, np_b3, npout, N, 64, 1, nullptr);
}

// Round 9
// 719.992 us; speedup vs baseline: 3.5871x; 1.0360x over previous
//
#include <hip/hip_runtime.h>
#include <math.h>

#define DEV __device__ __forceinline__

typedef __attribute__((ext_vector_type(8))) short bf16x8;
typedef __attribute__((ext_vector_type(4))) float f32x4;

DEV float leakyf(float x, float s) { return x > 0.f ? x : s * x; }

DEV unsigned short f2bf(float f) {
  unsigned u = __float_as_uint(f);
  unsigned r = (u + 0x7fff + ((u >> 16) & 1)) >> 16;
  return (unsigned short)r;
}
DEV float bf2f(unsigned short h) { return __uint_as_float((unsigned)h << 16); }

DEV float wave_sum(float v) {
#pragma unroll
  for (int o = 1; o < 64; o <<= 1) v += __shfl_xor(v, o);
  return v;
}
DEV float wave_max(float v) {
#pragma unroll
  for (int o = 1; o < 64; o <<= 1) v = fmaxf(v, __shfl_xor(v, o));
  return v;
}

// ---------------- weight pre-convert: W[K,Nc] f32 -> WT[Nc,K] bf16 ----------------
struct WJob { const float* in; unsigned short* out; int K; int Nc; };
struct WJobs { WJob j[13]; };

__global__ __launch_bounds__(256) void wt_kernel(WJobs jobs) {
  WJob jb = jobs.j[blockIdx.y];
  int total = jb.K * jb.Nc;
  for (int i = blockIdx.x * 256 + threadIdx.x; i < total; i += gridDim.x * 256) {
    int c = i / jb.K, k = i - c * jb.K;
    jb.out[i] = f2bf(jb.in[(size_t)k * jb.Nc + c]);
  }
}

// ---------------- BatchNorm (eval) ----------------
__global__ __launch_bounds__(256) void bn_kernel(
    const float* __restrict__ xin, const float* __restrict__ g,
    const float* __restrict__ b, const float* __restrict__ m,
    const float* __restrict__ v, float* __restrict__ xout, int total) {
  int i = blockIdx.x * 256 + threadIdx.x;
  if (i < total) {
    int c = i & 63;
    xout[i] = (xin[i] - m[c]) * rsqrtf(v[c] + 1e-5f) * g[c] + b[c];
  }
}

// ---------------- Edge encoder: fully-MFMA fused 2-layer MLP + L2 norm ----------------
__global__ __launch_bounds__(256) void edge_enc_kernel(
    const float* __restrict__ edge_attr, const unsigned short* __restrict__ WT1,
    const float* __restrict__ b1, const unsigned short* __restrict__ WT2,
    const float* __restrict__ b2, unsigned short* __restrict__ ea_bf, int E) {
  __shared__ unsigned short sEa1[64][136];  // bf16, pad 8
  int tid = threadIdx.x, lane = tid & 63, w = tid >> 6;
  int g = lane >> 4, q = lane & 15;
  bf16x8 w1f[8];
#pragma unroll
  for (int t = 0; t < 8; t++) {
    bf16x8 v = {};
    if (g < 2) v = *(const bf16x8*)(WT1 + (size_t)(16 * t + q) * 16 + 8 * g);
    w1f[t] = v;
  }
  float b1v[8];
#pragma unroll
  for (int t = 0; t < 8; t++) b1v[t] = b1[16 * t + q];
  bf16x8 w2f[4][4];
#pragma unroll
  for (int t = 0; t < 4; t++)
#pragma unroll
    for (int kc = 0; kc < 4; kc++)
      w2f[t][kc] = *(const bf16x8*)(WT2 + (size_t)(16 * t + q) * 128 + 32 * kc + 8 * g);
  float b2v[4];
#pragma unroll
  for (int t = 0; t < 4; t++) b2v[t] = b2[16 * t + q];

  int e0 = blockIdx.x * 64 + w * 16;
  bf16x8 af = {};
  if (g < 2) {
    int e = e0 + q;
    if (e >= E) e = E - 1;
    const float* ap = edge_attr + (size_t)e * 16 + 8 * g;
    float4 x0 = *(const float4*)ap;
    float4 x1 = *(const float4*)(ap + 4);
    af[0] = (short)f2bf(x0.x); af[1] = (short)f2bf(x0.y);
    af[2] = (short)f2bf(x0.z); af[3] = (short)f2bf(x0.w);
    af[4] = (short)f2bf(x1.x); af[5] = (short)f2bf(x1.y);
    af[6] = (short)f2bf(x1.z); af[7] = (short)f2bf(x1.w);
  }
  f32x4 acc1[8];
#pragma unroll
  for (int t = 0; t < 8; t++) acc1[t] = (f32x4){0.f, 0.f, 0.f, 0.f};
#pragma unroll
  for (int t = 0; t < 8; t++)
    acc1[t] = __builtin_amdgcn_mfma_f32_16x16x32_bf16(af, w1f[t], acc1[t], 0, 0, 0);
#pragma unroll
  for (int t = 0; t < 8; t++)
#pragma unroll
    for (int r = 0; r < 4; r++) {
      float v = leakyf(acc1[t][r] + b1v[t], 0.01f);
      sEa1[w * 16 + g * 4 + r][16 * t + q] = f2bf(v);
    }
  f32x4 acc2[4];
#pragma unroll
  for (int t = 0; t < 4; t++) acc2[t] = (f32x4){0.f, 0.f, 0.f, 0.f};
#pragma unroll
  for (int kc = 0; kc < 4; kc++) {
    bf16x8 a2 = *(const bf16x8*)&sEa1[w * 16 + q][32 * kc + 8 * g];
#pragma unroll
    for (int t = 0; t < 4; t++)
      acc2[t] = __builtin_amdgcn_mfma_f32_16x16x32_bf16(a2, w2f[t][kc], acc2[t], 0, 0, 0);
  }
#pragma unroll
  for (int r = 0; r < 4; r++) {
    float vv[4];
    float p = 0.f;
#pragma unroll
    for (int t = 0; t < 4; t++) {
      float v = leakyf(acc2[t][r] + b2v[t], 0.01f);
      vv[t] = v;
      p += v * v;
    }
#pragma unroll
    for (int o = 1; o < 16; o <<= 1) p += __shfl_xor(p, o);
    float sc = 1.f / fmaxf(sqrtf(p), 1e-12f);
    int e = e0 + g * 4 + r;
    if (e < E) {
#pragma unroll
      for (int t = 0; t < 4; t++)
        ea_bf[(size_t)e * 64 + 16 * t + q] = f2bf(vv[t] * sc);
    }
  }
}

// ---------------- CSR build ----------------
__global__ __launch_bounds__(256) void count_kernel(const int* __restrict__ dst0,
                                                    int* __restrict__ counts, int E, int E2) {
  int i = blockIdx.x * 256 + threadIdx.x;
  if (i < E2) {
    int d = (i < E) ? dst0[i] : (i - E);
    atomicAdd(&counts[d], 1);
  }
}

__global__ __launch_bounds__(256) void scan_kernel(const int* __restrict__ counts,
                                                   int* __restrict__ rowptr,
                                                   int* __restrict__ fill, int N) {
  __shared__ int part[256];
  int tid = threadIdx.x;
  int chunk = (N + 255) / 256;
  int lo = tid * chunk, hi = lo + chunk;
  if (hi > N) hi = N;
  if (lo > N) lo = N;
  int s = 0;
  for (int i = lo; i < hi; i++) s += counts[i];
  part[tid] = s;
  __syncthreads();
  if (tid == 0) {
    int run = 0;
    for (int i = 0; i < 256; i++) {
      int t = part[i];
      part[i] = run;
      run += t;
    }
    rowptr[N] = run;
  }
  __syncthreads();
  int off = part[tid];
  for (int i = lo; i < hi; i++) {
    rowptr[i] = off;
    fill[i] = off;
    off += counts[i];
  }
}

__global__ __launch_bounds__(256) void fill_kernel(const int* __restrict__ dst0,
                                                   int* __restrict__ fill,
                                                   int* __restrict__ csr, int E, int E2) {
  int i = blockIdx.x * 256 + threadIdx.x;
  if (i < E2) {
    int d = (i < E) ? dst0[i] : (i - E);
    int pos = atomicAdd(&fill[d], 1);
    csr[pos] = i;
  }
}

// ---------------- self-loop attr = mean of incoming encoded attrs (bf16 in/out) ----------------
__global__ __launch_bounds__(256) void loopattr_kernel(unsigned short* __restrict__ ea_bf,
                                                       const int* __restrict__ rowptr,
                                                       const int* __restrict__ csr, int N, int E) {
  int lane = threadIdx.x & 63, wv = threadIdx.x >> 6;
  int stride = gridDim.x * 4;
  for (int n = blockIdx.x * 4 + wv; n < N; n += stride) {
    int r0 = rowptr[n], r1 = rowptr[n + 1];
    float acc = 0.f;
    int cnt = 0;
    for (int i = r0; i < r1; i++) {
      int e = csr[i];
      if (e < E) {
        acc += bf2f(ea_bf[(size_t)e * 64 + lane]);
        cnt++;
      }
    }
    ea_bf[((size_t)E + n) * 64 + lane] = f2bf(acc / fmaxf((float)cnt, 1.f));
  }
}

// ---------------- bf16 MFMA GEMM: C = act(A[M,K] @ B[K,Nc] + bias) ----------------
// MODE: 0 f32 out, 1 bf16 out, 2 elu f32 out, 3 mix f32 out
template <int MODE>
__global__ __launch_bounds__(256) void gemm_mfma_kernel(
    const float* __restrict__ A, const unsigned short* __restrict__ BT,
    const float* __restrict__ bias, void* __restrict__ Cout, int M, int K, int Nc,
    const float* __restrict__ aux, const float* __restrict__ alpha_p) {
  __shared__ unsigned short sA[64][40];
  __shared__ unsigned short sB[64][40];
  int tid = threadIdx.x, lane = tid & 63, w = tid >> 6;
  int g = lane >> 4, q = lane & 15;
  int bm = blockIdx.y * 64, bn = blockIdx.x * 64;
  f32x4 acc[4];
#pragma unroll
  for (int t = 0; t < 4; t++) acc[t] = (f32x4){0.f, 0.f, 0.f, 0.f};
  int r = tid >> 2, ko = (tid & 3) * 8;
  for (int k0 = 0; k0 < K; k0 += 32) {
    {
      int gm = bm + r;
      bf16x8 v = {};
      if (gm < M) {
        const float* ap = A + (size_t)gm * K + k0 + ko;
        float4 x0 = *(const float4*)ap;
        float4 x1 = *(const float4*)(ap + 4);
        v[0] = (short)f2bf(x0.x); v[1] = (short)f2bf(x0.y);
        v[2] = (short)f2bf(x0.z); v[3] = (short)f2bf(x0.w);
        v[4] = (short)f2bf(x1.x); v[5] = (short)f2bf(x1.y);
        v[6] = (short)f2bf(x1.z); v[7] = (short)f2bf(x1.w);
      }
      *(bf16x8*)&sA[r][ko] = v;
      int gc = bn + r;
      bf16x8 bv = {};
      if (gc < Nc) bv = *(const bf16x8*)(BT + (size_t)gc * K + k0 + ko);
      *(bf16x8*)&sB[r][ko] = bv;
    }
    __syncthreads();
    bf16x8 a = *(const bf16x8*)&sA[w * 16 + q][8 * g];
#pragma unroll
    for (int t = 0; t < 4; t++) {
      bf16x8 b = *(const bf16x8*)&sB[16 * t + q][8 * g];
      acc[t] = __builtin_amdgcn_mfma_f32_16x16x32_bf16(a, b, acc[t], 0, 0, 0);
    }
    __syncthreads();
  }
  float s = 0.f;
  if (MODE == 3) s = 1.f / (1.f + __expf(-alpha_p[0]));
#pragma unroll
  for (int t = 0; t < 4; t++) {
    int col = bn + 16 * t + q;
#pragma unroll
    for (int rr = 0; rr < 4; rr++) {
      int row = bm + w * 16 + g * 4 + rr;
      if (row < M && col < Nc) {
        float v = acc[t][rr] + bias[col];
        if (MODE == 2) v = v > 0.f ? v : (__expf(v) - 1.f);
        if (MODE == 3) v = s * v + (1.f - s) * aux[(size_t)row * Nc + col];
        if (MODE == 1)
          ((unsigned short*)Cout)[(size_t)row * Nc + col] = f2bf(v);
        else
          ((float*)Cout)[(size_t)row * Nc + col] = v;
      }
    }
  }
}

// ---------------- GATv2 edge scores via MFMA (bf16 xl/xr) ----------------
template <int C>
__global__ __launch_bounds__(256) void score_mfma_kernel(
    const unsigned short* __restrict__ ea_bf, const unsigned short* __restrict__ xl,
    const unsigned short* __restrict__ xr, const float* __restrict__ We,
    const float* __restrict__ att, const int* __restrict__ src0,
    const int* __restrict__ dst0, float* __restrict__ e_s, int E, int E2,
    int HCfull, int col_off) {
  int lane = threadIdx.x & 63;
  int wv = threadIdx.x >> 6;
  int g = lane >> 4, q = lane & 15;
  bf16x8 bfrag[8][2];
#pragma unroll
  for (int t = 0; t < 8; t++)
#pragma unroll
    for (int kc = 0; kc < 2; kc++) {
      bf16x8 bv;
#pragma unroll
      for (int j = 0; j < 8; j++) {
        int k = kc * 32 + g * 8 + j;
        bv[j] = (short)f2bf(We[(size_t)k * HCfull + col_off + 16 * t + q]);
      }
      bfrag[t][kc] = bv;
    }
  float attv[8];
#pragma unroll
  for (int t = 0; t < 8; t++) attv[t] = att[col_off + 16 * t + q];

  constexpr int TPH = C / 16;
  constexpr int NH = 8 / TPH;
  const int headbase = col_off / C;

  int tiles = (E2 + 15) / 16;
  int nw = gridDim.x * 4;
  for (int tile = blockIdx.x * 4 + wv; tile < tiles; tile += nw) {
    int e0 = tile * 16;
    int erow = e0 + q;
    if (erow >= E2) erow = E2 - 1;
    const unsigned short* ap = ea_bf + (size_t)erow * 64 + g * 8;
    bf16x8 a0 = *(const bf16x8*)(ap);
    bf16x8 a1 = *(const bf16x8*)(ap + 32);
    f32x4 acc[8];
#pragma unroll
    for (int t = 0; t < 8; t++) acc[t] = (f32x4){0.f, 0.f, 0.f, 0.f};
#pragma unroll
    for (int t = 0; t < 8; t++) {
      acc[t] = __builtin_amdgcn_mfma_f32_16x16x32_bf16(a0, bfrag[t][0], acc[t], 0, 0, 0);
      acc[t] = __builtin_amdgcn_mfma_f32_16x16x32_bf16(a1, bfrag[t][1], acc[t], 0, 0, 0);
    }
    int sn[4], dn[4];
#pragma unroll
    for (int r = 0; r < 4; r++) {
      int e = e0 + g * 4 + r;
      if (e >= E2) e = E2 - 1;
      if (e < E) {
        sn[r] = src0[e];
        dn[r] = dst0[e];
      } else {
        sn[r] = dn[r] = e - E;
      }
    }
    float p[NH][4];
#pragma unroll
    for (int hh = 0; hh < NH; hh++)
#pragma unroll
      for (int r = 0; r < 4; r++) p[hh][r] = 0.f;
#pragma unroll
    for (int t = 0; t < 8; t++) {
      int col = col_off + 16 * t + q;
#pragma unroll
      for (int r = 0; r < 4; r++) {
        float xv = bf2f(xl[(size_t)sn[r] * HCfull + col]) +
                   bf2f(xr[(size_t)dn[r] * HCfull + col]) + acc[t][r];
        xv = xv > 0.f ? xv : 0.2f * xv;
        p[t / TPH][r] += xv * attv[t];
      }
    }
#pragma unroll
    for (int hh = 0; hh < NH; hh++)
#pragma unroll
      for (int r = 0; r < 4; r++) {
#pragma unroll
        for (int o = 1; o < 16; o <<= 1) p[hh][r] += __shfl_xor(p[hh][r], o);
      }
    if (q == 0) {
#pragma unroll
      for (int r = 0; r < 4; r++) {
        int e = e0 + g * 4 + r;
        if (e < E2) {
#pragma unroll
          for (int hh = 0; hh < NH; hh++)
            e_s[(size_t)e * 4 + headbase + hh] = p[hh][r];
        }
      }
    }
  }
}

// ---------------- per-node softmax + aggregation (bf16 xl gather) + bias + LN + leaky ----------------
template <int HC, bool L1MODE>
__global__ __launch_bounds__(256) void aggr_kernel(
    const float* __restrict__ e_s, const unsigned short* __restrict__ xl,
    const int* __restrict__ rowptr, const int* __restrict__ csr,
    const int* __restrict__ src0, const float* __restrict__ bias,
    const float* __restrict__ lng, const float* __restrict__ lnb,
    float* __restrict__ alpha_out, float* __restrict__ xout,
    float* __restrict__ x1out, const float* __restrict__ skipproj, int N, int E) {
  constexpr int CPL = HC / 64;
  int lane = threadIdx.x & 63, wv = threadIdx.x >> 6;
  int stride = gridDim.x * 4;
  for (int n = blockIdx.x * 4 + wv; n < N; n += stride) {
    int r0 = rowptr[n], r1 = rowptr[n + 1];
    float m0 = -1e30f, m1 = -1e30f, m2 = -1e30f, m3 = -1e30f;
    for (int i = r0 + lane; i < r1; i += 64) {
      int e = csr[i];
      float4 v = *reinterpret_cast<const float4*>(e_s + (size_t)e * 4);
      m0 = fmaxf(m0, v.x);
      m1 = fmaxf(m1, v.y);
      m2 = fmaxf(m2, v.z);
      m3 = fmaxf(m3, v.w);
    }
    m0 = wave_max(m0);
    m1 = wave_max(m1);
    m2 = wave_max(m2);
    m3 = wave_max(m3);
    float d0 = 0.f, d1 = 0.f, d2 = 0.f, d3 = 0.f;
    for (int i = r0 + lane; i < r1; i += 64) {
      int e = csr[i];
      float4 v = *reinterpret_cast<const float4*>(e_s + (size_t)e * 4);
      d0 += __expf(v.x - m0);
      d1 += __expf(v.y - m1);
      d2 += __expf(v.z - m2);
      d3 += __expf(v.w - m3);
    }
    d0 = wave_sum(d0);
    d1 = wave_sum(d1);
    d2 = wave_sum(d2);
    d3 = wave_sum(d3);
    float i0 = 1.f / (d0 + 1e-16f), i1 = 1.f / (d1 + 1e-16f);
    float i2 = 1.f / (d2 + 1e-16f), i3 = 1.f / (d3 + 1e-16f);
    int h = lane >> 4;
    float mh = (h & 2) ? ((h & 1) ? m3 : m2) : ((h & 1) ? m1 : m0);
    float ih = (h & 2) ? ((h & 1) ? i3 : i2) : ((h & 1) ? i1 : i0);
    float acc[CPL];
#pragma unroll
    for (int j = 0; j < CPL; j++) acc[j] = 0.f;
    int c0 = lane * CPL;
    for (int i = r0; i < r1; i++) {
      int e = csr[i];
      int sn = (e < E) ? src0[e] : (e - E);
      float a = __expf(e_s[(size_t)e * 4 + h] - mh) * ih;
      if ((lane & 15) == 0) alpha_out[(size_t)e * 4 + h] = a;
      const unsigned short* xp = xl + (size_t)sn * HC + c0;
      if constexpr (CPL == 2) {
        ushort2 t = *(const ushort2*)xp;
        acc[0] += a * bf2f(t.x);
        acc[1] += a * bf2f(t.y);
      } else {
        ushort4 t = *(const ushort4*)xp;
        acc[0] += a * bf2f(t.x);
        acc[1] += a * bf2f(t.y);
        acc[2] += a * bf2f(t.z);
        acc[3] += a * bf2f(t.w);
      }
    }
    float vals[CPL];
    float vs = 0.f, vq = 0.f;
#pragma unroll
    for (int j = 0; j < CPL; j++) {
      float t = acc[j] + bias[c0 + j];
      vals[j] = t;
      vs += t;
      vq += t * t;
    }
    vs = wave_sum(vs);
    vq = wave_sum(vq);
    float mean = vs * (1.f / HC);
    float var = vq * (1.f / HC) - mean * mean;
    float rstd = rsqrtf(fmaxf(var, 0.f) + 1e-5f);
#pragma unroll
    for (int j = 0; j < CPL; j++) {
      int c = c0 + j;
      float y = (vals[j] - mean) * rstd * lng[c] + lnb[c];
      y = leakyf(y, 0.01f);
      if constexpr (L1MODE) {
        x1out[(size_t)n * HC + c] = y;
        xout[(size_t)n * HC + c] = 0.01f * skipproj[(size_t)n * HC + c] + y;
      } else {
        xout[(size_t)n * HC + c] = y;
      }
    }
  }
}

extern "C" void kernel_launch(void* const* d_in, const int* in_sizes, int n_in,
                              void* d_out, int out_size, void* d_ws, size_t ws_size,
                              hipStream_t stream) {
  (void)n_in;
  (void)out_size;
  (void)ws_size;
  const float* x_in = (const float*)d_in[0];
  const int* edge_index = (const int*)d_in[1];
  const float* edge_attr = (const float*)d_in[2];
  const float* bn0_g = (const float*)d_in[3];
  const float* bn0_b = (const float*)d_in[4];
  const float* bn0_m = (const float*)d_in[5];
  const float* bn0_v = (const float*)d_in[6];
  const float* eeW1 = (const float*)d_in[7];
  const float* eeb1 = (const float*)d_in[8];
  const float* eeW2 = (const float*)d_in[9];
  const float* eeb2 = (const float*)d_in[10];
  const float* g1_Wl = (const float*)d_in[11];
  const float* g1_bl = (const float*)d_in[12];
  const float* g1_Wr = (const float*)d_in[13];
  const float* g1_br = (const float*)d_in[14];
  const float* g1_We = (const float*)d_in[15];
  const float* g1_att = (const float*)d_in[16];
  const float* g1_bias = (const float*)d_in[17];
  const float* g2_Wl = (const float*)d_in[18];
  const float* g2_bl = (const float*)d_in[19];
  const float* g2_Wr = (const float*)d_in[20];
  const float* g2_br = (const float*)d_in[21];
  const float* g2_We = (const float*)d_in[22];
  const float* g2_att = (const float*)d_in[23];
  const float* g2_bias = (const float*)d_in[24];
  const float* g3_Wl = (const float*)d_in[25];
  const float* g3_bl = (const float*)d_in[26];
  const float* g3_Wr = (const float*)d_in[27];
  const float* g3_br = (const float*)d_in[28];
  const float* g3_We = (const float*)d_in[29];
  const float* g3_att = (const float*)d_in[30];
  const float* g3_bias = (const float*)d_in[31];
  const float* ln1_g = (const float*)d_in[32];
  const float* ln1_b = (const float*)d_in[33];
  const float* ln2_g = (const float*)d_in[34];
  const float* ln2_b = (const float*)d_in[35];
  const float* ln3_g = (const float*)d_in[36];
  const float* ln3_b = (const float*)d_in[37];
  const float* skip_W = (const float*)d_in[38];
  const float* skip_b = (const float*)d_in[39];
  const float* alpha_p = (const float*)d_in[40];
  const float* fp_W = (const float*)d_in[41];
  const float* fp_b = (const float*)d_in[42];
  const float* np_W1 = (const float*)d_in[43];
  const float* np_b1 = (const float*)d_in[44];
  const float* np_W2 = (const float*)d_in[45];
  const float* np_b2 = (const float*)d_in[46];
  const float* np_W3 = (const float*)d_in[47];
  const float* np_b3 = (const float*)d_in[48];

  const int N = in_sizes[0] / 64;
  const int E = in_sizes[2] / 16;
  const int E2 = E + N;
  const int* src0 = edge_index;
  const int* dst0 = edge_index + E;

  float* ws = (float*)d_ws;
  size_t off = 0;
  float* x = ws + off;         off += (size_t)N * 64;
  unsigned short* ea_bf = (unsigned short*)(ws + off); off += (size_t)E2 * 32;
  unsigned short* xl = (unsigned short*)(ws + off);    off += (size_t)N * 128;  // bf16 [N][256 max]
  unsigned short* xr = (unsigned short*)(ws + off);    off += (size_t)N * 128;
  float* skipproj = ws + off;  off += (size_t)N * 128;  // reused as h1 at the end
  float* x1 = ws + off;        off += (size_t)N * 128;
  float* skip1 = ws + off;     off += (size_t)N * 128;
  float* x2 = ws + off;        off += (size_t)N * 128;
  float* x3 = ws + off;        off += (size_t)N * 256;
  float* e_s = ws + off;       off += (size_t)E2 * 4;
  float* h2 = ws + off;        off += (size_t)N * 64;
  int* counts = (int*)(ws + off);
  int* rowptr = counts + N;
  int* fill = rowptr + N + 1;
  int* csr = fill + N;
  off += (size_t)(3 * N + 1 + E2);
  off = (off + 3) & ~(size_t)3;
  unsigned short* wtp = (unsigned short*)(ws + off);
  auto alloc_wt = [&](int elems) {
    unsigned short* p = wtp;
    wtp += (elems + 7) & ~7;
    return p;
  };
  unsigned short* wt_g1l = alloc_wt(64 * 128);
  unsigned short* wt_g1r = alloc_wt(64 * 128);
  unsigned short* wt_skip = alloc_wt(64 * 128);
  unsigned short* wt_g2l = alloc_wt(128 * 128);
  unsigned short* wt_g2r = alloc_wt(128 * 128);
  unsigned short* wt_g3l = alloc_wt(128 * 256);
  unsigned short* wt_g3r = alloc_wt(128 * 256);
  unsigned short* wt_fp = alloc_wt(128 * 256);
  unsigned short* wt_np1 = alloc_wt(256 * 128);
  unsigned short* wt_np2 = alloc_wt(128 * 64);
  unsigned short* wt_np3 = alloc_wt(64 * 1);
  unsigned short* wt_ee1 = alloc_wt(16 * 128);
  unsigned short* wt_ee2 = alloc_wt(128 * 64);

  float* out = (float*)d_out;
  float* xf = out;
  float* npout = out + (size_t)N * 256;
  float* a1 = npout + N;
  float* a2 = a1 + (size_t)E2 * 4;
  float* a3 = a2 + (size_t)E2 * 4;

  WJobs jobs;
  jobs.j[0] = {g1_Wl, wt_g1l, 64, 128};
  jobs.j[1] = {g1_Wr, wt_g1r, 64, 128};
  jobs.j[2] = {skip_W, wt_skip, 64, 128};
  jobs.j[3] = {g2_Wl, wt_g2l, 128, 128};
  jobs.j[4] = {g2_Wr, wt_g2r, 128, 128};
  jobs.j[5] = {g3_Wl, wt_g3l, 128, 256};
  jobs.j[6] = {g3_Wr, wt_g3r, 128, 256};
  jobs.j[7] = {fp_W, wt_fp, 128, 256};
  jobs.j[8] = {np_W1, wt_np1, 256, 128};
  jobs.j[9] = {np_W2, wt_np2, 128, 64};
  jobs.j[10] = {np_W3, wt_np3, 64, 1};
  jobs.j[11] = {eeW1, wt_ee1, 16, 128};
  jobs.j[12] = {eeW2, wt_ee2, 128, 64};

  hipMemsetAsync(counts, 0, (size_t)N * sizeof(int), stream);
  wt_kernel<<<dim3(64, 13), 256, 0, stream>>>(jobs);
  bn_kernel<<<(N * 64 + 255) / 256, 256, 0, stream>>>(x_in, bn0_g, bn0_b, bn0_m, bn0_v, x, N * 64);
  edge_enc_kernel<<<(E + 63) / 64, 256, 0, stream>>>(edge_attr, wt_ee1, eeb1, wt_ee2, eeb2, ea_bf, E);
  count_kernel<<<(E2 + 255) / 256, 256, 0, stream>>>(dst0, counts, E, E2);
  scan_kernel<<<1, 256, 0, stream>>>(counts, rowptr, fill, N);
  fill_kernel<<<(E2 + 255) / 256, 256, 0, stream>>>(dst0, fill, csr, E, E2);
  loopattr_kernel<<<(N + 3) / 4, 256, 0, stream>>>(ea_bf, rowptr, csr, N, E);

  auto gemm = [&](int mode, const float* A, const unsigned short* BT, const float* bias,
                  void* Cp, int M, int K, int Nc, const float* aux) {
    dim3 gdim((Nc + 63) / 64, (M + 63) / 64);
    switch (mode) {
      case 0: gemm_mfma_kernel<0><<<gdim, 256, 0, stream>>>(A, BT, bias, Cp, M, K, Nc, nullptr, nullptr); break;
      case 1: gemm_mfma_kernel<1><<<gdim, 256, 0, stream>>>(A, BT, bias, Cp, M, K, Nc, nullptr, nullptr); break;
      case 2: gemm_mfma_kernel<2><<<gdim, 256, 0, stream>>>(A, BT, bias, Cp, M, K, Nc, nullptr, nullptr); break;
      case 3: gemm_mfma_kernel<3><<<gdim, 256, 0, stream>>>(A, BT, bias, Cp, M, K, Nc, aux, alpha_p); break;
    }
  };

  const int nblk_node = (N + 3) / 4;
  const int score_blocks = 1024;

  // ---- Layer 1 (din=64, HC=128, C=32) ----
  gemm(1, x, wt_g1l, g1_bl, xl, N, 64, 128, nullptr);
  gemm(1, x, wt_g1r, g1_br, xr, N, 64, 128, nullptr);
  gemm(0, x, wt_skip, skip_b, skipproj, N, 64, 128, nullptr);
  score_mfma_kernel<32><<<score_blocks, 256, 0, stream>>>(ea_bf, xl, xr, g1_We, g1_att, src0, dst0, e_s, E, E2, 128, 0);
  aggr_kernel<128, true><<<nblk_node, 256, 0, stream>>>(e_s, xl, rowptr, csr, src0, g1_bias, ln1_g, ln1_b,
                                                        a1, skip1, x1, skipproj, N, E);
  // ---- Layer 2 (din=128, HC=128, C=32) ----
  gemm(1, skip1, wt_g2l, g2_bl, xl, N, 128, 128, nullptr);
  gemm(1, skip1, wt_g2r, g2_br, xr, N, 128, 128, nullptr);
  score_mfma_kernel<32><<<score_blocks, 256, 0, stream>>>(ea_bf, xl, xr, g2_We, g2_att, src0, dst0, e_s, E, E2, 128, 0);
  aggr_kernel<128, false><<<nblk_node, 256, 0, stream>>>(e_s, xl, rowptr, csr, src0, g2_bias, ln2_g, ln2_b,
                                                         a2, x2, nullptr, nullptr, N, E);
  // ---- Layer 3 (din=128, HC=256, C=64) ----
  gemm(1, x2, wt_g3l, g3_bl, xl, N, 128, 256, nullptr);
  gemm(1, x2, wt_g3r, g3_br, xr, N, 128, 256, nullptr);
  score_mfma_kernel<64><<<score_blocks, 256, 0, stream>>>(ea_bf, xl, xr, g3_We, g3_att, src0, dst0, e_s, E, E2, 256, 0);
  score_mfma_kernel<64><<<score_blocks, 256, 0, stream>>>(ea_bf, xl, xr, g3_We, g3_att, src0, dst0, e_s, E, E2, 256, 128);
  aggr_kernel<256, false><<<nblk_node, 256, 0, stream>>>(e_s, xl, rowptr, csr, src0, g3_bias, ln3_g, ln3_b,
                                                         a3, x3, nullptr, nullptr, N, E);
  // ---- Final: xf = s*(x1@fp_W+fp_b) + (1-s)*x3 ; node MLP ----
  gemm(3, x1, wt_fp, fp_b, xf, N, 128, 256, x3);
  gemm(2, xf, wt_np1, np_b1, skipproj, N, 256, 128, nullptr);   // h1
  gemm(2, skipproj, wt_np2, np_b2, h2, N, 128, 64, nullptr);    // h2
  gemm(0, h2, wt_np3, np_b3, npout, N, 64, 1, nullptr);
}

// Round 10
// 689.288 us; speedup vs baseline: 3.7469x; 1.0445x over previous
//
#include <hip/hip_runtime.h>
#include <math.h>

#define DEV __device__ __forceinline__

typedef __attribute__((ext_vector_type(8))) short bf16x8;
typedef __attribute__((ext_vector_type(4))) float f32x4;

DEV float leakyf(float x, float s) { return x > 0.f ? x : s * x; }

DEV unsigned short f2bf(float f) {
  unsigned u = __float_as_uint(f);
  unsigned r = (u + 0x7fff + ((u >> 16) & 1)) >> 16;
  return (unsigned short)r;
}
DEV float bf2f(unsigned short h) { return __uint_as_float((unsigned)h << 16); }

DEV float wave_sum(float v) {
#pragma unroll
  for (int o = 1; o < 64; o <<= 1) v += __shfl_xor(v, o);
  return v;
}
DEV float wave_max(float v) {
#pragma unroll
  for (int o = 1; o < 64; o <<= 1) v = fmaxf(v, __shfl_xor(v, o));
  return v;
}

// ---------------- weight pre-convert: W[K,Nc] f32 -> WT[Nc,K] bf16 ----------------
struct WJob { const float* in; unsigned short* out; int K; int Nc; };
struct WJobs { WJob j[13]; };

__global__ __launch_bounds__(256) void wt_kernel(WJobs jobs) {
  WJob jb = jobs.j[blockIdx.y];
  int total = jb.K * jb.Nc;
  for (int i = blockIdx.x * 256 + threadIdx.x; i < total; i += gridDim.x * 256) {
    int c = i / jb.K, k = i - c * jb.K;
    jb.out[i] = f2bf(jb.in[(size_t)k * jb.Nc + c]);
  }
}

// ---------------- BatchNorm (eval) ----------------
__global__ __launch_bounds__(256) void bn_kernel(
    const float* __restrict__ xin, const float* __restrict__ g,
    const float* __restrict__ b, const float* __restrict__ m,
    const float* __restrict__ v, float* __restrict__ xout, int total) {
  int i = blockIdx.x * 256 + threadIdx.x;
  if (i < total) {
    int c = i & 63;
    xout[i] = (xin[i] - m[c]) * rsqrtf(v[c] + 1e-5f) * g[c] + b[c];
  }
}

// ---------------- Edge encoder: fully-MFMA fused 2-layer MLP + L2 norm ----------------
__global__ __launch_bounds__(256) void edge_enc_kernel(
    const float* __restrict__ edge_attr, const unsigned short* __restrict__ WT1,
    const float* __restrict__ b1, const unsigned short* __restrict__ WT2,
    const float* __restrict__ b2, unsigned short* __restrict__ ea_bf, int E) {
  __shared__ unsigned short sEa1[64][136];  // bf16, pad 8
  int tid = threadIdx.x, lane = tid & 63, w = tid >> 6;
  int g = lane >> 4, q = lane & 15;
  bf16x8 w1f[8];
#pragma unroll
  for (int t = 0; t < 8; t++) {
    bf16x8 v = {};
    if (g < 2) v = *(const bf16x8*)(WT1 + (size_t)(16 * t + q) * 16 + 8 * g);
    w1f[t] = v;
  }
  float b1v[8];
#pragma unroll
  for (int t = 0; t < 8; t++) b1v[t] = b1[16 * t + q];
  bf16x8 w2f[4][4];
#pragma unroll
  for (int t = 0; t < 4; t++)
#pragma unroll
    for (int kc = 0; kc < 4; kc++)
      w2f[t][kc] = *(const bf16x8*)(WT2 + (size_t)(16 * t + q) * 128 + 32 * kc + 8 * g);
  float b2v[4];
#pragma unroll
  for (int t = 0; t < 4; t++) b2v[t] = b2[16 * t + q];

  int e0 = blockIdx.x * 64 + w * 16;
  bf16x8 af = {};
  if (g < 2) {
    int e = e0 + q;
    if (e >= E) e = E - 1;
    const float* ap = edge_attr + (size_t)e * 16 + 8 * g;
    float4 x0 = *(const float4*)ap;
    float4 x1 = *(const float4*)(ap + 4);
    af[0] = (short)f2bf(x0.x); af[1] = (short)f2bf(x0.y);
    af[2] = (short)f2bf(x0.z); af[3] = (short)f2bf(x0.w);
    af[4] = (short)f2bf(x1.x); af[5] = (short)f2bf(x1.y);
    af[6] = (short)f2bf(x1.z); af[7] = (short)f2bf(x1.w);
  }
  f32x4 acc1[8];
#pragma unroll
  for (int t = 0; t < 8; t++) acc1[t] = (f32x4){0.f, 0.f, 0.f, 0.f};
#pragma unroll
  for (int t = 0; t < 8; t++)
    acc1[t] = __builtin_amdgcn_mfma_f32_16x16x32_bf16(af, w1f[t], acc1[t], 0, 0, 0);
#pragma unroll
  for (int t = 0; t < 8; t++)
#pragma unroll
    for (int r = 0; r < 4; r++) {
      float v = leakyf(acc1[t][r] + b1v[t], 0.01f);
      sEa1[w * 16 + g * 4 + r][16 * t + q] = f2bf(v);
    }
  f32x4 acc2[4];
#pragma unroll
  for (int t = 0; t < 4; t++) acc2[t] = (f32x4){0.f, 0.f, 0.f, 0.f};
#pragma unroll
  for (int kc = 0; kc < 4; kc++) {
    bf16x8 a2 = *(const bf16x8*)&sEa1[w * 16 + q][32 * kc + 8 * g];
#pragma unroll
    for (int t = 0; t < 4; t++)
      acc2[t] = __builtin_amdgcn_mfma_f32_16x16x32_bf16(a2, w2f[t][kc], acc2[t], 0, 0, 0);
  }
#pragma unroll
  for (int r = 0; r < 4; r++) {
    float vv[4];
    float p = 0.f;
#pragma unroll
    for (int t = 0; t < 4; t++) {
      float v = leakyf(acc2[t][r] + b2v[t], 0.01f);
      vv[t] = v;
      p += v * v;
    }
#pragma unroll
    for (int o = 1; o < 16; o <<= 1) p += __shfl_xor(p, o);
    float sc = 1.f / fmaxf(sqrtf(p), 1e-12f);
    int e = e0 + g * 4 + r;
    if (e < E) {
#pragma unroll
      for (int t = 0; t < 4; t++)
        ea_bf[(size_t)e * 64 + 16 * t + q] = f2bf(vv[t] * sc);
    }
  }
}

// ---------------- CSR build ----------------
__global__ __launch_bounds__(256) void count_kernel(const int* __restrict__ dst0,
                                                    int* __restrict__ counts, int E, int E2) {
  int i = blockIdx.x * 256 + threadIdx.x;
  if (i < E2) {
    int d = (i < E) ? dst0[i] : (i - E);
    atomicAdd(&counts[d], 1);
  }
}

__global__ __launch_bounds__(256) void scan_kernel(const int* __restrict__ counts,
                                                   int* __restrict__ rowptr,
                                                   int* __restrict__ fill, int N) {
  __shared__ int part[256];
  int tid = threadIdx.x;
  int chunk = (N + 255) / 256;
  int lo = tid * chunk, hi = lo + chunk;
  if (hi > N) hi = N;
  if (lo > N) lo = N;
  int s = 0;
  for (int i = lo; i < hi; i++) s += counts[i];
  part[tid] = s;
  __syncthreads();
  if (tid == 0) {
    int run = 0;
    for (int i = 0; i < 256; i++) {
      int t = part[i];
      part[i] = run;
      run += t;
    }
    rowptr[N] = run;
  }
  __syncthreads();
  int off = part[tid];
  for (int i = lo; i < hi; i++) {
    rowptr[i] = off;
    fill[i] = off;
    off += counts[i];
  }
}

// builds csr (edge id), srcpos (src node), dstpos (dst node) by CSR position
__global__ __launch_bounds__(256) void fill_kernel(const int* __restrict__ src0,
                                                   const int* __restrict__ dst0,
                                                   int* __restrict__ fill,
                                                   int* __restrict__ csr,
                                                   int* __restrict__ srcpos,
                                                   int* __restrict__ dstpos, int E, int E2) {
  int i = blockIdx.x * 256 + threadIdx.x;
  if (i < E2) {
    int d, s;
    if (i < E) {
      d = dst0[i];
      s = src0[i];
    } else {
      d = s = i - E;
    }
    int pos = atomicAdd(&fill[d], 1);
    csr[pos] = i;
    srcpos[pos] = s;
    dstpos[pos] = d;
  }
}

// ---------------- self-loop attr = mean of incoming encoded attrs (bf16 in/out) ----------------
__global__ __launch_bounds__(256) void loopattr_kernel(unsigned short* __restrict__ ea_bf,
                                                       const int* __restrict__ rowptr,
                                                       const int* __restrict__ csr, int N, int E) {
  int lane = threadIdx.x & 63, wv = threadIdx.x >> 6;
  int stride = gridDim.x * 4;
  for (int n = blockIdx.x * 4 + wv; n < N; n += stride) {
    int r0 = rowptr[n], r1 = rowptr[n + 1];
    float acc = 0.f;
    int cnt = 0;
    for (int i = r0; i < r1; i++) {
      int e = csr[i];
      if (e < E) {
        acc += bf2f(ea_bf[(size_t)e * 64 + lane]);
        cnt++;
      }
    }
    ea_bf[((size_t)E + n) * 64 + lane] = f2bf(acc / fmaxf((float)cnt, 1.f));
  }
}

// ---------------- bf16 MFMA GEMM ----------------
// MODE: 0 f32 out, 1 bf16 out, 2 elu f32 out, 3 mix f32 out
template <int MODE>
__global__ __launch_bounds__(256) void gemm_mfma_kernel(
    const float* __restrict__ A, const unsigned short* __restrict__ BT,
    const float* __restrict__ bias, void* __restrict__ Cout, int M, int K, int Nc,
    const float* __restrict__ aux, const float* __restrict__ alpha_p) {
  __shared__ unsigned short sA[64][40];
  __shared__ unsigned short sB[64][40];
  int tid = threadIdx.x, lane = tid & 63, w = tid >> 6;
  int g = lane >> 4, q = lane & 15;
  int bm = blockIdx.y * 64, bn = blockIdx.x * 64;
  f32x4 acc[4];
#pragma unroll
  for (int t = 0; t < 4; t++) acc[t] = (f32x4){0.f, 0.f, 0.f, 0.f};
  int r = tid >> 2, ko = (tid & 3) * 8;
  for (int k0 = 0; k0 < K; k0 += 32) {
    {
      int gm = bm + r;
      bf16x8 v = {};
      if (gm < M) {
        const float* ap = A + (size_t)gm * K + k0 + ko;
        float4 x0 = *(const float4*)ap;
        float4 x1 = *(const float4*)(ap + 4);
        v[0] = (short)f2bf(x0.x); v[1] = (short)f2bf(x0.y);
        v[2] = (short)f2bf(x0.z); v[3] = (short)f2bf(x0.w);
        v[4] = (short)f2bf(x1.x); v[5] = (short)f2bf(x1.y);
        v[6] = (short)f2bf(x1.z); v[7] = (short)f2bf(x1.w);
      }
      *(bf16x8*)&sA[r][ko] = v;
      int gc = bn + r;
      bf16x8 bv = {};
      if (gc < Nc) bv = *(const bf16x8*)(BT + (size_t)gc * K + k0 + ko);
      *(bf16x8*)&sB[r][ko] = bv;
    }
    __syncthreads();
    bf16x8 a = *(const bf16x8*)&sA[w * 16 + q][8 * g];
#pragma unroll
    for (int t = 0; t < 4; t++) {
      bf16x8 b = *(const bf16x8*)&sB[16 * t + q][8 * g];
      acc[t] = __builtin_amdgcn_mfma_f32_16x16x32_bf16(a, b, acc[t], 0, 0, 0);
    }
    __syncthreads();
  }
  float s = 0.f;
  if (MODE == 3) s = 1.f / (1.f + __expf(-alpha_p[0]));
#pragma unroll
  for (int t = 0; t < 4; t++) {
    int col = bn + 16 * t + q;
#pragma unroll
    for (int rr = 0; rr < 4; rr++) {
      int row = bm + w * 16 + g * 4 + rr;
      if (row < M && col < Nc) {
        float v = acc[t][rr] + bias[col];
        if (MODE == 2) v = v > 0.f ? v : (__expf(v) - 1.f);
        if (MODE == 3) v = s * v + (1.f - s) * aux[(size_t)row * Nc + col];
        if (MODE == 1)
          ((unsigned short*)Cout)[(size_t)row * Nc + col] = f2bf(v);
        else
          ((float*)Cout)[(size_t)row * Nc + col] = v;
      }
    }
  }
}

// ---------------- GATv2 edge scores via MFMA, iterated in CSR-position order ----------------
// e_s is indexed by CSR POSITION (coalesced write here, coalesced read in aggr).
// dstpos runs are clustered (CSR) -> xr row gathers mostly L1/L2-hit.
template <int C>
__global__ __launch_bounds__(256) void score_mfma_kernel(
    const unsigned short* __restrict__ ea_bf, const unsigned short* __restrict__ xl,
    const unsigned short* __restrict__ xr, const float* __restrict__ We,
    const float* __restrict__ att, const int* __restrict__ csr,
    const int* __restrict__ srcpos, const int* __restrict__ dstpos,
    float* __restrict__ e_s, int E2, int HCfull, int col_off) {
  int lane = threadIdx.x & 63;
  int wv = threadIdx.x >> 6;
  int g = lane >> 4, q = lane & 15;
  bf16x8 bfrag[8][2];
#pragma unroll
  for (int t = 0; t < 8; t++)
#pragma unroll
    for (int kc = 0; kc < 2; kc++) {
      bf16x8 bv;
#pragma unroll
      for (int j = 0; j < 8; j++) {
        int k = kc * 32 + g * 8 + j;
        bv[j] = (short)f2bf(We[(size_t)k * HCfull + col_off + 16 * t + q]);
      }
      bfrag[t][kc] = bv;
    }
  float attv[8];
#pragma unroll
  for (int t = 0; t < 8; t++) attv[t] = att[col_off + 16 * t + q];

  constexpr int TPH = C / 16;
  constexpr int NH = 8 / TPH;
  const int headbase = col_off / C;

  int tiles = (E2 + 15) / 16;
  int nw = gridDim.x * 4;
  for (int tile = blockIdx.x * 4 + wv; tile < tiles; tile += nw) {
    int i0 = tile * 16;
    int ia = i0 + q;
    if (ia >= E2) ia = E2 - 1;
    int erow = csr[ia];
    const unsigned short* ap = ea_bf + (size_t)erow * 64 + g * 8;
    bf16x8 a0 = *(const bf16x8*)(ap);
    bf16x8 a1 = *(const bf16x8*)(ap + 32);
    f32x4 acc[8];
#pragma unroll
    for (int t = 0; t < 8; t++) acc[t] = (f32x4){0.f, 0.f, 0.f, 0.f};
#pragma unroll
    for (int t = 0; t < 8; t++) {
      acc[t] = __builtin_amdgcn_mfma_f32_16x16x32_bf16(a0, bfrag[t][0], acc[t], 0, 0, 0);
      acc[t] = __builtin_amdgcn_mfma_f32_16x16x32_bf16(a1, bfrag[t][1], acc[t], 0, 0, 0);
    }
    int sn[4], dn[4];
#pragma unroll
    for (int r = 0; r < 4; r++) {
      int i = i0 + g * 4 + r;
      if (i >= E2) i = E2 - 1;
      sn[r] = srcpos[i];
      dn[r] = dstpos[i];
    }
    float p[NH][4];
#pragma unroll
    for (int hh = 0; hh < NH; hh++)
#pragma unroll
      for (int r = 0; r < 4; r++) p[hh][r] = 0.f;
#pragma unroll
    for (int t = 0; t < 8; t++) {
      int col = col_off + 16 * t + q;
#pragma unroll
      for (int r = 0; r < 4; r++) {
        float xv = bf2f(xl[(size_t)sn[r] * HCfull + col]) +
                   bf2f(xr[(size_t)dn[r] * HCfull + col]) + acc[t][r];
        xv = xv > 0.f ? xv : 0.2f * xv;
        p[t / TPH][r] += xv * attv[t];
      }
    }
#pragma unroll
    for (int hh = 0; hh < NH; hh++)
#pragma unroll
      for (int r = 0; r < 4; r++) {
#pragma unroll
        for (int o = 1; o < 16; o <<= 1) p[hh][r] += __shfl_xor(p[hh][r], o);
      }
    if (q == 0) {
#pragma unroll
      for (int r = 0; r < 4; r++) {
        int i = i0 + g * 4 + r;
        if (i < E2) {
#pragma unroll
          for (int hh = 0; hh < NH; hh++)
            e_s[(size_t)i * 4 + headbase + hh] = p[hh][r];
        }
      }
    }
  }
}

// ---------------- per-node softmax + aggregation; stores md = {m[4], inv_den[4]} ----------------
template <int HC, bool L1MODE>
__global__ __launch_bounds__(256) void aggr_kernel(
    const float* __restrict__ e_s, const unsigned short* __restrict__ xl,
    const int* __restrict__ rowptr, const int* __restrict__ srcpos,
    const float* __restrict__ bias,
    const float* __restrict__ lng, const float* __restrict__ lnb,
    float* __restrict__ xout,
    float* __restrict__ x1out, const float* __restrict__ skipproj,
    float* __restrict__ md, int N) {
  constexpr int CPL = HC / 64;
  int lane = threadIdx.x & 63, wv = threadIdx.x >> 6;
  int stride = gridDim.x * 4;
  const float4* e_s4 = (const float4*)e_s;
  for (int n = blockIdx.x * 4 + wv; n < N; n += stride) {
    int r0 = rowptr[n], r1 = rowptr[n + 1];
    float m0 = -1e30f, m1 = -1e30f, m2 = -1e30f, m3 = -1e30f;
    for (int i = r0 + lane; i < r1; i += 64) {
      float4 v = e_s4[i];
      m0 = fmaxf(m0, v.x);
      m1 = fmaxf(m1, v.y);
      m2 = fmaxf(m2, v.z);
      m3 = fmaxf(m3, v.w);
    }
    m0 = wave_max(m0);
    m1 = wave_max(m1);
    m2 = wave_max(m2);
    m3 = wave_max(m3);
    float d0 = 0.f, d1 = 0.f, d2 = 0.f, d3 = 0.f;
    for (int i = r0 + lane; i < r1; i += 64) {
      float4 v = e_s4[i];
      d0 += __expf(v.x - m0);
      d1 += __expf(v.y - m1);
      d2 += __expf(v.z - m2);
      d3 += __expf(v.w - m3);
    }
    d0 = wave_sum(d0);
    d1 = wave_sum(d1);
    d2 = wave_sum(d2);
    d3 = wave_sum(d3);
    float i0 = 1.f / (d0 + 1e-16f), i1 = 1.f / (d1 + 1e-16f);
    float i2 = 1.f / (d2 + 1e-16f), i3 = 1.f / (d3 + 1e-16f);
    if (lane == 0) {
      float* mp = md + (size_t)n * 8;
      mp[0] = m0; mp[1] = m1; mp[2] = m2; mp[3] = m3;
      mp[4] = i0; mp[5] = i1; mp[6] = i2; mp[7] = i3;
    }
    int h = lane >> 4;
    float mh = (h & 2) ? ((h & 1) ? m3 : m2) : ((h & 1) ? m1 : m0);
    float ih = (h & 2) ? ((h & 1) ? i3 : i2) : ((h & 1) ? i1 : i0);
    float acc[CPL];
#pragma unroll
    for (int j = 0; j < CPL; j++) acc[j] = 0.f;
    int c0 = lane * CPL;
    for (int i = r0; i < r1; i++) {
      float4 sv = e_s4[i];
      float sh = ((const float*)&sv)[h];
      float a = __expf(sh - mh) * ih;
      int sn = srcpos[i];
      const unsigned short* xp = xl + (size_t)sn * HC + c0;
      if constexpr (CPL == 2) {
        ushort2 t = *(const ushort2*)xp;
        acc[0] += a * bf2f(t.x);
        acc[1] += a * bf2f(t.y);
      } else {
        ushort4 t = *(const ushort4*)xp;
        acc[0] += a * bf2f(t.x);
        acc[1] += a * bf2f(t.y);
        acc[2] += a * bf2f(t.z);
        acc[3] += a * bf2f(t.w);
      }
    }
    float vals[CPL];
    float vs = 0.f, vq = 0.f;
#pragma unroll
    for (int j = 0; j < CPL; j++) {
      float t = acc[j] + bias[c0 + j];
      vals[j] = t;
      vs += t;
      vq += t * t;
    }
    vs = wave_sum(vs);
    vq = wave_sum(vq);
    float mean = vs * (1.f / HC);
    float var = vq * (1.f / HC) - mean * mean;
    float rstd = rsqrtf(fmaxf(var, 0.f) + 1e-5f);
#pragma unroll
    for (int j = 0; j < CPL; j++) {
      int c = c0 + j;
      float y = (vals[j] - mean) * rstd * lng[c] + lnb[c];
      y = leakyf(y, 0.01f);
      if constexpr (L1MODE) {
        x1out[(size_t)n * HC + c] = y;
        xout[(size_t)n * HC + c] = 0.01f * skipproj[(size_t)n * HC + c] + y;
      } else {
        xout[(size_t)n * HC + c] = y;
      }
    }
  }
}

// ---------------- alpha: coalesced e_s/dstpos read, md L2-hit, one scattered 16B write ----------------
__global__ __launch_bounds__(256) void alpha_kernel(
    const float* __restrict__ e_s, const int* __restrict__ csr,
    const int* __restrict__ dstpos, const float* __restrict__ md,
    float* __restrict__ alpha_out, int E2) {
  int i = blockIdx.x * 256 + threadIdx.x;
  if (i < E2) {
    float4 sv = ((const float4*)e_s)[i];
    int d = dstpos[i];
    const float* mp = md + (size_t)d * 8;
    float4 a;
    a.x = __expf(sv.x - mp[0]) * mp[4];
    a.y = __expf(sv.y - mp[1]) * mp[5];
    a.z = __expf(sv.z - mp[2]) * mp[6];
    a.w = __expf(sv.w - mp[3]) * mp[7];
    ((float4*)alpha_out)[csr[i]] = a;
  }
}

extern "C" void kernel_launch(void* const* d_in, const int* in_sizes, int n_in,
                              void* d_out, int out_size, void* d_ws, size_t ws_size,
                              hipStream_t stream) {
  (void)n_in;
  (void)out_size;
  (void)ws_size;
  const float* x_in = (const float*)d_in[0];
  const int* edge_index = (const int*)d_in[1];
  const float* edge_attr = (const float*)d_in[2];
  const float* bn0_g = (const float*)d_in[3];
  const float* bn0_b = (const float*)d_in[4];
  const float* bn0_m = (const float*)d_in[5];
  const float* bn0_v = (const float*)d_in[6];
  const float* eeW1 = (const float*)d_in[7];
  const float* eeb1 = (const float*)d_in[8];
  const float* eeW2 = (const float*)d_in[9];
  const float* eeb2 = (const float*)d_in[10];
  const float* g1_Wl = (const float*)d_in[11];
  const float* g1_bl = (const float*)d_in[12];
  const float* g1_Wr = (const float*)d_in[13];
  const float* g1_br = (const float*)d_in[14];
  const float* g1_We = (const float*)d_in[15];
  const float* g1_att = (const float*)d_in[16];
  const float* g1_bias = (const float*)d_in[17];
  const float* g2_Wl = (const float*)d_in[18];
  const float* g2_bl = (const float*)d_in[19];
  const float* g2_Wr = (const float*)d_in[20];
  const float* g2_br = (const float*)d_in[21];
  const float* g2_We = (const float*)d_in[22];
  const float* g2_att = (const float*)d_in[23];
  const float* g2_bias = (const float*)d_in[24];
  const float* g3_Wl = (const float*)d_in[25];
  const float* g3_bl = (const float*)d_in[26];
  const float* g3_Wr = (const float*)d_in[27];
  const float* g3_br = (const float*)d_in[28];
  const float* g3_We = (const float*)d_in[29];
  const float* g3_att = (const float*)d_in[30];
  const float* g3_bias = (const float*)d_in[31];
  const float* ln1_g = (const float*)d_in[32];
  const float* ln1_b = (const float*)d_in[33];
  const float* ln2_g = (const float*)d_in[34];
  const float* ln2_b = (const float*)d_in[35];
  const float* ln3_g = (const float*)d_in[36];
  const float* ln3_b = (const float*)d_in[37];
  const float* skip_W = (const float*)d_in[38];
  const float* skip_b = (const float*)d_in[39];
  const float* alpha_p = (const float*)d_in[40];
  const float* fp_W = (const float*)d_in[41];
  const float* fp_b = (const float*)d_in[42];
  const float* np_W1 = (const float*)d_in[43];
  const float* np_b1 = (const float*)d_in[44];
  const float* np_W2 = (const float*)d_in[45];
  const float* np_b2 = (const float*)d_in[46];
  const float* np_W3 = (const float*)d_in[47];
  const float* np_b3 = (const float*)d_in[48];

  const int N = in_sizes[0] / 64;
  const int E = in_sizes[2] / 16;
  const int E2 = E + N;
  const int* src0 = edge_index;
  const int* dst0 = edge_index + E;

  float* ws = (float*)d_ws;
  size_t off = 0;
  float* x = ws + off;         off += (size_t)N * 64;
  unsigned short* ea_bf = (unsigned short*)(ws + off); off += (size_t)E2 * 32;
  unsigned short* xl = (unsigned short*)(ws + off);    off += (size_t)N * 128;
  unsigned short* xr = (unsigned short*)(ws + off);    off += (size_t)N * 128;
  float* skipproj = ws + off;  off += (size_t)N * 128;  // reused as h1 at the end
  float* x1 = ws + off;        off += (size_t)N * 128;
  float* skip1 = ws + off;     off += (size_t)N * 128;
  float* x2 = ws + off;        off += (size_t)N * 128;
  float* x3 = ws + off;        off += (size_t)N * 256;
  float* e_s = ws + off;       off += (size_t)E2 * 4;
  float* h2 = ws + off;        off += (size_t)N * 64;
  float* md = ws + off;        off += (size_t)N * 8;
  int* counts = (int*)(ws + off);
  int* rowptr = counts + N;
  int* fill = rowptr + N + 1;
  int* csr = fill + N;
  int* srcpos = csr + E2;
  int* dstpos = srcpos + E2;
  off += (size_t)(3 * N + 1 + 3 * E2);
  off = (off + 3) & ~(size_t)3;
  unsigned short* wtp = (unsigned short*)(ws + off);
  auto alloc_wt = [&](int elems) {
    unsigned short* p = wtp;
    wtp += (elems + 7) & ~7;
    return p;
  };
  unsigned short* wt_g1l = alloc_wt(64 * 128);
  unsigned short* wt_g1r = alloc_wt(64 * 128);
  unsigned short* wt_skip = alloc_wt(64 * 128);
  unsigned short* wt_g2l = alloc_wt(128 * 128);
  unsigned short* wt_g2r = alloc_wt(128 * 128);
  unsigned short* wt_g3l = alloc_wt(128 * 256);
  unsigned short* wt_g3r = alloc_wt(128 * 256);
  unsigned short* wt_fp = alloc_wt(128 * 256);
  unsigned short* wt_np1 = alloc_wt(256 * 128);
  unsigned short* wt_np2 = alloc_wt(128 * 64);
  unsigned short* wt_np3 = alloc_wt(64 * 1);
  unsigned short* wt_ee1 = alloc_wt(16 * 128);
  unsigned short* wt_ee2 = alloc_wt(128 * 64);

  float* out = (float*)d_out;
  float* xf = out;
  float* npout = out + (size_t)N * 256;
  float* a1 = npout + N;
  float* a2 = a1 + (size_t)E2 * 4;
  float* a3 = a2 + (size_t)E2 * 4;

  WJobs jobs;
  jobs.j[0] = {g1_Wl, wt_g1l, 64, 128};
  jobs.j[1] = {g1_Wr, wt_g1r, 64, 128};
  jobs.j[2] = {skip_W, wt_skip, 64, 128};
  jobs.j[3] = {g2_Wl, wt_g2l, 128, 128};
  jobs.j[4] = {g2_Wr, wt_g2r, 128, 128};
  jobs.j[5] = {g3_Wl, wt_g3l, 128, 256};
  jobs.j[6] = {g3_Wr, wt_g3r, 128, 256};
  jobs.j[7] = {fp_W, wt_fp, 128, 256};
  jobs.j[8] = {np_W1, wt_np1, 256, 128};
  jobs.j[9] = {np_W2, wt_np2, 128, 64};
  jobs.j[10] = {np_W3, wt_np3, 64, 1};
  jobs.j[11] = {eeW1, wt_ee1, 16, 128};
  jobs.j[12] = {eeW2, wt_ee2, 128, 64};

  hipMemsetAsync(counts, 0, (size_t)N * sizeof(int), stream);
  wt_kernel<<<dim3(64, 13), 256, 0, stream>>>(jobs);
  bn_kernel<<<(N * 64 + 255) / 256, 256, 0, stream>>>(x_in, bn0_g, bn0_b, bn0_m, bn0_v, x, N * 64);
  edge_enc_kernel<<<(E + 63) / 64, 256, 0, stream>>>(edge_attr, wt_ee1, eeb1, wt_ee2, eeb2, ea_bf, E);
  count_kernel<<<(E2 + 255) / 256, 256, 0, stream>>>(dst0, counts, E, E2);
  scan_kernel<<<1, 256, 0, stream>>>(counts, rowptr, fill, N);
  fill_kernel<<<(E2 + 255) / 256, 256, 0, stream>>>(src0, dst0, fill, csr, srcpos, dstpos, E, E2);
  loopattr_kernel<<<(N + 3) / 4, 256, 0, stream>>>(ea_bf, rowptr, csr, N, E);

  auto gemm = [&](int mode, const float* A, const unsigned short* BT, const float* bias,
                  void* Cp, int M, int K, int Nc, const float* aux) {
    dim3 gdim((Nc + 63) / 64, (M + 63) / 64);
    switch (mode) {
      case 0: gemm_mfma_kernel<0><<<gdim, 256, 0, stream>>>(A, BT, bias, Cp, M, K, Nc, nullptr, nullptr); break;
      case 1: gemm_mfma_kernel<1><<<gdim, 256, 0, stream>>>(A, BT, bias, Cp, M, K, Nc, nullptr, nullptr); break;
      case 2: gemm_mfma_kernel<2><<<gdim, 256, 0, stream>>>(A, BT, bias, Cp, M, K, Nc, nullptr, nullptr); break;
      case 3: gemm_mfma_kernel<3><<<gdim, 256, 0, stream>>>(A, BT, bias, Cp, M, K, Nc, aux, alpha_p); break;
    }
  };

  const int nblk_node = (N + 3) / 4;
  const int score_blocks = 1024;
  const int nblk_edge = (E2 + 255) / 256;

  // ---- Layer 1 (din=64, HC=128, C=32) ----
  gemm(1, x, wt_g1l, g1_bl, xl, N, 64, 128, nullptr);
  gemm(1, x, wt_g1r, g1_br, xr, N, 64, 128, nullptr);
  gemm(0, x, wt_skip, skip_b, skipproj, N, 64, 128, nullptr);
  score_mfma_kernel<32><<<score_blocks, 256, 0, stream>>>(ea_bf, xl, xr, g1_We, g1_att, csr, srcpos, dstpos, e_s, E2, 128, 0);
  aggr_kernel<128, true><<<nblk_node, 256, 0, stream>>>(e_s, xl, rowptr, srcpos, g1_bias, ln1_g, ln1_b,
                                                        skip1, x1, skipproj, md, N);
  alpha_kernel<<<nblk_edge, 256, 0, stream>>>(e_s, csr, dstpos, md, a1, E2);
  // ---- Layer 2 (din=128, HC=128, C=32) ----
  gemm(1, skip1, wt_g2l, g2_bl, xl, N, 128, 128, nullptr);
  gemm(1, skip1, wt_g2r, g2_br, xr, N, 128, 128, nullptr);
  score_mfma_kernel<32><<<score_blocks, 256, 0, stream>>>(ea_bf, xl, xr, g2_We, g2_att, csr, srcpos, dstpos, e_s, E2, 128, 0);
  aggr_kernel<128, false><<<nblk_node, 256, 0, stream>>>(e_s, xl, rowptr, srcpos, g2_bias, ln2_g, ln2_b,
                                                         x2, nullptr, nullptr, md, N);
  alpha_kernel<<<nblk_edge, 256, 0, stream>>>(e_s, csr, dstpos, md, a2, E2);
  // ---- Layer 3 (din=128, HC=256, C=64) ----
  gemm(1, x2, wt_g3l, g3_bl, xl, N, 128, 256, nullptr);
  gemm(1, x2, wt_g3r, g3_br, xr, N, 128, 256, nullptr);
  score_mfma_kernel<64><<<score_blocks, 256, 0, stream>>>(ea_bf, xl, xr, g3_We, g3_att, csr, srcpos, dstpos, e_s, E2, 256, 0);
  score_mfma_kernel<64><<<score_blocks, 256, 0, stream>>>(ea_bf, xl, xr, g3_We, g3_att, csr, srcpos, dstpos, e_s, E2, 256, 128);
  aggr_kernel<256, false><<<nblk_node, 256, 0, stream>>>(e_s, xl, rowptr, srcpos, g3_bias, ln3_g, ln3_b,
                                                         x3, nullptr, nullptr, md, N);
  alpha_kernel<<<nblk_edge, 256, 0, stream>>>(e_s, csr, dstpos, md, a3, E2);
  // ---- Final: xf = s*(x1@fp_W+fp_b) + (1-s)*x3 ; node MLP ----
  gemm(3, x1, wt_fp, fp_b, xf, N, 128, 256, x3);
  gemm(2, xf, wt_np1, np_b1, skipproj, N, 256, 128, nullptr);   // h1
  gemm(2, skipproj, wt_np2, np_b2, h2, N, 128, 64, nullptr);    // h2
  gemm(0, h2, wt_np3, np_b3, npout, N, 64, 1, nullptr);
}

// Round 12
// 678.160 us; speedup vs baseline: 3.8084x; 1.0164x over previous
//
#include <hip/hip_runtime.h>
#include <math.h>

#define DEV __device__ __forceinline__

typedef __attribute__((ext_vector_type(8))) short bf16x8;
typedef __attribute__((ext_vector_type(4))) float f32x4;

DEV float leakyf(float x, float s) { return x > 0.f ? x : s * x; }

DEV unsigned short f2bf(float f) {
  unsigned u = __float_as_uint(f);
  unsigned r = (u + 0x7fff + ((u >> 16) & 1)) >> 16;
  return (unsigned short)r;
}
DEV float bf2f(unsigned short h) { return __uint_as_float((unsigned)h << 16); }

DEV float wave_sum(float v) {
#pragma unroll
  for (int o = 1; o < 64; o <<= 1) v += __shfl_xor(v, o);
  return v;
}
DEV float wave_max(float v) {
#pragma unroll
  for (int o = 1; o < 64; o <<= 1) v = fmaxf(v, __shfl_xor(v, o));
  return v;
}

// ---------------- weight pre-convert: W[K,Nc] f32 -> WT[Nc,K] bf16 ----------------
struct WJob { const float* in; unsigned short* out; int K; int Nc; };
struct WJobs { WJob j[13]; };

__global__ __launch_bounds__(256) void wt_kernel(WJobs jobs) {
  WJob jb = jobs.j[blockIdx.y];
  int total = jb.K * jb.Nc;
  for (int i = blockIdx.x * 256 + threadIdx.x; i < total; i += gridDim.x * 256) {
    int c = i / jb.K, k = i - c * jb.K;
    jb.out[i] = f2bf(jb.in[(size_t)k * jb.Nc + c]);
  }
}

// ---------------- BatchNorm (eval) ----------------
__global__ __launch_bounds__(256) void bn_kernel(
    const float* __restrict__ xin, const float* __restrict__ g,
    const float* __restrict__ b, const float* __restrict__ m,
    const float* __restrict__ v, float* __restrict__ xout, int total) {
  int i = blockIdx.x * 256 + threadIdx.x;
  if (i < total) {
    int c = i & 63;
    xout[i] = (xin[i] - m[c]) * rsqrtf(v[c] + 1e-5f) * g[c] + b[c];
  }
}

// ---------------- Edge encoder: fully-MFMA fused 2-layer MLP + L2 norm ----------------
__global__ __launch_bounds__(256) void edge_enc_kernel(
    const float* __restrict__ edge_attr, const unsigned short* __restrict__ WT1,
    const float* __restrict__ b1, const unsigned short* __restrict__ WT2,
    const float* __restrict__ b2, unsigned short* __restrict__ ea_bf, int E) {
  __shared__ unsigned short sEa1[64][136];  // bf16, pad 8
  int tid = threadIdx.x, lane = tid & 63, w = tid >> 6;
  int g = lane >> 4, q = lane & 15;
  bf16x8 w1f[8];
#pragma unroll
  for (int t = 0; t < 8; t++) {
    bf16x8 v = {};
    if (g < 2) v = *(const bf16x8*)(WT1 + (size_t)(16 * t + q) * 16 + 8 * g);
    w1f[t] = v;
  }
  float b1v[8];
#pragma unroll
  for (int t = 0; t < 8; t++) b1v[t] = b1[16 * t + q];
  bf16x8 w2f[4][4];
#pragma unroll
  for (int t = 0; t < 4; t++)
#pragma unroll
    for (int kc = 0; kc < 4; kc++)
      w2f[t][kc] = *(const bf16x8*)(WT2 + (size_t)(16 * t + q) * 128 + 32 * kc + 8 * g);
  float b2v[4];
#pragma unroll
  for (int t = 0; t < 4; t++) b2v[t] = b2[16 * t + q];

  int e0 = blockIdx.x * 64 + w * 16;
  bf16x8 af = {};
  if (g < 2) {
    int e = e0 + q;
    if (e >= E) e = E - 1;
    const float* ap = edge_attr + (size_t)e * 16 + 8 * g;
    float4 x0 = *(const float4*)ap;
    float4 x1 = *(const float4*)(ap + 4);
    af[0] = (short)f2bf(x0.x); af[1] = (short)f2bf(x0.y);
    af[2] = (short)f2bf(x0.z); af[3] = (short)f2bf(x0.w);
    af[4] = (short)f2bf(x1.x); af[5] = (short)f2bf(x1.y);
    af[6] = (short)f2bf(x1.z); af[7] = (short)f2bf(x1.w);
  }
  f32x4 acc1[8];
#pragma unroll
  for (int t = 0; t < 8; t++) acc1[t] = (f32x4){0.f, 0.f, 0.f, 0.f};
#pragma unroll
  for (int t = 0; t < 8; t++)
    acc1[t] = __builtin_amdgcn_mfma_f32_16x16x32_bf16(af, w1f[t], acc1[t], 0, 0, 0);
#pragma unroll
  for (int t = 0; t < 8; t++)
#pragma unroll
    for (int r = 0; r < 4; r++) {
      float v = leakyf(acc1[t][r] + b1v[t], 0.01f);
      sEa1[w * 16 + g * 4 + r][16 * t + q] = f2bf(v);
    }
  f32x4 acc2[4];
#pragma unroll
  for (int t = 0; t < 4; t++) acc2[t] = (f32x4){0.f, 0.f, 0.f, 0.f};
#pragma unroll
  for (int kc = 0; kc < 4; kc++) {
    bf16x8 a2 = *(const bf16x8*)&sEa1[w * 16 + q][32 * kc + 8 * g];
#pragma unroll
    for (int t = 0; t < 4; t++)
      acc2[t] = __builtin_amdgcn_mfma_f32_16x16x32_bf16(a2, w2f[t][kc], acc2[t], 0, 0, 0);
  }
#pragma unroll
  for (int r = 0; r < 4; r++) {
    float vv[4];
    float p = 0.f;
#pragma unroll
    for (int t = 0; t < 4; t++) {
      float v = leakyf(acc2[t][r] + b2v[t], 0.01f);
      vv[t] = v;
      p += v * v;
    }
#pragma unroll
    for (int o = 1; o < 16; o <<= 1) p += __shfl_xor(p, o);
    float sc = 1.f / fmaxf(sqrtf(p), 1e-12f);
    int e = e0 + g * 4 + r;
    if (e < E) {
#pragma unroll
      for (int t = 0; t < 4; t++)
        ea_bf[(size_t)e * 64 + 16 * t + q] = f2bf(vv[t] * sc);
    }
  }
}

// ---------------- CSR build ----------------
__global__ __launch_bounds__(256) void count_kernel(const int* __restrict__ dst0,
                                                    int* __restrict__ counts, int E, int E2) {
  int i = blockIdx.x * 256 + threadIdx.x;
  if (i < E2) {
    int d = (i < E) ? dst0[i] : (i - E);
    atomicAdd(&counts[d], 1);
  }
}

__global__ __launch_bounds__(256) void scan_kernel(const int* __restrict__ counts,
                                                   int* __restrict__ rowptr,
                                                   int* __restrict__ fill, int N) {
  __shared__ int part[256];
  int tid = threadIdx.x;
  int chunk = (N + 255) / 256;
  int lo = tid * chunk, hi = lo + chunk;
  if (hi > N) hi = N;
  if (lo > N) lo = N;
  int s = 0;
  for (int i = lo; i < hi; i++) s += counts[i];
  part[tid] = s;
  __syncthreads();
  if (tid == 0) {
    int run = 0;
    for (int i = 0; i < 256; i++) {
      int t = part[i];
      part[i] = run;
      run += t;
    }
    rowptr[N] = run;
  }
  __syncthreads();
  int off = part[tid];
  for (int i = lo; i < hi; i++) {
    rowptr[i] = off;
    fill[i] = off;
    off += counts[i];
  }
}

// builds csr (edge id), srcpos (src node), dstpos (dst node) by CSR position
__global__ __launch_bounds__(256) void fill_kernel(const int* __restrict__ src0,
                                                   const int* __restrict__ dst0,
                                                   int* __restrict__ fill,
                                                   int* __restrict__ csr,
                                                   int* __restrict__ srcpos,
                                                   int* __restrict__ dstpos, int E, int E2) {
  int i = blockIdx.x * 256 + threadIdx.x;
  if (i < E2) {
    int d, s;
    if (i < E) {
      d = dst0[i];
      s = src0[i];
    } else {
      d = s = i - E;
    }
    int pos = atomicAdd(&fill[d], 1);
    csr[pos] = i;
    srcpos[pos] = s;
    dstpos[pos] = d;
  }
}

// ---------------- self-loop attr = mean of incoming encoded attrs (bf16 in/out) ----------------
__global__ __launch_bounds__(256) void loopattr_kernel(unsigned short* __restrict__ ea_bf,
                                                       const int* __restrict__ rowptr,
                                                       const int* __restrict__ csr, int N, int E) {
  int lane = threadIdx.x & 63, wv = threadIdx.x >> 6;
  int stride = gridDim.x * 4;
  for (int n = blockIdx.x * 4 + wv; n < N; n += stride) {
    int r0 = rowptr[n], r1 = rowptr[n + 1];
    float acc = 0.f;
    int cnt = 0;
    for (int i = r0; i < r1; i++) {
      int e = csr[i];
      if (e < E) {
        acc += bf2f(ea_bf[(size_t)e * 64 + lane]);
        cnt++;
      }
    }
    ea_bf[((size_t)E + n) * 64 + lane] = f2bf(acc / fmaxf((float)cnt, 1.f));
  }
}

// ---------------- bf16 MFMA GEMM ----------------
// MODE: 0 f32 out, 1 bf16 out, 2 elu f32 out, 3 mix f32 out
template <int MODE>
__global__ __launch_bounds__(256) void gemm_mfma_kernel(
    const float* __restrict__ A, const unsigned short* __restrict__ BT,
    const float* __restrict__ bias, void* __restrict__ Cout, int M, int K, int Nc,
    const float* __restrict__ aux, const float* __restrict__ alpha_p) {
  __shared__ unsigned short sA[64][40];
  __shared__ unsigned short sB[64][40];
  int tid = threadIdx.x, lane = tid & 63, w = tid >> 6;
  int g = lane >> 4, q = lane & 15;
  int bm = blockIdx.y * 64, bn = blockIdx.x * 64;
  f32x4 acc[4];
#pragma unroll
  for (int t = 0; t < 4; t++) acc[t] = (f32x4){0.f, 0.f, 0.f, 0.f};
  int r = tid >> 2, ko = (tid & 3) * 8;
  for (int k0 = 0; k0 < K; k0 += 32) {
    {
      int gm = bm + r;
      bf16x8 v = {};
      if (gm < M) {
        const float* ap = A + (size_t)gm * K + k0 + ko;
        float4 x0 = *(const float4*)ap;
        float4 x1 = *(const float4*)(ap + 4);
        v[0] = (short)f2bf(x0.x); v[1] = (short)f2bf(x0.y);
        v[2] = (short)f2bf(x0.z); v[3] = (short)f2bf(x0.w);
        v[4] = (short)f2bf(x1.x); v[5] = (short)f2bf(x1.y);
        v[6] = (short)f2bf(x1.z); v[7] = (short)f2bf(x1.w);
      }
      *(bf16x8*)&sA[r][ko] = v;
      int gc = bn + r;
      bf16x8 bv = {};
      if (gc < Nc) bv = *(const bf16x8*)(BT + (size_t)gc * K + k0 + ko);
      *(bf16x8*)&sB[r][ko] = bv;
    }
    __syncthreads();
    bf16x8 a = *(const bf16x8*)&sA[w * 16 + q][8 * g];
#pragma unroll
    for (int t = 0; t < 4; t++) {
      bf16x8 b = *(const bf16x8*)&sB[16 * t + q][8 * g];
      acc[t] = __builtin_amdgcn_mfma_f32_16x16x32_bf16(a, b, acc[t], 0, 0, 0);
    }
    __syncthreads();
  }
  float s = 0.f;
  if (MODE == 3) s = 1.f / (1.f + __expf(-alpha_p[0]));
#pragma unroll
  for (int t = 0; t < 4; t++) {
    int col = bn + 16 * t + q;
#pragma unroll
    for (int rr = 0; rr < 4; rr++) {
      int row = bm + w * 16 + g * 4 + rr;
      if (row < M && col < Nc) {
        float v = acc[t][rr] + bias[col];
        if (MODE == 2) v = v > 0.f ? v : (__expf(v) - 1.f);
        if (MODE == 3) v = s * v + (1.f - s) * aux[(size_t)row * Nc + col];
        if (MODE == 1)
          ((unsigned short*)Cout)[(size_t)row * Nc + col] = f2bf(v);
        else
          ((float*)Cout)[(size_t)row * Nc + col] = v;
      }
    }
  }
}

// ---------------- GATv2 edge scores via MFMA, iterated in CSR-position order ----------------
template <int C>
__global__ __launch_bounds__(256) void score_mfma_kernel(
    const unsigned short* __restrict__ ea_bf, const unsigned short* __restrict__ xl,
    const unsigned short* __restrict__ xr, const float* __restrict__ We,
    const float* __restrict__ att, const int* __restrict__ csr,
    const int* __restrict__ srcpos, const int* __restrict__ dstpos,
    float* __restrict__ e_s, int E2, int HCfull, int col_off) {
  int lane = threadIdx.x & 63;
  int wv = threadIdx.x >> 6;
  int g = lane >> 4, q = lane & 15;
  bf16x8 bfrag[8][2];
#pragma unroll
  for (int t = 0; t < 8; t++)
#pragma unroll
    for (int kc = 0; kc < 2; kc++) {
      bf16x8 bv;
#pragma unroll
      for (int j = 0; j < 8; j++) {
        int k = kc * 32 + g * 8 + j;
        bv[j] = (short)f2bf(We[(size_t)k * HCfull + col_off + 16 * t + q]);
      }
      bfrag[t][kc] = bv;
    }
  float attv[8];
#pragma unroll
  for (int t = 0; t < 8; t++) attv[t] = att[col_off + 16 * t + q];

  constexpr int TPH = C / 16;
  constexpr int NH = 8 / TPH;
  const int headbase = col_off / C;

  int tiles = (E2 + 15) / 16;
  int nw = gridDim.x * 4;
  for (int tile = blockIdx.x * 4 + wv; tile < tiles; tile += nw) {
    int i0 = tile * 16;
    int ia = i0 + q;
    if (ia >= E2) ia = E2 - 1;
    int erow = csr[ia];
    const unsigned short* ap = ea_bf + (size_t)erow * 64 + g * 8;
    bf16x8 a0 = *(const bf16x8*)(ap);
    bf16x8 a1 = *(const bf16x8*)(ap + 32);
    f32x4 acc[8];
#pragma unroll
    for (int t = 0; t < 8; t++) acc[t] = (f32x4){0.f, 0.f, 0.f, 0.f};
#pragma unroll
    for (int t = 0; t < 8; t++) {
      acc[t] = __builtin_amdgcn_mfma_f32_16x16x32_bf16(a0, bfrag[t][0], acc[t], 0, 0, 0);
      acc[t] = __builtin_amdgcn_mfma_f32_16x16x32_bf16(a1, bfrag[t][1], acc[t], 0, 0, 0);
    }
    int sn[4], dn[4];
#pragma unroll
    for (int r = 0; r < 4; r++) {
      int i = i0 + g * 4 + r;
      if (i >= E2) i = E2 - 1;
      sn[r] = srcpos[i];
      dn[r] = dstpos[i];
    }
    float p[NH][4];
#pragma unroll
    for (int hh = 0; hh < NH; hh++)
#pragma unroll
      for (int r = 0; r < 4; r++) p[hh][r] = 0.f;
#pragma unroll
    for (int t = 0; t < 8; t++) {
      int col = col_off + 16 * t + q;
#pragma unroll
      for (int r = 0; r < 4; r++) {
        float xv = bf2f(xl[(size_t)sn[r] * HCfull + col]) +
                   bf2f(xr[(size_t)dn[r] * HCfull + col]) + acc[t][r];
        xv = xv > 0.f ? xv : 0.2f * xv;
        p[t / TPH][r] += xv * attv[t];
      }
    }
#pragma unroll
    for (int hh = 0; hh < NH; hh++)
#pragma unroll
      for (int r = 0; r < 4; r++) {
#pragma unroll
        for (int o = 1; o < 16; o <<= 1) p[hh][r] += __shfl_xor(p[hh][r], o);
      }
    if (q == 0) {
#pragma unroll
      for (int r = 0; r < 4; r++) {
        int i = i0 + g * 4 + r;
        if (i < E2) {
#pragma unroll
          for (int hh = 0; hh < NH; hh++)
            e_s[(size_t)i * 4 + headbase + hh] = p[hh][r];
        }
      }
    }
  }
}

// ---------------- per-node softmax + aggregation; 4x-unrolled gather for MLP ----------------
template <int HC, bool L1MODE>
__global__ __launch_bounds__(256) void aggr_kernel(
    const float* __restrict__ e_s, const unsigned short* __restrict__ xl,
    const int* __restrict__ rowptr, const int* __restrict__ srcpos,
    const float* __restrict__ bias,
    const float* __restrict__ lng, const float* __restrict__ lnb,
    float* __restrict__ xout,
    float* __restrict__ x1out, const float* __restrict__ skipproj,
    float* __restrict__ md, int N) {
  constexpr int CPL = HC / 64;
  int lane = threadIdx.x & 63, wv = threadIdx.x >> 6;
  int stride = gridDim.x * 4;
  const float4* e_s4 = (const float4*)e_s;
  for (int n = blockIdx.x * 4 + wv; n < N; n += stride) {
    int r0 = rowptr[n], r1 = rowptr[n + 1];
    float m0 = -1e30f, m1 = -1e30f, m2 = -1e30f, m3 = -1e30f;
    for (int i = r0 + lane; i < r1; i += 64) {
      float4 v = e_s4[i];
      m0 = fmaxf(m0, v.x);
      m1 = fmaxf(m1, v.y);
      m2 = fmaxf(m2, v.z);
      m3 = fmaxf(m3, v.w);
    }
    m0 = wave_max(m0);
    m1 = wave_max(m1);
    m2 = wave_max(m2);
    m3 = wave_max(m3);
    float d0 = 0.f, d1 = 0.f, d2 = 0.f, d3 = 0.f;
    for (int i = r0 + lane; i < r1; i += 64) {
      float4 v = e_s4[i];
      d0 += __expf(v.x - m0);
      d1 += __expf(v.y - m1);
      d2 += __expf(v.z - m2);
      d3 += __expf(v.w - m3);
    }
    d0 = wave_sum(d0);
    d1 = wave_sum(d1);
    d2 = wave_sum(d2);
    d3 = wave_sum(d3);
    float i0 = 1.f / (d0 + 1e-16f), i1 = 1.f / (d1 + 1e-16f);
    float i2 = 1.f / (d2 + 1e-16f), i3 = 1.f / (d3 + 1e-16f);
    if (lane == 0) {
      float* mp = md + (size_t)n * 8;
      mp[0] = m0; mp[1] = m1; mp[2] = m2; mp[3] = m3;
      mp[4] = i0; mp[5] = i1; mp[6] = i2; mp[7] = i3;
    }
    int h = lane >> 4;
    float mh = (h & 2) ? ((h & 1) ? m3 : m2) : ((h & 1) ? m1 : m0);
    float ih = (h & 2) ? ((h & 1) ? i3 : i2) : ((h & 1) ? i1 : i0);
    float acc[CPL];
#pragma unroll
    for (int j = 0; j < CPL; j++) acc[j] = 0.f;
    int c0 = lane * CPL;
    int i = r0;
    // 4x unrolled: batch the 4 random row-gathers so their latencies overlap
    for (; i + 4 <= r1; i += 4) {
      float4 sv[4];
      int sn[4];
#pragma unroll
      for (int u = 0; u < 4; u++) {
        sv[u] = e_s4[i + u];
        sn[u] = srcpos[i + u];
      }
      if constexpr (CPL == 2) {
        ushort2 t[4];
#pragma unroll
        for (int u = 0; u < 4; u++)
          t[u] = *(const ushort2*)(xl + (size_t)sn[u] * HC + c0);
#pragma unroll
        for (int u = 0; u < 4; u++) {
          float a = __expf(((const float*)&sv[u])[h] - mh) * ih;
          acc[0] += a * bf2f(t[u].x);
          acc[1] += a * bf2f(t[u].y);
        }
      } else {
        ushort4 t[4];
#pragma unroll
        for (int u = 0; u < 4; u++)
          t[u] = *(const ushort4*)(xl + (size_t)sn[u] * HC + c0);
#pragma unroll
        for (int u = 0; u < 4; u++) {
          float a = __expf(((const float*)&sv[u])[h] - mh) * ih;
          acc[0] += a * bf2f(t[u].x);
          acc[1] += a * bf2f(t[u].y);
          acc[2] += a * bf2f(t[u].z);
          acc[3] += a * bf2f(t[u].w);
        }
      }
    }
    for (; i < r1; i++) {
      float4 sv = e_s4[i];
      float sh = ((const float*)&sv)[h];
      float a = __expf(sh - mh) * ih;
      int sn = srcpos[i];
      const unsigned short* xp = xl + (size_t)sn * HC + c0;
      if constexpr (CPL == 2) {
        ushort2 t = *(const ushort2*)xp;
        acc[0] += a * bf2f(t.x);
        acc[1] += a * bf2f(t.y);
      } else {
        ushort4 t = *(const ushort4*)xp;
        acc[0] += a * bf2f(t.x);
        acc[1] += a * bf2f(t.y);
        acc[2] += a * bf2f(t.z);
        acc[3] += a * bf2f(t.w);
      }
    }
    float vals[CPL];
    float vs = 0.f, vq = 0.f;
#pragma unroll
    for (int j = 0; j < CPL; j++) {
      float t = acc[j] + bias[c0 + j];
      vals[j] = t;
      vs += t;
      vq += t * t;
    }
    vs = wave_sum(vs);
    vq = wave_sum(vq);
    float mean = vs * (1.f / HC);
    float var = vq * (1.f / HC) - mean * mean;
    float rstd = rsqrtf(fmaxf(var, 0.f) + 1e-5f);
#pragma unroll
    for (int j = 0; j < CPL; j++) {
      int c = c0 + j;
      float y = (vals[j] - mean) * rstd * lng[c] + lnb[c];
      y = leakyf(y, 0.01f);
      if constexpr (L1MODE) {
        x1out[(size_t)n * HC + c] = y;
        xout[(size_t)n * HC + c] = 0.01f * skipproj[(size_t)n * HC + c] + y;
      } else {
        xout[(size_t)n * HC + c] = y;
      }
    }
  }
}

// ---------------- alpha: coalesced e_s/dstpos read, md L2-hit, one scattered 16B write ----------------
__global__ __launch_bounds__(256) void alpha_kernel(
    const float* __restrict__ e_s, const int* __restrict__ csr,
    const int* __restrict__ dstpos, const float* __restrict__ md,
    float* __restrict__ alpha_out, int E2) {
  int i = blockIdx.x * 256 + threadIdx.x;
  if (i < E2) {
    float4 sv = ((const float4*)e_s)[i];
    int d = dstpos[i];
    const float* mp = md + (size_t)d * 8;
    float4 a;
    a.x = __expf(sv.x - mp[0]) * mp[4];
    a.y = __expf(sv.y - mp[1]) * mp[5];
    a.z = __expf(sv.z - mp[2]) * mp[6];
    a.w = __expf(sv.w - mp[3]) * mp[7];
    ((float4*)alpha_out)[csr[i]] = a;
  }
}

extern "C" void kernel_launch(void* const* d_in, const int* in_sizes, int n_in,
                              void* d_out, int out_size, void* d_ws, size_t ws_size,
                              hipStream_t stream) {
  (void)n_in;
  (void)out_size;
  (void)ws_size;
  const float* x_in = (const float*)d_in[0];
  const int* edge_index = (const int*)d_in[1];
  const float* edge_attr = (const float*)d_in[2];
  const float* bn0_g = (const float*)d_in[3];
  const float* bn0_b = (const float*)d_in[4];
  const float* bn0_m = (const float*)d_in[5];
  const float* bn0_v = (const float*)d_in[6];
  const float* eeW1 = (const float*)d_in[7];
  const float* eeb1 = (const float*)d_in[8];
  const float* eeW2 = (const float*)d_in[9];
  const float* eeb2 = (const float*)d_in[10];
  const float* g1_Wl = (const float*)d_in[11];
  const float* g1_bl = (const float*)d_in[12];
  const float* g1_Wr = (const float*)d_in[13];
  const float* g1_br = (const float*)d_in[14];
  const float* g1_We = (const float*)d_in[15];
  const float* g1_att = (const float*)d_in[16];
  const float* g1_bias = (const float*)d_in[17];
  const float* g2_Wl = (const float*)d_in[18];
  const float* g2_bl = (const float*)d_in[19];
  const float* g2_Wr = (const float*)d_in[20];
  const float* g2_br = (const float*)d_in[21];
  const float* g2_We = (const float*)d_in[22];
  const float* g2_att = (const float*)d_in[23];
  const float* g2_bias = (const float*)d_in[24];
  const float* g3_Wl = (const float*)d_in[25];
  const float* g3_bl = (const float*)d_in[26];
  const float* g3_Wr = (const float*)d_in[27];
  const float* g3_br = (const float*)d_in[28];
  const float* g3_We = (const float*)d_in[29];
  const float* g3_att = (const float*)d_in[30];
  const float* g3_bias = (const float*)d_in[31];
  const float* ln1_g = (const float*)d_in[32];
  const float* ln1_b = (const float*)d_in[33];
  const float* ln2_g = (const float*)d_in[34];
  const float* ln2_b = (const float*)d_in[35];
  const float* ln3_g = (const float*)d_in[36];
  const float* ln3_b = (const float*)d_in[37];
  const float* skip_W = (const float*)d_in[38];
  const float* skip_b = (const float*)d_in[39];
  const float* alpha_p = (const float*)d_in[40];
  const float* fp_W = (const float*)d_in[41];
  const float* fp_b = (const float*)d_in[42];
  const float* np_W1 = (const float*)d_in[43];
  const float* np_b1 = (const float*)d_in[44];
  const float* np_W2 = (const float*)d_in[45];
  const float* np_b2 = (const float*)d_in[46];
  const float* np_W3 = (const float*)d_in[47];
  const float* np_b3 = (const float*)d_in[48];

  const int N = in_sizes[0] / 64;
  const int E = in_sizes[2] / 16;
  const int E2 = E + N;
  const int* src0 = edge_index;
  const int* dst0 = edge_index + E;

  float* ws = (float*)d_ws;
  size_t off = 0;
  float* x = ws + off;         off += (size_t)N * 64;
  unsigned short* ea_bf = (unsigned short*)(ws + off); off += (size_t)E2 * 32;
  unsigned short* xl = (unsigned short*)(ws + off);    off += (size_t)N * 128;
  unsigned short* xr = (unsigned short*)(ws + off);    off += (size_t)N * 128;
  float* skipproj = ws + off;  off += (size_t)N * 128;  // reused as h1 at the end
  float* x1 = ws + off;        off += (size_t)N * 128;
  float* skip1 = ws + off;     off += (size_t)N * 128;
  float* x2 = ws + off;        off += (size_t)N * 128;
  float* x3 = ws + off;        off += (size_t)N * 256;
  float* e_s = ws + off;       off += (size_t)E2 * 4;
  float* h2 = ws + off;        off += (size_t)N * 64;
  float* md = ws + off;        off += (size_t)N * 8;
  int* counts = (int*)(ws + off);
  int* rowptr = counts + N;
  int* fill = rowptr + N + 1;
  int* csr = fill + N;
  int* srcpos = csr + E2;
  int* dstpos = srcpos + E2;
  off += (size_t)(3 * N + 1 + 3 * E2);
  off = (off + 3) & ~(size_t)3;
  unsigned short* wtp = (unsigned short*)(ws + off);
  auto alloc_wt = [&](int elems) {
    unsigned short* p = wtp;
    wtp += (elems + 7) & ~7;
    return p;
  };
  unsigned short* wt_g1l = alloc_wt(64 * 128);
  unsigned short* wt_g1r = alloc_wt(64 * 128);
  unsigned short* wt_skip = alloc_wt(64 * 128);
  unsigned short* wt_g2l = alloc_wt(128 * 128);
  unsigned short* wt_g2r = alloc_wt(128 * 128);
  unsigned short* wt_g3l = alloc_wt(128 * 256);
  unsigned short* wt_g3r = alloc_wt(128 * 256);
  unsigned short* wt_fp = alloc_wt(128 * 256);
  unsigned short* wt_np1 = alloc_wt(256 * 128);
  unsigned short* wt_np2 = alloc_wt(128 * 64);
  unsigned short* wt_np3 = alloc_wt(64 * 1);
  unsigned short* wt_ee1 = alloc_wt(16 * 128);
  unsigned short* wt_ee2 = alloc_wt(128 * 64);

  float* out = (float*)d_out;
  float* xf = out;
  float* npout = out + (size_t)N * 256;
  float* a1 = npout + N;
  float* a2 = a1 + (size_t)E2 * 4;
  float* a3 = a2 + (size_t)E2 * 4;

  WJobs jobs;
  jobs.j[0] = {g1_Wl, wt_g1l, 64, 128};
  jobs.j[1] = {g1_Wr, wt_g1r, 64, 128};
  jobs.j[2] = {skip_W, wt_skip, 64, 128};
  jobs.j[3] = {g2_Wl, wt_g2l, 128, 128};
  jobs.j[4] = {g2_Wr, wt_g2r, 128, 128};
  jobs.j[5] = {g3_Wl, wt_g3l, 128, 256};
  jobs.j[6] = {g3_Wr, wt_g3r, 128, 256};
  jobs.j[7] = {fp_W, wt_fp, 128, 256};
  jobs.j[8] = {np_W1, wt_np1, 256, 128};
  jobs.j[9] = {np_W2, wt_np2, 128, 64};
  jobs.j[10] = {np_W3, wt_np3, 64, 1};
  jobs.j[11] = {eeW1, wt_ee1, 16, 128};
  jobs.j[12] = {eeW2, wt_ee2, 128, 64};

  hipMemsetAsync(counts, 0, (size_t)N * sizeof(int), stream);
  wt_kernel<<<dim3(64, 13), 256, 0, stream>>>(jobs);
  bn_kernel<<<(N * 64 + 255) / 256, 256, 0, stream>>>(x_in, bn0_g, bn0_b, bn0_m, bn0_v, x, N * 64);
  edge_enc_kernel<<<(E + 63) / 64, 256, 0, stream>>>(edge_attr, wt_ee1, eeb1, wt_ee2, eeb2, ea_bf, E);
  count_kernel<<<(E2 + 255) / 256, 256, 0, stream>>>(dst0, counts, E, E2);
  scan_kernel<<<1, 256, 0, stream>>>(counts, rowptr, fill, N);
  fill_kernel<<<(E2 + 255) / 256, 256, 0, stream>>>(src0, dst0, fill, csr, srcpos, dstpos, E, E2);
  loopattr_kernel<<<(N + 3) / 4, 256, 0, stream>>>(ea_bf, rowptr, csr, N, E);

  auto gemm = [&](int mode, const float* A, const unsigned short* BT, const float* bias,
                  void* Cp, int M, int K, int Nc, const float* aux) {
    dim3 gdim((Nc + 63) / 64, (M + 63) / 64);
    switch (mode) {
      case 0: gemm_mfma_kernel<0><<<gdim, 256, 0, stream>>>(A, BT, bias, Cp, M, K, Nc, nullptr, nullptr); break;
      case 1: gemm_mfma_kernel<1><<<gdim, 256, 0, stream>>>(A, BT, bias, Cp, M, K, Nc, nullptr, nullptr); break;
      case 2: gemm_mfma_kernel<2><<<gdim, 256, 0, stream>>>(A, BT, bias, Cp, M, K, Nc, nullptr, nullptr); break;
      case 3: gemm_mfma_kernel<3><<<gdim, 256, 0, stream>>>(A, BT, bias, Cp, M, K, Nc, aux, alpha_p); break;
    }
  };

  const int nblk_node = (N + 3) / 4;
  const int score_blocks = 1024;
  const int nblk_edge = (E2 + 255) / 256;

  // ---- Layer 1 (din=64, HC=128, C=32) ----
  gemm(1, x, wt_g1l, g1_bl, xl, N, 64, 128, nullptr);
  gemm(1, x, wt_g1r, g1_br, xr, N, 64, 128, nullptr);
  gemm(0, x, wt_skip, skip_b, skipproj, N, 64, 128, nullptr);
  score_mfma_kernel<32><<<score_blocks, 256, 0, stream>>>(ea_bf, xl, xr, g1_We, g1_att, csr, srcpos, dstpos, e_s, E2, 128, 0);
  aggr_kernel<128, true><<<nblk_node, 256, 0, stream>>>(e_s, xl, rowptr, srcpos, g1_bias, ln1_g, ln1_b,
                                                        skip1, x1, skipproj, md, N);
  alpha_kernel<<<nblk_edge, 256, 0, stream>>>(e_s, csr, dstpos, md, a1, E2);
  // ---- Layer 2 (din=128, HC=128, C=32) ----
  gemm(1, skip1, wt_g2l, g2_bl, xl, N, 128, 128, nullptr);
  gemm(1, skip1, wt_g2r, g2_br, xr, N, 128, 128, nullptr);
  score_mfma_kernel<32><<<score_blocks, 256, 0, stream>>>(ea_bf, xl, xr, g2_We, g2_att, csr, srcpos, dstpos, e_s, E2, 128, 0);
  aggr_kernel<128, false><<<nblk_node, 256, 0, stream>>>(e_s, xl, rowptr, srcpos, g2_bias, ln2_g, ln2_b,
                                                         x2, nullptr, nullptr, md, N);
  alpha_kernel<<<nblk_edge, 256, 0, stream>>>(e_s, csr, dstpos, md, a2, E2);
  // ---- Layer 3 (din=128, HC=256, C=64) ----
  gemm(1, x2, wt_g3l, g3_bl, xl, N, 128, 256, nullptr);
  gemm(1, x2, wt_g3r, g3_br, xr, N, 128, 256, nullptr);
  score_mfma_kernel<64><<<score_blocks, 256, 0, stream>>>(ea_bf, xl, xr, g3_We, g3_att, csr, srcpos, dstpos, e_s, E2, 256, 0);
  score_mfma_kernel<64><<<score_blocks, 256, 0, stream>>>(ea_bf, xl, xr, g3_We, g3_att, csr, srcpos, dstpos, e_s, E2, 256, 128);
  aggr_kernel<256, false><<<nblk_node, 256, 0, stream>>>(e_s, xl, rowptr, srcpos, g3_bias, ln3_g, ln3_b,
                                                         x3, nullptr, nullptr, md, N);
  alpha_kernel<<<nblk_edge, 256, 0, stream>>>(e_s, csr, dstpos, md, a3, E2);
  // ---- Final: xf = s*(x1@fp_W+fp_b) + (1-s)*x3 ; node MLP ----
  gemm(3, x1, wt_fp, fp_b, xf, N, 128, 256, x3);
  gemm(2, xf, wt_np1, np_b1, skipproj, N, 256, 128, nullptr);   // h1
  gemm(2, skipproj, wt_np2, np_b2, h2, N, 128, 64, nullptr);    // h2
  gemm(0, h2, wt_np3, np_b3, npout, N, 64, 1, nullptr);
}

// Round 13
// 567.597 us; speedup vs baseline: 4.5502x; 1.1948x over previous
//
#include <hip/hip_runtime.h>
#include <math.h>

#define DEV __device__ __forceinline__

typedef __attribute__((ext_vector_type(8))) short bf16x8;
typedef __attribute__((ext_vector_type(4))) float f32x4;

DEV float leakyf(float x, float s) { return x > 0.f ? x : s * x; }

DEV unsigned short f2bf(float f) {
  unsigned u = __float_as_uint(f);
  unsigned r = (u + 0x7fff + ((u >> 16) & 1)) >> 16;
  return (unsigned short)r;
}
DEV float bf2f(unsigned short h) { return __uint_as_float((unsigned)h << 16); }

DEV float sel4(float4 v, int h) {
  float a = (h & 1) ? v.y : v.x;
  float b = (h & 1) ? v.w : v.z;
  return (h & 2) ? b : a;
}

DEV float wave_sum(float v) {
#pragma unroll
  for (int o = 1; o < 64; o <<= 1) v += __shfl_xor(v, o);
  return v;
}
DEV float wave_max(float v) {
#pragma unroll
  for (int o = 1; o < 64; o <<= 1) v = fmaxf(v, __shfl_xor(v, o));
  return v;
}

// ---------------- weight pre-convert: W[K,Nc] f32 -> WT[Nc,K] bf16 ----------------
struct WJob { const float* in; unsigned short* out; int K; int Nc; };
struct WJobs { WJob j[13]; };

__global__ __launch_bounds__(256) void wt_kernel(WJobs jobs) {
  WJob jb = jobs.j[blockIdx.y];
  int total = jb.K * jb.Nc;
  for (int i = blockIdx.x * 256 + threadIdx.x; i < total; i += gridDim.x * 256) {
    int c = i / jb.K, k = i - c * jb.K;
    jb.out[i] = f2bf(jb.in[(size_t)k * jb.Nc + c]);
  }
}

// ---------------- BatchNorm (eval) ----------------
__global__ __launch_bounds__(256) void bn_kernel(
    const float* __restrict__ xin, const float* __restrict__ g,
    const float* __restrict__ b, const float* __restrict__ m,
    const float* __restrict__ v, float* __restrict__ xout, int total) {
  int i = blockIdx.x * 256 + threadIdx.x;
  if (i < total) {
    int c = i & 63;
    xout[i] = (xin[i] - m[c]) * rsqrtf(v[c] + 1e-5f) * g[c] + b[c];
  }
}

// ---------------- Edge encoder: fully-MFMA fused 2-layer MLP + L2 norm ----------------
__global__ __launch_bounds__(256) void edge_enc_kernel(
    const float* __restrict__ edge_attr, const unsigned short* __restrict__ WT1,
    const float* __restrict__ b1, const unsigned short* __restrict__ WT2,
    const float* __restrict__ b2, unsigned short* __restrict__ ea_bf, int E) {
  __shared__ unsigned short sEa1[64][136];  // bf16, pad 8
  int tid = threadIdx.x, lane = tid & 63, w = tid >> 6;
  int g = lane >> 4, q = lane & 15;
  bf16x8 w1f[8];
#pragma unroll
  for (int t = 0; t < 8; t++) {
    bf16x8 v = {};
    if (g < 2) v = *(const bf16x8*)(WT1 + (size_t)(16 * t + q) * 16 + 8 * g);
    w1f[t] = v;
  }
  float b1v[8];
#pragma unroll
  for (int t = 0; t < 8; t++) b1v[t] = b1[16 * t + q];
  bf16x8 w2f[4][4];
#pragma unroll
  for (int t = 0; t < 4; t++)
#pragma unroll
    for (int kc = 0; kc < 4; kc++)
      w2f[t][kc] = *(const bf16x8*)(WT2 + (size_t)(16 * t + q) * 128 + 32 * kc + 8 * g);
  float b2v[4];
#pragma unroll
  for (int t = 0; t < 4; t++) b2v[t] = b2[16 * t + q];

  int e0 = blockIdx.x * 64 + w * 16;
  bf16x8 af = {};
  if (g < 2) {
    int e = e0 + q;
    if (e >= E) e = E - 1;
    const float* ap = edge_attr + (size_t)e * 16 + 8 * g;
    float4 x0 = *(const float4*)ap;
    float4 x1 = *(const float4*)(ap + 4);
    af[0] = (short)f2bf(x0.x); af[1] = (short)f2bf(x0.y);
    af[2] = (short)f2bf(x0.z); af[3] = (short)f2bf(x0.w);
    af[4] = (short)f2bf(x1.x); af[5] = (short)f2bf(x1.y);
    af[6] = (short)f2bf(x1.z); af[7] = (short)f2bf(x1.w);
  }
  f32x4 acc1[8];
#pragma unroll
  for (int t = 0; t < 8; t++) acc1[t] = (f32x4){0.f, 0.f, 0.f, 0.f};
#pragma unroll
  for (int t = 0; t < 8; t++)
    acc1[t] = __builtin_amdgcn_mfma_f32_16x16x32_bf16(af, w1f[t], acc1[t], 0, 0, 0);
#pragma unroll
  for (int t = 0; t < 8; t++)
#pragma unroll
    for (int r = 0; r < 4; r++) {
      float v = leakyf(acc1[t][r] + b1v[t], 0.01f);
      sEa1[w * 16 + g * 4 + r][16 * t + q] = f2bf(v);
    }
  f32x4 acc2[4];
#pragma unroll
  for (int t = 0; t < 4; t++) acc2[t] = (f32x4){0.f, 0.f, 0.f, 0.f};
#pragma unroll
  for (int kc = 0; kc < 4; kc++) {
    bf16x8 a2 = *(const bf16x8*)&sEa1[w * 16 + q][32 * kc + 8 * g];
#pragma unroll
    for (int t = 0; t < 4; t++)
      acc2[t] = __builtin_amdgcn_mfma_f32_16x16x32_bf16(a2, w2f[t][kc], acc2[t], 0, 0, 0);
  }
#pragma unroll
  for (int r = 0; r < 4; r++) {
    float vv[4];
    float p = 0.f;
#pragma unroll
    for (int t = 0; t < 4; t++) {
      float v = leakyf(acc2[t][r] + b2v[t], 0.01f);
      vv[t] = v;
      p += v * v;
    }
#pragma unroll
    for (int o = 1; o < 16; o <<= 1) p += __shfl_xor(p, o);
    float sc = 1.f / fmaxf(sqrtf(p), 1e-12f);
    int e = e0 + g * 4 + r;
    if (e < E) {
#pragma unroll
      for (int t = 0; t < 4; t++)
        ea_bf[(size_t)e * 64 + 16 * t + q] = f2bf(vv[t] * sc);
    }
  }
}

// ---------------- CSR build ----------------
__global__ __launch_bounds__(256) void count_kernel(const int* __restrict__ dst0,
                                                    int* __restrict__ counts, int E, int E2) {
  int i = blockIdx.x * 256 + threadIdx.x;
  if (i < E2) {
    int d = (i < E) ? dst0[i] : (i - E);
    atomicAdd(&counts[d], 1);
  }
}

__global__ __launch_bounds__(256) void scan_kernel(const int* __restrict__ counts,
                                                   int* __restrict__ rowptr,
                                                   int* __restrict__ fill, int N) {
  __shared__ int part[256];
  int tid = threadIdx.x;
  int chunk = (N + 255) / 256;
  int lo = tid * chunk, hi = lo + chunk;
  if (hi > N) hi = N;
  if (lo > N) lo = N;
  int s = 0;
  for (int i = lo; i < hi; i++) s += counts[i];
  part[tid] = s;
  __syncthreads();
  if (tid == 0) {
    int run = 0;
    for (int i = 0; i < 256; i++) {
      int t = part[i];
      part[i] = run;
      run += t;
    }
    rowptr[N] = run;
  }
  __syncthreads();
  int off = part[tid];
  for (int i = lo; i < hi; i++) {
    rowptr[i] = off;
    fill[i] = off;
    off += counts[i];
  }
}

// builds csr (edge id), srcpos (src node), dstpos (dst node) by CSR position
__global__ __launch_bounds__(256) void fill_kernel(const int* __restrict__ src0,
                                                   const int* __restrict__ dst0,
                                                   int* __restrict__ fill,
                                                   int* __restrict__ csr,
                                                   int* __restrict__ srcpos,
                                                   int* __restrict__ dstpos, int E, int E2) {
  int i = blockIdx.x * 256 + threadIdx.x;
  if (i < E2) {
    int d, s;
    if (i < E) {
      d = dst0[i];
      s = src0[i];
    } else {
      d = s = i - E;
    }
    int pos = atomicAdd(&fill[d], 1);
    csr[pos] = i;
    srcpos[pos] = s;
    dstpos[pos] = d;
  }
}

// ---------------- self-loop attr = mean of incoming encoded attrs (bf16 in/out) ----------------
__global__ __launch_bounds__(256) void loopattr_kernel(unsigned short* __restrict__ ea_bf,
                                                       const int* __restrict__ rowptr,
                                                       const int* __restrict__ csr, int N, int E) {
  int lane = threadIdx.x & 63, wv = threadIdx.x >> 6;
  int stride = gridDim.x * 4;
  for (int n = blockIdx.x * 4 + wv; n < N; n += stride) {
    int r0 = rowptr[n], r1 = rowptr[n + 1];
    float acc = 0.f;
    int cnt = 0;
    for (int i = r0; i < r1; i++) {
      int e = csr[i];
      if (e < E) {
        acc += bf2f(ea_bf[(size_t)e * 64 + lane]);
        cnt++;
      }
    }
    ea_bf[((size_t)E + n) * 64 + lane] = f2bf(acc / fmaxf((float)cnt, 1.f));
  }
}

// ---------------- bf16 MFMA GEMM ----------------
// MODE: 0 f32 out, 1 bf16 out, 2 elu f32 out, 3 mix f32 out
template <int MODE>
__global__ __launch_bounds__(256) void gemm_mfma_kernel(
    const float* __restrict__ A, const unsigned short* __restrict__ BT,
    const float* __restrict__ bias, void* __restrict__ Cout, int M, int K, int Nc,
    const float* __restrict__ aux, const float* __restrict__ alpha_p) {
  __shared__ unsigned short sA[64][40];
  __shared__ unsigned short sB[64][40];
  int tid = threadIdx.x, lane = tid & 63, w = tid >> 6;
  int g = lane >> 4, q = lane & 15;
  int bm = blockIdx.y * 64, bn = blockIdx.x * 64;
  f32x4 acc[4];
#pragma unroll
  for (int t = 0; t < 4; t++) acc[t] = (f32x4){0.f, 0.f, 0.f, 0.f};
  int r = tid >> 2, ko = (tid & 3) * 8;
  for (int k0 = 0; k0 < K; k0 += 32) {
    {
      int gm = bm + r;
      bf16x8 v = {};
      if (gm < M) {
        const float* ap = A + (size_t)gm * K + k0 + ko;
        float4 x0 = *(const float4*)ap;
        float4 x1 = *(const float4*)(ap + 4);
        v[0] = (short)f2bf(x0.x); v[1] = (short)f2bf(x0.y);
        v[2] = (short)f2bf(x0.z); v[3] = (short)f2bf(x0.w);
        v[4] = (short)f2bf(x1.x); v[5] = (short)f2bf(x1.y);
        v[6] = (short)f2bf(x1.z); v[7] = (short)f2bf(x1.w);
      }
      *(bf16x8*)&sA[r][ko] = v;
      int gc = bn + r;
      bf16x8 bv = {};
      if (gc < Nc) bv = *(const bf16x8*)(BT + (size_t)gc * K + k0 + ko);
      *(bf16x8*)&sB[r][ko] = bv;
    }
    __syncthreads();
    bf16x8 a = *(const bf16x8*)&sA[w * 16 + q][8 * g];
#pragma unroll
    for (int t = 0; t < 4; t++) {
      bf16x8 b = *(const bf16x8*)&sB[16 * t + q][8 * g];
      acc[t] = __builtin_amdgcn_mfma_f32_16x16x32_bf16(a, b, acc[t], 0, 0, 0);
    }
    __syncthreads();
  }
  float s = 0.f;
  if (MODE == 3) s = 1.f / (1.f + __expf(-alpha_p[0]));
#pragma unroll
  for (int t = 0; t < 4; t++) {
    int col = bn + 16 * t + q;
#pragma unroll
    for (int rr = 0; rr < 4; rr++) {
      int row = bm + w * 16 + g * 4 + rr;
      if (row < M && col < Nc) {
        float v = acc[t][rr] + bias[col];
        if (MODE == 2) v = v > 0.f ? v : (__expf(v) - 1.f);
        if (MODE == 3) v = s * v + (1.f - s) * aux[(size_t)row * Nc + col];
        if (MODE == 1)
          ((unsigned short*)Cout)[(size_t)row * Nc + col] = f2bf(v);
        else
          ((float*)Cout)[(size_t)row * Nc + col] = v;
      }
    }
  }
}

// ---------------- GATv2 edge scores via MFMA, iterated in CSR-position order ----------------
template <int C>
__global__ __launch_bounds__(256) void score_mfma_kernel(
    const unsigned short* __restrict__ ea_bf, const unsigned short* __restrict__ xl,
    const unsigned short* __restrict__ xr, const float* __restrict__ We,
    const float* __restrict__ att, const int* __restrict__ csr,
    const int* __restrict__ srcpos, const int* __restrict__ dstpos,
    float* __restrict__ e_s, int E2, int HCfull, int col_off) {
  int lane = threadIdx.x & 63;
  int wv = threadIdx.x >> 6;
  int g = lane >> 4, q = lane & 15;
  bf16x8 bfrag[8][2];
#pragma unroll
  for (int t = 0; t < 8; t++)
#pragma unroll
    for (int kc = 0; kc < 2; kc++) {
      bf16x8 bv;
#pragma unroll
      for (int j = 0; j < 8; j++) {
        int k = kc * 32 + g * 8 + j;
        bv[j] = (short)f2bf(We[(size_t)k * HCfull + col_off + 16 * t + q]);
      }
      bfrag[t][kc] = bv;
    }
  float attv[8];
#pragma unroll
  for (int t = 0; t < 8; t++) attv[t] = att[col_off + 16 * t + q];

  constexpr int TPH = C / 16;
  constexpr int NH = 8 / TPH;
  const int headbase = col_off / C;

  int tiles = (E2 + 15) / 16;
  int nw = gridDim.x * 4;
  for (int tile = blockIdx.x * 4 + wv; tile < tiles; tile += nw) {
    int i0 = tile * 16;
    int ia = i0 + q;
    if (ia >= E2) ia = E2 - 1;
    int erow = csr[ia];
    const unsigned short* ap = ea_bf + (size_t)erow * 64 + g * 8;
    bf16x8 a0 = *(const bf16x8*)(ap);
    bf16x8 a1 = *(const bf16x8*)(ap + 32);
    f32x4 acc[8];
#pragma unroll
    for (int t = 0; t < 8; t++) acc[t] = (f32x4){0.f, 0.f, 0.f, 0.f};
#pragma unroll
    for (int t = 0; t < 8; t++) {
      acc[t] = __builtin_amdgcn_mfma_f32_16x16x32_bf16(a0, bfrag[t][0], acc[t], 0, 0, 0);
      acc[t] = __builtin_amdgcn_mfma_f32_16x16x32_bf16(a1, bfrag[t][1], acc[t], 0, 0, 0);
    }
    int sn[4], dn[4];
#pragma unroll
    for (int r = 0; r < 4; r++) {
      int i = i0 + g * 4 + r;
      if (i >= E2) i = E2 - 1;
      sn[r] = srcpos[i];
      dn[r] = dstpos[i];
    }
    float p[NH][4];
#pragma unroll
    for (int hh = 0; hh < NH; hh++)
#pragma unroll
      for (int r = 0; r < 4; r++) p[hh][r] = 0.f;
#pragma unroll
    for (int t = 0; t < 8; t++) {
      int col = col_off + 16 * t + q;
#pragma unroll
      for (int r = 0; r < 4; r++) {
        float xv = bf2f(xl[(size_t)sn[r] * HCfull + col]) +
                   bf2f(xr[(size_t)dn[r] * HCfull + col]) + acc[t][r];
        xv = xv > 0.f ? xv : 0.2f * xv;
        p[t / TPH][r] += xv * attv[t];
      }
    }
#pragma unroll
    for (int hh = 0; hh < NH; hh++)
#pragma unroll
      for (int r = 0; r < 4; r++) {
#pragma unroll
        for (int o = 1; o < 16; o <<= 1) p[hh][r] += __shfl_xor(p[hh][r], o);
      }
    if (q == 0) {
#pragma unroll
      for (int r = 0; r < 4; r++) {
        int i = i0 + g * 4 + r;
        if (i < E2) {
#pragma unroll
          for (int hh = 0; hh < NH; hh++)
            e_s[(size_t)i * 4 + headbase + hh] = p[hh][r];
        }
      }
    }
  }
}

// ---------------- per-node softmax + aggregation; 4x-unrolled gather, register-only selects ----------------
template <int HC, bool L1MODE>
__global__ __launch_bounds__(256) void aggr_kernel(
    const float* __restrict__ e_s, const unsigned short* __restrict__ xl,
    const int* __restrict__ rowptr, const int* __restrict__ srcpos,
    const float* __restrict__ bias,
    const float* __restrict__ lng, const float* __restrict__ lnb,
    float* __restrict__ xout,
    float* __restrict__ x1out, const float* __restrict__ skipproj,
    float* __restrict__ md, int N) {
  constexpr int CPL = HC / 64;
  int lane = threadIdx.x & 63, wv = threadIdx.x >> 6;
  int stride = gridDim.x * 4;
  const float4* e_s4 = (const float4*)e_s;
  for (int n = blockIdx.x * 4 + wv; n < N; n += stride) {
    int r0 = rowptr[n], r1 = rowptr[n + 1];
    float m0 = -1e30f, m1 = -1e30f, m2 = -1e30f, m3 = -1e30f;
    for (int i = r0 + lane; i < r1; i += 64) {
      float4 v = e_s4[i];
      m0 = fmaxf(m0, v.x);
      m1 = fmaxf(m1, v.y);
      m2 = fmaxf(m2, v.z);
      m3 = fmaxf(m3, v.w);
    }
    m0 = wave_max(m0);
    m1 = wave_max(m1);
    m2 = wave_max(m2);
    m3 = wave_max(m3);
    float d0 = 0.f, d1 = 0.f, d2 = 0.f, d3 = 0.f;
    for (int i = r0 + lane; i < r1; i += 64) {
      float4 v = e_s4[i];
      d0 += __expf(v.x - m0);
      d1 += __expf(v.y - m1);
      d2 += __expf(v.z - m2);
      d3 += __expf(v.w - m3);
    }
    d0 = wave_sum(d0);
    d1 = wave_sum(d1);
    d2 = wave_sum(d2);
    d3 = wave_sum(d3);
    float i0 = 1.f / (d0 + 1e-16f), i1 = 1.f / (d1 + 1e-16f);
    float i2 = 1.f / (d2 + 1e-16f), i3 = 1.f / (d3 + 1e-16f);
    if (lane == 0) {
      float* mp = md + (size_t)n * 8;
      mp[0] = m0; mp[1] = m1; mp[2] = m2; mp[3] = m3;
      mp[4] = i0; mp[5] = i1; mp[6] = i2; mp[7] = i3;
    }
    int h = lane >> 4;
    float mh = (h & 2) ? ((h & 1) ? m3 : m2) : ((h & 1) ? m1 : m0);
    float ih = (h & 2) ? ((h & 1) ? i3 : i2) : ((h & 1) ? i1 : i0);
    float acc[CPL];
#pragma unroll
    for (int j = 0; j < CPL; j++) acc[j] = 0.f;
    int c0 = lane * CPL;
    int i = r0;
    // 4x unrolled: batch the 4 random row-gathers so their latencies overlap.
    // All h-extractions are branchless register selects (no runtime array indexing).
    for (; i + 4 <= r1; i += 4) {
      float sh0, sh1, sh2, sh3;
      int sn0, sn1, sn2, sn3;
      {
        float4 a = e_s4[i], b = e_s4[i + 1], c = e_s4[i + 2], d = e_s4[i + 3];
        sh0 = sel4(a, h); sh1 = sel4(b, h); sh2 = sel4(c, h); sh3 = sel4(d, h);
      }
      sn0 = srcpos[i]; sn1 = srcpos[i + 1]; sn2 = srcpos[i + 2]; sn3 = srcpos[i + 3];
      if constexpr (CPL == 2) {
        ushort2 t0 = *(const ushort2*)(xl + (size_t)sn0 * HC + c0);
        ushort2 t1 = *(const ushort2*)(xl + (size_t)sn1 * HC + c0);
        ushort2 t2 = *(const ushort2*)(xl + (size_t)sn2 * HC + c0);
        ushort2 t3 = *(const ushort2*)(xl + (size_t)sn3 * HC + c0);
        float a0 = __expf(sh0 - mh) * ih;
        float a1 = __expf(sh1 - mh) * ih;
        float a2 = __expf(sh2 - mh) * ih;
        float a3 = __expf(sh3 - mh) * ih;
        acc[0] += a0 * bf2f(t0.x) + a1 * bf2f(t1.x) + a2 * bf2f(t2.x) + a3 * bf2f(t3.x);
        acc[1] += a0 * bf2f(t0.y) + a1 * bf2f(t1.y) + a2 * bf2f(t2.y) + a3 * bf2f(t3.y);
      } else {
        ushort4 t0 = *(const ushort4*)(xl + (size_t)sn0 * HC + c0);
        ushort4 t1 = *(const ushort4*)(xl + (size_t)sn1 * HC + c0);
        ushort4 t2 = *(const ushort4*)(xl + (size_t)sn2 * HC + c0);
        ushort4 t3 = *(const ushort4*)(xl + (size_t)sn3 * HC + c0);
        float a0 = __expf(sh0 - mh) * ih;
        float a1 = __expf(sh1 - mh) * ih;
        float a2 = __expf(sh2 - mh) * ih;
        float a3 = __expf(sh3 - mh) * ih;
        acc[0] += a0 * bf2f(t0.x) + a1 * bf2f(t1.x) + a2 * bf2f(t2.x) + a3 * bf2f(t3.x);
        acc[1] += a0 * bf2f(t0.y) + a1 * bf2f(t1.y) + a2 * bf2f(t2.y) + a3 * bf2f(t3.y);
        acc[2] += a0 * bf2f(t0.z) + a1 * bf2f(t1.z) + a2 * bf2f(t2.z) + a3 * bf2f(t3.z);
        acc[3] += a0 * bf2f(t0.w) + a1 * bf2f(t1.w) + a2 * bf2f(t2.w) + a3 * bf2f(t3.w);
      }
    }
    for (; i < r1; i++) {
      float sh = sel4(e_s4[i], h);
      float a = __expf(sh - mh) * ih;
      int sn = srcpos[i];
      const unsigned short* xp = xl + (size_t)sn * HC + c0;
      if constexpr (CPL == 2) {
        ushort2 t = *(const ushort2*)xp;
        acc[0] += a * bf2f(t.x);
        acc[1] += a * bf2f(t.y);
      } else {
        ushort4 t = *(const ushort4*)xp;
        acc[0] += a * bf2f(t.x);
        acc[1] += a * bf2f(t.y);
        acc[2] += a * bf2f(t.z);
        acc[3] += a * bf2f(t.w);
      }
    }
    float vals[CPL];
    float vs = 0.f, vq = 0.f;
#pragma unroll
    for (int j = 0; j < CPL; j++) {
      float t = acc[j] + bias[c0 + j];
      vals[j] = t;
      vs += t;
      vq += t * t;
    }
    vs = wave_sum(vs);
    vq = wave_sum(vq);
    float mean = vs * (1.f / HC);
    float var = vq * (1.f / HC) - mean * mean;
    float rstd = rsqrtf(fmaxf(var, 0.f) + 1e-5f);
#pragma unroll
    for (int j = 0; j < CPL; j++) {
      int c = c0 + j;
      float y = (vals[j] - mean) * rstd * lng[c] + lnb[c];
      y = leakyf(y, 0.01f);
      if constexpr (L1MODE) {
        x1out[(size_t)n * HC + c] = y;
        xout[(size_t)n * HC + c] = 0.01f * skipproj[(size_t)n * HC + c] + y;
      } else {
        xout[(size_t)n * HC + c] = y;
      }
    }
  }
}

// ---------------- alpha: coalesced e_s/dstpos read, md L2-hit, one scattered 16B write ----------------
__global__ __launch_bounds__(256) void alpha_kernel(
    const float* __restrict__ e_s, const int* __restrict__ csr,
    const int* __restrict__ dstpos, const float* __restrict__ md,
    float* __restrict__ alpha_out, int E2) {
  int i = blockIdx.x * 256 + threadIdx.x;
  if (i < E2) {
    float4 sv = ((const float4*)e_s)[i];
    int d = dstpos[i];
    const float* mp = md + (size_t)d * 8;
    float4 a;
    a.x = __expf(sv.x - mp[0]) * mp[4];
    a.y = __expf(sv.y - mp[1]) * mp[5];
    a.z = __expf(sv.z - mp[2]) * mp[6];
    a.w = __expf(sv.w - mp[3]) * mp[7];
    ((float4*)alpha_out)[csr[i]] = a;
  }
}

extern "C" void kernel_launch(void* const* d_in, const int* in_sizes, int n_in,
                              void* d_out, int out_size, void* d_ws, size_t ws_size,
                              hipStream_t stream) {
  (void)n_in;
  (void)out_size;
  (void)ws_size;
  const float* x_in = (const float*)d_in[0];
  const int* edge_index = (const int*)d_in[1];
  const float* edge_attr = (const float*)d_in[2];
  const float* bn0_g = (const float*)d_in[3];
  const float* bn0_b = (const float*)d_in[4];
  const float* bn0_m = (const float*)d_in[5];
  const float* bn0_v = (const float*)d_in[6];
  const float* eeW1 = (const float*)d_in[7];
  const float* eeb1 = (const float*)d_in[8];
  const float* eeW2 = (const float*)d_in[9];
  const float* eeb2 = (const float*)d_in[10];
  const float* g1_Wl = (const float*)d_in[11];
  const float* g1_bl = (const float*)d_in[12];
  const float* g1_Wr = (const float*)d_in[13];
  const float* g1_br = (const float*)d_in[14];
  const float* g1_We = (const float*)d_in[15];
  const float* g1_att = (const float*)d_in[16];
  const float* g1_bias = (const float*)d_in[17];
  const float* g2_Wl = (const float*)d_in[18];
  const float* g2_bl = (const float*)d_in[19];
  const float* g2_Wr = (const float*)d_in[20];
  const float* g2_br = (const float*)d_in[21];
  const float* g2_We = (const float*)d_in[22];
  const float* g2_att = (const float*)d_in[23];
  const float* g2_bias = (const float*)d_in[24];
  const float* g3_Wl = (const float*)d_in[25];
  const float* g3_bl = (const float*)d_in[26];
  const float* g3_Wr = (const float*)d_in[27];
  const float* g3_br = (const float*)d_in[28];
  const float* g3_We = (const float*)d_in[29];
  const float* g3_att = (const float*)d_in[30];
  const float* g3_bias = (const float*)d_in[31];
  const float* ln1_g = (const float*)d_in[32];
  const float* ln1_b = (const float*)d_in[33];
  const float* ln2_g = (const float*)d_in[34];
  const float* ln2_b = (const float*)d_in[35];
  const float* ln3_g = (const float*)d_in[36];
  const float* ln3_b = (const float*)d_in[37];
  const float* skip_W = (const float*)d_in[38];
  const float* skip_b = (const float*)d_in[39];
  const float* alpha_p = (const float*)d_in[40];
  const float* fp_W = (const float*)d_in[41];
  const float* fp_b = (const float*)d_in[42];
  const float* np_W1 = (const float*)d_in[43];
  const float* np_b1 = (const float*)d_in[44];
  const float* np_W2 = (const float*)d_in[45];
  const float* np_b2 = (const float*)d_in[46];
  const float* np_W3 = (const float*)d_in[47];
  const float* np_b3 = (const float*)d_in[48];

  const int N = in_sizes[0] / 64;
  const int E = in_sizes[2] / 16;
  const int E2 = E + N;
  const int* src0 = edge_index;
  const int* dst0 = edge_index + E;

  float* ws = (float*)d_ws;
  size_t off = 0;
  float* x = ws + off;         off += (size_t)N * 64;
  unsigned short* ea_bf = (unsigned short*)(ws + off); off += (size_t)E2 * 32;
  unsigned short* xl = (unsigned short*)(ws + off);    off += (size_t)N * 128;
  unsigned short* xr = (unsigned short*)(ws + off);    off += (size_t)N * 128;
  float* skipproj = ws + off;  off += (size_t)N * 128;  // reused as h1 at the end
  float* x1 = ws + off;        off += (size_t)N * 128;
  float* skip1 = ws + off;     off += (size_t)N * 128;
  float* x2 = ws + off;        off += (size_t)N * 128;
  float* x3 = ws + off;        off += (size_t)N * 256;
  float* e_s = ws + off;       off += (size_t)E2 * 4;
  float* h2 = ws + off;        off += (size_t)N * 64;
  float* md = ws + off;        off += (size_t)N * 8;
  int* counts = (int*)(ws + off);
  int* rowptr = counts + N;
  int* fill = rowptr + N + 1;
  int* csr = fill + N;
  int* srcpos = csr + E2;
  int* dstpos = srcpos + E2;
  off += (size_t)(3 * N + 1 + 3 * E2);
  off = (off + 3) & ~(size_t)3;
  unsigned short* wtp = (unsigned short*)(ws + off);
  auto alloc_wt = [&](int elems) {
    unsigned short* p = wtp;
    wtp += (elems + 7) & ~7;
    return p;
  };
  unsigned short* wt_g1l = alloc_wt(64 * 128);
  unsigned short* wt_g1r = alloc_wt(64 * 128);
  unsigned short* wt_skip = alloc_wt(64 * 128);
  unsigned short* wt_g2l = alloc_wt(128 * 128);
  unsigned short* wt_g2r = alloc_wt(128 * 128);
  unsigned short* wt_g3l = alloc_wt(128 * 256);
  unsigned short* wt_g3r = alloc_wt(128 * 256);
  unsigned short* wt_fp = alloc_wt(128 * 256);
  unsigned short* wt_np1 = alloc_wt(256 * 128);
  unsigned short* wt_np2 = alloc_wt(128 * 64);
  unsigned short* wt_np3 = alloc_wt(64 * 1);
  unsigned short* wt_ee1 = alloc_wt(16 * 128);
  unsigned short* wt_ee2 = alloc_wt(128 * 64);

  float* out = (float*)d_out;
  float* xf = out;
  float* npout = out + (size_t)N * 256;
  float* a1 = npout + N;
  float* a2 = a1 + (size_t)E2 * 4;
  float* a3 = a2 + (size_t)E2 * 4;

  WJobs jobs;
  jobs.j[0] = {g1_Wl, wt_g1l, 64, 128};
  jobs.j[1] = {g1_Wr, wt_g1r, 64, 128};
  jobs.j[2] = {skip_W, wt_skip, 64, 128};
  jobs.j[3] = {g2_Wl, wt_g2l, 128, 128};
  jobs.j[4] = {g2_Wr, wt_g2r, 128, 128};
  jobs.j[5] = {g3_Wl, wt_g3l, 128, 256};
  jobs.j[6] = {g3_Wr, wt_g3r, 128, 256};
  jobs.j[7] = {fp_W, wt_fp, 128, 256};
  jobs.j[8] = {np_W1, wt_np1, 256, 128};
  jobs.j[9] = {np_W2, wt_np2, 128, 64};
  jobs.j[10] = {np_W3, wt_np3, 64, 1};
  jobs.j[11] = {eeW1, wt_ee1, 16, 128};
  jobs.j[12] = {eeW2, wt_ee2, 128, 64};

  hipMemsetAsync(counts, 0, (size_t)N * sizeof(int), stream);
  wt_kernel<<<dim3(64, 13), 256, 0, stream>>>(jobs);
  bn_kernel<<<(N * 64 + 255) / 256, 256, 0, stream>>>(x_in, bn0_g, bn0_b, bn0_m, bn0_v, x, N * 64);
  edge_enc_kernel<<<(E + 63) / 64, 256, 0, stream>>>(edge_attr, wt_ee1, eeb1, wt_ee2, eeb2, ea_bf, E);
  count_kernel<<<(E2 + 255) / 256, 256, 0, stream>>>(dst0, counts, E, E2);
  scan_kernel<<<1, 256, 0, stream>>>(counts, rowptr, fill, N);
  fill_kernel<<<(E2 + 255) / 256, 256, 0, stream>>>(src0, dst0, fill, csr, srcpos, dstpos, E, E2);
  loopattr_kernel<<<(N + 3) / 4, 256, 0, stream>>>(ea_bf, rowptr, csr, N, E);

  auto gemm = [&](int mode, const float* A, const unsigned short* BT, const float* bias,
                  void* Cp, int M, int K, int Nc, const float* aux) {
    dim3 gdim((Nc + 63) / 64, (M + 63) / 64);
    switch (mode) {
      case 0: gemm_mfma_kernel<0><<<gdim, 256, 0, stream>>>(A, BT, bias, Cp, M, K, Nc, nullptr, nullptr); break;
      case 1: gemm_mfma_kernel<1><<<gdim, 256, 0, stream>>>(A, BT, bias, Cp, M, K, Nc, nullptr, nullptr); break;
      case 2: gemm_mfma_kernel<2><<<gdim, 256, 0, stream>>>(A, BT, bias, Cp, M, K, Nc, nullptr, nullptr); break;
      case 3: gemm_mfma_kernel<3><<<gdim, 256, 0, stream>>>(A, BT, bias, Cp, M, K, Nc, aux, alpha_p); break;
    }
  };

  const int nblk_node = (N + 3) / 4;
  const int score_blocks = 1024;
  const int nblk_edge = (E2 + 255) / 256;

  // ---- Layer 1 (din=64, HC=128, C=32) ----
  gemm(1, x, wt_g1l, g1_bl, xl, N, 64, 128, nullptr);
  gemm(1, x, wt_g1r, g1_br, xr, N, 64, 128, nullptr);
  gemm(0, x, wt_skip, skip_b, skipproj, N, 64, 128, nullptr);
  score_mfma_kernel<32><<<score_blocks, 256, 0, stream>>>(ea_bf, xl, xr, g1_We, g1_att, csr, srcpos, dstpos, e_s, E2, 128, 0);
  aggr_kernel<128, true><<<nblk_node, 256, 0, stream>>>(e_s, xl, rowptr, srcpos, g1_bias, ln1_g, ln1_b,
                                                        skip1, x1, skipproj, md, N);
  alpha_kernel<<<nblk_edge, 256, 0, stream>>>(e_s, csr, dstpos, md, a1, E2);
  // ---- Layer 2 (din=128, HC=128, C=32) ----
  gemm(1, skip1, wt_g2l, g2_bl, xl, N, 128, 128, nullptr);
  gemm(1, skip1, wt_g2r, g2_br, xr, N, 128, 128, nullptr);
  score_mfma_kernel<32><<<score_blocks, 256, 0, stream>>>(ea_bf, xl, xr, g2_We, g2_att, csr, srcpos, dstpos, e_s, E2, 128, 0);
  aggr_kernel<128, false><<<nblk_node, 256, 0, stream>>>(e_s, xl, rowptr, srcpos, g2_bias, ln2_g, ln2_b,
                                                         x2, nullptr, nullptr, md, N);
  alpha_kernel<<<nblk_edge, 256, 0, stream>>>(e_s, csr, dstpos, md, a2, E2);
  // ---- Layer 3 (din=128, HC=256, C=64) ----
  gemm(1, x2, wt_g3l, g3_bl, xl, N, 128, 256, nullptr);
  gemm(1, x2, wt_g3r, g3_br, xr, N, 128, 256, nullptr);
  score_mfma_kernel<64><<<score_blocks, 256, 0, stream>>>(ea_bf, xl, xr, g3_We, g3_att, csr, srcpos, dstpos, e_s, E2, 256, 0);
  score_mfma_kernel<64><<<score_blocks, 256, 0, stream>>>(ea_bf, xl, xr, g3_We, g3_att, csr, srcpos, dstpos, e_s, E2, 256, 128);
  aggr_kernel<256, false><<<nblk_node, 256, 0, stream>>>(e_s, xl, rowptr, srcpos, g3_bias, ln3_g, ln3_b,
                                                         x3, nullptr, nullptr, md, N);
  alpha_kernel<<<nblk_edge, 256, 0, stream>>>(e_s, csr, dstpos, md, a3, E2);
  // ---- Final: xf = s*(x1@fp_W+fp_b) + (1-s)*x3 ; node MLP ----
  gemm(3, x1, wt_fp, fp_b, xf, N, 128, 256, x3);
  gemm(2, xf, wt_np1, np_b1, skipproj, N, 256, 128, nullptr);   // h1
  gemm(2, skipproj, wt_np2, np_b2, h2, N, 128, 64, nullptr);    // h2
  gemm(0, h2, wt_np3, np_b3, npout, N, 64, 1, nullptr);
}

// Round 14
// 556.304 us; speedup vs baseline: 4.6426x; 1.0203x over previous
//
#include <hip/hip_runtime.h>
#include <math.h>

#define DEV __device__ __forceinline__

typedef __attribute__((ext_vector_type(8))) short bf16x8;
typedef __attribute__((ext_vector_type(4))) float f32x4;

DEV float leakyf(float x, float s) { return x > 0.f ? x : s * x; }

DEV unsigned short f2bf(float f) {
  unsigned u = __float_as_uint(f);
  unsigned r = (u + 0x7fff + ((u >> 16) & 1)) >> 16;
  return (unsigned short)r;
}
DEV float bf2f(unsigned short h) { return __uint_as_float((unsigned)h << 16); }

DEV float sel4(float4 v, int h) {
  float a = (h & 1) ? v.y : v.x;
  float b = (h & 1) ? v.w : v.z;
  return (h & 2) ? b : a;
}

DEV float wave_sum(float v) {
#pragma unroll
  for (int o = 1; o < 64; o <<= 1) v += __shfl_xor(v, o);
  return v;
}
DEV float wave_max(float v) {
#pragma unroll
  for (int o = 1; o < 64; o <<= 1) v = fmaxf(v, __shfl_xor(v, o));
  return v;
}

// ---------------- weight pre-convert: W[K,Nc] f32 -> WT[Nc,K] bf16 ----------------
struct WJob { const float* in; unsigned short* out; int K; int Nc; };
struct WJobs { WJob j[13]; };

__global__ __launch_bounds__(256) void wt_kernel(WJobs jobs) {
  WJob jb = jobs.j[blockIdx.y];
  int total = jb.K * jb.Nc;
  for (int i = blockIdx.x * 256 + threadIdx.x; i < total; i += gridDim.x * 256) {
    int c = i / jb.K, k = i - c * jb.K;
    jb.out[i] = f2bf(jb.in[(size_t)k * jb.Nc + c]);
  }
}

// ---------------- BatchNorm (eval) ----------------
__global__ __launch_bounds__(256) void bn_kernel(
    const float* __restrict__ xin, const float* __restrict__ g,
    const float* __restrict__ b, const float* __restrict__ m,
    const float* __restrict__ v, float* __restrict__ xout, int total) {
  int i = blockIdx.x * 256 + threadIdx.x;
  if (i < total) {
    int c = i & 63;
    xout[i] = (xin[i] - m[c]) * rsqrtf(v[c] + 1e-5f) * g[c] + b[c];
  }
}

// ---------------- Edge encoder: fully-MFMA, persistent blocks (weights loaded once) ----------------
__global__ __launch_bounds__(256) void edge_enc_kernel(
    const float* __restrict__ edge_attr, const unsigned short* __restrict__ WT1,
    const float* __restrict__ b1, const unsigned short* __restrict__ WT2,
    const float* __restrict__ b2, unsigned short* __restrict__ ea_bf, int E) {
  __shared__ unsigned short sEa1[64][136];  // bf16, pad 8
  int tid = threadIdx.x, lane = tid & 63, w = tid >> 6;
  int g = lane >> 4, q = lane & 15;
  // weight fragments loaded ONCE per block, reused across all tiles
  bf16x8 w1f[8];
#pragma unroll
  for (int t = 0; t < 8; t++) {
    bf16x8 v = {};
    if (g < 2) v = *(const bf16x8*)(WT1 + (size_t)(16 * t + q) * 16 + 8 * g);
    w1f[t] = v;
  }
  float b1v[8];
#pragma unroll
  for (int t = 0; t < 8; t++) b1v[t] = b1[16 * t + q];
  bf16x8 w2f[4][4];
#pragma unroll
  for (int t = 0; t < 4; t++)
#pragma unroll
    for (int kc = 0; kc < 4; kc++)
      w2f[t][kc] = *(const bf16x8*)(WT2 + (size_t)(16 * t + q) * 128 + 32 * kc + 8 * g);
  float b2v[4];
#pragma unroll
  for (int t = 0; t < 4; t++) b2v[t] = b2[16 * t + q];

  int gstride = gridDim.x * 64;
  for (int base = blockIdx.x * 64; base < E; base += gstride) {
    int e0 = base + w * 16;
    bf16x8 af = {};
    if (g < 2) {
      int e = e0 + q;
      if (e >= E) e = E - 1;
      const float* ap = edge_attr + (size_t)e * 16 + 8 * g;
      float4 x0 = *(const float4*)ap;
      float4 x1 = *(const float4*)(ap + 4);
      af[0] = (short)f2bf(x0.x); af[1] = (short)f2bf(x0.y);
      af[2] = (short)f2bf(x0.z); af[3] = (short)f2bf(x0.w);
      af[4] = (short)f2bf(x1.x); af[5] = (short)f2bf(x1.y);
      af[6] = (short)f2bf(x1.z); af[7] = (short)f2bf(x1.w);
    }
    f32x4 acc1[8];
#pragma unroll
    for (int t = 0; t < 8; t++) acc1[t] = (f32x4){0.f, 0.f, 0.f, 0.f};
#pragma unroll
    for (int t = 0; t < 8; t++)
      acc1[t] = __builtin_amdgcn_mfma_f32_16x16x32_bf16(af, w1f[t], acc1[t], 0, 0, 0);
    // wave-private rows; same wave writes then reads -> intra-wave ordering suffices
#pragma unroll
    for (int t = 0; t < 8; t++)
#pragma unroll
      for (int r = 0; r < 4; r++) {
        float v = leakyf(acc1[t][r] + b1v[t], 0.01f);
        sEa1[w * 16 + g * 4 + r][16 * t + q] = f2bf(v);
      }
    f32x4 acc2[4];
#pragma unroll
    for (int t = 0; t < 4; t++) acc2[t] = (f32x4){0.f, 0.f, 0.f, 0.f};
#pragma unroll
    for (int kc = 0; kc < 4; kc++) {
      bf16x8 a2 = *(const bf16x8*)&sEa1[w * 16 + q][32 * kc + 8 * g];
#pragma unroll
      for (int t = 0; t < 4; t++)
        acc2[t] = __builtin_amdgcn_mfma_f32_16x16x32_bf16(a2, w2f[t][kc], acc2[t], 0, 0, 0);
    }
#pragma unroll
    for (int r = 0; r < 4; r++) {
      float vv[4];
      float p = 0.f;
#pragma unroll
      for (int t = 0; t < 4; t++) {
        float v = leakyf(acc2[t][r] + b2v[t], 0.01f);
        vv[t] = v;
        p += v * v;
      }
#pragma unroll
      for (int o = 1; o < 16; o <<= 1) p += __shfl_xor(p, o);
      float sc = 1.f / fmaxf(sqrtf(p), 1e-12f);
      int e = e0 + g * 4 + r;
      if (e < E) {
#pragma unroll
        for (int t = 0; t < 4; t++)
          ea_bf[(size_t)e * 64 + 16 * t + q] = f2bf(vv[t] * sc);
      }
    }
  }
}

// ---------------- CSR build ----------------
__global__ __launch_bounds__(256) void count_kernel(const int* __restrict__ dst0,
                                                    int* __restrict__ counts, int E, int E2) {
  int i = blockIdx.x * 256 + threadIdx.x;
  if (i < E2) {
    int d = (i < E) ? dst0[i] : (i - E);
    atomicAdd(&counts[d], 1);
  }
}

__global__ __launch_bounds__(256) void scan_kernel(const int* __restrict__ counts,
                                                   int* __restrict__ rowptr,
                                                   int* __restrict__ fill, int N) {
  __shared__ int part[256];
  int tid = threadIdx.x;
  int chunk = (N + 255) / 256;
  int lo = tid * chunk, hi = lo + chunk;
  if (hi > N) hi = N;
  if (lo > N) lo = N;
  int s = 0;
  for (int i = lo; i < hi; i++) s += counts[i];
  part[tid] = s;
  __syncthreads();
  if (tid == 0) {
    int run = 0;
    for (int i = 0; i < 256; i++) {
      int t = part[i];
      part[i] = run;
      run += t;
    }
    rowptr[N] = run;
  }
  __syncthreads();
  int off = part[tid];
  for (int i = lo; i < hi; i++) {
    rowptr[i] = off;
    fill[i] = off;
    off += counts[i];
  }
}

// builds csr (edge id), srcpos (src node), dstpos (dst node) by CSR position
__global__ __launch_bounds__(256) void fill_kernel(const int* __restrict__ src0,
                                                   const int* __restrict__ dst0,
                                                   int* __restrict__ fill,
                                                   int* __restrict__ csr,
                                                   int* __restrict__ srcpos,
                                                   int* __restrict__ dstpos, int E, int E2) {
  int i = blockIdx.x * 256 + threadIdx.x;
  if (i < E2) {
    int d, s;
    if (i < E) {
      d = dst0[i];
      s = src0[i];
    } else {
      d = s = i - E;
    }
    int pos = atomicAdd(&fill[d], 1);
    csr[pos] = i;
    srcpos[pos] = s;
    dstpos[pos] = d;
  }
}

// ---------------- self-loop attr = mean of incoming encoded attrs (bf16 in/out) ----------------
__global__ __launch_bounds__(256) void loopattr_kernel(unsigned short* __restrict__ ea_bf,
                                                       const int* __restrict__ rowptr,
                                                       const int* __restrict__ csr, int N, int E) {
  int lane = threadIdx.x & 63, wv = threadIdx.x >> 6;
  int stride = gridDim.x * 4;
  for (int n = blockIdx.x * 4 + wv; n < N; n += stride) {
    int r0 = rowptr[n], r1 = rowptr[n + 1];
    float acc = 0.f;
    int cnt = 0;
    for (int i = r0; i < r1; i++) {
      int e = csr[i];
      if (e < E) {
        acc += bf2f(ea_bf[(size_t)e * 64 + lane]);
        cnt++;
      }
    }
    ea_bf[((size_t)E + n) * 64 + lane] = f2bf(acc / fmaxf((float)cnt, 1.f));
  }
}

// ---------------- bf16 MFMA GEMM ----------------
// MODE: 0 f32 out, 1 bf16 out, 2 elu f32 out, 3 mix f32 out
template <int MODE>
__global__ __launch_bounds__(256) void gemm_mfma_kernel(
    const float* __restrict__ A, const unsigned short* __restrict__ BT,
    const float* __restrict__ bias, void* __restrict__ Cout, int M, int K, int Nc,
    const float* __restrict__ aux, const float* __restrict__ alpha_p) {
  __shared__ unsigned short sA[64][40];
  __shared__ unsigned short sB[64][40];
  int tid = threadIdx.x, lane = tid & 63, w = tid >> 6;
  int g = lane >> 4, q = lane & 15;
  int bm = blockIdx.y * 64, bn = blockIdx.x * 64;
  f32x4 acc[4];
#pragma unroll
  for (int t = 0; t < 4; t++) acc[t] = (f32x4){0.f, 0.f, 0.f, 0.f};
  int r = tid >> 2, ko = (tid & 3) * 8;
  for (int k0 = 0; k0 < K; k0 += 32) {
    {
      int gm = bm + r;
      bf16x8 v = {};
      if (gm < M) {
        const float* ap = A + (size_t)gm * K + k0 + ko;
        float4 x0 = *(const float4*)ap;
        float4 x1 = *(const float4*)(ap + 4);
        v[0] = (short)f2bf(x0.x); v[1] = (short)f2bf(x0.y);
        v[2] = (short)f2bf(x0.z); v[3] = (short)f2bf(x0.w);
        v[4] = (short)f2bf(x1.x); v[5] = (short)f2bf(x1.y);
        v[6] = (short)f2bf(x1.z); v[7] = (short)f2bf(x1.w);
      }
      *(bf16x8*)&sA[r][ko] = v;
      int gc = bn + r;
      bf16x8 bv = {};
      if (gc < Nc) bv = *(const bf16x8*)(BT + (size_t)gc * K + k0 + ko);
      *(bf16x8*)&sB[r][ko] = bv;
    }
    __syncthreads();
    bf16x8 a = *(const bf16x8*)&sA[w * 16 + q][8 * g];
#pragma unroll
    for (int t = 0; t < 4; t++) {
      bf16x8 b = *(const bf16x8*)&sB[16 * t + q][8 * g];
      acc[t] = __builtin_amdgcn_mfma_f32_16x16x32_bf16(a, b, acc[t], 0, 0, 0);
    }
    __syncthreads();
  }
  float s = 0.f;
  if (MODE == 3) s = 1.f / (1.f + __expf(-alpha_p[0]));
#pragma unroll
  for (int t = 0; t < 4; t++) {
    int col = bn + 16 * t + q;
#pragma unroll
    for (int rr = 0; rr < 4; rr++) {
      int row = bm + w * 16 + g * 4 + rr;
      if (row < M && col < Nc) {
        float v = acc[t][rr] + bias[col];
        if (MODE == 2) v = v > 0.f ? v : (__expf(v) - 1.f);
        if (MODE == 3) v = s * v + (1.f - s) * aux[(size_t)row * Nc + col];
        if (MODE == 1)
          ((unsigned short*)Cout)[(size_t)row * Nc + col] = f2bf(v);
        else
          ((float*)Cout)[(size_t)row * Nc + col] = v;
      }
    }
  }
}

// ---------------- GATv2 edge scores via MFMA, iterated in CSR-position order ----------------
template <int C>
__global__ __launch_bounds__(256) void score_mfma_kernel(
    const unsigned short* __restrict__ ea_bf, const unsigned short* __restrict__ xl,
    const unsigned short* __restrict__ xr, const float* __restrict__ We,
    const float* __restrict__ att, const int* __restrict__ csr,
    const int* __restrict__ srcpos, const int* __restrict__ dstpos,
    float* __restrict__ e_s, int E2, int HCfull, int col_off) {
  int lane = threadIdx.x & 63;
  int wv = threadIdx.x >> 6;
  int g = lane >> 4, q = lane & 15;
  bf16x8 bfrag[8][2];
#pragma unroll
  for (int t = 0; t < 8; t++)
#pragma unroll
    for (int kc = 0; kc < 2; kc++) {
      bf16x8 bv;
#pragma unroll
      for (int j = 0; j < 8; j++) {
        int k = kc * 32 + g * 8 + j;
        bv[j] = (short)f2bf(We[(size_t)k * HCfull + col_off + 16 * t + q]);
      }
      bfrag[t][kc] = bv;
    }
  float attv[8];
#pragma unroll
  for (int t = 0; t < 8; t++) attv[t] = att[col_off + 16 * t + q];

  constexpr int TPH = C / 16;
  constexpr int NH = 8 / TPH;
  const int headbase = col_off / C;

  int tiles = (E2 + 15) / 16;
  int nw = gridDim.x * 4;
  for (int tile = blockIdx.x * 4 + wv; tile < tiles; tile += nw) {
    int i0 = tile * 16;
    int ia = i0 + q;
    if (ia >= E2) ia = E2 - 1;
    int erow = csr[ia];
    const unsigned short* ap = ea_bf + (size_t)erow * 64 + g * 8;
    bf16x8 a0 = *(const bf16x8*)(ap);
    bf16x8 a1 = *(const bf16x8*)(ap + 32);
    f32x4 acc[8];
#pragma unroll
    for (int t = 0; t < 8; t++) acc[t] = (f32x4){0.f, 0.f, 0.f, 0.f};
#pragma unroll
    for (int t = 0; t < 8; t++) {
      acc[t] = __builtin_amdgcn_mfma_f32_16x16x32_bf16(a0, bfrag[t][0], acc[t], 0, 0, 0);
      acc[t] = __builtin_amdgcn_mfma_f32_16x16x32_bf16(a1, bfrag[t][1], acc[t], 0, 0, 0);
    }
    int sn[4], dn[4];
#pragma unroll
    for (int r = 0; r < 4; r++) {
      int i = i0 + g * 4 + r;
      if (i >= E2) i = E2 - 1;
      sn[r] = srcpos[i];
      dn[r] = dstpos[i];
    }
    float p[NH][4];
#pragma unroll
    for (int hh = 0; hh < NH; hh++)
#pragma unroll
      for (int r = 0; r < 4; r++) p[hh][r] = 0.f;
#pragma unroll
    for (int t = 0; t < 8; t++) {
      int col = col_off + 16 * t + q;
#pragma unroll
      for (int r = 0; r < 4; r++) {
        float xv = bf2f(xl[(size_t)sn[r] * HCfull + col]) +
                   bf2f(xr[(size_t)dn[r] * HCfull + col]) + acc[t][r];
        xv = xv > 0.f ? xv : 0.2f * xv;
        p[t / TPH][r] += xv * attv[t];
      }
    }
#pragma unroll
    for (int hh = 0; hh < NH; hh++)
#pragma unroll
      for (int r = 0; r < 4; r++) {
#pragma unroll
        for (int o = 1; o < 16; o <<= 1) p[hh][r] += __shfl_xor(p[hh][r], o);
      }
    if (q == 0) {
#pragma unroll
      for (int r = 0; r < 4; r++) {
        int i = i0 + g * 4 + r;
        if (i < E2) {
#pragma unroll
          for (int hh = 0; hh < NH; hh++)
            e_s[(size_t)i * 4 + headbase + hh] = p[hh][r];
        }
      }
    }
  }
}

// ---------------- per-node softmax + aggregation; 4x-unrolled gather, register-only selects ----------------
template <int HC, bool L1MODE>
__global__ __launch_bounds__(256) void aggr_kernel(
    const float* __restrict__ e_s, const unsigned short* __restrict__ xl,
    const int* __restrict__ rowptr, const int* __restrict__ srcpos,
    const float* __restrict__ bias,
    const float* __restrict__ lng, const float* __restrict__ lnb,
    float* __restrict__ xout,
    float* __restrict__ x1out, const float* __restrict__ skipproj,
    float* __restrict__ md, int N) {
  constexpr int CPL = HC / 64;
  int lane = threadIdx.x & 63, wv = threadIdx.x >> 6;
  int stride = gridDim.x * 4;
  const float4* e_s4 = (const float4*)e_s;
  for (int n = blockIdx.x * 4 + wv; n < N; n += stride) {
    int r0 = rowptr[n], r1 = rowptr[n + 1];
    float m0 = -1e30f, m1 = -1e30f, m2 = -1e30f, m3 = -1e30f;
    for (int i = r0 + lane; i < r1; i += 64) {
      float4 v = e_s4[i];
      m0 = fmaxf(m0, v.x);
      m1 = fmaxf(m1, v.y);
      m2 = fmaxf(m2, v.z);
      m3 = fmaxf(m3, v.w);
    }
    m0 = wave_max(m0);
    m1 = wave_max(m1);
    m2 = wave_max(m2);
    m3 = wave_max(m3);
    float d0 = 0.f, d1 = 0.f, d2 = 0.f, d3 = 0.f;
    for (int i = r0 + lane; i < r1; i += 64) {
      float4 v = e_s4[i];
      d0 += __expf(v.x - m0);
      d1 += __expf(v.y - m1);
      d2 += __expf(v.z - m2);
      d3 += __expf(v.w - m3);
    }
    d0 = wave_sum(d0);
    d1 = wave_sum(d1);
    d2 = wave_sum(d2);
    d3 = wave_sum(d3);
    float i0 = 1.f / (d0 + 1e-16f), i1 = 1.f / (d1 + 1e-16f);
    float i2 = 1.f / (d2 + 1e-16f), i3 = 1.f / (d3 + 1e-16f);
    if (lane == 0) {
      float* mp = md + (size_t)n * 8;
      mp[0] = m0; mp[1] = m1; mp[2] = m2; mp[3] = m3;
      mp[4] = i0; mp[5] = i1; mp[6] = i2; mp[7] = i3;
    }
    int h = lane >> 4;
    float mh = (h & 2) ? ((h & 1) ? m3 : m2) : ((h & 1) ? m1 : m0);
    float ih = (h & 2) ? ((h & 1) ? i3 : i2) : ((h & 1) ? i1 : i0);
    float acc[CPL];
#pragma unroll
    for (int j = 0; j < CPL; j++) acc[j] = 0.f;
    int c0 = lane * CPL;
    int i = r0;
    // 4x unrolled: batch the 4 random row-gathers so their latencies overlap.
    // All h-extractions are branchless register selects (no runtime array indexing).
    for (; i + 4 <= r1; i += 4) {
      float sh0, sh1, sh2, sh3;
      int sn0, sn1, sn2, sn3;
      {
        float4 a = e_s4[i], b = e_s4[i + 1], c = e_s4[i + 2], d = e_s4[i + 3];
        sh0 = sel4(a, h); sh1 = sel4(b, h); sh2 = sel4(c, h); sh3 = sel4(d, h);
      }
      sn0 = srcpos[i]; sn1 = srcpos[i + 1]; sn2 = srcpos[i + 2]; sn3 = srcpos[i + 3];
      if constexpr (CPL == 2) {
        ushort2 t0 = *(const ushort2*)(xl + (size_t)sn0 * HC + c0);
        ushort2 t1 = *(const ushort2*)(xl + (size_t)sn1 * HC + c0);
        ushort2 t2 = *(const ushort2*)(xl + (size_t)sn2 * HC + c0);
        ushort2 t3 = *(const ushort2*)(xl + (size_t)sn3 * HC + c0);
        float a0 = __expf(sh0 - mh) * ih;
        float a1 = __expf(sh1 - mh) * ih;
        float a2 = __expf(sh2 - mh) * ih;
        float a3 = __expf(sh3 - mh) * ih;
        acc[0] += a0 * bf2f(t0.x) + a1 * bf2f(t1.x) + a2 * bf2f(t2.x) + a3 * bf2f(t3.x);
        acc[1] += a0 * bf2f(t0.y) + a1 * bf2f(t1.y) + a2 * bf2f(t2.y) + a3 * bf2f(t3.y);
      } else {
        ushort4 t0 = *(const ushort4*)(xl + (size_t)sn0 * HC + c0);
        ushort4 t1 = *(const ushort4*)(xl + (size_t)sn1 * HC + c0);
        ushort4 t2 = *(const ushort4*)(xl + (size_t)sn2 * HC + c0);
        ushort4 t3 = *(const ushort4*)(xl + (size_t)sn3 * HC + c0);
        float a0 = __expf(sh0 - mh) * ih;
        float a1 = __expf(sh1 - mh) * ih;
        float a2 = __expf(sh2 - mh) * ih;
        float a3 = __expf(sh3 - mh) * ih;
        acc[0] += a0 * bf2f(t0.x) + a1 * bf2f(t1.x) + a2 * bf2f(t2.x) + a3 * bf2f(t3.x);
        acc[1] += a0 * bf2f(t0.y) + a1 * bf2f(t1.y) + a2 * bf2f(t2.y) + a3 * bf2f(t3.y);
        acc[2] += a0 * bf2f(t0.z) + a1 * bf2f(t1.z) + a2 * bf2f(t2.z) + a3 * bf2f(t3.z);
        acc[3] += a0 * bf2f(t0.w) + a1 * bf2f(t1.w) + a2 * bf2f(t2.w) + a3 * bf2f(t3.w);
      }
    }
    for (; i < r1; i++) {
      float sh = sel4(e_s4[i], h);
      float a = __expf(sh - mh) * ih;
      int sn = srcpos[i];
      const unsigned short* xp = xl + (size_t)sn * HC + c0;
      if constexpr (CPL == 2) {
        ushort2 t = *(const ushort2*)xp;
        acc[0] += a * bf2f(t.x);
        acc[1] += a * bf2f(t.y);
      } else {
        ushort4 t = *(const ushort4*)xp;
        acc[0] += a * bf2f(t.x);
        acc[1] += a * bf2f(t.y);
        acc[2] += a * bf2f(t.z);
        acc[3] += a * bf2f(t.w);
      }
    }
    float vals[CPL];
    float vs = 0.f, vq = 0.f;
#pragma unroll
    for (int j = 0; j < CPL; j++) {
      float t = acc[j] + bias[c0 + j];
      vals[j] = t;
      vs += t;
      vq += t * t;
    }
    vs = wave_sum(vs);
    vq = wave_sum(vq);
    float mean = vs * (1.f / HC);
    float var = vq * (1.f / HC) - mean * mean;
    float rstd = rsqrtf(fmaxf(var, 0.f) + 1e-5f);
#pragma unroll
    for (int j = 0; j < CPL; j++) {
      int c = c0 + j;
      float y = (vals[j] - mean) * rstd * lng[c] + lnb[c];
      y = leakyf(y, 0.01f);
      if constexpr (L1MODE) {
        x1out[(size_t)n * HC + c] = y;
        xout[(size_t)n * HC + c] = 0.01f * skipproj[(size_t)n * HC + c] + y;
      } else {
        xout[(size_t)n * HC + c] = y;
      }
    }
  }
}

// ---------------- alpha: coalesced e_s/dstpos read, md L2-hit, one scattered 16B write ----------------
__global__ __launch_bounds__(256) void alpha_kernel(
    const float* __restrict__ e_s, const int* __restrict__ csr,
    const int* __restrict__ dstpos, const float* __restrict__ md,
    float* __restrict__ alpha_out, int E2) {
  int i = blockIdx.x * 256 + threadIdx.x;
  if (i < E2) {
    float4 sv = ((const float4*)e_s)[i];
    int d = dstpos[i];
    const float* mp = md + (size_t)d * 8;
    float4 a;
    a.x = __expf(sv.x - mp[0]) * mp[4];
    a.y = __expf(sv.y - mp[1]) * mp[5];
    a.z = __expf(sv.z - mp[2]) * mp[6];
    a.w = __expf(sv.w - mp[3]) * mp[7];
    ((float4*)alpha_out)[csr[i]] = a;
  }
}

extern "C" void kernel_launch(void* const* d_in, const int* in_sizes, int n_in,
                              void* d_out, int out_size, void* d_ws, size_t ws_size,
                              hipStream_t stream) {
  (void)n_in;
  (void)out_size;
  (void)ws_size;
  const float* x_in = (const float*)d_in[0];
  const int* edge_index = (const int*)d_in[1];
  const float* edge_attr = (const float*)d_in[2];
  const float* bn0_g = (const float*)d_in[3];
  const float* bn0_b = (const float*)d_in[4];
  const float* bn0_m = (const float*)d_in[5];
  const float* bn0_v = (const float*)d_in[6];
  const float* eeW1 = (const float*)d_in[7];
  const float* eeb1 = (const float*)d_in[8];
  const float* eeW2 = (const float*)d_in[9];
  const float* eeb2 = (const float*)d_in[10];
  const float* g1_Wl = (const float*)d_in[11];
  const float* g1_bl = (const float*)d_in[12];
  const float* g1_Wr = (const float*)d_in[13];
  const float* g1_br = (const float*)d_in[14];
  const float* g1_We = (const float*)d_in[15];
  const float* g1_att = (const float*)d_in[16];
  const float* g1_bias = (const float*)d_in[17];
  const float* g2_Wl = (const float*)d_in[18];
  const float* g2_bl = (const float*)d_in[19];
  const float* g2_Wr = (const float*)d_in[20];
  const float* g2_br = (const float*)d_in[21];
  const float* g2_We = (const float*)d_in[22];
  const float* g2_att = (const float*)d_in[23];
  const float* g2_bias = (const float*)d_in[24];
  const float* g3_Wl = (const float*)d_in[25];
  const float* g3_bl = (const float*)d_in[26];
  const float* g3_Wr = (const float*)d_in[27];
  const float* g3_br = (const float*)d_in[28];
  const float* g3_We = (const float*)d_in[29];
  const float* g3_att = (const float*)d_in[30];
  const float* g3_bias = (const float*)d_in[31];
  const float* ln1_g = (const float*)d_in[32];
  const float* ln1_b = (const float*)d_in[33];
  const float* ln2_g = (const float*)d_in[34];
  const float* ln2_b = (const float*)d_in[35];
  const float* ln3_g = (const float*)d_in[36];
  const float* ln3_b = (const float*)d_in[37];
  const float* skip_W = (const float*)d_in[38];
  const float* skip_b = (const float*)d_in[39];
  const float* alpha_p = (const float*)d_in[40];
  const float* fp_W = (const float*)d_in[41];
  const float* fp_b = (const float*)d_in[42];
  const float* np_W1 = (const float*)d_in[43];
  const float* np_b1 = (const float*)d_in[44];
  const float* np_W2 = (const float*)d_in[45];
  const float* np_b2 = (const float*)d_in[46];
  const float* np_W3 = (const float*)d_in[47];
  const float* np_b3 = (const float*)d_in[48];

  const int N = in_sizes[0] / 64;
  const int E = in_sizes[2] / 16;
  const int E2 = E + N;
  const int* src0 = edge_index;
  const int* dst0 = edge_index + E;

  float* ws = (float*)d_ws;
  size_t off = 0;
  float* x = ws + off;         off += (size_t)N * 64;
  unsigned short* ea_bf = (unsigned short*)(ws + off); off += (size_t)E2 * 32;
  unsigned short* xl = (unsigned short*)(ws + off);    off += (size_t)N * 128;
  unsigned short* xr = (unsigned short*)(ws + off);    off += (size_t)N * 128;
  float* skipproj = ws + off;  off += (size_t)N * 128;  // reused as h1 at the end
  float* x1 = ws + off;        off += (size_t)N * 128;
  float* skip1 = ws + off;     off += (size_t)N * 128;
  float* x2 = ws + off;        off += (size_t)N * 128;
  float* x3 = ws + off;        off += (size_t)N * 256;
  float* e_s = ws + off;       off += (size_t)E2 * 4;
  float* h2 = ws + off;        off += (size_t)N * 64;
  float* md = ws + off;        off += (size_t)N * 8;
  int* counts = (int*)(ws + off);
  int* rowptr = counts + N;
  int* fill = rowptr + N + 1;
  int* csr = fill + N;
  int* srcpos = csr + E2;
  int* dstpos = srcpos + E2;
  off += (size_t)(3 * N + 1 + 3 * E2);
  off = (off + 3) & ~(size_t)3;
  unsigned short* wtp = (unsigned short*)(ws + off);
  auto alloc_wt = [&](int elems) {
    unsigned short* p = wtp;
    wtp += (elems + 7) & ~7;
    return p;
  };
  unsigned short* wt_g1l = alloc_wt(64 * 128);
  unsigned short* wt_g1r = alloc_wt(64 * 128);
  unsigned short* wt_skip = alloc_wt(64 * 128);
  unsigned short* wt_g2l = alloc_wt(128 * 128);
  unsigned short* wt_g2r = alloc_wt(128 * 128);
  unsigned short* wt_g3l = alloc_wt(128 * 256);
  unsigned short* wt_g3r = alloc_wt(128 * 256);
  unsigned short* wt_fp = alloc_wt(128 * 256);
  unsigned short* wt_np1 = alloc_wt(256 * 128);
  unsigned short* wt_np2 = alloc_wt(128 * 64);
  unsigned short* wt_np3 = alloc_wt(64 * 1);
  unsigned short* wt_ee1 = alloc_wt(16 * 128);
  unsigned short* wt_ee2 = alloc_wt(128 * 64);

  float* out = (float*)d_out;
  float* xf = out;
  float* npout = out + (size_t)N * 256;
  float* a1 = npout + N;
  float* a2 = a1 + (size_t)E2 * 4;
  float* a3 = a2 + (size_t)E2 * 4;

  WJobs jobs;
  jobs.j[0] = {g1_Wl, wt_g1l, 64, 128};
  jobs.j[1] = {g1_Wr, wt_g1r, 64, 128};
  jobs.j[2] = {skip_W, wt_skip, 64, 128};
  jobs.j[3] = {g2_Wl, wt_g2l, 128, 128};
  jobs.j[4] = {g2_Wr, wt_g2r, 128, 128};
  jobs.j[5] = {g3_Wl, wt_g3l, 128, 256};
  jobs.j[6] = {g3_Wr, wt_g3r, 128, 256};
  jobs.j[7] = {fp_W, wt_fp, 128, 256};
  jobs.j[8] = {np_W1, wt_np1, 256, 128};
  jobs.j[9] = {np_W2, wt_np2, 128, 64};
  jobs.j[10] = {np_W3, wt_np3, 64, 1};
  jobs.j[11] = {eeW1, wt_ee1, 16, 128};
  jobs.j[12] = {eeW2, wt_ee2, 128, 64};

  hipMemsetAsync(counts, 0, (size_t)N * sizeof(int), stream);
  wt_kernel<<<dim3(64, 13), 256, 0, stream>>>(jobs);
  bn_kernel<<<(N * 64 + 255) / 256, 256, 0, stream>>>(x_in, bn0_g, bn0_b, bn0_m, bn0_v, x, N * 64);
  edge_enc_kernel<<<1280, 256, 0, stream>>>(edge_attr, wt_ee1, eeb1, wt_ee2, eeb2, ea_bf, E);
  count_kernel<<<(E2 + 255) / 256, 256, 0, stream>>>(dst0, counts, E, E2);
  scan_kernel<<<1, 256, 0, stream>>>(counts, rowptr, fill, N);
  fill_kernel<<<(E2 + 255) / 256, 256, 0, stream>>>(src0, dst0, fill, csr, srcpos, dstpos, E, E2);
  loopattr_kernel<<<(N + 3) / 4, 256, 0, stream>>>(ea_bf, rowptr, csr, N, E);

  auto gemm = [&](int mode, const float* A, const unsigned short* BT, const float* bias,
                  void* Cp, int M, int K, int Nc, const float* aux) {
    dim3 gdim((Nc + 63) / 64, (M + 63) / 64);
    switch (mode) {
      case 0: gemm_mfma_kernel<0><<<gdim, 256, 0, stream>>>(A, BT, bias, Cp, M, K, Nc, nullptr, nullptr); break;
      case 1: gemm_mfma_kernel<1><<<gdim, 256, 0, stream>>>(A, BT, bias, Cp, M, K, Nc, nullptr, nullptr); break;
      case 2: gemm_mfma_kernel<2><<<gdim, 256, 0, stream>>>(A, BT, bias, Cp, M, K, Nc, nullptr, nullptr); break;
      case 3: gemm_mfma_kernel<3><<<gdim, 256, 0, stream>>>(A, BT, bias, Cp, M, K, Nc, aux, alpha_p); break;
    }
  };

  const int nblk_node = (N + 3) / 4;
  const int score_blocks = 1024;
  const int nblk_edge = (E2 + 255) / 256;

  // ---- Layer 1 (din=64, HC=128, C=32) ----
  gemm(1, x, wt_g1l, g1_bl, xl, N, 64, 128, nullptr);
  gemm(1, x, wt_g1r, g1_br, xr, N, 64, 128, nullptr);
  gemm(0, x, wt_skip, skip_b, skipproj, N, 64, 128, nullptr);
  score_mfma_kernel<32><<<score_blocks, 256, 0, stream>>>(ea_bf, xl, xr, g1_We, g1_att, csr, srcpos, dstpos, e_s, E2, 128, 0);
  aggr_kernel<128, true><<<nblk_node, 256, 0, stream>>>(e_s, xl, rowptr, srcpos, g1_bias, ln1_g, ln1_b,
                                                        skip1, x1, skipproj, md, N);
  alpha_kernel<<<nblk_edge, 256, 0, stream>>>(e_s, csr, dstpos, md, a1, E2);
  // ---- Layer 2 (din=128, HC=128, C=32) ----
  gemm(1, skip1, wt_g2l, g2_bl, xl, N, 128, 128, nullptr);
  gemm(1, skip1, wt_g2r, g2_br, xr, N, 128, 128, nullptr);
  score_mfma_kernel<32><<<score_blocks, 256, 0, stream>>>(ea_bf, xl, xr, g2_We, g2_att, csr, srcpos, dstpos, e_s, E2, 128, 0);
  aggr_kernel<128, false><<<nblk_node, 256, 0, stream>>>(e_s, xl, rowptr, srcpos, g2_bias, ln2_g, ln2_b,
                                                         x2, nullptr, nullptr, md, N);
  alpha_kernel<<<nblk_edge, 256, 0, stream>>>(e_s, csr, dstpos, md, a2, E2);
  // ---- Layer 3 (din=128, HC=256, C=64) ----
  gemm(1, x2, wt_g3l, g3_bl, xl, N, 128, 256, nullptr);
  gemm(1, x2, wt_g3r, g3_br, xr, N, 128, 256, nullptr);
  score_mfma_kernel<64><<<score_blocks, 256, 0, stream>>>(ea_bf, xl, xr, g3_We, g3_att, csr, srcpos, dstpos, e_s, E2, 256, 0);
  score_mfma_kernel<64><<<score_blocks, 256, 0, stream>>>(ea_bf, xl, xr, g3_We, g3_att, csr, srcpos, dstpos, e_s, E2, 256, 128);
  aggr_kernel<256, false><<<nblk_node, 256, 0, stream>>>(e_s, xl, rowptr, srcpos, g3_bias, ln3_g, ln3_b,
                                                         x3, nullptr, nullptr, md, N);
  alpha_kernel<<<nblk_edge, 256, 0, stream>>>(e_s, csr, dstpos, md, a3, E2);
  // ---- Final: xf = s*(x1@fp_W+fp_b) + (1-s)*x3 ; node MLP ----
  gemm(3, x1, wt_fp, fp_b, xf, N, 128, 256, x3);
  gemm(2, xf, wt_np1, np_b1, skipproj, N, 256, 128, nullptr);   // h1
  gemm(2, skipproj, wt_np2, np_b2, h2, N, 128, 64, nullptr);    // h2
  gemm(0, h2, wt_np3, np_b3, npout, N, 64, 1, nullptr);
}

// Round 15
// 541.543 us; speedup vs baseline: 4.7691x; 1.0273x over previous
//
#include <hip/hip_runtime.h>
#include <math.h>

#define DEV __device__ __forceinline__

typedef __attribute__((ext_vector_type(8))) short bf16x8;
typedef __attribute__((ext_vector_type(4))) float f32x4;

DEV float leakyf(float x, float s) { return x > 0.f ? x : s * x; }

DEV unsigned short f2bf(float f) {
  unsigned u = __float_as_uint(f);
  unsigned r = (u + 0x7fff + ((u >> 16) & 1)) >> 16;
  return (unsigned short)r;
}
DEV float bf2f(unsigned short h) { return __uint_as_float((unsigned)h << 16); }

DEV float sel4(float4 v, int h) {
  float a = (h & 1) ? v.y : v.x;
  float b = (h & 1) ? v.w : v.z;
  return (h & 2) ? b : a;
}

DEV float wave_sum(float v) {
#pragma unroll
  for (int o = 1; o < 64; o <<= 1) v += __shfl_xor(v, o);
  return v;
}
DEV float wave_max(float v) {
#pragma unroll
  for (int o = 1; o < 64; o <<= 1) v = fmaxf(v, __shfl_xor(v, o));
  return v;
}

// ---------------- weight pre-convert: W[K,Nc] f32 -> WT[Nc,K] bf16 ----------------
struct WJob { const float* in; unsigned short* out; int K; int Nc; };
struct WJobs { WJob j[13]; };

__global__ __launch_bounds__(256) void wt_kernel(WJobs jobs) {
  WJob jb = jobs.j[blockIdx.y];
  int total = jb.K * jb.Nc;
  for (int i = blockIdx.x * 256 + threadIdx.x; i < total; i += gridDim.x * 256) {
    int c = i / jb.K, k = i - c * jb.K;
    jb.out[i] = f2bf(jb.in[(size_t)k * jb.Nc + c]);
  }
}

// ---------------- BatchNorm (eval) ----------------
__global__ __launch_bounds__(256) void bn_kernel(
    const float* __restrict__ xin, const float* __restrict__ g,
    const float* __restrict__ b, const float* __restrict__ m,
    const float* __restrict__ v, float* __restrict__ xout, int total) {
  int i = blockIdx.x * 256 + threadIdx.x;
  if (i < total) {
    int c = i & 63;
    xout[i] = (xin[i] - m[c]) * rsqrtf(v[c] + 1e-5f) * g[c] + b[c];
  }
}

// ---------------- Edge encoder: fully-MFMA, persistent, attr-prefetch pipelined ----------------
__global__ __launch_bounds__(256) void edge_enc_kernel(
    const float* __restrict__ edge_attr, const unsigned short* __restrict__ WT1,
    const float* __restrict__ b1, const unsigned short* __restrict__ WT2,
    const float* __restrict__ b2, unsigned short* __restrict__ ea_bf, int E) {
  __shared__ unsigned short sEa1[64][136];  // bf16, pad 8
  int tid = threadIdx.x, lane = tid & 63, w = tid >> 6;
  int g = lane >> 4, q = lane & 15;
  // weight fragments loaded ONCE per block
  bf16x8 w1f[8];
#pragma unroll
  for (int t = 0; t < 8; t++) {
    bf16x8 v = {};
    if (g < 2) v = *(const bf16x8*)(WT1 + (size_t)(16 * t + q) * 16 + 8 * g);
    w1f[t] = v;
  }
  float b1v[8];
#pragma unroll
  for (int t = 0; t < 8; t++) b1v[t] = b1[16 * t + q];
  bf16x8 w2f[4][4];
#pragma unroll
  for (int t = 0; t < 4; t++)
#pragma unroll
    for (int kc = 0; kc < 4; kc++)
      w2f[t][kc] = *(const bf16x8*)(WT2 + (size_t)(16 * t + q) * 128 + 32 * kc + 8 * g);
  float b2v[4];
#pragma unroll
  for (int t = 0; t < 4; t++) b2v[t] = b2[16 * t + q];

  int gstride = gridDim.x * 64;

  auto load_attr = [&](int base) -> bf16x8 {
    bf16x8 af = {};
    if (g < 2) {
      int e = base + w * 16 + q;
      if (e >= E) e = E - 1;
      const float* ap = edge_attr + (size_t)e * 16 + 8 * g;
      float4 x0 = *(const float4*)ap;
      float4 x1 = *(const float4*)(ap + 4);
      af[0] = (short)f2bf(x0.x); af[1] = (short)f2bf(x0.y);
      af[2] = (short)f2bf(x0.z); af[3] = (short)f2bf(x0.w);
      af[4] = (short)f2bf(x1.x); af[5] = (short)f2bf(x1.y);
      af[6] = (short)f2bf(x1.z); af[7] = (short)f2bf(x1.w);
    }
    return af;
  };

  int base = blockIdx.x * 64;
  if (base >= E) return;
  bf16x8 af = load_attr(base);
  for (; base < E; ) {
    int next = base + gstride;
    bf16x8 af_next = {};
    if (next < E) af_next = load_attr(next);  // prefetch overlaps with compute below
    int e0 = base + w * 16;
    f32x4 acc1[8];
#pragma unroll
    for (int t = 0; t < 8; t++) acc1[t] = (f32x4){0.f, 0.f, 0.f, 0.f};
#pragma unroll
    for (int t = 0; t < 8; t++)
      acc1[t] = __builtin_amdgcn_mfma_f32_16x16x32_bf16(af, w1f[t], acc1[t], 0, 0, 0);
    // wave-private rows; same wave writes then reads -> intra-wave ordering suffices
#pragma unroll
    for (int t = 0; t < 8; t++)
#pragma unroll
      for (int r = 0; r < 4; r++) {
        float v = leakyf(acc1[t][r] + b1v[t], 0.01f);
        sEa1[w * 16 + g * 4 + r][16 * t + q] = f2bf(v);
      }
    f32x4 acc2[4];
#pragma unroll
    for (int t = 0; t < 4; t++) acc2[t] = (f32x4){0.f, 0.f, 0.f, 0.f};
#pragma unroll
    for (int kc = 0; kc < 4; kc++) {
      bf16x8 a2 = *(const bf16x8*)&sEa1[w * 16 + q][32 * kc + 8 * g];
#pragma unroll
      for (int t = 0; t < 4; t++)
        acc2[t] = __builtin_amdgcn_mfma_f32_16x16x32_bf16(a2, w2f[t][kc], acc2[t], 0, 0, 0);
    }
#pragma unroll
    for (int r = 0; r < 4; r++) {
      float vv[4];
      float p = 0.f;
#pragma unroll
      for (int t = 0; t < 4; t++) {
        float v = leakyf(acc2[t][r] + b2v[t], 0.01f);
        vv[t] = v;
        p += v * v;
      }
#pragma unroll
      for (int o = 1; o < 16; o <<= 1) p += __shfl_xor(p, o);
      float sc = 1.f / fmaxf(sqrtf(p), 1e-12f);
      int e = e0 + g * 4 + r;
      if (e < E) {
#pragma unroll
        for (int t = 0; t < 4; t++)
          ea_bf[(size_t)e * 64 + 16 * t + q] = f2bf(vv[t] * sc);
      }
    }
    af = af_next;
    base = next;
  }
}

// ---------------- CSR build ----------------
__global__ __launch_bounds__(256) void count_kernel(const int* __restrict__ dst0,
                                                    int* __restrict__ counts, int E, int E2) {
  int i = blockIdx.x * 256 + threadIdx.x;
  if (i < E2) {
    int d = (i < E) ? dst0[i] : (i - E);
    atomicAdd(&counts[d], 1);
  }
}

// 1024-thread block scan: 20 elems/thread serial + 10-step Hillis-Steele over partials
__global__ __launch_bounds__(1024) void scan_kernel(const int* __restrict__ counts,
                                                    int* __restrict__ rowptr,
                                                    int* __restrict__ fill, int N) {
  __shared__ int part[1024];
  int tid = threadIdx.x;
  int chunk = (N + 1023) / 1024;
  int lo = tid * chunk, hi = lo + chunk;
  if (hi > N) hi = N;
  if (lo > N) lo = N;
  int s = 0;
  for (int i = lo; i < hi; i++) s += counts[i];
  part[tid] = s;
  __syncthreads();
#pragma unroll
  for (int o = 1; o < 1024; o <<= 1) {
    int v = (tid >= o) ? part[tid - o] : 0;
    __syncthreads();
    part[tid] += v;
    __syncthreads();
  }
  if (tid == 1023) rowptr[N] = part[1023];
  int off = part[tid] - s;  // exclusive prefix
  for (int i = lo; i < hi; i++) {
    rowptr[i] = off;
    fill[i] = off;
    off += counts[i];
  }
}

// builds csr (edge id), srcpos (src node), dstpos (dst node) by CSR position
__global__ __launch_bounds__(256) void fill_kernel(const int* __restrict__ src0,
                                                   const int* __restrict__ dst0,
                                                   int* __restrict__ fill,
                                                   int* __restrict__ csr,
                                                   int* __restrict__ srcpos,
                                                   int* __restrict__ dstpos, int E, int E2) {
  int i = blockIdx.x * 256 + threadIdx.x;
  if (i < E2) {
    int d, s;
    if (i < E) {
      d = dst0[i];
      s = src0[i];
    } else {
      d = s = i - E;
    }
    int pos = atomicAdd(&fill[d], 1);
    csr[pos] = i;
    srcpos[pos] = s;
    dstpos[pos] = d;
  }
}

// ---------------- self-loop attr = mean of incoming encoded attrs (bf16 in/out) ----------------
__global__ __launch_bounds__(256) void loopattr_kernel(unsigned short* __restrict__ ea_bf,
                                                       const int* __restrict__ rowptr,
                                                       const int* __restrict__ csr, int N, int E) {
  int lane = threadIdx.x & 63, wv = threadIdx.x >> 6;
  int stride = gridDim.x * 4;
  for (int n = blockIdx.x * 4 + wv; n < N; n += stride) {
    int r0 = rowptr[n], r1 = rowptr[n + 1];
    float acc = 0.f;
    int cnt = 0;
    for (int i = r0; i < r1; i++) {
      int e = csr[i];
      if (e < E) {
        acc += bf2f(ea_bf[(size_t)e * 64 + lane]);
        cnt++;
      }
    }
    ea_bf[((size_t)E + n) * 64 + lane] = f2bf(acc / fmaxf((float)cnt, 1.f));
  }
}

// ---------------- bf16 MFMA GEMM ----------------
// MODE: 0 f32 out, 1 bf16 out, 2 elu f32 out, 3 mix f32 out
template <int MODE>
__global__ __launch_bounds__(256) void gemm_mfma_kernel(
    const float* __restrict__ A, const unsigned short* __restrict__ BT,
    const float* __restrict__ bias, void* __restrict__ Cout, int M, int K, int Nc,
    const float* __restrict__ aux, const float* __restrict__ alpha_p) {
  __shared__ unsigned short sA[64][40];
  __shared__ unsigned short sB[64][40];
  int tid = threadIdx.x, lane = tid & 63, w = tid >> 6;
  int g = lane >> 4, q = lane & 15;
  int bm = blockIdx.y * 64, bn = blockIdx.x * 64;
  f32x4 acc[4];
#pragma unroll
  for (int t = 0; t < 4; t++) acc[t] = (f32x4){0.f, 0.f, 0.f, 0.f};
  int r = tid >> 2, ko = (tid & 3) * 8;
  for (int k0 = 0; k0 < K; k0 += 32) {
    {
      int gm = bm + r;
      bf16x8 v = {};
      if (gm < M) {
        const float* ap = A + (size_t)gm * K + k0 + ko;
        float4 x0 = *(const float4*)ap;
        float4 x1 = *(const float4*)(ap + 4);
        v[0] = (short)f2bf(x0.x); v[1] = (short)f2bf(x0.y);
        v[2] = (short)f2bf(x0.z); v[3] = (short)f2bf(x0.w);
        v[4] = (short)f2bf(x1.x); v[5] = (short)f2bf(x1.y);
        v[6] = (short)f2bf(x1.z); v[7] = (short)f2bf(x1.w);
      }
      *(bf16x8*)&sA[r][ko] = v;
      int gc = bn + r;
      bf16x8 bv = {};
      if (gc < Nc) bv = *(const bf16x8*)(BT + (size_t)gc * K + k0 + ko);
      *(bf16x8*)&sB[r][ko] = bv;
    }
    __syncthreads();
    bf16x8 a = *(const bf16x8*)&sA[w * 16 + q][8 * g];
#pragma unroll
    for (int t = 0; t < 4; t++) {
      bf16x8 b = *(const bf16x8*)&sB[16 * t + q][8 * g];
      acc[t] = __builtin_amdgcn_mfma_f32_16x16x32_bf16(a, b, acc[t], 0, 0, 0);
    }
    __syncthreads();
  }
  float s = 0.f;
  if (MODE == 3) s = 1.f / (1.f + __expf(-alpha_p[0]));
#pragma unroll
  for (int t = 0; t < 4; t++) {
    int col = bn + 16 * t + q;
#pragma unroll
    for (int rr = 0; rr < 4; rr++) {
      int row = bm + w * 16 + g * 4 + rr;
      if (row < M && col < Nc) {
        float v = acc[t][rr] + bias[col];
        if (MODE == 2) v = v > 0.f ? v : (__expf(v) - 1.f);
        if (MODE == 3) v = s * v + (1.f - s) * aux[(size_t)row * Nc + col];
        if (MODE == 1)
          ((unsigned short*)Cout)[(size_t)row * Nc + col] = f2bf(v);
        else
          ((float*)Cout)[(size_t)row * Nc + col] = v;
      }
    }
  }
}

// ---------------- GATv2 edge scores via MFMA, iterated in CSR-position order ----------------
template <int C>
__global__ __launch_bounds__(256) void score_mfma_kernel(
    const unsigned short* __restrict__ ea_bf, const unsigned short* __restrict__ xl,
    const unsigned short* __restrict__ xr, const float* __restrict__ We,
    const float* __restrict__ att, const int* __restrict__ csr,
    const int* __restrict__ srcpos, const int* __restrict__ dstpos,
    float* __restrict__ e_s, int E2, int HCfull, int col_off) {
  int lane = threadIdx.x & 63;
  int wv = threadIdx.x >> 6;
  int g = lane >> 4, q = lane & 15;
  bf16x8 bfrag[8][2];
#pragma unroll
  for (int t = 0; t < 8; t++)
#pragma unroll
    for (int kc = 0; kc < 2; kc++) {
      bf16x8 bv;
#pragma unroll
      for (int j = 0; j < 8; j++) {
        int k = kc * 32 + g * 8 + j;
        bv[j] = (short)f2bf(We[(size_t)k * HCfull + col_off + 16 * t + q]);
      }
      bfrag[t][kc] = bv;
    }
  float attv[8];
#pragma unroll
  for (int t = 0; t < 8; t++) attv[t] = att[col_off + 16 * t + q];

  constexpr int TPH = C / 16;
  constexpr int NH = 8 / TPH;
  const int headbase = col_off / C;

  int tiles = (E2 + 15) / 16;
  int nw = gridDim.x * 4;
  for (int tile = blockIdx.x * 4 + wv; tile < tiles; tile += nw) {
    int i0 = tile * 16;
    int ia = i0 + q;
    if (ia >= E2) ia = E2 - 1;
    int erow = csr[ia];
    const unsigned short* ap = ea_bf + (size_t)erow * 64 + g * 8;
    bf16x8 a0 = *(const bf16x8*)(ap);
    bf16x8 a1 = *(const bf16x8*)(ap + 32);
    f32x4 acc[8];
#pragma unroll
    for (int t = 0; t < 8; t++) acc[t] = (f32x4){0.f, 0.f, 0.f, 0.f};
#pragma unroll
    for (int t = 0; t < 8; t++) {
      acc[t] = __builtin_amdgcn_mfma_f32_16x16x32_bf16(a0, bfrag[t][0], acc[t], 0, 0, 0);
      acc[t] = __builtin_amdgcn_mfma_f32_16x16x32_bf16(a1, bfrag[t][1], acc[t], 0, 0, 0);
    }
    int sn[4], dn[4];
#pragma unroll
    for (int r = 0; r < 4; r++) {
      int i = i0 + g * 4 + r;
      if (i >= E2) i = E2 - 1;
      sn[r] = srcpos[i];
      dn[r] = dstpos[i];
    }
    float p[NH][4];
#pragma unroll
    for (int hh = 0; hh < NH; hh++)
#pragma unroll
      for (int r = 0; r < 4; r++) p[hh][r] = 0.f;
#pragma unroll
    for (int t = 0; t < 8; t++) {
      int col = col_off + 16 * t + q;
#pragma unroll
      for (int r = 0; r < 4; r++) {
        float xv = bf2f(xl[(size_t)sn[r] * HCfull + col]) +
                   bf2f(xr[(size_t)dn[r] * HCfull + col]) + acc[t][r];
        xv = xv > 0.f ? xv : 0.2f * xv;
        p[t / TPH][r] += xv * attv[t];
      }
    }
#pragma unroll
    for (int hh = 0; hh < NH; hh++)
#pragma unroll
      for (int r = 0; r < 4; r++) {
#pragma unroll
        for (int o = 1; o < 16; o <<= 1) p[hh][r] += __shfl_xor(p[hh][r], o);
      }
    if (q == 0) {
#pragma unroll
      for (int r = 0; r < 4; r++) {
        int i = i0 + g * 4 + r;
        if (i < E2) {
#pragma unroll
          for (int hh = 0; hh < NH; hh++)
            e_s[(size_t)i * 4 + headbase + hh] = p[hh][r];
        }
      }
    }
  }
}

// ---------------- per-node softmax + aggregation; 4x-unrolled gather, register-only selects ----------------
template <int HC, bool L1MODE>
__global__ __launch_bounds__(256) void aggr_kernel(
    const float* __restrict__ e_s, const unsigned short* __restrict__ xl,
    const int* __restrict__ rowptr, const int* __restrict__ srcpos,
    const float* __restrict__ bias,
    const float* __restrict__ lng, const float* __restrict__ lnb,
    float* __restrict__ xout,
    float* __restrict__ x1out, const float* __restrict__ skipproj,
    float* __restrict__ md, int N) {
  constexpr int CPL = HC / 64;
  int lane = threadIdx.x & 63, wv = threadIdx.x >> 6;
  int stride = gridDim.x * 4;
  const float4* e_s4 = (const float4*)e_s;
  for (int n = blockIdx.x * 4 + wv; n < N; n += stride) {
    int r0 = rowptr[n], r1 = rowptr[n + 1];
    float m0 = -1e30f, m1 = -1e30f, m2 = -1e30f, m3 = -1e30f;
    for (int i = r0 + lane; i < r1; i += 64) {
      float4 v = e_s4[i];
      m0 = fmaxf(m0, v.x);
      m1 = fmaxf(m1, v.y);
      m2 = fmaxf(m2, v.z);
      m3 = fmaxf(m3, v.w);
    }
    m0 = wave_max(m0);
    m1 = wave_max(m1);
    m2 = wave_max(m2);
    m3 = wave_max(m3);
    float d0 = 0.f, d1 = 0.f, d2 = 0.f, d3 = 0.f;
    for (int i = r0 + lane; i < r1; i += 64) {
      float4 v = e_s4[i];
      d0 += __expf(v.x - m0);
      d1 += __expf(v.y - m1);
      d2 += __expf(v.z - m2);
      d3 += __expf(v.w - m3);
    }
    d0 = wave_sum(d0);
    d1 = wave_sum(d1);
    d2 = wave_sum(d2);
    d3 = wave_sum(d3);
    float i0 = 1.f / (d0 + 1e-16f), i1 = 1.f / (d1 + 1e-16f);
    float i2 = 1.f / (d2 + 1e-16f), i3 = 1.f / (d3 + 1e-16f);
    if (lane == 0) {
      float* mp = md + (size_t)n * 8;
      mp[0] = m0; mp[1] = m1; mp[2] = m2; mp[3] = m3;
      mp[4] = i0; mp[5] = i1; mp[6] = i2; mp[7] = i3;
    }
    int h = lane >> 4;
    float mh = (h & 2) ? ((h & 1) ? m3 : m2) : ((h & 1) ? m1 : m0);
    float ih = (h & 2) ? ((h & 1) ? i3 : i2) : ((h & 1) ? i1 : i0);
    float acc[CPL];
#pragma unroll
    for (int j = 0; j < CPL; j++) acc[j] = 0.f;
    int c0 = lane * CPL;
    int i = r0;
    for (; i + 4 <= r1; i += 4) {
      float sh0, sh1, sh2, sh3;
      int sn0, sn1, sn2, sn3;
      {
        float4 a = e_s4[i], b = e_s4[i + 1], c = e_s4[i + 2], d = e_s4[i + 3];
        sh0 = sel4(a, h); sh1 = sel4(b, h); sh2 = sel4(c, h); sh3 = sel4(d, h);
      }
      sn0 = srcpos[i]; sn1 = srcpos[i + 1]; sn2 = srcpos[i + 2]; sn3 = srcpos[i + 3];
      if constexpr (CPL == 2) {
        ushort2 t0 = *(const ushort2*)(xl + (size_t)sn0 * HC + c0);
        ushort2 t1 = *(const ushort2*)(xl + (size_t)sn1 * HC + c0);
        ushort2 t2 = *(const ushort2*)(xl + (size_t)sn2 * HC + c0);
        ushort2 t3 = *(const ushort2*)(xl + (size_t)sn3 * HC + c0);
        float a0 = __expf(sh0 - mh) * ih;
        float a1 = __expf(sh1 - mh) * ih;
        float a2 = __expf(sh2 - mh) * ih;
        float a3 = __expf(sh3 - mh) * ih;
        acc[0] += a0 * bf2f(t0.x) + a1 * bf2f(t1.x) + a2 * bf2f(t2.x) + a3 * bf2f(t3.x);
        acc[1] += a0 * bf2f(t0.y) + a1 * bf2f(t1.y) + a2 * bf2f(t2.y) + a3 * bf2f(t3.y);
      } else {
        ushort4 t0 = *(const ushort4*)(xl + (size_t)sn0 * HC + c0);
        ushort4 t1 = *(const ushort4*)(xl + (size_t)sn1 * HC + c0);
        ushort4 t2 = *(const ushort4*)(xl + (size_t)sn2 * HC + c0);
        ushort4 t3 = *(const ushort4*)(xl + (size_t)sn3 * HC + c0);
        float a0 = __expf(sh0 - mh) * ih;
        float a1 = __expf(sh1 - mh) * ih;
        float a2 = __expf(sh2 - mh) * ih;
        float a3 = __expf(sh3 - mh) * ih;
        acc[0] += a0 * bf2f(t0.x) + a1 * bf2f(t1.x) + a2 * bf2f(t2.x) + a3 * bf2f(t3.x);
        acc[1] += a0 * bf2f(t0.y) + a1 * bf2f(t1.y) + a2 * bf2f(t2.y) + a3 * bf2f(t3.y);
        acc[2] += a0 * bf2f(t0.z) + a1 * bf2f(t1.z) + a2 * bf2f(t2.z) + a3 * bf2f(t3.z);
        acc[3] += a0 * bf2f(t0.w) + a1 * bf2f(t1.w) + a2 * bf2f(t2.w) + a3 * bf2f(t3.w);
      }
    }
    for (; i < r1; i++) {
      float sh = sel4(e_s4[i], h);
      float a = __expf(sh - mh) * ih;
      int sn = srcpos[i];
      const unsigned short* xp = xl + (size_t)sn * HC + c0;
      if constexpr (CPL == 2) {
        ushort2 t = *(const ushort2*)xp;
        acc[0] += a * bf2f(t.x);
        acc[1] += a * bf2f(t.y);
      } else {
        ushort4 t = *(const ushort4*)xp;
        acc[0] += a * bf2f(t.x);
        acc[1] += a * bf2f(t.y);
        acc[2] += a * bf2f(t.z);
        acc[3] += a * bf2f(t.w);
      }
    }
    float vals[CPL];
    float vs = 0.f, vq = 0.f;
#pragma unroll
    for (int j = 0; j < CPL; j++) {
      float t = acc[j] + bias[c0 + j];
      vals[j] = t;
      vs += t;
      vq += t * t;
    }
    vs = wave_sum(vs);
    vq = wave_sum(vq);
    float mean = vs * (1.f / HC);
    float var = vq * (1.f / HC) - mean * mean;
    float rstd = rsqrtf(fmaxf(var, 0.f) + 1e-5f);
#pragma unroll
    for (int j = 0; j < CPL; j++) {
      int c = c0 + j;
      float y = (vals[j] - mean) * rstd * lng[c] + lnb[c];
      y = leakyf(y, 0.01f);
      if constexpr (L1MODE) {
        x1out[(size_t)n * HC + c] = y;
        xout[(size_t)n * HC + c] = 0.01f * skipproj[(size_t)n * HC + c] + y;
      } else {
        xout[(size_t)n * HC + c] = y;
      }
    }
  }
}

// ---------------- alpha: coalesced e_s/dstpos read, md L2-hit, one scattered 16B write ----------------
__global__ __launch_bounds__(256) void alpha_kernel(
    const float* __restrict__ e_s, const int* __restrict__ csr,
    const int* __restrict__ dstpos, const float* __restrict__ md,
    float* __restrict__ alpha_out, int E2) {
  int i = blockIdx.x * 256 + threadIdx.x;
  if (i < E2) {
    float4 sv = ((const float4*)e_s)[i];
    int d = dstpos[i];
    const float* mp = md + (size_t)d * 8;
    float4 a;
    a.x = __expf(sv.x - mp[0]) * mp[4];
    a.y = __expf(sv.y - mp[1]) * mp[5];
    a.z = __expf(sv.z - mp[2]) * mp[6];
    a.w = __expf(sv.w - mp[3]) * mp[7];
    ((float4*)alpha_out)[csr[i]] = a;
  }
}

extern "C" void kernel_launch(void* const* d_in, const int* in_sizes, int n_in,
                              void* d_out, int out_size, void* d_ws, size_t ws_size,
                              hipStream_t stream) {
  (void)n_in;
  (void)out_size;
  (void)ws_size;
  const float* x_in = (const float*)d_in[0];
  const int* edge_index = (const int*)d_in[1];
  const float* edge_attr = (const float*)d_in[2];
  const float* bn0_g = (const float*)d_in[3];
  const float* bn0_b = (const float*)d_in[4];
  const float* bn0_m = (const float*)d_in[5];
  const float* bn0_v = (const float*)d_in[6];
  const float* eeW1 = (const float*)d_in[7];
  const float* eeb1 = (const float*)d_in[8];
  const float* eeW2 = (const float*)d_in[9];
  const float* eeb2 = (const float*)d_in[10];
  const float* g1_Wl = (const float*)d_in[11];
  const float* g1_bl = (const float*)d_in[12];
  const float* g1_Wr = (const float*)d_in[13];
  const float* g1_br = (const float*)d_in[14];
  const float* g1_We = (const float*)d_in[15];
  const float* g1_att = (const float*)d_in[16];
  const float* g1_bias = (const float*)d_in[17];
  const float* g2_Wl = (const float*)d_in[18];
  const float* g2_bl = (const float*)d_in[19];
  const float* g2_Wr = (const float*)d_in[20];
  const float* g2_br = (const float*)d_in[21];
  const float* g2_We = (const float*)d_in[22];
  const float* g2_att = (const float*)d_in[23];
  const float* g2_bias = (const float*)d_in[24];
  const float* g3_Wl = (const float*)d_in[25];
  const float* g3_bl = (const float*)d_in[26];
  const float* g3_Wr = (const float*)d_in[27];
  const float* g3_br = (const float*)d_in[28];
  const float* g3_We = (const float*)d_in[29];
  const float* g3_att = (const float*)d_in[30];
  const float* g3_bias = (const float*)d_in[31];
  const float* ln1_g = (const float*)d_in[32];
  const float* ln1_b = (const float*)d_in[33];
  const float* ln2_g = (const float*)d_in[34];
  const float* ln2_b = (const float*)d_in[35];
  const float* ln3_g = (const float*)d_in[36];
  const float* ln3_b = (const float*)d_in[37];
  const float* skip_W = (const float*)d_in[38];
  const float* skip_b = (const float*)d_in[39];
  const float* alpha_p = (const float*)d_in[40];
  const float* fp_W = (const float*)d_in[41];
  const float* fp_b = (const float*)d_in[42];
  const float* np_W1 = (const float*)d_in[43];
  const float* np_b1 = (const float*)d_in[44];
  const float* np_W2 = (const float*)d_in[45];
  const float* np_b2 = (const float*)d_in[46];
  const float* np_W3 = (const float*)d_in[47];
  const float* np_b3 = (const float*)d_in[48];

  const int N = in_sizes[0] / 64;
  const int E = in_sizes[2] / 16;
  const int E2 = E + N;
  const int* src0 = edge_index;
  const int* dst0 = edge_index + E;

  float* ws = (float*)d_ws;
  size_t off = 0;
  float* x = ws + off;         off += (size_t)N * 64;
  unsigned short* ea_bf = (unsigned short*)(ws + off); off += (size_t)E2 * 32;
  unsigned short* xl = (unsigned short*)(ws + off);    off += (size_t)N * 128;
  unsigned short* xr = (unsigned short*)(ws + off);    off += (size_t)N * 128;
  float* skipproj = ws + off;  off += (size_t)N * 128;  // reused as h1 at the end
  float* x1 = ws + off;        off += (size_t)N * 128;
  float* skip1 = ws + off;     off += (size_t)N * 128;
  float* x2 = ws + off;        off += (size_t)N * 128;
  float* x3 = ws + off;        off += (size_t)N * 256;
  float* e_s = ws + off;       off += (size_t)E2 * 4;
  float* h2 = ws + off;        off += (size_t)N * 64;
  float* md = ws + off;        off += (size_t)N * 8;
  int* counts = (int*)(ws + off);
  int* rowptr = counts + N;
  int* fill = rowptr + N + 1;
  int* csr = fill + N;
  int* srcpos = csr + E2;
  int* dstpos = srcpos + E2;
  off += (size_t)(3 * N + 1 + 3 * E2);
  off = (off + 3) & ~(size_t)3;
  unsigned short* wtp = (unsigned short*)(ws + off);
  auto alloc_wt = [&](int elems) {
    unsigned short* p = wtp;
    wtp += (elems + 7) & ~7;
    return p;
  };
  unsigned short* wt_g1l = alloc_wt(64 * 128);
  unsigned short* wt_g1r = alloc_wt(64 * 128);
  unsigned short* wt_skip = alloc_wt(64 * 128);
  unsigned short* wt_g2l = alloc_wt(128 * 128);
  unsigned short* wt_g2r = alloc_wt(128 * 128);
  unsigned short* wt_g3l = alloc_wt(128 * 256);
  unsigned short* wt_g3r = alloc_wt(128 * 256);
  unsigned short* wt_fp = alloc_wt(128 * 256);
  unsigned short* wt_np1 = alloc_wt(256 * 128);
  unsigned short* wt_np2 = alloc_wt(128 * 64);
  unsigned short* wt_np3 = alloc_wt(64 * 1);
  unsigned short* wt_ee1 = alloc_wt(16 * 128);
  unsigned short* wt_ee2 = alloc_wt(128 * 64);

  float* out = (float*)d_out;
  float* xf = out;
  float* npout = out + (size_t)N * 256;
  float* a1 = npout + N;
  float* a2 = a1 + (size_t)E2 * 4;
  float* a3 = a2 + (size_t)E2 * 4;

  WJobs jobs;
  jobs.j[0] = {g1_Wl, wt_g1l, 64, 128};
  jobs.j[1] = {g1_Wr, wt_g1r, 64, 128};
  jobs.j[2] = {skip_W, wt_skip, 64, 128};
  jobs.j[3] = {g2_Wl, wt_g2l, 128, 128};
  jobs.j[4] = {g2_Wr, wt_g2r, 128, 128};
  jobs.j[5] = {g3_Wl, wt_g3l, 128, 256};
  jobs.j[6] = {g3_Wr, wt_g3r, 128, 256};
  jobs.j[7] = {fp_W, wt_fp, 128, 256};
  jobs.j[8] = {np_W1, wt_np1, 256, 128};
  jobs.j[9] = {np_W2, wt_np2, 128, 64};
  jobs.j[10] = {np_W3, wt_np3, 64, 1};
  jobs.j[11] = {eeW1, wt_ee1, 16, 128};
  jobs.j[12] = {eeW2, wt_ee2, 128, 64};

  hipMemsetAsync(counts, 0, (size_t)N * sizeof(int), stream);
  wt_kernel<<<dim3(64, 13), 256, 0, stream>>>(jobs);
  bn_kernel<<<(N * 64 + 255) / 256, 256, 0, stream>>>(x_in, bn0_g, bn0_b, bn0_m, bn0_v, x, N * 64);
  edge_enc_kernel<<<1280, 256, 0, stream>>>(edge_attr, wt_ee1, eeb1, wt_ee2, eeb2, ea_bf, E);
  count_kernel<<<(E2 + 255) / 256, 256, 0, stream>>>(dst0, counts, E, E2);
  scan_kernel<<<1, 1024, 0, stream>>>(counts, rowptr, fill, N);
  fill_kernel<<<(E2 + 255) / 256, 256, 0, stream>>>(src0, dst0, fill, csr, srcpos, dstpos, E, E2);
  loopattr_kernel<<<(N + 3) / 4, 256, 0, stream>>>(ea_bf, rowptr, csr, N, E);

  auto gemm = [&](int mode, const float* A, const unsigned short* BT, const float* bias,
                  void* Cp, int M, int K, int Nc, const float* aux) {
    dim3 gdim((Nc + 63) / 64, (M + 63) / 64);
    switch (mode) {
      case 0: gemm_mfma_kernel<0><<<gdim, 256, 0, stream>>>(A, BT, bias, Cp, M, K, Nc, nullptr, nullptr); break;
      case 1: gemm_mfma_kernel<1><<<gdim, 256, 0, stream>>>(A, BT, bias, Cp, M, K, Nc, nullptr, nullptr); break;
      case 2: gemm_mfma_kernel<2><<<gdim, 256, 0, stream>>>(A, BT, bias, Cp, M, K, Nc, nullptr, nullptr); break;
      case 3: gemm_mfma_kernel<3><<<gdim, 256, 0, stream>>>(A, BT, bias, Cp, M, K, Nc, aux, alpha_p); break;
    }
  };

  const int nblk_node = (N + 3) / 4;
  const int score_blocks = 1024;
  const int nblk_edge = (E2 + 255) / 256;

  // ---- Layer 1 (din=64, HC=128, C=32) ----
  gemm(1, x, wt_g1l, g1_bl, xl, N, 64, 128, nullptr);
  gemm(1, x, wt_g1r, g1_br, xr, N, 64, 128, nullptr);
  gemm(0, x, wt_skip, skip_b, skipproj, N, 64, 128, nullptr);
  score_mfma_kernel<32><<<score_blocks, 256, 0, stream>>>(ea_bf, xl, xr, g1_We, g1_att, csr, srcpos, dstpos, e_s, E2, 128, 0);
  aggr_kernel<128, true><<<nblk_node, 256, 0, stream>>>(e_s, xl, rowptr, srcpos, g1_bias, ln1_g, ln1_b,
                                                        skip1, x1, skipproj, md, N);
  alpha_kernel<<<nblk_edge, 256, 0, stream>>>(e_s, csr, dstpos, md, a1, E2);
  // ---- Layer 2 (din=128, HC=128, C=32) ----
  gemm(1, skip1, wt_g2l, g2_bl, xl, N, 128, 128, nullptr);
  gemm(1, skip1, wt_g2r, g2_br, xr, N, 128, 128, nullptr);
  score_mfma_kernel<32><<<score_blocks, 256, 0, stream>>>(ea_bf, xl, xr, g2_We, g2_att, csr, srcpos, dstpos, e_s, E2, 128, 0);
  aggr_kernel<128, false><<<nblk_node, 256, 0, stream>>>(e_s, xl, rowptr, srcpos, g2_bias, ln2_g, ln2_b,
                                                         x2, nullptr, nullptr, md, N);
  alpha_kernel<<<nblk_edge, 256, 0, stream>>>(e_s, csr, dstpos, md, a2, E2);
  // ---- Layer 3 (din=128, HC=256, C=64) ----
  gemm(1, x2, wt_g3l, g3_bl, xl, N, 128, 256, nullptr);
  gemm(1, x2, wt_g3r, g3_br, xr, N, 128, 256, nullptr);
  score_mfma_kernel<64><<<score_blocks, 256, 0, stream>>>(ea_bf, xl, xr, g3_We, g3_att, csr, srcpos, dstpos, e_s, E2, 256, 0);
  score_mfma_kernel<64><<<score_blocks, 256, 0, stream>>>(ea_bf, xl, xr, g3_We, g3_att, csr, srcpos, dstpos, e_s, E2, 256, 128);
  aggr_kernel<256, false><<<nblk_node, 256, 0, stream>>>(e_s, xl, rowptr, srcpos, g3_bias, ln3_g, ln3_b,
                                                         x3, nullptr, nullptr, md, N);
  alpha_kernel<<<nblk_edge, 256, 0, stream>>>(e_s, csr, dstpos, md, a3, E2);
  // ---- Final: xf = s*(x1@fp_W+fp_b) + (1-s)*x3 ; node MLP ----
  gemm(3, x1, wt_fp, fp_b, xf, N, 128, 256, x3);
  gemm(2, xf, wt_np1, np_b1, skipproj, N, 256, 128, nullptr);   // h1
  gemm(2, skipproj, wt_np2, np_b2, h2, N, 128, 64, nullptr);    // h2
  gemm(0, h2, wt_np3, np_b3, npout, N, 64, 1, nullptr);
}

// Round 16
// 530.549 us; speedup vs baseline: 4.8680x; 1.0207x over previous
//
#include <hip/hip_runtime.h>
#include <math.h>

#define DEV __device__ __forceinline__

typedef __attribute__((ext_vector_type(8))) short bf16x8;
typedef __attribute__((ext_vector_type(4))) float f32x4;

DEV float leakyf(float x, float s) { return x > 0.f ? x : s * x; }

DEV unsigned short f2bf(float f) {
  unsigned u = __float_as_uint(f);
  unsigned r = (u + 0x7fff + ((u >> 16) & 1)) >> 16;
  return (unsigned short)r;
}
DEV float bf2f(unsigned short h) { return __uint_as_float((unsigned)h << 16); }

DEV float sel4(float4 v, int h) {
  float a = (h & 1) ? v.y : v.x;
  float b = (h & 1) ? v.w : v.z;
  return (h & 2) ? b : a;
}

DEV float wave_sum(float v) {
#pragma unroll
  for (int o = 1; o < 64; o <<= 1) v += __shfl_xor(v, o);
  return v;
}
DEV float wave_max(float v) {
#pragma unroll
  for (int o = 1; o < 64; o <<= 1) v = fmaxf(v, __shfl_xor(v, o));
  return v;
}

// ---------------- weight pre-convert: W[K,Nc] f32 -> WT[Nc,K] bf16 ----------------
struct WJob { const float* in; unsigned short* out; int K; int Nc; };
struct WJobs { WJob j[13]; };

__global__ __launch_bounds__(256) void wt_kernel(WJobs jobs) {
  WJob jb = jobs.j[blockIdx.y];
  int total = jb.K * jb.Nc;
  for (int i = blockIdx.x * 256 + threadIdx.x; i < total; i += gridDim.x * 256) {
    int c = i / jb.K, k = i - c * jb.K;
    jb.out[i] = f2bf(jb.in[(size_t)k * jb.Nc + c]);
  }
}

// ---------------- BatchNorm (eval) ----------------
__global__ __launch_bounds__(256) void bn_kernel(
    const float* __restrict__ xin, const float* __restrict__ g,
    const float* __restrict__ b, const float* __restrict__ m,
    const float* __restrict__ v, float* __restrict__ xout, int total) {
  int i = blockIdx.x * 256 + threadIdx.x;
  if (i < total) {
    int c = i & 63;
    xout[i] = (xin[i] - m[c]) * rsqrtf(v[c] + 1e-5f) * g[c] + b[c];
  }
}

// ---------------- Edge encoder: fully-MFMA, persistent, coalesced writeback ----------------
__global__ __launch_bounds__(256) void edge_enc_kernel(
    const float* __restrict__ edge_attr, const unsigned short* __restrict__ WT1,
    const float* __restrict__ b1, const unsigned short* __restrict__ WT2,
    const float* __restrict__ b2, unsigned short* __restrict__ ea_bf, int E) {
  __shared__ __align__(16) unsigned short sEa1[64][136];  // bf16, pad 8; reused for output staging
  int tid = threadIdx.x, lane = tid & 63, w = tid >> 6;
  int g = lane >> 4, q = lane & 15;
  // weight fragments loaded ONCE per block
  bf16x8 w1f[8];
#pragma unroll
  for (int t = 0; t < 8; t++) {
    bf16x8 v = {};
    if (g < 2) v = *(const bf16x8*)(WT1 + (size_t)(16 * t + q) * 16 + 8 * g);
    w1f[t] = v;
  }
  float b1v[8];
#pragma unroll
  for (int t = 0; t < 8; t++) b1v[t] = b1[16 * t + q];
  bf16x8 w2f[4][4];
#pragma unroll
  for (int t = 0; t < 4; t++)
#pragma unroll
    for (int kc = 0; kc < 4; kc++)
      w2f[t][kc] = *(const bf16x8*)(WT2 + (size_t)(16 * t + q) * 128 + 32 * kc + 8 * g);
  float b2v[4];
#pragma unroll
  for (int t = 0; t < 4; t++) b2v[t] = b2[16 * t + q];

  int gstride = gridDim.x * 64;

  auto load_attr = [&](int base) -> bf16x8 {
    bf16x8 af = {};
    if (g < 2) {
      int e = base + w * 16 + q;
      if (e >= E) e = E - 1;
      const float* ap = edge_attr + (size_t)e * 16 + 8 * g;
      float4 x0 = *(const float4*)ap;
      float4 x1 = *(const float4*)(ap + 4);
      af[0] = (short)f2bf(x0.x); af[1] = (short)f2bf(x0.y);
      af[2] = (short)f2bf(x0.z); af[3] = (short)f2bf(x0.w);
      af[4] = (short)f2bf(x1.x); af[5] = (short)f2bf(x1.y);
      af[6] = (short)f2bf(x1.z); af[7] = (short)f2bf(x1.w);
    }
    return af;
  };

  int base = blockIdx.x * 64;
  if (base >= E) return;
  bf16x8 af = load_attr(base);
  for (; base < E; ) {
    int next = base + gstride;
    bf16x8 af_next = {};
    if (next < E) af_next = load_attr(next);  // prefetch overlaps with compute below
    f32x4 acc1[8];
#pragma unroll
    for (int t = 0; t < 8; t++) acc1[t] = (f32x4){0.f, 0.f, 0.f, 0.f};
#pragma unroll
    for (int t = 0; t < 8; t++)
      acc1[t] = __builtin_amdgcn_mfma_f32_16x16x32_bf16(af, w1f[t], acc1[t], 0, 0, 0);
    // wave-private rows; same wave writes then reads -> intra-wave ordering suffices
#pragma unroll
    for (int t = 0; t < 8; t++)
#pragma unroll
      for (int r = 0; r < 4; r++) {
        float v = leakyf(acc1[t][r] + b1v[t], 0.01f);
        sEa1[w * 16 + g * 4 + r][16 * t + q] = f2bf(v);
      }
    f32x4 acc2[4];
#pragma unroll
    for (int t = 0; t < 4; t++) acc2[t] = (f32x4){0.f, 0.f, 0.f, 0.f};
#pragma unroll
    for (int kc = 0; kc < 4; kc++) {
      bf16x8 a2 = *(const bf16x8*)&sEa1[w * 16 + q][32 * kc + 8 * g];
#pragma unroll
      for (int t = 0; t < 4; t++)
        acc2[t] = __builtin_amdgcn_mfma_f32_16x16x32_bf16(a2, w2f[t][kc], acc2[t], 0, 0, 0);
    }
    // scale + stage to LDS (wave-private), then coalesced 16B global stores
#pragma unroll
    for (int r = 0; r < 4; r++) {
      float vv[4];
      float p = 0.f;
#pragma unroll
      for (int t = 0; t < 4; t++) {
        float v = leakyf(acc2[t][r] + b2v[t], 0.01f);
        vv[t] = v;
        p += v * v;
      }
#pragma unroll
      for (int o = 1; o < 16; o <<= 1) p += __shfl_xor(p, o);
      float sc = 1.f / fmaxf(sqrtf(p), 1e-12f);
#pragma unroll
      for (int t = 0; t < 4; t++)
        sEa1[w * 16 + g * 4 + r][16 * t + q] = f2bf(vv[t] * sc);
    }
    // writeback: 2 passes; lane covers row w*16 + p*8 + (lane>>3), 16B at col (lane&7)*8
#pragma unroll
    for (int p = 0; p < 2; p++) {
      int rl = p * 8 + (lane >> 3);
      int e = base + w * 16 + rl;
      if (e < E) {
        bf16x8 v = *(const bf16x8*)&sEa1[w * 16 + rl][(lane & 7) * 8];
        *(bf16x8*)(ea_bf + (size_t)e * 64 + (lane & 7) * 8) = v;
      }
    }
    af = af_next;
    base = next;
  }
}

// ---------------- CSR build ----------------
__global__ __launch_bounds__(256) void count_kernel(const int* __restrict__ dst0,
                                                    int* __restrict__ counts, int E, int E2) {
  int i = blockIdx.x * 256 + threadIdx.x;
  if (i < E2) {
    int d = (i < E) ? dst0[i] : (i - E);
    atomicAdd(&counts[d], 1);
  }
}

// 1024-thread block scan: ~20 elems/thread serial + Hillis-Steele over partials
__global__ __launch_bounds__(1024) void scan_kernel(const int* __restrict__ counts,
                                                    int* __restrict__ rowptr,
                                                    int* __restrict__ fill, int N) {
  __shared__ int part[1024];
  int tid = threadIdx.x;
  int chunk = (N + 1023) / 1024;
  int lo = tid * chunk, hi = lo + chunk;
  if (hi > N) hi = N;
  if (lo > N) lo = N;
  int s = 0;
  for (int i = lo; i < hi; i++) s += counts[i];
  part[tid] = s;
  __syncthreads();
#pragma unroll
  for (int o = 1; o < 1024; o <<= 1) {
    int v = (tid >= o) ? part[tid - o] : 0;
    __syncthreads();
    part[tid] += v;
    __syncthreads();
  }
  if (tid == 1023) rowptr[N] = part[1023];
  int off = part[tid] - s;  // exclusive prefix
  for (int i = lo; i < hi; i++) {
    rowptr[i] = off;
    fill[i] = off;
    off += counts[i];
  }
}

// builds csr (edge id), srcpos (src node), dstpos (dst node) by CSR position
__global__ __launch_bounds__(256) void fill_kernel(const int* __restrict__ src0,
                                                   const int* __restrict__ dst0,
                                                   int* __restrict__ fill,
                                                   int* __restrict__ csr,
                                                   int* __restrict__ srcpos,
                                                   int* __restrict__ dstpos, int E, int E2) {
  int i = blockIdx.x * 256 + threadIdx.x;
  if (i < E2) {
    int d, s;
    if (i < E) {
      d = dst0[i];
      s = src0[i];
    } else {
      d = s = i - E;
    }
    int pos = atomicAdd(&fill[d], 1);
    csr[pos] = i;
    srcpos[pos] = s;
    dstpos[pos] = d;
  }
}

// ---------------- self-loop attr = mean of incoming encoded attrs (bf16 in/out) ----------------
__global__ __launch_bounds__(256) void loopattr_kernel(unsigned short* __restrict__ ea_bf,
                                                       const int* __restrict__ rowptr,
                                                       const int* __restrict__ csr, int N, int E) {
  int lane = threadIdx.x & 63, wv = threadIdx.x >> 6;
  int stride = gridDim.x * 4;
  for (int n = blockIdx.x * 4 + wv; n < N; n += stride) {
    int r0 = rowptr[n], r1 = rowptr[n + 1];
    float acc = 0.f;
    int cnt = 0;
    for (int i = r0; i < r1; i++) {
      int e = csr[i];
      if (e < E) {
        acc += bf2f(ea_bf[(size_t)e * 64 + lane]);
        cnt++;
      }
    }
    ea_bf[((size_t)E + n) * 64 + lane] = f2bf(acc / fmaxf((float)cnt, 1.f));
  }
}

// ---------------- bf16 MFMA GEMM (single) ----------------
// MODE: 0 f32 out, 1 bf16 out, 2 elu f32 out, 3 mix f32 out
template <int MODE>
__global__ __launch_bounds__(256) void gemm_mfma_kernel(
    const float* __restrict__ A, const unsigned short* __restrict__ BT,
    const float* __restrict__ bias, void* __restrict__ Cout, int M, int K, int Nc,
    const float* __restrict__ aux, const float* __restrict__ alpha_p) {
  __shared__ unsigned short sA[64][40];
  __shared__ unsigned short sB[64][40];
  int tid = threadIdx.x, lane = tid & 63, w = tid >> 6;
  int g = lane >> 4, q = lane & 15;
  int bm = blockIdx.y * 64, bn = blockIdx.x * 64;
  f32x4 acc[4];
#pragma unroll
  for (int t = 0; t < 4; t++) acc[t] = (f32x4){0.f, 0.f, 0.f, 0.f};
  int r = tid >> 2, ko = (tid & 3) * 8;
  for (int k0 = 0; k0 < K; k0 += 32) {
    {
      int gm = bm + r;
      bf16x8 v = {};
      if (gm < M) {
        const float* ap = A + (size_t)gm * K + k0 + ko;
        float4 x0 = *(const float4*)ap;
        float4 x1 = *(const float4*)(ap + 4);
        v[0] = (short)f2bf(x0.x); v[1] = (short)f2bf(x0.y);
        v[2] = (short)f2bf(x0.z); v[3] = (short)f2bf(x0.w);
        v[4] = (short)f2bf(x1.x); v[5] = (short)f2bf(x1.y);
        v[6] = (short)f2bf(x1.z); v[7] = (short)f2bf(x1.w);
      }
      *(bf16x8*)&sA[r][ko] = v;
      int gc = bn + r;
      bf16x8 bv = {};
      if (gc < Nc) bv = *(const bf16x8*)(BT + (size_t)gc * K + k0 + ko);
      *(bf16x8*)&sB[r][ko] = bv;
    }
    __syncthreads();
    bf16x8 a = *(const bf16x8*)&sA[w * 16 + q][8 * g];
#pragma unroll
    for (int t = 0; t < 4; t++) {
      bf16x8 b = *(const bf16x8*)&sB[16 * t + q][8 * g];
      acc[t] = __builtin_amdgcn_mfma_f32_16x16x32_bf16(a, b, acc[t], 0, 0, 0);
    }
    __syncthreads();
  }
  float s = 0.f;
  if (MODE == 3) s = 1.f / (1.f + __expf(-alpha_p[0]));
#pragma unroll
  for (int t = 0; t < 4; t++) {
    int col = bn + 16 * t + q;
#pragma unroll
    for (int rr = 0; rr < 4; rr++) {
      int row = bm + w * 16 + g * 4 + rr;
      if (row < M && col < Nc) {
        float v = acc[t][rr] + bias[col];
        if (MODE == 2) v = v > 0.f ? v : (__expf(v) - 1.f);
        if (MODE == 3) v = s * v + (1.f - s) * aux[(size_t)row * Nc + col];
        if (MODE == 1)
          ((unsigned short*)Cout)[(size_t)row * Nc + col] = f2bf(v);
        else
          ((float*)Cout)[(size_t)row * Nc + col] = v;
      }
    }
  }
}

// ---------------- bf16 MFMA GEMM (batched over grid.z: same A/M/K/Nc, different B/out) ----------------
struct GJob { const unsigned short* BT; const float* bias; void* out; int mode; };  // mode 0=f32, 1=bf16
struct GJobs { GJob j[3]; };

__global__ __launch_bounds__(256) void gemm_mfma_batched(
    const float* __restrict__ A, GJobs jobs, int M, int K, int Nc) {
  __shared__ unsigned short sA[64][40];
  __shared__ unsigned short sB[64][40];
  GJob jb = jobs.j[blockIdx.z];
  const unsigned short* BT = jb.BT;
  int tid = threadIdx.x, lane = tid & 63, w = tid >> 6;
  int g = lane >> 4, q = lane & 15;
  int bm = blockIdx.y * 64, bn = blockIdx.x * 64;
  f32x4 acc[4];
#pragma unroll
  for (int t = 0; t < 4; t++) acc[t] = (f32x4){0.f, 0.f, 0.f, 0.f};
  int r = tid >> 2, ko = (tid & 3) * 8;
  for (int k0 = 0; k0 < K; k0 += 32) {
    {
      int gm = bm + r;
      bf16x8 v = {};
      if (gm < M) {
        const float* ap = A + (size_t)gm * K + k0 + ko;
        float4 x0 = *(const float4*)ap;
        float4 x1 = *(const float4*)(ap + 4);
        v[0] = (short)f2bf(x0.x); v[1] = (short)f2bf(x0.y);
        v[2] = (short)f2bf(x0.z); v[3] = (short)f2bf(x0.w);
        v[4] = (short)f2bf(x1.x); v[5] = (short)f2bf(x1.y);
        v[6] = (short)f2bf(x1.z); v[7] = (short)f2bf(x1.w);
      }
      *(bf16x8*)&sA[r][ko] = v;
      int gc = bn + r;
      bf16x8 bv = {};
      if (gc < Nc) bv = *(const bf16x8*)(BT + (size_t)gc * K + k0 + ko);
      *(bf16x8*)&sB[r][ko] = bv;
    }
    __syncthreads();
    bf16x8 a = *(const bf16x8*)&sA[w * 16 + q][8 * g];
#pragma unroll
    for (int t = 0; t < 4; t++) {
      bf16x8 b = *(const bf16x8*)&sB[16 * t + q][8 * g];
      acc[t] = __builtin_amdgcn_mfma_f32_16x16x32_bf16(a, b, acc[t], 0, 0, 0);
    }
    __syncthreads();
  }
#pragma unroll
  for (int t = 0; t < 4; t++) {
    int col = bn + 16 * t + q;
#pragma unroll
    for (int rr = 0; rr < 4; rr++) {
      int row = bm + w * 16 + g * 4 + rr;
      if (row < M && col < Nc) {
        float v = acc[t][rr] + jb.bias[col];
        if (jb.mode == 1)
          ((unsigned short*)jb.out)[(size_t)row * Nc + col] = f2bf(v);
        else
          ((float*)jb.out)[(size_t)row * Nc + col] = v;
      }
    }
  }
}

// ---------------- GATv2 edge scores via MFMA, iterated in CSR-position order ----------------
template <int C>
__global__ __launch_bounds__(256) void score_mfma_kernel(
    const unsigned short* __restrict__ ea_bf, const unsigned short* __restrict__ xl,
    const unsigned short* __restrict__ xr, const float* __restrict__ We,
    const float* __restrict__ att, const int* __restrict__ csr,
    const int* __restrict__ srcpos, const int* __restrict__ dstpos,
    float* __restrict__ e_s, int E2, int HCfull, int col_off) {
  int lane = threadIdx.x & 63;
  int wv = threadIdx.x >> 6;
  int g = lane >> 4, q = lane & 15;
  bf16x8 bfrag[8][2];
#pragma unroll
  for (int t = 0; t < 8; t++)
#pragma unroll
    for (int kc = 0; kc < 2; kc++) {
      bf16x8 bv;
#pragma unroll
      for (int j = 0; j < 8; j++) {
        int k = kc * 32 + g * 8 + j;
        bv[j] = (short)f2bf(We[(size_t)k * HCfull + col_off + 16 * t + q]);
      }
      bfrag[t][kc] = bv;
    }
  float attv[8];
#pragma unroll
  for (int t = 0; t < 8; t++) attv[t] = att[col_off + 16 * t + q];

  constexpr int TPH = C / 16;
  constexpr int NH = 8 / TPH;
  const int headbase = col_off / C;

  int tiles = (E2 + 15) / 16;
  int nw = gridDim.x * 4;
  for (int tile = blockIdx.x * 4 + wv; tile < tiles; tile += nw) {
    int i0 = tile * 16;
    int ia = i0 + q;
    if (ia >= E2) ia = E2 - 1;
    int erow = csr[ia];
    const unsigned short* ap = ea_bf + (size_t)erow * 64 + g * 8;
    bf16x8 a0 = *(const bf16x8*)(ap);
    bf16x8 a1 = *(const bf16x8*)(ap + 32);
    f32x4 acc[8];
#pragma unroll
    for (int t = 0; t < 8; t++) acc[t] = (f32x4){0.f, 0.f, 0.f, 0.f};
#pragma unroll
    for (int t = 0; t < 8; t++) {
      acc[t] = __builtin_amdgcn_mfma_f32_16x16x32_bf16(a0, bfrag[t][0], acc[t], 0, 0, 0);
      acc[t] = __builtin_amdgcn_mfma_f32_16x16x32_bf16(a1, bfrag[t][1], acc[t], 0, 0, 0);
    }
    int sn[4], dn[4];
#pragma unroll
    for (int r = 0; r < 4; r++) {
      int i = i0 + g * 4 + r;
      if (i >= E2) i = E2 - 1;
      sn[r] = srcpos[i];
      dn[r] = dstpos[i];
    }
    float p[NH][4];
#pragma unroll
    for (int hh = 0; hh < NH; hh++)
#pragma unroll
      for (int r = 0; r < 4; r++) p[hh][r] = 0.f;
#pragma unroll
    for (int t = 0; t < 8; t++) {
      int col = col_off + 16 * t + q;
#pragma unroll
      for (int r = 0; r < 4; r++) {
        float xv = bf2f(xl[(size_t)sn[r] * HCfull + col]) +
                   bf2f(xr[(size_t)dn[r] * HCfull + col]) + acc[t][r];
        xv = xv > 0.f ? xv : 0.2f * xv;
        p[t / TPH][r] += xv * attv[t];
      }
    }
#pragma unroll
    for (int hh = 0; hh < NH; hh++)
#pragma unroll
      for (int r = 0; r < 4; r++) {
#pragma unroll
        for (int o = 1; o < 16; o <<= 1) p[hh][r] += __shfl_xor(p[hh][r], o);
      }
    if (q == 0) {
#pragma unroll
      for (int r = 0; r < 4; r++) {
        int i = i0 + g * 4 + r;
        if (i < E2) {
#pragma unroll
          for (int hh = 0; hh < NH; hh++)
            e_s[(size_t)i * 4 + headbase + hh] = p[hh][r];
        }
      }
    }
  }
}

// ---------------- per-node softmax + aggregation; 4x-unrolled gather, register-only selects ----------------
template <int HC, bool L1MODE>
__global__ __launch_bounds__(256) void aggr_kernel(
    const float* __restrict__ e_s, const unsigned short* __restrict__ xl,
    const int* __restrict__ rowptr, const int* __restrict__ srcpos,
    const float* __restrict__ bias,
    const float* __restrict__ lng, const float* __restrict__ lnb,
    float* __restrict__ xout,
    float* __restrict__ x1out, const float* __restrict__ skipproj,
    float* __restrict__ md, int N) {
  constexpr int CPL = HC / 64;
  int lane = threadIdx.x & 63, wv = threadIdx.x >> 6;
  int stride = gridDim.x * 4;
  const float4* e_s4 = (const float4*)e_s;
  for (int n = blockIdx.x * 4 + wv; n < N; n += stride) {
    int r0 = rowptr[n], r1 = rowptr[n + 1];
    float m0 = -1e30f, m1 = -1e30f, m2 = -1e30f, m3 = -1e30f;
    for (int i = r0 + lane; i < r1; i += 64) {
      float4 v = e_s4[i];
      m0 = fmaxf(m0, v.x);
      m1 = fmaxf(m1, v.y);
      m2 = fmaxf(m2, v.z);
      m3 = fmaxf(m3, v.w);
    }
    m0 = wave_max(m0);
    m1 = wave_max(m1);
    m2 = wave_max(m2);
    m3 = wave_max(m3);
    float d0 = 0.f, d1 = 0.f, d2 = 0.f, d3 = 0.f;
    for (int i = r0 + lane; i < r1; i += 64) {
      float4 v = e_s4[i];
      d0 += __expf(v.x - m0);
      d1 += __expf(v.y - m1);
      d2 += __expf(v.z - m2);
      d3 += __expf(v.w - m3);
    }
    d0 = wave_sum(d0);
    d1 = wave_sum(d1);
    d2 = wave_sum(d2);
    d3 = wave_sum(d3);
    float i0 = 1.f / (d0 + 1e-16f), i1 = 1.f / (d1 + 1e-16f);
    float i2 = 1.f / (d2 + 1e-16f), i3 = 1.f / (d3 + 1e-16f);
    if (lane == 0) {
      float* mp = md + (size_t)n * 8;
      mp[0] = m0; mp[1] = m1; mp[2] = m2; mp[3] = m3;
      mp[4] = i0; mp[5] = i1; mp[6] = i2; mp[7] = i3;
    }
    int h = lane >> 4;
    float mh = (h & 2) ? ((h & 1) ? m3 : m2) : ((h & 1) ? m1 : m0);
    float ih = (h & 2) ? ((h & 1) ? i3 : i2) : ((h & 1) ? i1 : i0);
    float acc[CPL];
#pragma unroll
    for (int j = 0; j < CPL; j++) acc[j] = 0.f;
    int c0 = lane * CPL;
    int i = r0;
    for (; i + 4 <= r1; i += 4) {
      float sh0, sh1, sh2, sh3;
      int sn0, sn1, sn2, sn3;
      {
        float4 a = e_s4[i], b = e_s4[i + 1], c = e_s4[i + 2], d = e_s4[i + 3];
        sh0 = sel4(a, h); sh1 = sel4(b, h); sh2 = sel4(c, h); sh3 = sel4(d, h);
      }
      sn0 = srcpos[i]; sn1 = srcpos[i + 1]; sn2 = srcpos[i + 2]; sn3 = srcpos[i + 3];
      if constexpr (CPL == 2) {
        ushort2 t0 = *(const ushort2*)(xl + (size_t)sn0 * HC + c0);
        ushort2 t1 = *(const ushort2*)(xl + (size_t)sn1 * HC + c0);
        ushort2 t2 = *(const ushort2*)(xl + (size_t)sn2 * HC + c0);
        ushort2 t3 = *(const ushort2*)(xl + (size_t)sn3 * HC + c0);
        float a0 = __expf(sh0 - mh) * ih;
        float a1 = __expf(sh1 - mh) * ih;
        float a2 = __expf(sh2 - mh) * ih;
        float a3 = __expf(sh3 - mh) * ih;
        acc[0] += a0 * bf2f(t0.x) + a1 * bf2f(t1.x) + a2 * bf2f(t2.x) + a3 * bf2f(t3.x);
        acc[1] += a0 * bf2f(t0.y) + a1 * bf2f(t1.y) + a2 * bf2f(t2.y) + a3 * bf2f(t3.y);
      } else {
        ushort4 t0 = *(const ushort4*)(xl + (size_t)sn0 * HC + c0);
        ushort4 t1 = *(const ushort4*)(xl + (size_t)sn1 * HC + c0);
        ushort4 t2 = *(const ushort4*)(xl + (size_t)sn2 * HC + c0);
        ushort4 t3 = *(const ushort4*)(xl + (size_t)sn3 * HC + c0);
        float a0 = __expf(sh0 - mh) * ih;
        float a1 = __expf(sh1 - mh) * ih;
        float a2 = __expf(sh2 - mh) * ih;
        float a3 = __expf(sh3 - mh) * ih;
        acc[0] += a0 * bf2f(t0.x) + a1 * bf2f(t1.x) + a2 * bf2f(t2.x) + a3 * bf2f(t3.x);
        acc[1] += a0 * bf2f(t0.y) + a1 * bf2f(t1.y) + a2 * bf2f(t2.y) + a3 * bf2f(t3.y);
        acc[2] += a0 * bf2f(t0.z) + a1 * bf2f(t1.z) + a2 * bf2f(t2.z) + a3 * bf2f(t3.z);
        acc[3] += a0 * bf2f(t0.w) + a1 * bf2f(t1.w) + a2 * bf2f(t2.w) + a3 * bf2f(t3.w);
      }
    }
    for (; i < r1; i++) {
      float sh = sel4(e_s4[i], h);
      float a = __expf(sh - mh) * ih;
      int sn = srcpos[i];
      const unsigned short* xp = xl + (size_t)sn * HC + c0;
      if constexpr (CPL == 2) {
        ushort2 t = *(const ushort2*)xp;
        acc[0] += a * bf2f(t.x);
        acc[1] += a * bf2f(t.y);
      } else {
        ushort4 t = *(const ushort4*)xp;
        acc[0] += a * bf2f(t.x);
        acc[1] += a * bf2f(t.y);
        acc[2] += a * bf2f(t.z);
        acc[3] += a * bf2f(t.w);
      }
    }
    float vals[CPL];
    float vs = 0.f, vq = 0.f;
#pragma unroll
    for (int j = 0; j < CPL; j++) {
      float t = acc[j] + bias[c0 + j];
      vals[j] = t;
      vs += t;
      vq += t * t;
    }
    vs = wave_sum(vs);
    vq = wave_sum(vq);
    float mean = vs * (1.f / HC);
    float var = vq * (1.f / HC) - mean * mean;
    float rstd = rsqrtf(fmaxf(var, 0.f) + 1e-5f);
#pragma unroll
    for (int j = 0; j < CPL; j++) {
      int c = c0 + j;
      float y = (vals[j] - mean) * rstd * lng[c] + lnb[c];
      y = leakyf(y, 0.01f);
      if constexpr (L1MODE) {
        x1out[(size_t)n * HC + c] = y;
        xout[(size_t)n * HC + c] = 0.01f * skipproj[(size_t)n * HC + c] + y;
      } else {
        xout[(size_t)n * HC + c] = y;
      }
    }
  }
}

// ---------------- alpha: coalesced e_s/dstpos read, md L2-hit, one scattered 16B write ----------------
__global__ __launch_bounds__(256) void alpha_kernel(
    const float* __restrict__ e_s, const int* __restrict__ csr,
    const int* __restrict__ dstpos, const float* __restrict__ md,
    float* __restrict__ alpha_out, int E2) {
  int i = blockIdx.x * 256 + threadIdx.x;
  if (i < E2) {
    float4 sv = ((const float4*)e_s)[i];
    int d = dstpos[i];
    const float* mp = md + (size_t)d * 8;
    float4 a;
    a.x = __expf(sv.x - mp[0]) * mp[4];
    a.y = __expf(sv.y - mp[1]) * mp[5];
    a.z = __expf(sv.z - mp[2]) * mp[6];
    a.w = __expf(sv.w - mp[3]) * mp[7];
    ((float4*)alpha_out)[csr[i]] = a;
  }
}

extern "C" void kernel_launch(void* const* d_in, const int* in_sizes, int n_in,
                              void* d_out, int out_size, void* d_ws, size_t ws_size,
                              hipStream_t stream) {
  (void)n_in;
  (void)out_size;
  (void)ws_size;
  const float* x_in = (const float*)d_in[0];
  const int* edge_index = (const int*)d_in[1];
  const float* edge_attr = (const float*)d_in[2];
  const float* bn0_g = (const float*)d_in[3];
  const float* bn0_b = (const float*)d_in[4];
  const float* bn0_m = (const float*)d_in[5];
  const float* bn0_v = (const float*)d_in[6];
  const float* eeW1 = (const float*)d_in[7];
  const float* eeb1 = (const float*)d_in[8];
  const float* eeW2 = (const float*)d_in[9];
  const float* eeb2 = (const float*)d_in[10];
  const float* g1_Wl = (const float*)d_in[11];
  const float* g1_bl = (const float*)d_in[12];
  const float* g1_Wr = (const float*)d_in[13];
  const float* g1_br = (const float*)d_in[14];
  const float* g1_We = (const float*)d_in[15];
  const float* g1_att = (const float*)d_in[16];
  const float* g1_bias = (const float*)d_in[17];
  const float* g2_Wl = (const float*)d_in[18];
  const float* g2_bl = (const float*)d_in[19];
  const float* g2_Wr = (const float*)d_in[20];
  const float* g2_br = (const float*)d_in[21];
  const float* g2_We = (const float*)d_in[22];
  const float* g2_att = (const float*)d_in[23];
  const float* g2_bias = (const float*)d_in[24];
  const float* g3_Wl = (const float*)d_in[25];
  const float* g3_bl = (const float*)d_in[26];
  const float* g3_Wr = (const float*)d_in[27];
  const float* g3_br = (const float*)d_in[28];
  const float* g3_We = (const float*)d_in[29];
  const float* g3_att = (const float*)d_in[30];
  const float* g3_bias = (const float*)d_in[31];
  const float* ln1_g = (const float*)d_in[32];
  const float* ln1_b = (const float*)d_in[33];
  const float* ln2_g = (const float*)d_in[34];
  const float* ln2_b = (const float*)d_in[35];
  const float* ln3_g = (const float*)d_in[36];
  const float* ln3_b = (const float*)d_in[37];
  const float* skip_W = (const float*)d_in[38];
  const float* skip_b = (const float*)d_in[39];
  const float* alpha_p = (const float*)d_in[40];
  const float* fp_W = (const float*)d_in[41];
  const float* fp_b = (const float*)d_in[42];
  const float* np_W1 = (const float*)d_in[43];
  const float* np_b1 = (const float*)d_in[44];
  const float* np_W2 = (const float*)d_in[45];
  const float* np_b2 = (const float*)d_in[46];
  const float* np_W3 = (const float*)d_in[47];
  const float* np_b3 = (const float*)d_in[48];

  const int N = in_sizes[0] / 64;
  const int E = in_sizes[2] / 16;
  const int E2 = E + N;
  const int* src0 = edge_index;
  const int* dst0 = edge_index + E;

  float* ws = (float*)d_ws;
  size_t off = 0;
  float* x = ws + off;         off += (size_t)N * 64;
  unsigned short* ea_bf = (unsigned short*)(ws + off); off += (size_t)E2 * 32;
  unsigned short* xl = (unsigned short*)(ws + off);    off += (size_t)N * 128;
  unsigned short* xr = (unsigned short*)(ws + off);    off += (size_t)N * 128;
  float* skipproj = ws + off;  off += (size_t)N * 128;  // reused as h1 at the end
  float* x1 = ws + off;        off += (size_t)N * 128;
  float* skip1 = ws + off;     off += (size_t)N * 128;
  float* x2 = ws + off;        off += (size_t)N * 128;
  float* x3 = ws + off;        off += (size_t)N * 256;
  float* e_s = ws + off;       off += (size_t)E2 * 4;
  float* h2 = ws + off;        off += (size_t)N * 64;
  float* md = ws + off;        off += (size_t)N * 8;
  int* counts = (int*)(ws + off);
  int* rowptr = counts + N;
  int* fill = rowptr + N + 1;
  int* csr = fill + N;
  int* srcpos = csr + E2;
  int* dstpos = srcpos + E2;
  off += (size_t)(3 * N + 1 + 3 * E2);
  off = (off + 3) & ~(size_t)3;
  unsigned short* wtp = (unsigned short*)(ws + off);
  auto alloc_wt = [&](int elems) {
    unsigned short* p = wtp;
    wtp += (elems + 7) & ~7;
    return p;
  };
  unsigned short* wt_g1l = alloc_wt(64 * 128);
  unsigned short* wt_g1r = alloc_wt(64 * 128);
  unsigned short* wt_skip = alloc_wt(64 * 128);
  unsigned short* wt_g2l = alloc_wt(128 * 128);
  unsigned short* wt_g2r = alloc_wt(128 * 128);
  unsigned short* wt_g3l = alloc_wt(128 * 256);
  unsigned short* wt_g3r = alloc_wt(128 * 256);
  unsigned short* wt_fp = alloc_wt(128 * 256);
  unsigned short* wt_np1 = alloc_wt(256 * 128);
  unsigned short* wt_np2 = alloc_wt(128 * 64);
  unsigned short* wt_np3 = alloc_wt(64 * 1);
  unsigned short* wt_ee1 = alloc_wt(16 * 128);
  unsigned short* wt_ee2 = alloc_wt(128 * 64);

  float* out = (float*)d_out;
  float* xf = out;
  float* npout = out + (size_t)N * 256;
  float* a1 = npout + N;
  float* a2 = a1 + (size_t)E2 * 4;
  float* a3 = a2 + (size_t)E2 * 4;

  WJobs jobs;
  jobs.j[0] = {g1_Wl, wt_g1l, 64, 128};
  jobs.j[1] = {g1_Wr, wt_g1r, 64, 128};
  jobs.j[2] = {skip_W, wt_skip, 64, 128};
  jobs.j[3] = {g2_Wl, wt_g2l, 128, 128};
  jobs.j[4] = {g2_Wr, wt_g2r, 128, 128};
  jobs.j[5] = {g3_Wl, wt_g3l, 128, 256};
  jobs.j[6] = {g3_Wr, wt_g3r, 128, 256};
  jobs.j[7] = {fp_W, wt_fp, 128, 256};
  jobs.j[8] = {np_W1, wt_np1, 256, 128};
  jobs.j[9] = {np_W2, wt_np2, 128, 64};
  jobs.j[10] = {np_W3, wt_np3, 64, 1};
  jobs.j[11] = {eeW1, wt_ee1, 16, 128};
  jobs.j[12] = {eeW2, wt_ee2, 128, 64};

  hipMemsetAsync(counts, 0, (size_t)N * sizeof(int), stream);
  wt_kernel<<<dim3(64, 13), 256, 0, stream>>>(jobs);
  bn_kernel<<<(N * 64 + 255) / 256, 256, 0, stream>>>(x_in, bn0_g, bn0_b, bn0_m, bn0_v, x, N * 64);
  edge_enc_kernel<<<2560, 256, 0, stream>>>(edge_attr, wt_ee1, eeb1, wt_ee2, eeb2, ea_bf, E);
  count_kernel<<<(E2 + 255) / 256, 256, 0, stream>>>(dst0, counts, E, E2);
  scan_kernel<<<1, 1024, 0, stream>>>(counts, rowptr, fill, N);
  fill_kernel<<<(E2 + 255) / 256, 256, 0, stream>>>(src0, dst0, fill, csr, srcpos, dstpos, E, E2);
  loopattr_kernel<<<(N + 3) / 4, 256, 0, stream>>>(ea_bf, rowptr, csr, N, E);

  auto gemm = [&](int mode, const float* A, const unsigned short* BT, const float* bias,
                  void* Cp, int M, int K, int Nc, const float* aux) {
    dim3 gdim((Nc + 63) / 64, (M + 63) / 64);
    switch (mode) {
      case 0: gemm_mfma_kernel<0><<<gdim, 256, 0, stream>>>(A, BT, bias, Cp, M, K, Nc, nullptr, nullptr); break;
      case 2: gemm_mfma_kernel<2><<<gdim, 256, 0, stream>>>(A, BT, bias, Cp, M, K, Nc, nullptr, nullptr); break;
      case 3: gemm_mfma_kernel<3><<<gdim, 256, 0, stream>>>(A, BT, bias, Cp, M, K, Nc, aux, alpha_p); break;
    }
  };
  auto gemm_batch = [&](const float* A, int M, int K, int Nc, GJobs gj, int nz) {
    dim3 gdim((Nc + 63) / 64, (M + 63) / 64, nz);
    gemm_mfma_batched<<<gdim, 256, 0, stream>>>(A, gj, M, K, Nc);
  };

  const int nblk_node = (N + 3) / 4;
  const int score_blocks = 1024;
  const int nblk_edge = (E2 + 255) / 256;

  // ---- Layer 1 (din=64, HC=128, C=32) ----
  {
    GJobs gj;
    gj.j[0] = {wt_g1l, g1_bl, xl, 1};
    gj.j[1] = {wt_g1r, g1_br, xr, 1};
    gj.j[2] = {wt_skip, skip_b, skipproj, 0};
    gemm_batch(x, N, 64, 128, gj, 3);
  }
  score_mfma_kernel<32><<<score_blocks, 256, 0, stream>>>(ea_bf, xl, xr, g1_We, g1_att, csr, srcpos, dstpos, e_s, E2, 128, 0);
  aggr_kernel<128, true><<<nblk_node, 256, 0, stream>>>(e_s, xl, rowptr, srcpos, g1_bias, ln1_g, ln1_b,
                                                        skip1, x1, skipproj, md, N);
  alpha_kernel<<<nblk_edge, 256, 0, stream>>>(e_s, csr, dstpos, md, a1, E2);
  // ---- Layer 2 (din=128, HC=128, C=32) ----
  {
    GJobs gj;
    gj.j[0] = {wt_g2l, g2_bl, xl, 1};
    gj.j[1] = {wt_g2r, g2_br, xr, 1};
    gj.j[2] = {nullptr, nullptr, nullptr, 0};
    gemm_batch(skip1, N, 128, 128, gj, 2);
  }
  score_mfma_kernel<32><<<score_blocks, 256, 0, stream>>>(ea_bf, xl, xr, g2_We, g2_att, csr, srcpos, dstpos, e_s, E2, 128, 0);
  aggr_kernel<128, false><<<nblk_node, 256, 0, stream>>>(e_s, xl, rowptr, srcpos, g2_bias, ln2_g, ln2_b,
                                                         x2, nullptr, nullptr, md, N);
  alpha_kernel<<<nblk_edge, 256, 0, stream>>>(e_s, csr, dstpos, md, a2, E2);
  // ---- Layer 3 (din=128, HC=256, C=64) ----
  {
    GJobs gj;
    gj.j[0] = {wt_g3l, g3_bl, xl, 1};
    gj.j[1] = {wt_g3r, g3_br, xr, 1};
    gj.j[2] = {nullptr, nullptr, nullptr, 0};
    gemm_batch(x2, N, 128, 256, gj, 2);
  }
  score_mfma_kernel<64><<<score_blocks, 256, 0, stream>>>(ea_bf, xl, xr, g3_We, g3_att, csr, srcpos, dstpos, e_s, E2, 256, 0);
  score_mfma_kernel<64><<<score_blocks, 256, 0, stream>>>(ea_bf, xl, xr, g3_We, g3_att, csr, srcpos, dstpos, e_s, E2, 256, 128);
  aggr_kernel<256, false><<<nblk_node, 256, 0, stream>>>(e_s, xl, rowptr, srcpos, g3_bias, ln3_g, ln3_b,
                                                         x3, nullptr, nullptr, md, N);
  alpha_kernel<<<nblk_edge, 256, 0, stream>>>(e_s, csr, dstpos, md, a3, E2);
  // ---- Final: xf = s*(x1@fp_W+fp_b) + (1-s)*x3 ; node MLP ----
  gemm(3, x1, wt_fp, fp_b, xf, N, 128, 256, x3);
  gemm(2, xf, wt_np1, np_b1, skipproj, N, 256, 128, nullptr);   // h1
  gemm(2, skipproj, wt_np2, np_b2, h2, N, 128, 64, nullptr);    // h2
  gemm(0, h2, wt_np3, np_b3, npout, N, 64, 1, nullptr);
}

// Round 17
// 505.714 us; speedup vs baseline: 5.1070x; 1.0491x over previous
//
#include <hip/hip_runtime.h>
#include <math.h>

#define DEV __device__ __forceinline__

typedef __attribute__((ext_vector_type(8))) short bf16x8;
typedef __attribute__((ext_vector_type(4))) float f32x4;

DEV float leakyf(float x, float s) { return x > 0.f ? x : s * x; }

DEV unsigned short f2bf(float f) {
  unsigned u = __float_as_uint(f);
  unsigned r = (u + 0x7fff + ((u >> 16) & 1)) >> 16;
  return (unsigned short)r;
}
DEV float bf2f(unsigned short h) { return __uint_as_float((unsigned)h << 16); }

DEV float sel4(float4 v, int h) {
  float a = (h & 1) ? v.y : v.x;
  float b = (h & 1) ? v.w : v.z;
  return (h & 2) ? b : a;
}

DEV float wave_sum(float v) {
#pragma unroll
  for (int o = 1; o < 64; o <<= 1) v += __shfl_xor(v, o);
  return v;
}
DEV float wave_max(float v) {
#pragma unroll
  for (int o = 1; o < 64; o <<= 1) v = fmaxf(v, __shfl_xor(v, o));
  return v;
}

// ---------------- weight pre-convert: W[K,Nc] f32 -> WT[Nc,K] bf16 ----------------
struct WJob { const float* in; unsigned short* out; int K; int Nc; };
struct WJobs { WJob j[13]; };

__global__ __launch_bounds__(256) void wt_kernel(WJobs jobs) {
  WJob jb = jobs.j[blockIdx.y];
  int total = jb.K * jb.Nc;
  for (int i = blockIdx.x * 256 + threadIdx.x; i < total; i += gridDim.x * 256) {
    int c = i / jb.K, k = i - c * jb.K;
    jb.out[i] = f2bf(jb.in[(size_t)k * jb.Nc + c]);
  }
}

// ---------------- BatchNorm (eval) ----------------
__global__ __launch_bounds__(256) void bn_kernel(
    const float* __restrict__ xin, const float* __restrict__ g,
    const float* __restrict__ b, const float* __restrict__ m,
    const float* __restrict__ v, float* __restrict__ xout, int total) {
  int i = blockIdx.x * 256 + threadIdx.x;
  if (i < total) {
    int c = i & 63;
    xout[i] = (xin[i] - m[c]) * rsqrtf(v[c] + 1e-5f) * g[c] + b[c];
  }
}

// ---------------- Edge encoder: fully-MFMA, persistent; launch_bounds(256,2) so
// the weight fragments (~96 VGPRs) actually stay resident across tiles ----------------
__global__ __launch_bounds__(256, 2) void edge_enc_kernel(
    const float* __restrict__ edge_attr, const unsigned short* __restrict__ WT1,
    const float* __restrict__ b1, const unsigned short* __restrict__ WT2,
    const float* __restrict__ b2, unsigned short* __restrict__ ea_bf, int E) {
  __shared__ unsigned short sEa1[64][136];  // bf16, pad 8
  int tid = threadIdx.x, lane = tid & 63, w = tid >> 6;
  int g = lane >> 4, q = lane & 15;
  // weight fragments loaded ONCE per block (kept in VGPRs)
  bf16x8 w1f[8];
#pragma unroll
  for (int t = 0; t < 8; t++) {
    bf16x8 v = {};
    if (g < 2) v = *(const bf16x8*)(WT1 + (size_t)(16 * t + q) * 16 + 8 * g);
    w1f[t] = v;
  }
  float b1v[8];
#pragma unroll
  for (int t = 0; t < 8; t++) b1v[t] = b1[16 * t + q];
  bf16x8 w2f[4][4];
#pragma unroll
  for (int t = 0; t < 4; t++)
#pragma unroll
    for (int kc = 0; kc < 4; kc++)
      w2f[t][kc] = *(const bf16x8*)(WT2 + (size_t)(16 * t + q) * 128 + 32 * kc + 8 * g);
  float b2v[4];
#pragma unroll
  for (int t = 0; t < 4; t++) b2v[t] = b2[16 * t + q];

  int gstride = gridDim.x * 64;

  auto load_attr = [&](int base) -> bf16x8 {
    bf16x8 af = {};
    if (g < 2) {
      int e = base + w * 16 + q;
      if (e >= E) e = E - 1;
      const float* ap = edge_attr + (size_t)e * 16 + 8 * g;
      float4 x0 = *(const float4*)ap;
      float4 x1 = *(const float4*)(ap + 4);
      af[0] = (short)f2bf(x0.x); af[1] = (short)f2bf(x0.y);
      af[2] = (short)f2bf(x0.z); af[3] = (short)f2bf(x0.w);
      af[4] = (short)f2bf(x1.x); af[5] = (short)f2bf(x1.y);
      af[6] = (short)f2bf(x1.z); af[7] = (short)f2bf(x1.w);
    }
    return af;
  };

  int base = blockIdx.x * 64;
  if (base >= E) return;
  bf16x8 af = load_attr(base);
  for (; base < E; ) {
    int next = base + gstride;
    bf16x8 af_next = {};
    if (next < E) af_next = load_attr(next);  // prefetch overlaps with compute below
    int e0 = base + w * 16;
    f32x4 acc1[8];
#pragma unroll
    for (int t = 0; t < 8; t++) acc1[t] = (f32x4){0.f, 0.f, 0.f, 0.f};
#pragma unroll
    for (int t = 0; t < 8; t++)
      acc1[t] = __builtin_amdgcn_mfma_f32_16x16x32_bf16(af, w1f[t], acc1[t], 0, 0, 0);
    // wave-private rows; same wave writes then reads -> intra-wave ordering suffices
#pragma unroll
    for (int t = 0; t < 8; t++)
#pragma unroll
      for (int r = 0; r < 4; r++) {
        float v = leakyf(acc1[t][r] + b1v[t], 0.01f);
        sEa1[w * 16 + g * 4 + r][16 * t + q] = f2bf(v);
      }
    f32x4 acc2[4];
#pragma unroll
    for (int t = 0; t < 4; t++) acc2[t] = (f32x4){0.f, 0.f, 0.f, 0.f};
#pragma unroll
    for (int kc = 0; kc < 4; kc++) {
      bf16x8 a2 = *(const bf16x8*)&sEa1[w * 16 + q][32 * kc + 8 * g];
#pragma unroll
      for (int t = 0; t < 4; t++)
        acc2[t] = __builtin_amdgcn_mfma_f32_16x16x32_bf16(a2, w2f[t][kc], acc2[t], 0, 0, 0);
    }
#pragma unroll
    for (int r = 0; r < 4; r++) {
      float vv[4];
      float p = 0.f;
#pragma unroll
      for (int t = 0; t < 4; t++) {
        float v = leakyf(acc2[t][r] + b2v[t], 0.01f);
        vv[t] = v;
        p += v * v;
      }
#pragma unroll
      for (int o = 1; o < 16; o <<= 1) p += __shfl_xor(p, o);
      float sc = 1.f / fmaxf(sqrtf(p), 1e-12f);
      int e = e0 + g * 4 + r;
      if (e < E) {
#pragma unroll
        for (int t = 0; t < 4; t++)
          ea_bf[(size_t)e * 64 + 16 * t + q] = f2bf(vv[t] * sc);
      }
    }
    af = af_next;
    base = next;
  }
}

// ---------------- CSR build ----------------
__global__ __launch_bounds__(256) void count_kernel(const int* __restrict__ dst0,
                                                    int* __restrict__ counts, int E, int E2) {
  int i = blockIdx.x * 256 + threadIdx.x;
  if (i < E2) {
    int d = (i < E) ? dst0[i] : (i - E);
    atomicAdd(&counts[d], 1);
  }
}

// 1024-thread block scan: ~20 elems/thread serial + Hillis-Steele over partials
__global__ __launch_bounds__(1024) void scan_kernel(const int* __restrict__ counts,
                                                    int* __restrict__ rowptr,
                                                    int* __restrict__ fill, int N) {
  __shared__ int part[1024];
  int tid = threadIdx.x;
  int chunk = (N + 1023) / 1024;
  int lo = tid * chunk, hi = lo + chunk;
  if (hi > N) hi = N;
  if (lo > N) lo = N;
  int s = 0;
  for (int i = lo; i < hi; i++) s += counts[i];
  part[tid] = s;
  __syncthreads();
#pragma unroll
  for (int o = 1; o < 1024; o <<= 1) {
    int v = (tid >= o) ? part[tid - o] : 0;
    __syncthreads();
    part[tid] += v;
    __syncthreads();
  }
  if (tid == 1023) rowptr[N] = part[1023];
  int off = part[tid] - s;  // exclusive prefix
  for (int i = lo; i < hi; i++) {
    rowptr[i] = off;
    fill[i] = off;
    off += counts[i];
  }
}

// builds csr (edge id), srcpos (src node), dstpos (dst node) by CSR position
__global__ __launch_bounds__(256) void fill_kernel(const int* __restrict__ src0,
                                                   const int* __restrict__ dst0,
                                                   int* __restrict__ fill,
                                                   int* __restrict__ csr,
                                                   int* __restrict__ srcpos,
                                                   int* __restrict__ dstpos, int E, int E2) {
  int i = blockIdx.x * 256 + threadIdx.x;
  if (i < E2) {
    int d, s;
    if (i < E) {
      d = dst0[i];
      s = src0[i];
    } else {
      d = s = i - E;
    }
    int pos = atomicAdd(&fill[d], 1);
    csr[pos] = i;
    srcpos[pos] = s;
    dstpos[pos] = d;
  }
}

// ---------------- self-loop attr = mean of incoming encoded attrs (bf16 in/out) ----------------
__global__ __launch_bounds__(256) void loopattr_kernel(unsigned short* __restrict__ ea_bf,
                                                       const int* __restrict__ rowptr,
                                                       const int* __restrict__ csr, int N, int E) {
  int lane = threadIdx.x & 63, wv = threadIdx.x >> 6;
  int stride = gridDim.x * 4;
  for (int n = blockIdx.x * 4 + wv; n < N; n += stride) {
    int r0 = rowptr[n], r1 = rowptr[n + 1];
    float acc = 0.f;
    int cnt = 0;
    for (int i = r0; i < r1; i++) {
      int e = csr[i];
      if (e < E) {
        acc += bf2f(ea_bf[(size_t)e * 64 + lane]);
        cnt++;
      }
    }
    ea_bf[((size_t)E + n) * 64 + lane] = f2bf(acc / fmaxf((float)cnt, 1.f));
  }
}

// ---------------- bf16 MFMA GEMM (single) ----------------
// MODE: 0 f32 out, 1 bf16 out, 2 elu f32 out, 3 mix f32 out
template <int MODE>
__global__ __launch_bounds__(256) void gemm_mfma_kernel(
    const float* __restrict__ A, const unsigned short* __restrict__ BT,
    const float* __restrict__ bias, void* __restrict__ Cout, int M, int K, int Nc,
    const float* __restrict__ aux, const float* __restrict__ alpha_p) {
  __shared__ unsigned short sA[64][40];
  __shared__ unsigned short sB[64][40];
  int tid = threadIdx.x, lane = tid & 63, w = tid >> 6;
  int g = lane >> 4, q = lane & 15;
  int bm = blockIdx.y * 64, bn = blockIdx.x * 64;
  f32x4 acc[4];
#pragma unroll
  for (int t = 0; t < 4; t++) acc[t] = (f32x4){0.f, 0.f, 0.f, 0.f};
  int r = tid >> 2, ko = (tid & 3) * 8;
  for (int k0 = 0; k0 < K; k0 += 32) {
    {
      int gm = bm + r;
      bf16x8 v = {};
      if (gm < M) {
        const float* ap = A + (size_t)gm * K + k0 + ko;
        float4 x0 = *(const float4*)ap;
        float4 x1 = *(const float4*)(ap + 4);
        v[0] = (short)f2bf(x0.x); v[1] = (short)f2bf(x0.y);
        v[2] = (short)f2bf(x0.z); v[3] = (short)f2bf(x0.w);
        v[4] = (short)f2bf(x1.x); v[5] = (short)f2bf(x1.y);
        v[6] = (short)f2bf(x1.z); v[7] = (short)f2bf(x1.w);
      }
      *(bf16x8*)&sA[r][ko] = v;
      int gc = bn + r;
      bf16x8 bv = {};
      if (gc < Nc) bv = *(const bf16x8*)(BT + (size_t)gc * K + k0 + ko);
      *(bf16x8*)&sB[r][ko] = bv;
    }
    __syncthreads();
    bf16x8 a = *(const bf16x8*)&sA[w * 16 + q][8 * g];
#pragma unroll
    for (int t = 0; t < 4; t++) {
      bf16x8 b = *(const bf16x8*)&sB[16 * t + q][8 * g];
      acc[t] = __builtin_amdgcn_mfma_f32_16x16x32_bf16(a, b, acc[t], 0, 0, 0);
    }
    __syncthreads();
  }
  float s = 0.f;
  if (MODE == 3) s = 1.f / (1.f + __expf(-alpha_p[0]));
#pragma unroll
  for (int t = 0; t < 4; t++) {
    int col = bn + 16 * t + q;
#pragma unroll
    for (int rr = 0; rr < 4; rr++) {
      int row = bm + w * 16 + g * 4 + rr;
      if (row < M && col < Nc) {
        float v = acc[t][rr] + bias[col];
        if (MODE == 2) v = v > 0.f ? v : (__expf(v) - 1.f);
        if (MODE == 3) v = s * v + (1.f - s) * aux[(size_t)row * Nc + col];
        if (MODE == 1)
          ((unsigned short*)Cout)[(size_t)row * Nc + col] = f2bf(v);
        else
          ((float*)Cout)[(size_t)row * Nc + col] = v;
      }
    }
  }
}

// ---------------- bf16 MFMA GEMM (batched over grid.z: same A/M/K/Nc, different B/out) ----------------
struct GJob { const unsigned short* BT; const float* bias; void* out; int mode; };  // mode 0=f32, 1=bf16
struct GJobs { GJob j[3]; };

__global__ __launch_bounds__(256) void gemm_mfma_batched(
    const float* __restrict__ A, GJobs jobs, int M, int K, int Nc) {
  __shared__ unsigned short sA[64][40];
  __shared__ unsigned short sB[64][40];
  GJob jb = jobs.j[blockIdx.z];
  const unsigned short* BT = jb.BT;
  int tid = threadIdx.x, lane = tid & 63, w = tid >> 6;
  int g = lane >> 4, q = lane & 15;
  int bm = blockIdx.y * 64, bn = blockIdx.x * 64;
  f32x4 acc[4];
#pragma unroll
  for (int t = 0; t < 4; t++) acc[t] = (f32x4){0.f, 0.f, 0.f, 0.f};
  int r = tid >> 2, ko = (tid & 3) * 8;
  for (int k0 = 0; k0 < K; k0 += 32) {
    {
      int gm = bm + r;
      bf16x8 v = {};
      if (gm < M) {
        const float* ap = A + (size_t)gm * K + k0 + ko;
        float4 x0 = *(const float4*)ap;
        float4 x1 = *(const float4*)(ap + 4);
        v[0] = (short)f2bf(x0.x); v[1] = (short)f2bf(x0.y);
        v[2] = (short)f2bf(x0.z); v[3] = (short)f2bf(x0.w);
        v[4] = (short)f2bf(x1.x); v[5] = (short)f2bf(x1.y);
        v[6] = (short)f2bf(x1.z); v[7] = (short)f2bf(x1.w);
      }
      *(bf16x8*)&sA[r][ko] = v;
      int gc = bn + r;
      bf16x8 bv = {};
      if (gc < Nc) bv = *(const bf16x8*)(BT + (size_t)gc * K + k0 + ko);
      *(bf16x8*)&sB[r][ko] = bv;
    }
    __syncthreads();
    bf16x8 a = *(const bf16x8*)&sA[w * 16 + q][8 * g];
#pragma unroll
    for (int t = 0; t < 4; t++) {
      bf16x8 b = *(const bf16x8*)&sB[16 * t + q][8 * g];
      acc[t] = __builtin_amdgcn_mfma_f32_16x16x32_bf16(a, b, acc[t], 0, 0, 0);
    }
    __syncthreads();
  }
#pragma unroll
  for (int t = 0; t < 4; t++) {
    int col = bn + 16 * t + q;
#pragma unroll
    for (int rr = 0; rr < 4; rr++) {
      int row = bm + w * 16 + g * 4 + rr;
      if (row < M && col < Nc) {
        float v = acc[t][rr] + jb.bias[col];
        if (jb.mode == 1)
          ((unsigned short*)jb.out)[(size_t)row * Nc + col] = f2bf(v);
        else
          ((float*)jb.out)[(size_t)row * Nc + col] = v;
      }
    }
  }
}

// ---------------- GATv2 edge scores via MFMA, CSR-position order ----------------
// SPLIT=true (HCfull=256): wave parity picks the 128-col half; one launch covers both.
template <int C, bool SPLIT>
__global__ __launch_bounds__(256) void score_mfma_kernel(
    const unsigned short* __restrict__ ea_bf, const unsigned short* __restrict__ xl,
    const unsigned short* __restrict__ xr, const float* __restrict__ We,
    const float* __restrict__ att, const int* __restrict__ csr,
    const int* __restrict__ srcpos, const int* __restrict__ dstpos,
    float* __restrict__ e_s, int E2, int HCfull, int col_off_in) {
  int lane = threadIdx.x & 63;
  int wv = threadIdx.x >> 6;
  int g = lane >> 4, q = lane & 15;
  int col_off = SPLIT ? (wv & 1) * 128 : col_off_in;
  bf16x8 bfrag[8][2];
#pragma unroll
  for (int t = 0; t < 8; t++)
#pragma unroll
    for (int kc = 0; kc < 2; kc++) {
      bf16x8 bv;
#pragma unroll
      for (int j = 0; j < 8; j++) {
        int k = kc * 32 + g * 8 + j;
        bv[j] = (short)f2bf(We[(size_t)k * HCfull + col_off + 16 * t + q]);
      }
      bfrag[t][kc] = bv;
    }
  float attv[8];
#pragma unroll
  for (int t = 0; t < 8; t++) attv[t] = att[col_off + 16 * t + q];

  constexpr int TPH = C / 16;
  constexpr int NH = 8 / TPH;
  const int headbase = col_off / C;

  int tiles = (E2 + 15) / 16;
  int tstart = SPLIT ? (blockIdx.x * 2 + (wv >> 1)) : (blockIdx.x * 4 + wv);
  int nw = SPLIT ? (gridDim.x * 2) : (gridDim.x * 4);
  for (int tile = tstart; tile < tiles; tile += nw) {
    int i0 = tile * 16;
    int ia = i0 + q;
    if (ia >= E2) ia = E2 - 1;
    int erow = csr[ia];
    const unsigned short* ap = ea_bf + (size_t)erow * 64 + g * 8;
    bf16x8 a0 = *(const bf16x8*)(ap);
    bf16x8 a1 = *(const bf16x8*)(ap + 32);
    f32x4 acc[8];
#pragma unroll
    for (int t = 0; t < 8; t++) acc[t] = (f32x4){0.f, 0.f, 0.f, 0.f};
#pragma unroll
    for (int t = 0; t < 8; t++) {
      acc[t] = __builtin_amdgcn_mfma_f32_16x16x32_bf16(a0, bfrag[t][0], acc[t], 0, 0, 0);
      acc[t] = __builtin_amdgcn_mfma_f32_16x16x32_bf16(a1, bfrag[t][1], acc[t], 0, 0, 0);
    }
    int sn[4], dn[4];
#pragma unroll
    for (int r = 0; r < 4; r++) {
      int i = i0 + g * 4 + r;
      if (i >= E2) i = E2 - 1;
      sn[r] = srcpos[i];
      dn[r] = dstpos[i];
    }
    float p[NH][4];
#pragma unroll
    for (int hh = 0; hh < NH; hh++)
#pragma unroll
      for (int r = 0; r < 4; r++) p[hh][r] = 0.f;
#pragma unroll
    for (int t = 0; t < 8; t++) {
      int col = col_off + 16 * t + q;
#pragma unroll
      for (int r = 0; r < 4; r++) {
        float xv = bf2f(xl[(size_t)sn[r] * HCfull + col]) +
                   bf2f(xr[(size_t)dn[r] * HCfull + col]) + acc[t][r];
        xv = xv > 0.f ? xv : 0.2f * xv;
        p[t / TPH][r] += xv * attv[t];
      }
    }
#pragma unroll
    for (int hh = 0; hh < NH; hh++)
#pragma unroll
      for (int r = 0; r < 4; r++) {
#pragma unroll
        for (int o = 1; o < 16; o <<= 1) p[hh][r] += __shfl_xor(p[hh][r], o);
      }
    if (q == 0) {
#pragma unroll
      for (int r = 0; r < 4; r++) {
        int i = i0 + g * 4 + r;
        if (i < E2) {
#pragma unroll
          for (int hh = 0; hh < NH; hh++)
            e_s[(size_t)i * 4 + headbase + hh] = p[hh][r];
        }
      }
    }
  }
}

// ---------------- per-node softmax + aggregation; 4x-unrolled gather, register-only selects ----------------
template <int HC, bool L1MODE>
__global__ __launch_bounds__(256) void aggr_kernel(
    const float* __restrict__ e_s, const unsigned short* __restrict__ xl,
    const int* __restrict__ rowptr, const int* __restrict__ srcpos,
    const float* __restrict__ bias,
    const float* __restrict__ lng, const float* __restrict__ lnb,
    float* __restrict__ xout,
    float* __restrict__ x1out, const float* __restrict__ skipproj,
    float* __restrict__ md, int N) {
  constexpr int CPL = HC / 64;
  int lane = threadIdx.x & 63, wv = threadIdx.x >> 6;
  int stride = gridDim.x * 4;
  const float4* e_s4 = (const float4*)e_s;
  for (int n = blockIdx.x * 4 + wv; n < N; n += stride) {
    int r0 = rowptr[n], r1 = rowptr[n + 1];
    float m0 = -1e30f, m1 = -1e30f, m2 = -1e30f, m3 = -1e30f;
    for (int i = r0 + lane; i < r1; i += 64) {
      float4 v = e_s4[i];
      m0 = fmaxf(m0, v.x);
      m1 = fmaxf(m1, v.y);
      m2 = fmaxf(m2, v.z);
      m3 = fmaxf(m3, v.w);
    }
    m0 = wave_max(m0);
    m1 = wave_max(m1);
    m2 = wave_max(m2);
    m3 = wave_max(m3);
    float d0 = 0.f, d1 = 0.f, d2 = 0.f, d3 = 0.f;
    for (int i = r0 + lane; i < r1; i += 64) {
      float4 v = e_s4[i];
      d0 += __expf(v.x - m0);
      d1 += __expf(v.y - m1);
      d2 += __expf(v.z - m2);
      d3 += __expf(v.w - m3);
    }
    d0 = wave_sum(d0);
    d1 = wave_sum(d1);
    d2 = wave_sum(d2);
    d3 = wave_sum(d3);
    float i0 = 1.f / (d0 + 1e-16f), i1 = 1.f / (d1 + 1e-16f);
    float i2 = 1.f / (d2 + 1e-16f), i3 = 1.f / (d3 + 1e-16f);
    if (lane == 0) {
      float* mp = md + (size_t)n * 8;
      mp[0] = m0; mp[1] = m1; mp[2] = m2; mp[3] = m3;
      mp[4] = i0; mp[5] = i1; mp[6] = i2; mp[7] = i3;
    }
    int h = lane >> 4;
    float mh = (h & 2) ? ((h & 1) ? m3 : m2) : ((h & 1) ? m1 : m0);
    float ih = (h & 2) ? ((h & 1) ? i3 : i2) : ((h & 1) ? i1 : i0);
    float acc[CPL];
#pragma unroll
    for (int j = 0; j < CPL; j++) acc[j] = 0.f;
    int c0 = lane * CPL;
    int i = r0;
    for (; i + 4 <= r1; i += 4) {
      float sh0, sh1, sh2, sh3;
      int sn0, sn1, sn2, sn3;
      {
        float4 a = e_s4[i], b = e_s4[i + 1], c = e_s4[i + 2], d = e_s4[i + 3];
        sh0 = sel4(a, h); sh1 = sel4(b, h); sh2 = sel4(c, h); sh3 = sel4(d, h);
      }
      sn0 = srcpos[i]; sn1 = srcpos[i + 1]; sn2 = srcpos[i + 2]; sn3 = srcpos[i + 3];
      if constexpr (CPL == 2) {
        ushort2 t0 = *(const ushort2*)(xl + (size_t)sn0 * HC + c0);
        ushort2 t1 = *(const ushort2*)(xl + (size_t)sn1 * HC + c0);
        ushort2 t2 = *(const ushort2*)(xl + (size_t)sn2 * HC + c0);
        ushort2 t3 = *(const ushort2*)(xl + (size_t)sn3 * HC + c0);
        float a0 = __expf(sh0 - mh) * ih;
        float a1 = __expf(sh1 - mh) * ih;
        float a2 = __expf(sh2 - mh) * ih;
        float a3 = __expf(sh3 - mh) * ih;
        acc[0] += a0 * bf2f(t0.x) + a1 * bf2f(t1.x) + a2 * bf2f(t2.x) + a3 * bf2f(t3.x);
        acc[1] += a0 * bf2f(t0.y) + a1 * bf2f(t1.y) + a2 * bf2f(t2.y) + a3 * bf2f(t3.y);
      } else {
        ushort4 t0 = *(const ushort4*)(xl + (size_t)sn0 * HC + c0);
        ushort4 t1 = *(const ushort4*)(xl + (size_t)sn1 * HC + c0);
        ushort4 t2 = *(const ushort4*)(xl + (size_t)sn2 * HC + c0);
        ushort4 t3 = *(const ushort4*)(xl + (size_t)sn3 * HC + c0);
        float a0 = __expf(sh0 - mh) * ih;
        float a1 = __expf(sh1 - mh) * ih;
        float a2 = __expf(sh2 - mh) * ih;
        float a3 = __expf(sh3 - mh) * ih;
        acc[0] += a0 * bf2f(t0.x) + a1 * bf2f(t1.x) + a2 * bf2f(t2.x) + a3 * bf2f(t3.x);
        acc[1] += a0 * bf2f(t0.y) + a1 * bf2f(t1.y) + a2 * bf2f(t2.y) + a3 * bf2f(t3.y);
        acc[2] += a0 * bf2f(t0.z) + a1 * bf2f(t1.z) + a2 * bf2f(t2.z) + a3 * bf2f(t3.z);
        acc[3] += a0 * bf2f(t0.w) + a1 * bf2f(t1.w) + a2 * bf2f(t2.w) + a3 * bf2f(t3.w);
      }
    }
    for (; i < r1; i++) {
      float sh = sel4(e_s4[i], h);
      float a = __expf(sh - mh) * ih;
      int sn = srcpos[i];
      const unsigned short* xp = xl + (size_t)sn * HC + c0;
      if constexpr (CPL == 2) {
        ushort2 t = *(const ushort2*)xp;
        acc[0] += a * bf2f(t.x);
        acc[1] += a * bf2f(t.y);
      } else {
        ushort4 t = *(const ushort4*)xp;
        acc[0] += a * bf2f(t.x);
        acc[1] += a * bf2f(t.y);
        acc[2] += a * bf2f(t.z);
        acc[3] += a * bf2f(t.w);
      }
    }
    float vals[CPL];
    float vs = 0.f, vq = 0.f;
#pragma unroll
    for (int j = 0; j < CPL; j++) {
      float t = acc[j] + bias[c0 + j];
      vals[j] = t;
      vs += t;
      vq += t * t;
    }
    vs = wave_sum(vs);
    vq = wave_sum(vq);
    float mean = vs * (1.f / HC);
    float var = vq * (1.f / HC) - mean * mean;
    float rstd = rsqrtf(fmaxf(var, 0.f) + 1e-5f);
#pragma unroll
    for (int j = 0; j < CPL; j++) {
      int c = c0 + j;
      float y = (vals[j] - mean) * rstd * lng[c] + lnb[c];
      y = leakyf(y, 0.01f);
      if constexpr (L1MODE) {
        x1out[(size_t)n * HC + c] = y;
        xout[(size_t)n * HC + c] = 0.01f * skipproj[(size_t)n * HC + c] + y;
      } else {
        xout[(size_t)n * HC + c] = y;
      }
    }
  }
}

// ---------------- alpha: coalesced e_s/dstpos read, md L2-hit, one scattered 16B write ----------------
__global__ __launch_bounds__(256) void alpha_kernel(
    const float* __restrict__ e_s, const int* __restrict__ csr,
    const int* __restrict__ dstpos, const float* __restrict__ md,
    float* __restrict__ alpha_out, int E2) {
  int i = blockIdx.x * 256 + threadIdx.x;
  if (i < E2) {
    float4 sv = ((const float4*)e_s)[i];
    int d = dstpos[i];
    const float* mp = md + (size_t)d * 8;
    float4 a;
    a.x = __expf(sv.x - mp[0]) * mp[4];
    a.y = __expf(sv.y - mp[1]) * mp[5];
    a.z = __expf(sv.z - mp[2]) * mp[6];
    a.w = __expf(sv.w - mp[3]) * mp[7];
    ((float4*)alpha_out)[csr[i]] = a;
  }
}

extern "C" void kernel_launch(void* const* d_in, const int* in_sizes, int n_in,
                              void* d_out, int out_size, void* d_ws, size_t ws_size,
                              hipStream_t stream) {
  (void)n_in;
  (void)out_size;
  (void)ws_size;
  const float* x_in = (const float*)d_in[0];
  const int* edge_index = (const int*)d_in[1];
  const float* edge_attr = (const float*)d_in[2];
  const float* bn0_g = (const float*)d_in[3];
  const float* bn0_b = (const float*)d_in[4];
  const float* bn0_m = (const float*)d_in[5];
  const float* bn0_v = (const float*)d_in[6];
  const float* eeW1 = (const float*)d_in[7];
  const float* eeb1 = (const float*)d_in[8];
  const float* eeW2 = (const float*)d_in[9];
  const float* eeb2 = (const float*)d_in[10];
  const float* g1_Wl = (const float*)d_in[11];
  const float* g1_bl = (const float*)d_in[12];
  const float* g1_Wr = (const float*)d_in[13];
  const float* g1_br = (const float*)d_in[14];
  const float* g1_We = (const float*)d_in[15];
  const float* g1_att = (const float*)d_in[16];
  const float* g1_bias = (const float*)d_in[17];
  const float* g2_Wl = (const float*)d_in[18];
  const float* g2_bl = (const float*)d_in[19];
  const float* g2_Wr = (const float*)d_in[20];
  const float* g2_br = (const float*)d_in[21];
  const float* g2_We = (const float*)d_in[22];
  const float* g2_att = (const float*)d_in[23];
  const float* g2_bias = (const float*)d_in[24];
  const float* g3_Wl = (const float*)d_in[25];
  const float* g3_bl = (const float*)d_in[26];
  const float* g3_Wr = (const float*)d_in[27];
  const float* g3_br = (const float*)d_in[28];
  const float* g3_We = (const float*)d_in[29];
  const float* g3_att = (const float*)d_in[30];
  const float* g3_bias = (const float*)d_in[31];
  const float* ln1_g = (const float*)d_in[32];
  const float* ln1_b = (const float*)d_in[33];
  const float* ln2_g = (const float*)d_in[34];
  const float* ln2_b = (const float*)d_in[35];
  const float* ln3_g = (const float*)d_in[36];
  const float* ln3_b = (const float*)d_in[37];
  const float* skip_W = (const float*)d_in[38];
  const float* skip_b = (const float*)d_in[39];
  const float* alpha_p = (const float*)d_in[40];
  const float* fp_W = (const float*)d_in[41];
  const float* fp_b = (const float*)d_in[42];
  const float* np_W1 = (const float*)d_in[43];
  const float* np_b1 = (const float*)d_in[44];
  const float* np_W2 = (const float*)d_in[45];
  const float* np_b2 = (const float*)d_in[46];
  const float* np_W3 = (const float*)d_in[47];
  const float* np_b3 = (const float*)d_in[48];

  const int N = in_sizes[0] / 64;
  const int E = in_sizes[2] / 16;
  const int E2 = E + N;
  const int* src0 = edge_index;
  const int* dst0 = edge_index + E;

  float* ws = (float*)d_ws;
  size_t off = 0;
  float* x = ws + off;         off += (size_t)N * 64;
  unsigned short* ea_bf = (unsigned short*)(ws + off); off += (size_t)E2 * 32;
  unsigned short* xl = (unsigned short*)(ws + off);    off += (size_t)N * 128;
  unsigned short* xr = (unsigned short*)(ws + off);    off += (size_t)N * 128;
  float* skipproj = ws + off;  off += (size_t)N * 128;  // reused as h1 at the end
  float* x1 = ws + off;        off += (size_t)N * 128;
  float* skip1 = ws + off;     off += (size_t)N * 128;
  float* x2 = ws + off;        off += (size_t)N * 128;
  float* x3 = ws + off;        off += (size_t)N * 256;
  float* e_s = ws + off;       off += (size_t)E2 * 4;
  float* h2 = ws + off;        off += (size_t)N * 64;
  float* md = ws + off;        off += (size_t)N * 8;
  int* counts = (int*)(ws + off);
  int* rowptr = counts + N;
  int* fill = rowptr + N + 1;
  int* csr = fill + N;
  int* srcpos = csr + E2;
  int* dstpos = srcpos + E2;
  off += (size_t)(3 * N + 1 + 3 * E2);
  off = (off + 3) & ~(size_t)3;
  unsigned short* wtp = (unsigned short*)(ws + off);
  auto alloc_wt = [&](int elems) {
    unsigned short* p = wtp;
    wtp += (elems + 7) & ~7;
    return p;
  };
  unsigned short* wt_g1l = alloc_wt(64 * 128);
  unsigned short* wt_g1r = alloc_wt(64 * 128);
  unsigned short* wt_skip = alloc_wt(64 * 128);
  unsigned short* wt_g2l = alloc_wt(128 * 128);
  unsigned short* wt_g2r = alloc_wt(128 * 128);
  unsigned short* wt_g3l = alloc_wt(128 * 256);
  unsigned short* wt_g3r = alloc_wt(128 * 256);
  unsigned short* wt_fp = alloc_wt(128 * 256);
  unsigned short* wt_np1 = alloc_wt(256 * 128);
  unsigned short* wt_np2 = alloc_wt(128 * 64);
  unsigned short* wt_np3 = alloc_wt(64 * 1);
  unsigned short* wt_ee1 = alloc_wt(16 * 128);
  unsigned short* wt_ee2 = alloc_wt(128 * 64);

  float* out = (float*)d_out;
  float* xf = out;
  float* npout = out + (size_t)N * 256;
  float* a1 = npout + N;
  float* a2 = a1 + (size_t)E2 * 4;
  float* a3 = a2 + (size_t)E2 * 4;

  WJobs jobs;
  jobs.j[0] = {g1_Wl, wt_g1l, 64, 128};
  jobs.j[1] = {g1_Wr, wt_g1r, 64, 128};
  jobs.j[2] = {skip_W, wt_skip, 64, 128};
  jobs.j[3] = {g2_Wl, wt_g2l, 128, 128};
  jobs.j[4] = {g2_Wr, wt_g2r, 128, 128};
  jobs.j[5] = {g3_Wl, wt_g3l, 128, 256};
  jobs.j[6] = {g3_Wr, wt_g3r, 128, 256};
  jobs.j[7] = {fp_W, wt_fp, 128, 256};
  jobs.j[8] = {np_W1, wt_np1, 256, 128};
  jobs.j[9] = {np_W2, wt_np2, 128, 64};
  jobs.j[10] = {np_W3, wt_np3, 64, 1};
  jobs.j[11] = {eeW1, wt_ee1, 16, 128};
  jobs.j[12] = {eeW2, wt_ee2, 128, 64};

  hipMemsetAsync(counts, 0, (size_t)N * sizeof(int), stream);
  wt_kernel<<<dim3(64, 13), 256, 0, stream>>>(jobs);
  bn_kernel<<<(N * 64 + 255) / 256, 256, 0, stream>>>(x_in, bn0_g, bn0_b, bn0_m, bn0_v, x, N * 64);
  edge_enc_kernel<<<1280, 256, 0, stream>>>(edge_attr, wt_ee1, eeb1, wt_ee2, eeb2, ea_bf, E);
  count_kernel<<<(E2 + 255) / 256, 256, 0, stream>>>(dst0, counts, E, E2);
  scan_kernel<<<1, 1024, 0, stream>>>(counts, rowptr, fill, N);
  fill_kernel<<<(E2 + 255) / 256, 256, 0, stream>>>(src0, dst0, fill, csr, srcpos, dstpos, E, E2);
  loopattr_kernel<<<(N + 3) / 4, 256, 0, stream>>>(ea_bf, rowptr, csr, N, E);

  auto gemm = [&](int mode, const float* A, const unsigned short* BT, const float* bias,
                  void* Cp, int M, int K, int Nc, const float* aux) {
    dim3 gdim((Nc + 63) / 64, (M + 63) / 64);
    switch (mode) {
      case 0: gemm_mfma_kernel<0><<<gdim, 256, 0, stream>>>(A, BT, bias, Cp, M, K, Nc, nullptr, nullptr); break;
      case 2: gemm_mfma_kernel<2><<<gdim, 256, 0, stream>>>(A, BT, bias, Cp, M, K, Nc, nullptr, nullptr); break;
      case 3: gemm_mfma_kernel<3><<<gdim, 256, 0, stream>>>(A, BT, bias, Cp, M, K, Nc, aux, alpha_p); break;
    }
  };
  auto gemm_batch = [&](const float* A, int M, int K, int Nc, GJobs gj, int nz) {
    dim3 gdim((Nc + 63) / 64, (M + 63) / 64, nz);
    gemm_mfma_batched<<<gdim, 256, 0, stream>>>(A, gj, M, K, Nc);
  };

  const int nblk_node = (N + 3) / 4;
  const int score_blocks = 1024;
  const int nblk_edge = (E2 + 255) / 256;

  // ---- Layer 1 (din=64, HC=128, C=32) ----
  {
    GJobs gj;
    gj.j[0] = {wt_g1l, g1_bl, xl, 1};
    gj.j[1] = {wt_g1r, g1_br, xr, 1};
    gj.j[2] = {wt_skip, skip_b, skipproj, 0};
    gemm_batch(x, N, 64, 128, gj, 3);
  }
  score_mfma_kernel<32, false><<<score_blocks, 256, 0, stream>>>(ea_bf, xl, xr, g1_We, g1_att, csr, srcpos, dstpos, e_s, E2, 128, 0);
  aggr_kernel<128, true><<<nblk_node, 256, 0, stream>>>(e_s, xl, rowptr, srcpos, g1_bias, ln1_g, ln1_b,
                                                        skip1, x1, skipproj, md, N);
  alpha_kernel<<<nblk_edge, 256, 0, stream>>>(e_s, csr, dstpos, md, a1, E2);
  // ---- Layer 2 (din=128, HC=128, C=32) ----
  {
    GJobs gj;
    gj.j[0] = {wt_g2l, g2_bl, xl, 1};
    gj.j[1] = {wt_g2r, g2_br, xr, 1};
    gj.j[2] = {nullptr, nullptr, nullptr, 0};
    gemm_batch(skip1, N, 128, 128, gj, 2);
  }
  score_mfma_kernel<32, false><<<score_blocks, 256, 0, stream>>>(ea_bf, xl, xr, g2_We, g2_att, csr, srcpos, dstpos, e_s, E2, 128, 0);
  aggr_kernel<128, false><<<nblk_node, 256, 0, stream>>>(e_s, xl, rowptr, srcpos, g2_bias, ln2_g, ln2_b,
                                                         x2, nullptr, nullptr, md, N);
  alpha_kernel<<<nblk_edge, 256, 0, stream>>>(e_s, csr, dstpos, md, a2, E2);
  // ---- Layer 3 (din=128, HC=256, C=64): one launch, wave-split col halves ----
  {
    GJobs gj;
    gj.j[0] = {wt_g3l, g3_bl, xl, 1};
    gj.j[1] = {wt_g3r, g3_br, xr, 1};
    gj.j[2] = {nullptr, nullptr, nullptr, 0};
    gemm_batch(x2, N, 128, 256, gj, 2);
  }
  score_mfma_kernel<64, true><<<score_blocks, 256, 0, stream>>>(ea_bf, xl, xr, g3_We, g3_att, csr, srcpos, dstpos, e_s, E2, 256, 0);
  aggr_kernel<256, false><<<nblk_node, 256, 0, stream>>>(e_s, xl, rowptr, srcpos, g3_bias, ln3_g, ln3_b,
                                                         x3, nullptr, nullptr, md, N);
  alpha_kernel<<<nblk_edge, 256, 0, stream>>>(e_s, csr, dstpos, md, a3, E2);
  // ---- Final: xf = s*(x1@fp_W+fp_b) + (1-s)*x3 ; node MLP ----
  gemm(3, x1, wt_fp, fp_b, xf, N, 128, 256, x3);
  gemm(2, xf, wt_np1, np_b1, skipproj, N, 256, 128, nullptr);   // h1
  gemm(2, skipproj, wt_np2, np_b2, h2, N, 128, 64, nullptr);    // h2
  gemm(0, h2, wt_np3, np_b3, npout, N, 64, 1, nullptr);
}

// Round 18
// 505.437 us; speedup vs baseline: 5.1098x; 1.0005x over previous
//
#include <hip/hip_runtime.h>
#include <math.h>

#define DEV __device__ __forceinline__

typedef __attribute__((ext_vector_type(8))) short bf16x8;
typedef __attribute__((ext_vector_type(4))) float f32x4;

DEV float leakyf(float x, float s) { return x > 0.f ? x : s * x; }

DEV unsigned short f2bf(float f) {
  unsigned u = __float_as_uint(f);
  unsigned r = (u + 0x7fff + ((u >> 16) & 1)) >> 16;
  return (unsigned short)r;
}
DEV float bf2f(unsigned short h) { return __uint_as_float((unsigned)h << 16); }

DEV float sel4(float4 v, int h) {
  float a = (h & 1) ? v.y : v.x;
  float b = (h & 1) ? v.w : v.z;
  return (h & 2) ? b : a;
}

DEV float wave_sum(float v) {
#pragma unroll
  for (int o = 1; o < 64; o <<= 1) v += __shfl_xor(v, o);
  return v;
}
DEV float wave_max(float v) {
#pragma unroll
  for (int o = 1; o < 64; o <<= 1) v = fmaxf(v, __shfl_xor(v, o));
  return v;
}

// ---------------- weight pre-convert: W[K,Nc] f32 -> WT[Nc,K] bf16 ----------------
struct WJob { const float* in; unsigned short* out; int K; int Nc; };
struct WJobs { WJob j[13]; };

__global__ __launch_bounds__(256) void wt_kernel(WJobs jobs) {
  WJob jb = jobs.j[blockIdx.y];
  int total = jb.K * jb.Nc;
  for (int i = blockIdx.x * 256 + threadIdx.x; i < total; i += gridDim.x * 256) {
    int c = i / jb.K, k = i - c * jb.K;
    jb.out[i] = f2bf(jb.in[(size_t)k * jb.Nc + c]);
  }
}

// ---------------- BatchNorm (eval) ----------------
__global__ __launch_bounds__(256) void bn_kernel(
    const float* __restrict__ xin, const float* __restrict__ g,
    const float* __restrict__ b, const float* __restrict__ m,
    const float* __restrict__ v, float* __restrict__ xout, int total) {
  int i = blockIdx.x * 256 + threadIdx.x;
  if (i < total) {
    int c = i & 63;
    xout[i] = (xin[i] - m[c]) * rsqrtf(v[c] + 1e-5f) * g[c] + b[c];
  }
}

// ---------------- Edge encoder: fully-MFMA, persistent; writes rows into CSR order via inv[] ----------------
__global__ __launch_bounds__(256, 2) void edge_enc_kernel(
    const float* __restrict__ edge_attr, const unsigned short* __restrict__ WT1,
    const float* __restrict__ b1, const unsigned short* __restrict__ WT2,
    const float* __restrict__ b2, unsigned short* __restrict__ ea_csr,
    const int* __restrict__ inv, int E) {
  __shared__ unsigned short sEa1[64][136];  // bf16, pad 8
  int tid = threadIdx.x, lane = tid & 63, w = tid >> 6;
  int g = lane >> 4, q = lane & 15;
  // weight fragments loaded ONCE per block (kept in VGPRs)
  bf16x8 w1f[8];
#pragma unroll
  for (int t = 0; t < 8; t++) {
    bf16x8 v = {};
    if (g < 2) v = *(const bf16x8*)(WT1 + (size_t)(16 * t + q) * 16 + 8 * g);
    w1f[t] = v;
  }
  float b1v[8];
#pragma unroll
  for (int t = 0; t < 8; t++) b1v[t] = b1[16 * t + q];
  bf16x8 w2f[4][4];
#pragma unroll
  for (int t = 0; t < 4; t++)
#pragma unroll
    for (int kc = 0; kc < 4; kc++)
      w2f[t][kc] = *(const bf16x8*)(WT2 + (size_t)(16 * t + q) * 128 + 32 * kc + 8 * g);
  float b2v[4];
#pragma unroll
  for (int t = 0; t < 4; t++) b2v[t] = b2[16 * t + q];

  int gstride = gridDim.x * 64;

  auto load_attr = [&](int base) -> bf16x8 {
    bf16x8 af = {};
    if (g < 2) {
      int e = base + w * 16 + q;
      if (e >= E) e = E - 1;
      const float* ap = edge_attr + (size_t)e * 16 + 8 * g;
      float4 x0 = *(const float4*)ap;
      float4 x1 = *(const float4*)(ap + 4);
      af[0] = (short)f2bf(x0.x); af[1] = (short)f2bf(x0.y);
      af[2] = (short)f2bf(x0.z); af[3] = (short)f2bf(x0.w);
      af[4] = (short)f2bf(x1.x); af[5] = (short)f2bf(x1.y);
      af[6] = (short)f2bf(x1.z); af[7] = (short)f2bf(x1.w);
    }
    return af;
  };

  int base = blockIdx.x * 64;
  if (base >= E) return;
  bf16x8 af = load_attr(base);
  for (; base < E; ) {
    int next = base + gstride;
    bf16x8 af_next = {};
    if (next < E) af_next = load_attr(next);  // prefetch overlaps with compute below
    int e0 = base + w * 16;
    f32x4 acc1[8];
#pragma unroll
    for (int t = 0; t < 8; t++) acc1[t] = (f32x4){0.f, 0.f, 0.f, 0.f};
#pragma unroll
    for (int t = 0; t < 8; t++)
      acc1[t] = __builtin_amdgcn_mfma_f32_16x16x32_bf16(af, w1f[t], acc1[t], 0, 0, 0);
    // wave-private rows; same wave writes then reads -> intra-wave ordering suffices
#pragma unroll
    for (int t = 0; t < 8; t++)
#pragma unroll
      for (int r = 0; r < 4; r++) {
        float v = leakyf(acc1[t][r] + b1v[t], 0.01f);
        sEa1[w * 16 + g * 4 + r][16 * t + q] = f2bf(v);
      }
    f32x4 acc2[4];
#pragma unroll
    for (int t = 0; t < 4; t++) acc2[t] = (f32x4){0.f, 0.f, 0.f, 0.f};
#pragma unroll
    for (int kc = 0; kc < 4; kc++) {
      bf16x8 a2 = *(const bf16x8*)&sEa1[w * 16 + q][32 * kc + 8 * g];
#pragma unroll
      for (int t = 0; t < 4; t++)
        acc2[t] = __builtin_amdgcn_mfma_f32_16x16x32_bf16(a2, w2f[t][kc], acc2[t], 0, 0, 0);
    }
#pragma unroll
    for (int r = 0; r < 4; r++) {
      float vv[4];
      float p = 0.f;
#pragma unroll
      for (int t = 0; t < 4; t++) {
        float v = leakyf(acc2[t][r] + b2v[t], 0.01f);
        vv[t] = v;
        p += v * v;
      }
#pragma unroll
      for (int o = 1; o < 16; o <<= 1) p += __shfl_xor(p, o);
      float sc = 1.f / fmaxf(sqrtf(p), 1e-12f);
      int e = e0 + g * 4 + r;
      if (e < E) {
        int pos = inv[e];  // CSR position of this edge
#pragma unroll
        for (int t = 0; t < 4; t++)
          ea_csr[(size_t)pos * 64 + 16 * t + q] = f2bf(vv[t] * sc);
      }
    }
    af = af_next;
    base = next;
  }
}

// ---------------- CSR build ----------------
__global__ __launch_bounds__(256) void count_kernel(const int* __restrict__ dst0,
                                                    int* __restrict__ counts, int E, int E2) {
  int i = blockIdx.x * 256 + threadIdx.x;
  if (i < E2) {
    int d = (i < E) ? dst0[i] : (i - E);
    atomicAdd(&counts[d], 1);
  }
}

// 1024-thread block scan: ~20 elems/thread serial + Hillis-Steele over partials
__global__ __launch_bounds__(1024) void scan_kernel(const int* __restrict__ counts,
                                                    int* __restrict__ rowptr,
                                                    int* __restrict__ fill, int N) {
  __shared__ int part[1024];
  int tid = threadIdx.x;
  int chunk = (N + 1023) / 1024;
  int lo = tid * chunk, hi = lo + chunk;
  if (hi > N) hi = N;
  if (lo > N) lo = N;
  int s = 0;
  for (int i = lo; i < hi; i++) s += counts[i];
  part[tid] = s;
  __syncthreads();
#pragma unroll
  for (int o = 1; o < 1024; o <<= 1) {
    int v = (tid >= o) ? part[tid - o] : 0;
    __syncthreads();
    part[tid] += v;
    __syncthreads();
  }
  if (tid == 1023) rowptr[N] = part[1023];
  int off = part[tid] - s;  // exclusive prefix
  for (int i = lo; i < hi; i++) {
    rowptr[i] = off;
    fill[i] = off;
    off += counts[i];
  }
}

// builds csr (edge id), srcpos, dstpos by CSR position; inv (edge -> position)
__global__ __launch_bounds__(256) void fill_kernel(const int* __restrict__ src0,
                                                   const int* __restrict__ dst0,
                                                   int* __restrict__ fill,
                                                   int* __restrict__ csr,
                                                   int* __restrict__ srcpos,
                                                   int* __restrict__ dstpos,
                                                   int* __restrict__ inv, int E, int E2) {
  int i = blockIdx.x * 256 + threadIdx.x;
  if (i < E2) {
    int d, s;
    if (i < E) {
      d = dst0[i];
      s = src0[i];
    } else {
      d = s = i - E;
    }
    int pos = atomicAdd(&fill[d], 1);
    csr[pos] = i;
    srcpos[pos] = s;
    dstpos[pos] = d;
    inv[i] = pos;
  }
}

// ---------------- self-loop attr = mean of incoming encoded attrs (CSR-linear) ----------------
__global__ __launch_bounds__(256) void loopattr_kernel(unsigned short* __restrict__ ea_csr,
                                                       const int* __restrict__ rowptr,
                                                       const int* __restrict__ csr, int N, int E) {
  int lane = threadIdx.x & 63, wv = threadIdx.x >> 6;
  int stride = gridDim.x * 4;
  for (int n = blockIdx.x * 4 + wv; n < N; n += stride) {
    int r0 = rowptr[n], r1 = rowptr[n + 1];
    float acc = 0.f;
    int loop_pos = r0;
    for (int i = r0; i < r1; i++) {
      int e = csr[i];
      if (e < E) {
        acc += bf2f(ea_csr[(size_t)i * 64 + lane]);  // linear row read
      } else {
        loop_pos = i;
      }
    }
    int cnt = r1 - r0 - 1;  // real incoming edges (exactly one self-loop per node)
    ea_csr[(size_t)loop_pos * 64 + lane] = f2bf(acc / fmaxf((float)cnt, 1.f));
  }
}

// ---------------- bf16 MFMA GEMM (single) ----------------
// MODE: 0 f32 out, 1 bf16 out, 2 elu f32 out, 3 mix f32 out
template <int MODE>
__global__ __launch_bounds__(256) void gemm_mfma_kernel(
    const float* __restrict__ A, const unsigned short* __restrict__ BT,
    const float* __restrict__ bias, void* __restrict__ Cout, int M, int K, int Nc,
    const float* __restrict__ aux, const float* __restrict__ alpha_p) {
  __shared__ unsigned short sA[64][40];
  __shared__ unsigned short sB[64][40];
  int tid = threadIdx.x, lane = tid & 63, w = tid >> 6;
  int g = lane >> 4, q = lane & 15;
  int bm = blockIdx.y * 64, bn = blockIdx.x * 64;
  f32x4 acc[4];
#pragma unroll
  for (int t = 0; t < 4; t++) acc[t] = (f32x4){0.f, 0.f, 0.f, 0.f};
  int r = tid >> 2, ko = (tid & 3) * 8;
  for (int k0 = 0; k0 < K; k0 += 32) {
    {
      int gm = bm + r;
      bf16x8 v = {};
      if (gm < M) {
        const float* ap = A + (size_t)gm * K + k0 + ko;
        float4 x0 = *(const float4*)ap;
        float4 x1 = *(const float4*)(ap + 4);
        v[0] = (short)f2bf(x0.x); v[1] = (short)f2bf(x0.y);
        v[2] = (short)f2bf(x0.z); v[3] = (short)f2bf(x0.w);
        v[4] = (short)f2bf(x1.x); v[5] = (short)f2bf(x1.y);
        v[6] = (short)f2bf(x1.z); v[7] = (short)f2bf(x1.w);
      }
      *(bf16x8*)&sA[r][ko] = v;
      int gc = bn + r;
      bf16x8 bv = {};
      if (gc < Nc) bv = *(const bf16x8*)(BT + (size_t)gc * K + k0 + ko);
      *(bf16x8*)&sB[r][ko] = bv;
    }
    __syncthreads();
    bf16x8 a = *(const bf16x8*)&sA[w * 16 + q][8 * g];
#pragma unroll
    for (int t = 0; t < 4; t++) {
      bf16x8 b = *(const bf16x8*)&sB[16 * t + q][8 * g];
      acc[t] = __builtin_amdgcn_mfma_f32_16x16x32_bf16(a, b, acc[t], 0, 0, 0);
    }
    __syncthreads();
  }
  float s = 0.f;
  if (MODE == 3) s = 1.f / (1.f + __expf(-alpha_p[0]));
#pragma unroll
  for (int t = 0; t < 4; t++) {
    int col = bn + 16 * t + q;
#pragma unroll
    for (int rr = 0; rr < 4; rr++) {
      int row = bm + w * 16 + g * 4 + rr;
      if (row < M && col < Nc) {
        float v = acc[t][rr] + bias[col];
        if (MODE == 2) v = v > 0.f ? v : (__expf(v) - 1.f);
        if (MODE == 3) v = s * v + (1.f - s) * aux[(size_t)row * Nc + col];
        if (MODE == 1)
          ((unsigned short*)Cout)[(size_t)row * Nc + col] = f2bf(v);
        else
          ((float*)Cout)[(size_t)row * Nc + col] = v;
      }
    }
  }
}

// ---------------- bf16 MFMA GEMM (batched over grid.z) ----------------
struct GJob { const unsigned short* BT; const float* bias; void* out; int mode; };
struct GJobs { GJob j[3]; };

__global__ __launch_bounds__(256) void gemm_mfma_batched(
    const float* __restrict__ A, GJobs jobs, int M, int K, int Nc) {
  __shared__ unsigned short sA[64][40];
  __shared__ unsigned short sB[64][40];
  GJob jb = jobs.j[blockIdx.z];
  const unsigned short* BT = jb.BT;
  int tid = threadIdx.x, lane = tid & 63, w = tid >> 6;
  int g = lane >> 4, q = lane & 15;
  int bm = blockIdx.y * 64, bn = blockIdx.x * 64;
  f32x4 acc[4];
#pragma unroll
  for (int t = 0; t < 4; t++) acc[t] = (f32x4){0.f, 0.f, 0.f, 0.f};
  int r = tid >> 2, ko = (tid & 3) * 8;
  for (int k0 = 0; k0 < K; k0 += 32) {
    {
      int gm = bm + r;
      bf16x8 v = {};
      if (gm < M) {
        const float* ap = A + (size_t)gm * K + k0 + ko;
        float4 x0 = *(const float4*)ap;
        float4 x1 = *(const float4*)(ap + 4);
        v[0] = (short)f2bf(x0.x); v[1] = (short)f2bf(x0.y);
        v[2] = (short)f2bf(x0.z); v[3] = (short)f2bf(x0.w);
        v[4] = (short)f2bf(x1.x); v[5] = (short)f2bf(x1.y);
        v[6] = (short)f2bf(x1.z); v[7] = (short)f2bf(x1.w);
      }
      *(bf16x8*)&sA[r][ko] = v;
      int gc = bn + r;
      bf16x8 bv = {};
      if (gc < Nc) bv = *(const bf16x8*)(BT + (size_t)gc * K + k0 + ko);
      *(bf16x8*)&sB[r][ko] = bv;
    }
    __syncthreads();
    bf16x8 a = *(const bf16x8*)&sA[w * 16 + q][8 * g];
#pragma unroll
    for (int t = 0; t < 4; t++) {
      bf16x8 b = *(const bf16x8*)&sB[16 * t + q][8 * g];
      acc[t] = __builtin_amdgcn_mfma_f32_16x16x32_bf16(a, b, acc[t], 0, 0, 0);
    }
    __syncthreads();
  }
#pragma unroll
  for (int t = 0; t < 4; t++) {
    int col = bn + 16 * t + q;
#pragma unroll
    for (int rr = 0; rr < 4; rr++) {
      int row = bm + w * 16 + g * 4 + rr;
      if (row < M && col < Nc) {
        float v = acc[t][rr] + jb.bias[col];
        if (jb.mode == 1)
          ((unsigned short*)jb.out)[(size_t)row * Nc + col] = f2bf(v);
        else
          ((float*)jb.out)[(size_t)row * Nc + col] = v;
      }
    }
  }
}

// ---------------- GATv2 edge scores via MFMA; ea_csr read linearly ----------------
template <int C, bool SPLIT>
__global__ __launch_bounds__(256) void score_mfma_kernel(
    const unsigned short* __restrict__ ea_csr, const unsigned short* __restrict__ xl,
    const unsigned short* __restrict__ xr, const float* __restrict__ We,
    const float* __restrict__ att, const int* __restrict__ srcpos,
    const int* __restrict__ dstpos,
    float* __restrict__ e_s, int E2, int HCfull, int col_off_in) {
  int lane = threadIdx.x & 63;
  int wv = threadIdx.x >> 6;
  int g = lane >> 4, q = lane & 15;
  int col_off = SPLIT ? (wv & 1) * 128 : col_off_in;
  bf16x8 bfrag[8][2];
#pragma unroll
  for (int t = 0; t < 8; t++)
#pragma unroll
    for (int kc = 0; kc < 2; kc++) {
      bf16x8 bv;
#pragma unroll
      for (int j = 0; j < 8; j++) {
        int k = kc * 32 + g * 8 + j;
        bv[j] = (short)f2bf(We[(size_t)k * HCfull + col_off + 16 * t + q]);
      }
      bfrag[t][kc] = bv;
    }
  float attv[8];
#pragma unroll
  for (int t = 0; t < 8; t++) attv[t] = att[col_off + 16 * t + q];

  constexpr int TPH = C / 16;
  constexpr int NH = 8 / TPH;
  const int headbase = col_off / C;

  int tiles = (E2 + 15) / 16;
  int tstart = SPLIT ? (blockIdx.x * 2 + (wv >> 1)) : (blockIdx.x * 4 + wv);
  int nw = SPLIT ? (gridDim.x * 2) : (gridDim.x * 4);
  for (int tile = tstart; tile < tiles; tile += nw) {
    int i0 = tile * 16;
    int ia = i0 + q;
    if (ia >= E2) ia = E2 - 1;
    const unsigned short* ap = ea_csr + (size_t)ia * 64 + g * 8;  // linear by CSR position
    bf16x8 a0 = *(const bf16x8*)(ap);
    bf16x8 a1 = *(const bf16x8*)(ap + 32);
    f32x4 acc[8];
#pragma unroll
    for (int t = 0; t < 8; t++) acc[t] = (f32x4){0.f, 0.f, 0.f, 0.f};
#pragma unroll
    for (int t = 0; t < 8; t++) {
      acc[t] = __builtin_amdgcn_mfma_f32_16x16x32_bf16(a0, bfrag[t][0], acc[t], 0, 0, 0);
      acc[t] = __builtin_amdgcn_mfma_f32_16x16x32_bf16(a1, bfrag[t][1], acc[t], 0, 0, 0);
    }
    int sn[4], dn[4];
#pragma unroll
    for (int r = 0; r < 4; r++) {
      int i = i0 + g * 4 + r;
      if (i >= E2) i = E2 - 1;
      sn[r] = srcpos[i];
      dn[r] = dstpos[i];
    }
    float p[NH][4];
#pragma unroll
    for (int hh = 0; hh < NH; hh++)
#pragma unroll
      for (int r = 0; r < 4; r++) p[hh][r] = 0.f;
#pragma unroll
    for (int t = 0; t < 8; t++) {
      int col = col_off + 16 * t + q;
#pragma unroll
      for (int r = 0; r < 4; r++) {
        float xv = bf2f(xl[(size_t)sn[r] * HCfull + col]) +
                   bf2f(xr[(size_t)dn[r] * HCfull + col]) + acc[t][r];
        xv = xv > 0.f ? xv : 0.2f * xv;
        p[t / TPH][r] += xv * attv[t];
      }
    }
#pragma unroll
    for (int hh = 0; hh < NH; hh++)
#pragma unroll
      for (int r = 0; r < 4; r++) {
#pragma unroll
        for (int o = 1; o < 16; o <<= 1) p[hh][r] += __shfl_xor(p[hh][r], o);
      }
    if (q == 0) {
#pragma unroll
      for (int r = 0; r < 4; r++) {
        int i = i0 + g * 4 + r;
        if (i < E2) {
#pragma unroll
          for (int hh = 0; hh < NH; hh++)
            e_s[(size_t)i * 4 + headbase + hh] = p[hh][r];
        }
      }
    }
  }
}

// ---------------- per-node softmax + aggregation; 4x-unrolled gather, register-only selects ----------------
template <int HC, bool L1MODE>
__global__ __launch_bounds__(256) void aggr_kernel(
    const float* __restrict__ e_s, const unsigned short* __restrict__ xl,
    const int* __restrict__ rowptr, const int* __restrict__ srcpos,
    const float* __restrict__ bias,
    const float* __restrict__ lng, const float* __restrict__ lnb,
    float* __restrict__ xout,
    float* __restrict__ x1out, const float* __restrict__ skipproj,
    float* __restrict__ md, int N) {
  constexpr int CPL = HC / 64;
  int lane = threadIdx.x & 63, wv = threadIdx.x >> 6;
  int stride = gridDim.x * 4;
  const float4* e_s4 = (const float4*)e_s;
  for (int n = blockIdx.x * 4 + wv; n < N; n += stride) {
    int r0 = rowptr[n], r1 = rowptr[n + 1];
    float m0 = -1e30f, m1 = -1e30f, m2 = -1e30f, m3 = -1e30f;
    for (int i = r0 + lane; i < r1; i += 64) {
      float4 v = e_s4[i];
      m0 = fmaxf(m0, v.x);
      m1 = fmaxf(m1, v.y);
      m2 = fmaxf(m2, v.z);
      m3 = fmaxf(m3, v.w);
    }
    m0 = wave_max(m0);
    m1 = wave_max(m1);
    m2 = wave_max(m2);
    m3 = wave_max(m3);
    float d0 = 0.f, d1 = 0.f, d2 = 0.f, d3 = 0.f;
    for (int i = r0 + lane; i < r1; i += 64) {
      float4 v = e_s4[i];
      d0 += __expf(v.x - m0);
      d1 += __expf(v.y - m1);
      d2 += __expf(v.z - m2);
      d3 += __expf(v.w - m3);
    }
    d0 = wave_sum(d0);
    d1 = wave_sum(d1);
    d2 = wave_sum(d2);
    d3 = wave_sum(d3);
    float i0 = 1.f / (d0 + 1e-16f), i1 = 1.f / (d1 + 1e-16f);
    float i2 = 1.f / (d2 + 1e-16f), i3 = 1.f / (d3 + 1e-16f);
    if (lane == 0) {
      float* mp = md + (size_t)n * 8;
      mp[0] = m0; mp[1] = m1; mp[2] = m2; mp[3] = m3;
      mp[4] = i0; mp[5] = i1; mp[6] = i2; mp[7] = i3;
    }
    int h = lane >> 4;
    float mh = (h & 2) ? ((h & 1) ? m3 : m2) : ((h & 1) ? m1 : m0);
    float ih = (h & 2) ? ((h & 1) ? i3 : i2) : ((h & 1) ? i1 : i0);
    float acc[CPL];
#pragma unroll
    for (int j = 0; j < CPL; j++) acc[j] = 0.f;
    int c0 = lane * CPL;
    int i = r0;
    for (; i + 4 <= r1; i += 4) {
      float sh0, sh1, sh2, sh3;
      int sn0, sn1, sn2, sn3;
      {
        float4 a = e_s4[i], b = e_s4[i + 1], c = e_s4[i + 2], d = e_s4[i + 3];
        sh0 = sel4(a, h); sh1 = sel4(b, h); sh2 = sel4(c, h); sh3 = sel4(d, h);
      }
      sn0 = srcpos[i]; sn1 = srcpos[i + 1]; sn2 = srcpos[i + 2]; sn3 = srcpos[i + 3];
      if constexpr (CPL == 2) {
        ushort2 t0 = *(const ushort2*)(xl + (size_t)sn0 * HC + c0);
        ushort2 t1 = *(const ushort2*)(xl + (size_t)sn1 * HC + c0);
        ushort2 t2 = *(const ushort2*)(xl + (size_t)sn2 * HC + c0);
        ushort2 t3 = *(const ushort2*)(xl + (size_t)sn3 * HC + c0);
        float a0 = __expf(sh0 - mh) * ih;
        float a1 = __expf(sh1 - mh) * ih;
        float a2 = __expf(sh2 - mh) * ih;
        float a3 = __expf(sh3 - mh) * ih;
        acc[0] += a0 * bf2f(t0.x) + a1 * bf2f(t1.x) + a2 * bf2f(t2.x) + a3 * bf2f(t3.x);
        acc[1] += a0 * bf2f(t0.y) + a1 * bf2f(t1.y) + a2 * bf2f(t2.y) + a3 * bf2f(t3.y);
      } else {
        ushort4 t0 = *(const ushort4*)(xl + (size_t)sn0 * HC + c0);
        ushort4 t1 = *(const ushort4*)(xl + (size_t)sn1 * HC + c0);
        ushort4 t2 = *(const ushort4*)(xl + (size_t)sn2 * HC + c0);
        ushort4 t3 = *(const ushort4*)(xl + (size_t)sn3 * HC + c0);
        float a0 = __expf(sh0 - mh) * ih;
        float a1 = __expf(sh1 - mh) * ih;
        float a2 = __expf(sh2 - mh) * ih;
        float a3 = __expf(sh3 - mh) * ih;
        acc[0] += a0 * bf2f(t0.x) + a1 * bf2f(t1.x) + a2 * bf2f(t2.x) + a3 * bf2f(t3.x);
        acc[1] += a0 * bf2f(t0.y) + a1 * bf2f(t1.y) + a2 * bf2f(t2.y) + a3 * bf2f(t3.y);
        acc[2] += a0 * bf2f(t0.z) + a1 * bf2f(t1.z) + a2 * bf2f(t2.z) + a3 * bf2f(t3.z);
        acc[3] += a0 * bf2f(t0.w) + a1 * bf2f(t1.w) + a2 * bf2f(t2.w) + a3 * bf2f(t3.w);
      }
    }
    for (; i < r1; i++) {
      float sh = sel4(e_s4[i], h);
      float a = __expf(sh - mh) * ih;
      int sn = srcpos[i];
      const unsigned short* xp = xl + (size_t)sn * HC + c0;
      if constexpr (CPL == 2) {
        ushort2 t = *(const ushort2*)xp;
        acc[0] += a * bf2f(t.x);
        acc[1] += a * bf2f(t.y);
      } else {
        ushort4 t = *(const ushort4*)xp;
        acc[0] += a * bf2f(t.x);
        acc[1] += a * bf2f(t.y);
        acc[2] += a * bf2f(t.z);
        acc[3] += a * bf2f(t.w);
      }
    }
    float vals[CPL];
    float vs = 0.f, vq = 0.f;
#pragma unroll
    for (int j = 0; j < CPL; j++) {
      float t = acc[j] + bias[c0 + j];
      vals[j] = t;
      vs += t;
      vq += t * t;
    }
    vs = wave_sum(vs);
    vq = wave_sum(vq);
    float mean = vs * (1.f / HC);
    float var = vq * (1.f / HC) - mean * mean;
    float rstd = rsqrtf(fmaxf(var, 0.f) + 1e-5f);
#pragma unroll
    for (int j = 0; j < CPL; j++) {
      int c = c0 + j;
      float y = (vals[j] - mean) * rstd * lng[c] + lnb[c];
      y = leakyf(y, 0.01f);
      if constexpr (L1MODE) {
        x1out[(size_t)n * HC + c] = y;
        xout[(size_t)n * HC + c] = 0.01f * skipproj[(size_t)n * HC + c] + y;
      } else {
        xout[(size_t)n * HC + c] = y;
      }
    }
  }
}

// ---------------- alpha: coalesced e_s/dstpos read, md L2-hit, one scattered 16B write ----------------
__global__ __launch_bounds__(256) void alpha_kernel(
    const float* __restrict__ e_s, const int* __restrict__ csr,
    const int* __restrict__ dstpos, const float* __restrict__ md,
    float* __restrict__ alpha_out, int E2) {
  int i = blockIdx.x * 256 + threadIdx.x;
  if (i < E2) {
    float4 sv = ((const float4*)e_s)[i];
    int d = dstpos[i];
    const float* mp = md + (size_t)d * 8;
    float4 a;
    a.x = __expf(sv.x - mp[0]) * mp[4];
    a.y = __expf(sv.y - mp[1]) * mp[5];
    a.z = __expf(sv.z - mp[2]) * mp[6];
    a.w = __expf(sv.w - mp[3]) * mp[7];
    ((float4*)alpha_out)[csr[i]] = a;
  }
}

extern "C" void kernel_launch(void* const* d_in, const int* in_sizes, int n_in,
                              void* d_out, int out_size, void* d_ws, size_t ws_size,
                              hipStream_t stream) {
  (void)n_in;
  (void)out_size;
  (void)ws_size;
  const float* x_in = (const float*)d_in[0];
  const int* edge_index = (const int*)d_in[1];
  const float* edge_attr = (const float*)d_in[2];
  const float* bn0_g = (const float*)d_in[3];
  const float* bn0_b = (const float*)d_in[4];
  const float* bn0_m = (const float*)d_in[5];
  const float* bn0_v = (const float*)d_in[6];
  const float* eeW1 = (const float*)d_in[7];
  const float* eeb1 = (const float*)d_in[8];
  const float* eeW2 = (const float*)d_in[9];
  const float* eeb2 = (const float*)d_in[10];
  const float* g1_Wl = (const float*)d_in[11];
  const float* g1_bl = (const float*)d_in[12];
  const float* g1_Wr = (const float*)d_in[13];
  const float* g1_br = (const float*)d_in[14];
  const float* g1_We = (const float*)d_in[15];
  const float* g1_att = (const float*)d_in[16];
  const float* g1_bias = (const float*)d_in[17];
  const float* g2_Wl = (const float*)d_in[18];
  const float* g2_bl = (const float*)d_in[19];
  const float* g2_Wr = (const float*)d_in[20];
  const float* g2_br = (const float*)d_in[21];
  const float* g2_We = (const float*)d_in[22];
  const float* g2_att = (const float*)d_in[23];
  const float* g2_bias = (const float*)d_in[24];
  const float* g3_Wl = (const float*)d_in[25];
  const float* g3_bl = (const float*)d_in[26];
  const float* g3_Wr = (const float*)d_in[27];
  const float* g3_br = (const float*)d_in[28];
  const float* g3_We = (const float*)d_in[29];
  const float* g3_att = (const float*)d_in[30];
  const float* g3_bias = (const float*)d_in[31];
  const float* ln1_g = (const float*)d_in[32];
  const float* ln1_b = (const float*)d_in[33];
  const float* ln2_g = (const float*)d_in[34];
  const float* ln2_b = (const float*)d_in[35];
  const float* ln3_g = (const float*)d_in[36];
  const float* ln3_b = (const float*)d_in[37];
  const float* skip_W = (const float*)d_in[38];
  const float* skip_b = (const float*)d_in[39];
  const float* alpha_p = (const float*)d_in[40];
  const float* fp_W = (const float*)d_in[41];
  const float* fp_b = (const float*)d_in[42];
  const float* np_W1 = (const float*)d_in[43];
  const float* np_b1 = (const float*)d_in[44];
  const float* np_W2 = (const float*)d_in[45];
  const float* np_b2 = (const float*)d_in[46];
  const float* np_W3 = (const float*)d_in[47];
  const float* np_b3 = (const float*)d_in[48];

  const int N = in_sizes[0] / 64;
  const int E = in_sizes[2] / 16;
  const int E2 = E + N;
  const int* src0 = edge_index;
  const int* dst0 = edge_index + E;

  float* ws = (float*)d_ws;
  size_t off = 0;
  float* x = ws + off;         off += (size_t)N * 64;
  unsigned short* ea_csr = (unsigned short*)(ws + off); off += (size_t)E2 * 32;
  unsigned short* xl = (unsigned short*)(ws + off);    off += (size_t)N * 128;
  unsigned short* xr = (unsigned short*)(ws + off);    off += (size_t)N * 128;
  float* skipproj = ws + off;  off += (size_t)N * 128;  // reused as h1 at the end
  float* x1 = ws + off;        off += (size_t)N * 128;
  float* skip1 = ws + off;     off += (size_t)N * 128;
  float* x2 = ws + off;        off += (size_t)N * 128;
  float* x3 = ws + off;        off += (size_t)N * 256;
  float* e_s = ws + off;       off += (size_t)E2 * 4;
  float* h2 = ws + off;        off += (size_t)N * 64;
  float* md = ws + off;        off += (size_t)N * 8;
  int* counts = (int*)(ws + off);
  int* rowptr = counts + N;
  int* fill = rowptr + N + 1;
  int* csr = fill + N;
  int* srcpos = csr + E2;
  int* dstpos = srcpos + E2;
  int* inv = dstpos + E2;
  off += (size_t)(3 * N + 1 + 4 * E2);
  off = (off + 3) & ~(size_t)3;
  unsigned short* wtp = (unsigned short*)(ws + off);
  auto alloc_wt = [&](int elems) {
    unsigned short* p = wtp;
    wtp += (elems + 7) & ~7;
    return p;
  };
  unsigned short* wt_g1l = alloc_wt(64 * 128);
  unsigned short* wt_g1r = alloc_wt(64 * 128);
  unsigned short* wt_skip = alloc_wt(64 * 128);
  unsigned short* wt_g2l = alloc_wt(128 * 128);
  unsigned short* wt_g2r = alloc_wt(128 * 128);
  unsigned short* wt_g3l = alloc_wt(128 * 256);
  unsigned short* wt_g3r = alloc_wt(128 * 256);
  unsigned short* wt_fp = alloc_wt(128 * 256);
  unsigned short* wt_np1 = alloc_wt(256 * 128);
  unsigned short* wt_np2 = alloc_wt(128 * 64);
  unsigned short* wt_np3 = alloc_wt(64 * 1);
  unsigned short* wt_ee1 = alloc_wt(16 * 128);
  unsigned short* wt_ee2 = alloc_wt(128 * 64);

  float* out = (float*)d_out;
  float* xf = out;
  float* npout = out + (size_t)N * 256;
  float* a1 = npout + N;
  float* a2 = a1 + (size_t)E2 * 4;
  float* a3 = a2 + (size_t)E2 * 4;

  WJobs jobs;
  jobs.j[0] = {g1_Wl, wt_g1l, 64, 128};
  jobs.j[1] = {g1_Wr, wt_g1r, 64, 128};
  jobs.j[2] = {skip_W, wt_skip, 64, 128};
  jobs.j[3] = {g2_Wl, wt_g2l, 128, 128};
  jobs.j[4] = {g2_Wr, wt_g2r, 128, 128};
  jobs.j[5] = {g3_Wl, wt_g3l, 128, 256};
  jobs.j[6] = {g3_Wr, wt_g3r, 128, 256};
  jobs.j[7] = {fp_W, wt_fp, 128, 256};
  jobs.j[8] = {np_W1, wt_np1, 256, 128};
  jobs.j[9] = {np_W2, wt_np2, 128, 64};
  jobs.j[10] = {np_W3, wt_np3, 64, 1};
  jobs.j[11] = {eeW1, wt_ee1, 16, 128};
  jobs.j[12] = {eeW2, wt_ee2, 128, 64};

  hipMemsetAsync(counts, 0, (size_t)N * sizeof(int), stream);
  wt_kernel<<<dim3(64, 13), 256, 0, stream>>>(jobs);
  bn_kernel<<<(N * 64 + 255) / 256, 256, 0, stream>>>(x_in, bn0_g, bn0_b, bn0_m, bn0_v, x, N * 64);
  count_kernel<<<(E2 + 255) / 256, 256, 0, stream>>>(dst0, counts, E, E2);
  scan_kernel<<<1, 1024, 0, stream>>>(counts, rowptr, fill, N);
  fill_kernel<<<(E2 + 255) / 256, 256, 0, stream>>>(src0, dst0, fill, csr, srcpos, dstpos, inv, E, E2);
  edge_enc_kernel<<<1280, 256, 0, stream>>>(edge_attr, wt_ee1, eeb1, wt_ee2, eeb2, ea_csr, inv, E);
  loopattr_kernel<<<(N + 3) / 4, 256, 0, stream>>>(ea_csr, rowptr, csr, N, E);

  auto gemm = [&](int mode, const float* A, const unsigned short* BT, const float* bias,
                  void* Cp, int M, int K, int Nc, const float* aux) {
    dim3 gdim((Nc + 63) / 64, (M + 63) / 64);
    switch (mode) {
      case 0: gemm_mfma_kernel<0><<<gdim, 256, 0, stream>>>(A, BT, bias, Cp, M, K, Nc, nullptr, nullptr); break;
      case 2: gemm_mfma_kernel<2><<<gdim, 256, 0, stream>>>(A, BT, bias, Cp, M, K, Nc, nullptr, nullptr); break;
      case 3: gemm_mfma_kernel<3><<<gdim, 256, 0, stream>>>(A, BT, bias, Cp, M, K, Nc, aux, alpha_p); break;
    }
  };
  auto gemm_batch = [&](const float* A, int M, int K, int Nc, GJobs gj, int nz) {
    dim3 gdim((Nc + 63) / 64, (M + 63) / 64, nz);
    gemm_mfma_batched<<<gdim, 256, 0, stream>>>(A, gj, M, K, Nc);
  };

  const int nblk_node = (N + 3) / 4;
  const int score_blocks = 1024;
  const int nblk_edge = (E2 + 255) / 256;

  // ---- Layer 1 (din=64, HC=128, C=32) ----
  {
    GJobs gj;
    gj.j[0] = {wt_g1l, g1_bl, xl, 1};
    gj.j[1] = {wt_g1r, g1_br, xr, 1};
    gj.j[2] = {wt_skip, skip_b, skipproj, 0};
    gemm_batch(x, N, 64, 128, gj, 3);
  }
  score_mfma_kernel<32, false><<<score_blocks, 256, 0, stream>>>(ea_csr, xl, xr, g1_We, g1_att, srcpos, dstpos, e_s, E2, 128, 0);
  aggr_kernel<128, true><<<nblk_node, 256, 0, stream>>>(e_s, xl, rowptr, srcpos, g1_bias, ln1_g, ln1_b,
                                                        skip1, x1, skipproj, md, N);
  alpha_kernel<<<nblk_edge, 256, 0, stream>>>(e_s, csr, dstpos, md, a1, E2);
  // ---- Layer 2 (din=128, HC=128, C=32) ----
  {
    GJobs gj;
    gj.j[0] = {wt_g2l, g2_bl, xl, 1};
    gj.j[1] = {wt_g2r, g2_br, xr, 1};
    gj.j[2] = {nullptr, nullptr, nullptr, 0};
    gemm_batch(skip1, N, 128, 128, gj, 2);
  }
  score_mfma_kernel<32, false><<<score_blocks, 256, 0, stream>>>(ea_csr, xl, xr, g2_We, g2_att, srcpos, dstpos, e_s, E2, 128, 0);
  aggr_kernel<128, false><<<nblk_node, 256, 0, stream>>>(e_s, xl, rowptr, srcpos, g2_bias, ln2_g, ln2_b,
                                                         x2, nullptr, nullptr, md, N);
  alpha_kernel<<<nblk_edge, 256, 0, stream>>>(e_s, csr, dstpos, md, a2, E2);
  // ---- Layer 3 (din=128, HC=256, C=64): one launch, wave-split col halves ----
  {
    GJobs gj;
    gj.j[0] = {wt_g3l, g3_bl, xl, 1};
    gj.j[1] = {wt_g3r, g3_br, xr, 1};
    gj.j[2] = {nullptr, nullptr, nullptr, 0};
    gemm_batch(x2, N, 128, 256, gj, 2);
  }
  score_mfma_kernel<64, true><<<score_blocks, 256, 0, stream>>>(ea_csr, xl, xr, g3_We, g3_att, srcpos, dstpos, e_s, E2, 256, 0);
  aggr_kernel<256, false><<<nblk_node, 256, 0, stream>>>(e_s, xl, rowptr, srcpos, g3_bias, ln3_g, ln3_b,
                                                         x3, nullptr, nullptr, md, N);
  alpha_kernel<<<nblk_edge, 256, 0, stream>>>(e_s, csr, dstpos, md, a3, E2);
  // ---- Final: xf = s*(x1@fp_W+fp_b) + (1-s)*x3 ; node MLP ----
  gemm(3, x1, wt_fp, fp_b, xf, N, 128, 256, x3);
  gemm(2, xf, wt_np1, np_b1, skipproj, N, 256, 128, nullptr);   // h1
  gemm(2, skipproj, wt_np2, np_b2, h2, N, 128, 64, nullptr);    // h2
  gemm(0, h2, wt_np3, np_b3, npout, N, 64, 1, nullptr);
}